// Round 7
// baseline (468.420 us; speedup 1.0000x reference)
//
#include <hip/hip_runtime.h>
#include <hip/hip_bf16.h>

typedef unsigned short u16;
typedef unsigned int   u32;
typedef __attribute__((ext_vector_type(8))) short short8;
typedef __attribute__((ext_vector_type(4))) float f32x4;

#define NN 4096        // nodes
#define NE 262144      // edges
#define EMB 256
#define NH 4
#define HD 64

__device__ __forceinline__ float4 load4f(const float* p) { return *reinterpret_cast<const float4*>(p); }
__device__ __forceinline__ float sanitize_f(float v) {
  v = (v != v) ? 0.f : v;                 // nan -> 0
  return fminf(fmaxf(v, -1000.f), 1000.f); // +-inf and clip -> +-1000
}
__device__ __forceinline__ u16 f2b_rne(float x) {          // f32 -> bf16 bits, round-nearest-even
  u32 b = __float_as_uint(x);
  b += 0x7fff + ((b >> 16) & 1);
  return (u16)(b >> 16);
}
__device__ __forceinline__ u32 pack2(float a, float b) {
  return (u32)f2b_rne(a) | ((u32)f2b_rne(b) << 16);
}
__device__ __forceinline__ float b2f(u16 u) { return __uint_as_float((u32)u << 16); }

// ================= generic MFMA GEMM: out = act(A[M,K] @ W^T + bias) =================
struct GTile {
  const float* W;     // 64 weight rows for this tile: [64][K]
  const float* bias;  // 64 entries
  float*       out;   // f32 or bf16 (obf16)
  int          colOff;
  int          ldOut;
  int          obf16; // 1: write bf16 (u16*)
};
struct GArgs { GTile t[16]; };

// 256 threads = 4 waves; block tile 64x64; wave tile 32x32 (2x2 frags of 16x16x32).
template<int ACT>   // 0 none, 1 sanitize, 2 lrelu(0.2)
__global__ __launch_bounds__(256) void gemm_mfma(const float* __restrict__ A, const GArgs ga, int K) {
  __shared__ short As[64 * 40];
  __shared__ short Bs[64 * 40];
  const int t = threadIdx.x;
  const int bm = blockIdx.x * 64;
  const GTile tl = ga.t[blockIdx.y];
  const int w = t >> 6, l = t & 63, g = l >> 4, r16 = l & 15;
  const int wr = w >> 1, wc = w & 1;
  const int lrow = t >> 2, lseg = (t & 3) * 8;

  const float* Ap = A + (size_t)(bm + lrow) * K + lseg;
  const float* Wp = tl.W + (size_t)lrow * K + lseg;

  f32x4 acc[2][2] = {{{0.f,0.f,0.f,0.f},{0.f,0.f,0.f,0.f}},{{0.f,0.f,0.f,0.f},{0.f,0.f,0.f,0.f}}};
  for (int k0 = 0; k0 < K; k0 += 32) {
    float4 a0 = load4f(Ap + k0), a1 = load4f(Ap + k0 + 4);
    float4 b0 = load4f(Wp + k0), b1 = load4f(Wp + k0 + 4);
    __syncthreads();
    *(uint4*)&As[lrow * 40 + lseg] =
        make_uint4(pack2(a0.x,a0.y), pack2(a0.z,a0.w), pack2(a1.x,a1.y), pack2(a1.z,a1.w));
    *(uint4*)&Bs[lrow * 40 + lseg] =
        make_uint4(pack2(b0.x,b0.y), pack2(b0.z,b0.w), pack2(b1.x,b1.y), pack2(b1.z,b1.w));
    __syncthreads();
    short8 af0 = *(const short8*)&As[(wr*32 +      r16) * 40 + 8*g];
    short8 af1 = *(const short8*)&As[(wr*32 + 16 + r16) * 40 + 8*g];
    short8 bf0 = *(const short8*)&Bs[(wc*32 +      r16) * 40 + 8*g];
    short8 bf1 = *(const short8*)&Bs[(wc*32 + 16 + r16) * 40 + 8*g];
    acc[0][0] = __builtin_amdgcn_mfma_f32_16x16x32_bf16(af0, bf0, acc[0][0], 0, 0, 0);
    acc[0][1] = __builtin_amdgcn_mfma_f32_16x16x32_bf16(af0, bf1, acc[0][1], 0, 0, 0);
    acc[1][0] = __builtin_amdgcn_mfma_f32_16x16x32_bf16(af1, bf0, acc[1][0], 0, 0, 0);
    acc[1][1] = __builtin_amdgcn_mfma_f32_16x16x32_bf16(af1, bf1, acc[1][1], 0, 0, 0);
  }
  const float bj[2] = { tl.bias[wc*32 + r16], tl.bias[wc*32 + 16 + r16] };
#pragma unroll
  for (int i = 0; i < 2; i++) {
#pragma unroll
    for (int j = 0; j < 2; j++) {
      int col = tl.colOff + wc*32 + 16*j + r16;
#pragma unroll
      for (int r = 0; r < 4; r++) {
        int row = bm + wr*32 + 16*i + 4*g + r;
        float v = acc[i][j][r] + bj[j];
        if (ACT == 1) v = sanitize_f(v);
        if (ACT == 2) v = (v > 0.f) ? v : 0.2f * v;
        if (tl.obf16) ((u16*)tl.out)[(size_t)row * tl.ldOut + col] = f2b_rne(v);
        else          tl.out[(size_t)row * tl.ldOut + col] = v;
      }
    }
  }
}

// ---------------- qkv f32 -> bf16 converts ----------------
__global__ __launch_bounds__(256) void conv_qk(const float* __restrict__ qkv, u16* __restrict__ qkb) {
  int i = (blockIdx.x * 256 + threadIdx.x) * 8;
  int n = i >> 9, c = i & 511;
  const float* p = qkv + (size_t)n * 768 + c;
  float4 a = load4f(p), b = load4f(p + 4);
  uint4 r = make_uint4(pack2(a.x, a.y), pack2(a.z, a.w), pack2(b.x, b.y), pack2(b.z, b.w));
  *(uint4*)&qkb[(size_t)n * 512 + c] = r;
}
__global__ __launch_bounds__(256) void conv_vt(const float* __restrict__ qkv, u16* __restrict__ vtb) {
  __shared__ u16 T[64][72];
  int t = threadIdx.x;
  int n0 = (blockIdx.x >> 2) * 64, c0 = (blockIdx.x & 3) * 64;
#pragma unroll
  for (int it = 0; it < 4; it++) {
    int nl = it * 16 + (t >> 4), c4 = (t & 15) * 4;
    float4 v = load4f(qkv + (size_t)(n0 + nl) * 768 + 512 + c0 + c4);
    T[nl][c4] = f2b_rne(v.x); T[nl][c4+1] = f2b_rne(v.y);
    T[nl][c4+2] = f2b_rne(v.z); T[nl][c4+3] = f2b_rne(v.w);
  }
  __syncthreads();
  int cl = t >> 2, chunk = t & 3;
  u16 buf[16];
#pragma unroll
  for (int j = 0; j < 16; j++) buf[j] = T[chunk * 16 + j][cl];
  *(uint4*)&vtb[(size_t)(c0 + cl) * 4096 + n0 + chunk * 16]     = *(uint4*)&buf[0];
  *(uint4*)&vtb[(size_t)(c0 + cl) * 4096 + n0 + chunk * 16 + 8] = *(uint4*)&buf[8];
}

// ---------------- causal MHA: MFMA flash, split-K over 4 waves ----------------
__global__ __launch_bounds__(256, 4) void mha_mfma2(const u16* __restrict__ qkb, const u16* __restrict__ vtb,
                                                    float* __restrict__ out) {
  __shared__ float Obuf[4][16][68];
  __shared__ float msh[4][16];
  __shared__ float ssh[4][16];
  const int bid  = blockIdx.x;
  const int h    = bid & 3;
  const int tile = 255 - (bid >> 2);
  const int q0   = tile * 16;
  const int w    = threadIdx.x >> 6;
  const int l    = threadIdx.x & 63;
  const int g    = l >> 4, r16 = l & 15;
  const int hofs = h * 64;

  const u16* qrow = qkb + (size_t)(q0 + r16) * 512 + hofs;
  short8 Qf0 = *(const short8*)&qrow[8 * g];
  short8 Qf1 = *(const short8*)&qrow[32 + 8 * g];

  f32x4 O0 = {0.f,0.f,0.f,0.f}, O1 = O0, O2 = O0, O3 = O0;
  float m = -INFINITY, ssum = 0.f;
  const int nkt = (q0 + 16 + 63) >> 6;

  for (int kt = w; kt < nkt; kt += 4) {
    const int k0 = kt * 64;
    f32x4 S0 = {0.f,0.f,0.f,0.f}, S1 = S0, S2 = S0, S3 = S0;
    {
      const u16* kb0 = qkb + (size_t)(k0 + r16) * 512 + 256 + hofs + 8 * g;
      short8 a0 = *(const short8*)&kb0[0];
      short8 b0 = *(const short8*)&kb0[32];
      const u16* kb1 = kb0 + (size_t)16 * 512;
      short8 a1 = *(const short8*)&kb1[0];
      short8 b1 = *(const short8*)&kb1[32];
      const u16* kb2 = kb1 + (size_t)16 * 512;
      short8 a2 = *(const short8*)&kb2[0];
      short8 b2 = *(const short8*)&kb2[32];
      const u16* kb3 = kb2 + (size_t)16 * 512;
      short8 a3 = *(const short8*)&kb3[0];
      short8 b3 = *(const short8*)&kb3[32];
      S0 = __builtin_amdgcn_mfma_f32_16x16x32_bf16(a0, Qf0, S0, 0, 0, 0);
      S1 = __builtin_amdgcn_mfma_f32_16x16x32_bf16(a1, Qf0, S1, 0, 0, 0);
      S2 = __builtin_amdgcn_mfma_f32_16x16x32_bf16(a2, Qf0, S2, 0, 0, 0);
      S3 = __builtin_amdgcn_mfma_f32_16x16x32_bf16(a3, Qf0, S3, 0, 0, 0);
      S0 = __builtin_amdgcn_mfma_f32_16x16x32_bf16(b0, Qf1, S0, 0, 0, 0);
      S1 = __builtin_amdgcn_mfma_f32_16x16x32_bf16(b1, Qf1, S1, 0, 0, 0);
      S2 = __builtin_amdgcn_mfma_f32_16x16x32_bf16(b2, Qf1, S2, 0, 0, 0);
      S3 = __builtin_amdgcn_mfma_f32_16x16x32_bf16(b3, Qf1, S3, 0, 0, 0);
    }
    float sc[4][4];
#pragma unroll
    for (int r = 0; r < 4; r++) {
      sc[0][r] = S0[r] * 0.125f; sc[1][r] = S1[r] * 0.125f;
      sc[2][r] = S2[r] * 0.125f; sc[3][r] = S3[r] * 0.125f;
    }
    if (kt == nkt - 1) {
#pragma unroll
      for (int mb = 0; mb < 4; mb++)
#pragma unroll
        for (int r = 0; r < 4; r++)
          if (k0 + 16 * mb + 4 * g + r > q0 + r16) sc[mb][r] = -INFINITY;
    }
    float tm = sc[0][0];
#pragma unroll
    for (int mb = 0; mb < 4; mb++)
#pragma unroll
      for (int r = 0; r < 4; r++) tm = fmaxf(tm, sc[mb][r]);
    tm = fmaxf(tm, __shfl_xor(tm, 16));
    tm = fmaxf(tm, __shfl_xor(tm, 32));
    float mn = fmaxf(m, tm);
    float ef = __expf(m - mn);
    float pv[4][4];
    float ps = 0.f;
#pragma unroll
    for (int mb = 0; mb < 4; mb++)
#pragma unroll
      for (int r = 0; r < 4; r++) { pv[mb][r] = __expf(sc[mb][r] - mn); ps += pv[mb][r]; }
    ps += __shfl_xor(ps, 16);
    ps += __shfl_xor(ps, 32);
    ssum = ssum * ef + ps;
    m = mn;
#pragma unroll
    for (int r = 0; r < 4; r++) {
      float efr = __shfl(ef, 4 * g + r);
      O0[r] *= efr; O1[r] *= efr; O2[r] *= efr; O3[r] *= efr;
    }
    short8 ap[2];
#pragma unroll
    for (int c = 0; c < 2; c++) {
#pragma unroll
      for (int jb = 0; jb < 2; jb++) {
        int x = 2 * g + jb;
        int hi = x >> 2;
        int src = r16 + 16 * (x & 3);
#pragma unroll
        for (int rs = 0; rs < 4; rs++) {
          float tl_ = __shfl(pv[2 * c][rs],     src);
          float th_ = __shfl(pv[2 * c + 1][rs], src);
          ap[c][jb * 4 + rs] = (short)f2b_rne(hi ? th_ : tl_);
        }
      }
    }
    {
      const u16* vb0 = vtb + (size_t)(hofs + r16) * 4096 + k0 + 8 * g;
#pragma unroll
      for (int c = 0; c < 2; c++) {
        short8 v0 = *(const short8*)&vb0[32 * c];
        short8 v1 = *(const short8*)&vb0[16 * 4096 + 32 * c];
        short8 v2 = *(const short8*)&vb0[32 * 4096 + 32 * c];
        short8 v3 = *(const short8*)&vb0[48 * 4096 + 32 * c];
        O0 = __builtin_amdgcn_mfma_f32_16x16x32_bf16(ap[c], v0, O0, 0, 0, 0);
        O1 = __builtin_amdgcn_mfma_f32_16x16x32_bf16(ap[c], v1, O1, 0, 0, 0);
        O2 = __builtin_amdgcn_mfma_f32_16x16x32_bf16(ap[c], v2, O2, 0, 0, 0);
        O3 = __builtin_amdgcn_mfma_f32_16x16x32_bf16(ap[c], v3, O3, 0, 0, 0);
      }
    }
  }

#pragma unroll
  for (int r = 0; r < 4; r++) {
    int q = 4 * g + r;
    Obuf[w][q][r16 +  0] = O0[r];
    Obuf[w][q][r16 + 16] = O1[r];
    Obuf[w][q][r16 + 32] = O2[r];
    Obuf[w][q][r16 + 48] = O3[r];
  }
  if (l < 16) { msh[w][l] = m; ssh[w][l] = ssum; }
  __syncthreads();

  int t = threadIdx.x;
  int q = t >> 4, dc = (t & 15) * 4;
  float M = fmaxf(fmaxf(msh[0][q], msh[1][q]), fmaxf(msh[2][q], msh[3][q]));
  float e0 = __expf(msh[0][q] - M), e1 = __expf(msh[1][q] - M);
  float e2 = __expf(msh[2][q] - M), e3 = __expf(msh[3][q] - M);
  float Stot = e0 * ssh[0][q] + e1 * ssh[1][q] + e2 * ssh[2][q] + e3 * ssh[3][q];
  float inv = 1.f / Stot;
  float4 res;
#pragma unroll
  for (int dd = 0; dd < 4; dd++) {
    float o = e0 * Obuf[0][q][dc+dd] + e1 * Obuf[1][q][dc+dd]
            + e2 * Obuf[2][q][dc+dd] + e3 * Obuf[3][q][dc+dd];
    ((float*)&res)[dd] = o * inv;
  }
  *(float4*)&out[(size_t)(q0 + q) * EMB + hofs + dc] = res;
}

// ---------------- CSR build ----------------
__global__ void zero_i32(int* p, int n) {
  int i = blockIdx.x * 256 + threadIdx.x;
  if (i < n) p[i] = 0;
}
__global__ void hist_dst(const int* __restrict__ adj, int* __restrict__ cnt) {
  int e = blockIdx.x * 256 + threadIdx.x;
  if (e < NE) atomicAdd(&cnt[adj[NE + e]], 1);
}
__global__ __launch_bounds__(1024) void scan4096(const int* __restrict__ cnt, int* __restrict__ indptr,
                                                 int* __restrict__ cursor) {
  int t = threadIdx.x;
  int4 c = *reinterpret_cast<const int4*>(cnt + t * 4);
  int s0 = c.x, s1 = s0 + c.y, s2 = s1 + c.z, s3 = s2 + c.w;
  int lane = t & 63, w = t >> 6;
  int x = s3;
#pragma unroll
  for (int off = 1; off < 64; off <<= 1) {
    int y = __shfl_up(x, off);
    if (lane >= off) x += y;
  }
  __shared__ int wsum[16];
  if (lane == 63) wsum[w] = x;
  __syncthreads();
  if (t == 0) {
    int acc = 0;
    for (int i = 0; i < 16; i++) { int tv = wsum[i]; wsum[i] = acc; acc += tv; }
  }
  __syncthreads();
  int b = wsum[w] + x - s3;
  indptr[t*4+0] = b;      indptr[t*4+1] = b + s0;
  indptr[t*4+2] = b + s1; indptr[t*4+3] = b + s2;
  cursor[t*4+0] = b;      cursor[t*4+1] = b + s0;
  cursor[t*4+2] = b + s1; cursor[t*4+3] = b + s2;
  if (t == 1023) indptr[4096] = b + s3;
}
__global__ void scatter_edges(const int* __restrict__ adj, int* __restrict__ cursor, int* __restrict__ esrc) {
  int e = blockIdx.x * 256 + threadIdx.x;
  if (e < NE) {
    int dst = adj[NE + e];
    int pos = atomicAdd(&cursor[dst], 1);
    esrc[pos] = adj[e];
  }
}

// ---------------- TransformerConv aggregation (bf16 K/V) ----------------
__global__ __launch_bounds__(256) void conv_agg(const float* __restrict__ qb, const u16* __restrict__ kb,
                                                const u16* __restrict__ vb, const int* __restrict__ indptr,
                                                const int* __restrict__ esrc, float* __restrict__ y) {
  __shared__ float q_s[EMB];
  int n = blockIdx.x;
  int tid = threadIdx.x;
  int h = tid >> 6, lane = tid & 63;
  q_s[tid] = qb[(size_t)n * EMB + tid];
  __syncthreads();
  int start = indptr[n], end = indptr[n + 1];
  float m = -INFINITY, s = 0.f, o = 0.f;
  for (int p0 = start; p0 < end; p0 += 64) {
    int nk = end - p0; if (nk > 64) nk = 64;
    int src = 0;
    float sc = -INFINITY;
    if (lane < nk) {
      src = esrc[p0 + lane];
      const u16* kr = kb + (size_t)src * EMB + h * HD;
      const float* qh = &q_s[h * HD];
      float acc = 0.f;
#pragma unroll
      for (int d = 0; d < HD; d += 8) {
        short8 k8 = *(const short8*)&kr[d];
#pragma unroll
        for (int e = 0; e < 8; e++) acc = fmaf(b2f((u16)k8[e]), qh[d + e], acc);
      }
      sc = acc * 0.125f;
    }
    float bm = sc;
#pragma unroll
    for (int off = 32; off; off >>= 1) bm = fmaxf(bm, __shfl_xor(bm, off));
    float mn = fmaxf(m, bm);
    float scale = __expf(m - mn);
    float p = (lane < nk) ? __expf(sc - mn) : 0.f;
    float ps = p;
#pragma unroll
    for (int off = 32; off; off >>= 1) ps += __shfl_xor(ps, off);
    s = s * scale + ps;
    o = o * scale;
    const u16* vl = vb + h * HD + lane;
    for (int jj = 0; jj < nk; jj++) {
      int   sj = __shfl(src, jj);
      float pj = __shfl(p, jj);
      o = fmaf(pj, b2f(vl[(size_t)sj * EMB]), o);
    }
    m = mn;
  }
  float agg = o / (s + 1e-16f);
  y[(size_t)n * EMB + h * HD + lane] += agg;
}

// ---------------- instance norm + lrelu + sanitize ----------------
__global__ __launch_bounds__(256) void colstats_partial(const float* __restrict__ y, float* __restrict__ part) {
  int c = threadIdx.x;
  int r0 = blockIdx.x * 128;
  float s = 0.f, q = 0.f;
  for (int r = r0; r < r0 + 128; r++) {
    float v = y[(size_t)r * EMB + c];
    s += v; q = fmaf(v, v, q);
  }
  part[blockIdx.x * 512 + c] = s;
  part[blockIdx.x * 512 + 256 + c] = q;
}
__global__ __launch_bounds__(256) void colstats_final(const float* __restrict__ part, float* __restrict__ stats) {
  int c = threadIdx.x;
  float s = 0.f, q = 0.f;
  for (int b = 0; b < 32; b++) { s += part[b * 512 + c]; q += part[b * 512 + 256 + c]; }
  float mean = s * (1.f / 4096.f);
  float var  = q * (1.f / 4096.f) - mean * mean;
  stats[c] = mean;
  stats[256 + c] = rsqrtf(var + 1e-5f);
}
__global__ __launch_bounds__(256) void norm_apply(const float* __restrict__ y, const float* __restrict__ stats,
                                                  float* __restrict__ f, int colOff) {
  int c = threadIdx.x;
  float mean = stats[c], rstd = stats[256 + c];
  int r0 = blockIdx.x * 16;
  for (int r = r0; r < r0 + 16; r++) {
    float v = (y[(size_t)r * EMB + c] - mean) * rstd;
    v = (v > 0.f) ? v : 0.2f * v;
    v = sanitize_f(v);
    f[(size_t)r * 512 + colOff + c] = v;
  }
}

// ---------------- classifier tail ----------------
__global__ __launch_bounds__(256) void final_softmax(const float* __restrict__ f1, const float* __restrict__ W2,
                                                     const float* __restrict__ b2, float* __restrict__ out) {
  int w = threadIdx.x >> 6, lane = threadIdx.x & 63;
  int row = blockIdx.x * 4 + w;
  const float* fr = f1 + (size_t)row * 128;
  float x0 = fr[lane], x1 = fr[lane + 64];
  float p0 = x0 * W2[lane]       + x1 * W2[64 + lane];
  float p1 = x0 * W2[128 + lane] + x1 * W2[192 + lane];
#pragma unroll
  for (int off = 32; off; off >>= 1) { p0 += __shfl_xor(p0, off); p1 += __shfl_xor(p1, off); }
  if (lane == 0) {
    float l0 = p0 + b2[0], l1 = p1 + b2[1];
    float mx = fmaxf(l0, l1);
    float e0 = __expf(l0 - mx), e1 = __expf(l1 - mx);
    float inv = 1.f / (e0 + e1);
    out[(size_t)row * 2 + 0] = l0;
    out[(size_t)row * 2 + 1] = l1;
    out[8192 + (size_t)row * 2 + 0] = e0 * inv;
    out[8192 + (size_t)row * 2 + 1] = e1 * inv;
  }
}

extern "C" void kernel_launch(void* const* d_in, const int* in_sizes, int n_in,
                              void* d_out, int out_size, void* d_ws, size_t ws_size,
                              hipStream_t stream) {
  const float* img   = (const float*)d_in[2];
  const int*   adj   = (const int*)d_in[3];
  const float* W_img = (const float*)d_in[4];  const float* b_img = (const float*)d_in[5];
  const float* W_qkv = (const float*)d_in[6];  const float* b_qkv = (const float*)d_in[7];
  const float* W_o   = (const float*)d_in[8];  const float* b_o   = (const float*)d_in[9];
  const float* Wq_o  = (const float*)d_in[10]; const float* bq_o  = (const float*)d_in[11];
  const float* Wk_o  = (const float*)d_in[12]; const float* bk_o  = (const float*)d_in[13];
  const float* Wv_o  = (const float*)d_in[14]; const float* bv_o  = (const float*)d_in[15];
  const float* Ws_o  = (const float*)d_in[16]; const float* bs_o  = (const float*)d_in[17];
  const float* Wq_a  = (const float*)d_in[18]; const float* bq_a  = (const float*)d_in[19];
  const float* Wk_a  = (const float*)d_in[20]; const float* bk_a  = (const float*)d_in[21];
  const float* Wv_a  = (const float*)d_in[22]; const float* bv_a  = (const float*)d_in[23];
  const float* Ws_a  = (const float*)d_in[24]; const float* bs_a  = (const float*)d_in[25];
  const float* W_c1  = (const float*)d_in[26]; const float* b_c1  = (const float*)d_in[27];
  const float* W_c2  = (const float*)d_in[28]; const float* b_c2  = (const float*)d_in[29];

  char* ws = (char*)d_ws;
  float* h     = (float*)(ws + 0);                    // 4 MB
  float* hattn = (float*)(ws + (4ull << 20));         // 4 MB (aliased as qkb during mha)
  float* qkv   = (float*)(ws + (8ull << 20));         // 12 MB (later conv q f32 + k/v bf16)
  float* y     = (float*)(ws + (20ull << 20));        // 4 MB
  float* f     = (float*)(ws + (24ull << 20));        // 8 MB
  float* f1    = (float*)(ws + (32ull << 20));        // 2 MB (aliased as vtb during mha)
  int*   indptr= (int*)  (ws + (34ull << 20));
  int*   cursor= (int*)  (ws + (34ull << 20) + 20480);
  int*   esrc  = (int*)  (ws + (34ull << 20) + 40960);
  float* part  = (float*)(ws + (34ull << 20) + 40960 + (1ull << 20));
  float* stats = (float*)(ws + (34ull << 20) + 40960 + (1ull << 20) + 65536);

  u16* qkb = (u16*)hattn;   // dead after mha
  u16* vtb = (u16*)f1;      // dead after mha

  float* qb   = qkv;                         // 4 MB f32
  u16*   kb16 = (u16*)(ws + (12ull << 20));  // 2 MB bf16
  u16*   vb16 = (u16*)(ws + (14ull << 20));  // 2 MB bf16

  dim3 b256(256);

  // 1. h = img_feat @ W_img^T + b_img   (M=4096,N=256,K=2048)
  {
    GArgs ga;
    for (int i = 0; i < 4; i++)
      ga.t[i] = { W_img + (size_t)i * 64 * 2048, b_img + i * 64, h, i * 64, 256, 0 };
    gemm_mfma<0><<<dim3(64, 4), b256, 0, stream>>>(img, ga, 2048);
  }
  // 2. qkv = h @ W_qkv^T + b_qkv   (N=768,K=256)
  {
    GArgs ga;
    for (int i = 0; i < 12; i++)
      ga.t[i] = { W_qkv + (size_t)i * 64 * 256, b_qkv + i * 64, qkv, i * 64, 768, 0 };
    gemm_mfma<0><<<dim3(64, 12), b256, 0, stream>>>(h, ga, 256);
  }
  // 3. causal MHA (MFMA flash, split-K) -> y
  conv_qk<<<1024, b256, 0, stream>>>(qkv, qkb);
  conv_vt<<<256, b256, 0, stream>>>(qkv, vtb);
  mha_mfma2<<<1024, b256, 0, stream>>>(qkb, vtb, y);
  // 4. h_attn = sanitize(y @ W_o^T + b_o)
  {
    GArgs ga;
    for (int i = 0; i < 4; i++)
      ga.t[i] = { W_o + (size_t)i * 64 * 256, b_o + i * 64, hattn, i * 64, 256, 0 };
    gemm_mfma<1><<<dim3(64, 4), b256, 0, stream>>>(y, ga, 256);
  }
  // 5. CSR of video_adj_list grouped by dst
  zero_i32<<<16, b256, 0, stream>>>(cursor, NN);
  hist_dst<<<NE / 256, b256, 0, stream>>>(adj, cursor);
  scan4096<<<1, 1024, 0, stream>>>(cursor, indptr, cursor);
  scatter_edges<<<NE / 256, b256, 0, stream>>>(adj, cursor, esrc);

  // 6. conv path O: q/k/v/skip fused (N=1024,K=256), input h; k,v in bf16
  {
    const float* Wg[4] = { Wq_o, Wk_o, Wv_o, Ws_o };
    const float* bg[4] = { bq_o, bk_o, bv_o, bs_o };
    float*       og[4] = { qb, (float*)kb16, (float*)vb16, y };
    const int    bf[4] = { 0, 1, 1, 0 };
    GArgs ga;
    for (int i = 0; i < 16; i++) {
      int gdx = i >> 2, li = i & 3;
      ga.t[i] = { Wg[gdx] + (size_t)li * 64 * 256, bg[gdx] + li * 64, og[gdx], li * 64, 256, bf[gdx] };
    }
    gemm_mfma<0><<<dim3(64, 16), b256, 0, stream>>>(h, ga, 256);
  }
  conv_agg<<<NN, b256, 0, stream>>>(qb, kb16, vb16, indptr, esrc, y);
  colstats_partial<<<32, b256, 0, stream>>>(y, part);
  colstats_final<<<1, b256, 0, stream>>>(part, stats);
  norm_apply<<<256, b256, 0, stream>>>(y, stats, f, 0);

  // 7. conv path A: same, input hattn
  {
    const float* Wg[4] = { Wq_a, Wk_a, Wv_a, Ws_a };
    const float* bg[4] = { bq_a, bk_a, bv_a, bs_a };
    float*       og[4] = { qb, (float*)kb16, (float*)vb16, y };
    const int    bf[4] = { 0, 1, 1, 0 };
    GArgs ga;
    for (int i = 0; i < 16; i++) {
      int gdx = i >> 2, li = i & 3;
      ga.t[i] = { Wg[gdx] + (size_t)li * 64 * 256, bg[gdx] + li * 64, og[gdx], li * 64, 256, bf[gdx] };
    }
    gemm_mfma<0><<<dim3(64, 16), b256, 0, stream>>>(hattn, ga, 256);
  }
  conv_agg<<<NN, b256, 0, stream>>>(qb, kb16, vb16, indptr, esrc, y);
  colstats_partial<<<32, b256, 0, stream>>>(y, part);
  colstats_final<<<1, b256, 0, stream>>>(part, stats);
  norm_apply<<<256, b256, 0, stream>>>(y, stats, f, 256);

  // 8. f1 = lrelu(f @ W_c1^T + b_c1)   (N=128,K=512)
  {
    GArgs ga;
    for (int i = 0; i < 2; i++)
      ga.t[i] = { W_c1 + (size_t)i * 64 * 512, b_c1 + i * 64, f1, i * 64, 128, 0 };
    gemm_mfma<2><<<dim3(64, 2), b256, 0, stream>>>(f, ga, 512);
  }
  // 9. logits + softmax -> out (f32): [0:8192] logits, [8192:16384] probs
  final_softmax<<<NN / 4, b256, 0, stream>>>(f1, W_c2, b_c2, (float*)d_out);
}

// Round 8
// 468.129 us; speedup vs baseline: 1.0006x; 1.0006x over previous
//
#include <hip/hip_runtime.h>
#include <hip/hip_bf16.h>

typedef unsigned short u16;
typedef unsigned int   u32;
typedef __attribute__((ext_vector_type(8))) short short8;
typedef __attribute__((ext_vector_type(4))) float f32x4;

#define NN 4096        // nodes
#define NE 262144      // edges
#define EMB 256
#define NH 4
#define HD 64

__device__ __forceinline__ float4 load4f(const float* p) { return *reinterpret_cast<const float4*>(p); }
__device__ __forceinline__ float sanitize_f(float v) {
  v = (v != v) ? 0.f : v;                 // nan -> 0
  return fminf(fmaxf(v, -1000.f), 1000.f); // +-inf and clip -> +-1000
}
__device__ __forceinline__ u16 f2b_rne(float x) {          // f32 -> bf16 bits, round-nearest-even
  u32 b = __float_as_uint(x);
  b += 0x7fff + ((b >> 16) & 1);
  return (u16)(b >> 16);
}
__device__ __forceinline__ u32 pack2(float a, float b) {
  return (u32)f2b_rne(a) | ((u32)f2b_rne(b) << 16);
}
__device__ __forceinline__ float b2f(u16 u) { return __uint_as_float((u32)u << 16); }

// ================= generic MFMA GEMM: out = act(A[M,K] @ W^T + bias) =================
struct GTile {
  const float* W;     // 64 weight rows for this tile: [64][K]
  const float* bias;  // 64 entries
  float*       out;   // f32 or bf16 (obf16)
  int          colOff;
  int          ldOut;
  int          obf16; // 1: write bf16 (u16*)
};
struct GArgs { GTile t[16]; };

// 256 threads = 4 waves; block tile 64x64; wave tile 32x32 (2x2 frags of 16x16x32).
template<int ACT>   // 0 none, 1 sanitize, 2 lrelu(0.2)
__global__ __launch_bounds__(256) void gemm_mfma(const float* __restrict__ A, const GArgs ga, int K) {
  __shared__ short As[64 * 40];
  __shared__ short Bs[64 * 40];
  const int t = threadIdx.x;
  const int bm = blockIdx.x * 64;
  const GTile tl = ga.t[blockIdx.y];
  const int w = t >> 6, l = t & 63, g = l >> 4, r16 = l & 15;
  const int wr = w >> 1, wc = w & 1;
  const int lrow = t >> 2, lseg = (t & 3) * 8;

  const float* Ap = A + (size_t)(bm + lrow) * K + lseg;
  const float* Wp = tl.W + (size_t)lrow * K + lseg;

  f32x4 acc[2][2] = {{{0.f,0.f,0.f,0.f},{0.f,0.f,0.f,0.f}},{{0.f,0.f,0.f,0.f},{0.f,0.f,0.f,0.f}}};
  for (int k0 = 0; k0 < K; k0 += 32) {
    float4 a0 = load4f(Ap + k0), a1 = load4f(Ap + k0 + 4);
    float4 b0 = load4f(Wp + k0), b1 = load4f(Wp + k0 + 4);
    __syncthreads();
    *(uint4*)&As[lrow * 40 + lseg] =
        make_uint4(pack2(a0.x,a0.y), pack2(a0.z,a0.w), pack2(a1.x,a1.y), pack2(a1.z,a1.w));
    *(uint4*)&Bs[lrow * 40 + lseg] =
        make_uint4(pack2(b0.x,b0.y), pack2(b0.z,b0.w), pack2(b1.x,b1.y), pack2(b1.z,b1.w));
    __syncthreads();
    short8 af0 = *(const short8*)&As[(wr*32 +      r16) * 40 + 8*g];
    short8 af1 = *(const short8*)&As[(wr*32 + 16 + r16) * 40 + 8*g];
    short8 bf0 = *(const short8*)&Bs[(wc*32 +      r16) * 40 + 8*g];
    short8 bf1 = *(const short8*)&Bs[(wc*32 + 16 + r16) * 40 + 8*g];
    acc[0][0] = __builtin_amdgcn_mfma_f32_16x16x32_bf16(af0, bf0, acc[0][0], 0, 0, 0);
    acc[0][1] = __builtin_amdgcn_mfma_f32_16x16x32_bf16(af0, bf1, acc[0][1], 0, 0, 0);
    acc[1][0] = __builtin_amdgcn_mfma_f32_16x16x32_bf16(af1, bf0, acc[1][0], 0, 0, 0);
    acc[1][1] = __builtin_amdgcn_mfma_f32_16x16x32_bf16(af1, bf1, acc[1][1], 0, 0, 0);
  }
  const float bj[2] = { tl.bias[wc*32 + r16], tl.bias[wc*32 + 16 + r16] };
#pragma unroll
  for (int i = 0; i < 2; i++) {
#pragma unroll
    for (int j = 0; j < 2; j++) {
      int col = tl.colOff + wc*32 + 16*j + r16;
#pragma unroll
      for (int r = 0; r < 4; r++) {
        int row = bm + wr*32 + 16*i + 4*g + r;
        float v = acc[i][j][r] + bj[j];
        if (ACT == 1) v = sanitize_f(v);
        if (ACT == 2) v = (v > 0.f) ? v : 0.2f * v;
        if (tl.obf16) ((u16*)tl.out)[(size_t)row * tl.ldOut + col] = f2b_rne(v);
        else          tl.out[(size_t)row * tl.ldOut + col] = v;
      }
    }
  }
}

// ---------------- qkv f32 -> bf16 converts ----------------
__global__ __launch_bounds__(256) void conv_qk(const float* __restrict__ qkv, u16* __restrict__ qkb) {
  int i = (blockIdx.x * 256 + threadIdx.x) * 8;
  int n = i >> 9, c = i & 511;
  const float* p = qkv + (size_t)n * 768 + c;
  float4 a = load4f(p), b = load4f(p + 4);
  uint4 r = make_uint4(pack2(a.x, a.y), pack2(a.z, a.w), pack2(b.x, b.y), pack2(b.z, b.w));
  *(uint4*)&qkb[(size_t)n * 512 + c] = r;
}
__global__ __launch_bounds__(256) void conv_vt(const float* __restrict__ qkv, u16* __restrict__ vtb) {
  __shared__ u16 T[64][72];
  int t = threadIdx.x;
  int n0 = (blockIdx.x >> 2) * 64, c0 = (blockIdx.x & 3) * 64;
#pragma unroll
  for (int it = 0; it < 4; it++) {
    int nl = it * 16 + (t >> 4), c4 = (t & 15) * 4;
    float4 v = load4f(qkv + (size_t)(n0 + nl) * 768 + 512 + c0 + c4);
    T[nl][c4] = f2b_rne(v.x); T[nl][c4+1] = f2b_rne(v.y);
    T[nl][c4+2] = f2b_rne(v.z); T[nl][c4+3] = f2b_rne(v.w);
  }
  __syncthreads();
  int cl = t >> 2, chunk = t & 3;
  u16 buf[16];
#pragma unroll
  for (int j = 0; j < 16; j++) buf[j] = T[chunk * 16 + j][cl];
  *(uint4*)&vtb[(size_t)(c0 + cl) * 4096 + n0 + chunk * 16]     = *(uint4*)&buf[0];
  *(uint4*)&vtb[(size_t)(c0 + cl) * 4096 + n0 + chunk * 16 + 8] = *(uint4*)&buf[8];
}

// ---------------- causal MHA: MFMA flash, split-K over 4 waves ----------------
__global__ __launch_bounds__(256, 4) void mha_mfma2(const u16* __restrict__ qkb, const u16* __restrict__ vtb,
                                                    float* __restrict__ out) {
  __shared__ float Obuf[4][16][68];
  __shared__ float msh[4][16];
  __shared__ float ssh[4][16];
  const int bid  = blockIdx.x;
  const int h    = bid & 3;
  const int tile = 255 - (bid >> 2);
  const int q0   = tile * 16;
  const int w    = threadIdx.x >> 6;
  const int l    = threadIdx.x & 63;
  const int g    = l >> 4, r16 = l & 15;
  const int hofs = h * 64;

  const u16* qrow = qkb + (size_t)(q0 + r16) * 512 + hofs;
  short8 Qf0 = *(const short8*)&qrow[8 * g];
  short8 Qf1 = *(const short8*)&qrow[32 + 8 * g];

  f32x4 O0 = {0.f,0.f,0.f,0.f}, O1 = O0, O2 = O0, O3 = O0;
  float m = -INFINITY, ssum = 0.f;
  const int nkt = (q0 + 16 + 63) >> 6;

  for (int kt = w; kt < nkt; kt += 4) {
    const int k0 = kt * 64;
    f32x4 S0 = {0.f,0.f,0.f,0.f}, S1 = S0, S2 = S0, S3 = S0;
    {
      const u16* kb0 = qkb + (size_t)(k0 + r16) * 512 + 256 + hofs + 8 * g;
      short8 a0 = *(const short8*)&kb0[0];
      short8 b0 = *(const short8*)&kb0[32];
      const u16* kb1 = kb0 + (size_t)16 * 512;
      short8 a1 = *(const short8*)&kb1[0];
      short8 b1 = *(const short8*)&kb1[32];
      const u16* kb2 = kb1 + (size_t)16 * 512;
      short8 a2 = *(const short8*)&kb2[0];
      short8 b2 = *(const short8*)&kb2[32];
      const u16* kb3 = kb2 + (size_t)16 * 512;
      short8 a3 = *(const short8*)&kb3[0];
      short8 b3 = *(const short8*)&kb3[32];
      S0 = __builtin_amdgcn_mfma_f32_16x16x32_bf16(a0, Qf0, S0, 0, 0, 0);
      S1 = __builtin_amdgcn_mfma_f32_16x16x32_bf16(a1, Qf0, S1, 0, 0, 0);
      S2 = __builtin_amdgcn_mfma_f32_16x16x32_bf16(a2, Qf0, S2, 0, 0, 0);
      S3 = __builtin_amdgcn_mfma_f32_16x16x32_bf16(a3, Qf0, S3, 0, 0, 0);
      S0 = __builtin_amdgcn_mfma_f32_16x16x32_bf16(b0, Qf1, S0, 0, 0, 0);
      S1 = __builtin_amdgcn_mfma_f32_16x16x32_bf16(b1, Qf1, S1, 0, 0, 0);
      S2 = __builtin_amdgcn_mfma_f32_16x16x32_bf16(b2, Qf1, S2, 0, 0, 0);
      S3 = __builtin_amdgcn_mfma_f32_16x16x32_bf16(b3, Qf1, S3, 0, 0, 0);
    }
    float sc[4][4];
#pragma unroll
    for (int r = 0; r < 4; r++) {
      sc[0][r] = S0[r] * 0.125f; sc[1][r] = S1[r] * 0.125f;
      sc[2][r] = S2[r] * 0.125f; sc[3][r] = S3[r] * 0.125f;
    }
    if (kt == nkt - 1) {
#pragma unroll
      for (int mb = 0; mb < 4; mb++)
#pragma unroll
        for (int r = 0; r < 4; r++)
          if (k0 + 16 * mb + 4 * g + r > q0 + r16) sc[mb][r] = -INFINITY;
    }
    float tm = sc[0][0];
#pragma unroll
    for (int mb = 0; mb < 4; mb++)
#pragma unroll
      for (int r = 0; r < 4; r++) tm = fmaxf(tm, sc[mb][r]);
    tm = fmaxf(tm, __shfl_xor(tm, 16));
    tm = fmaxf(tm, __shfl_xor(tm, 32));
    float mn = fmaxf(m, tm);
    float ef = __expf(m - mn);
    float pv[4][4];
    float ps = 0.f;
#pragma unroll
    for (int mb = 0; mb < 4; mb++)
#pragma unroll
      for (int r = 0; r < 4; r++) { pv[mb][r] = __expf(sc[mb][r] - mn); ps += pv[mb][r]; }
    ps += __shfl_xor(ps, 16);
    ps += __shfl_xor(ps, 32);
    ssum = ssum * ef + ps;
    m = mn;
#pragma unroll
    for (int r = 0; r < 4; r++) {
      float efr = __shfl(ef, 4 * g + r);
      O0[r] *= efr; O1[r] *= efr; O2[r] *= efr; O3[r] *= efr;
    }
    short8 ap[2];
#pragma unroll
    for (int c = 0; c < 2; c++) {
#pragma unroll
      for (int jb = 0; jb < 2; jb++) {
        int x = 2 * g + jb;
        int hi = x >> 2;
        int src = r16 + 16 * (x & 3);
#pragma unroll
        for (int rs = 0; rs < 4; rs++) {
          float tl_ = __shfl(pv[2 * c][rs],     src);
          float th_ = __shfl(pv[2 * c + 1][rs], src);
          ap[c][jb * 4 + rs] = (short)f2b_rne(hi ? th_ : tl_);
        }
      }
    }
    {
      const u16* vb0 = vtb + (size_t)(hofs + r16) * 4096 + k0 + 8 * g;
#pragma unroll
      for (int c = 0; c < 2; c++) {
        short8 v0 = *(const short8*)&vb0[32 * c];
        short8 v1 = *(const short8*)&vb0[16 * 4096 + 32 * c];
        short8 v2 = *(const short8*)&vb0[32 * 4096 + 32 * c];
        short8 v3 = *(const short8*)&vb0[48 * 4096 + 32 * c];
        O0 = __builtin_amdgcn_mfma_f32_16x16x32_bf16(ap[c], v0, O0, 0, 0, 0);
        O1 = __builtin_amdgcn_mfma_f32_16x16x32_bf16(ap[c], v1, O1, 0, 0, 0);
        O2 = __builtin_amdgcn_mfma_f32_16x16x32_bf16(ap[c], v2, O2, 0, 0, 0);
        O3 = __builtin_amdgcn_mfma_f32_16x16x32_bf16(ap[c], v3, O3, 0, 0, 0);
      }
    }
  }

#pragma unroll
  for (int r = 0; r < 4; r++) {
    int q = 4 * g + r;
    Obuf[w][q][r16 +  0] = O0[r];
    Obuf[w][q][r16 + 16] = O1[r];
    Obuf[w][q][r16 + 32] = O2[r];
    Obuf[w][q][r16 + 48] = O3[r];
  }
  if (l < 16) { msh[w][l] = m; ssh[w][l] = ssum; }
  __syncthreads();

  int t = threadIdx.x;
  int q = t >> 4, dc = (t & 15) * 4;
  float M = fmaxf(fmaxf(msh[0][q], msh[1][q]), fmaxf(msh[2][q], msh[3][q]));
  float e0 = __expf(msh[0][q] - M), e1 = __expf(msh[1][q] - M);
  float e2 = __expf(msh[2][q] - M), e3 = __expf(msh[3][q] - M);
  float Stot = e0 * ssh[0][q] + e1 * ssh[1][q] + e2 * ssh[2][q] + e3 * ssh[3][q];
  float inv = 1.f / Stot;
  float4 res;
#pragma unroll
  for (int dd = 0; dd < 4; dd++) {
    float o = e0 * Obuf[0][q][dc+dd] + e1 * Obuf[1][q][dc+dd]
            + e2 * Obuf[2][q][dc+dd] + e3 * Obuf[3][q][dc+dd];
    ((float*)&res)[dd] = o * inv;
  }
  *(float4*)&out[(size_t)(q0 + q) * EMB + hofs + dc] = res;
}

// ---------------- CSR build ----------------
__global__ void zero_i32(int* p, int n) {
  int i = blockIdx.x * 256 + threadIdx.x;
  if (i < n) p[i] = 0;
}
__global__ void hist_dst(const int* __restrict__ adj, int* __restrict__ cnt) {
  int e = blockIdx.x * 256 + threadIdx.x;
  if (e < NE) atomicAdd(&cnt[adj[NE + e]], 1);
}
__global__ __launch_bounds__(1024) void scan4096(const int* __restrict__ cnt, int* __restrict__ indptr,
                                                 int* __restrict__ cursor) {
  int t = threadIdx.x;
  int4 c = *reinterpret_cast<const int4*>(cnt + t * 4);
  int s0 = c.x, s1 = s0 + c.y, s2 = s1 + c.z, s3 = s2 + c.w;
  int lane = t & 63, w = t >> 6;
  int x = s3;
#pragma unroll
  for (int off = 1; off < 64; off <<= 1) {
    int y = __shfl_up(x, off);
    if (lane >= off) x += y;
  }
  __shared__ int wsum[16];
  if (lane == 63) wsum[w] = x;
  __syncthreads();
  if (t == 0) {
    int acc = 0;
    for (int i = 0; i < 16; i++) { int tv = wsum[i]; wsum[i] = acc; acc += tv; }
  }
  __syncthreads();
  int b = wsum[w] + x - s3;
  indptr[t*4+0] = b;      indptr[t*4+1] = b + s0;
  indptr[t*4+2] = b + s1; indptr[t*4+3] = b + s2;
  cursor[t*4+0] = b;      cursor[t*4+1] = b + s0;
  cursor[t*4+2] = b + s1; cursor[t*4+3] = b + s2;
  if (t == 1023) indptr[4096] = b + s3;
}
__global__ void scatter_edges(const int* __restrict__ adj, int* __restrict__ cursor, int* __restrict__ esrc) {
  int e = blockIdx.x * 256 + threadIdx.x;
  if (e < NE) {
    int dst = adj[NE + e];
    int pos = atomicAdd(&cursor[dst], 1);
    esrc[pos] = adj[e];
  }
}

// ---------------- TransformerConv aggregation (bf16 K/V, LDS-staged P, 4-way ILP) ----------------
__global__ __launch_bounds__(256, 8) void conv_agg(const float* __restrict__ qb, const u16* __restrict__ kb,
                                                   const u16* __restrict__ vb, const int* __restrict__ indptr,
                                                   const int* __restrict__ esrc, float* __restrict__ y) {
  __shared__ float q_s[EMB];
  __shared__ float p_s[NH][64];
  __shared__ int   s_s[64];
  int n = blockIdx.x;
  int tid = threadIdx.x;
  int h = tid >> 6, lane = tid & 63;
  q_s[tid] = qb[(size_t)n * EMB + tid] * 0.125f;   // fold 1/sqrt(D) into q
  int start = indptr[n], end = indptr[n + 1];
  __syncthreads();
  const float* qh = &q_s[h * HD];
  float m = -INFINITY, s = 0.f;
  float o0 = 0.f, o1 = 0.f, o2 = 0.f, o3 = 0.f;
  for (int p0 = start; p0 < end; p0 += 64) {
    int nk = end - p0; if (nk > 64) nk = 64;
    float sc = -INFINITY;
    int src = 0;
    if (lane < nk) {
      src = esrc[p0 + lane];
      const u16* kr = kb + (size_t)src * EMB + h * HD;
      float a0 = 0.f, a1 = 0.f, a2 = 0.f, a3 = 0.f;
#pragma unroll
      for (int d = 0; d < HD; d += 8) {
        short8 k8 = *(const short8*)&kr[d];
        a0 = fmaf(b2f((u16)k8[0]), qh[d+0], a0);
        a1 = fmaf(b2f((u16)k8[1]), qh[d+1], a1);
        a2 = fmaf(b2f((u16)k8[2]), qh[d+2], a2);
        a3 = fmaf(b2f((u16)k8[3]), qh[d+3], a3);
        a0 = fmaf(b2f((u16)k8[4]), qh[d+4], a0);
        a1 = fmaf(b2f((u16)k8[5]), qh[d+5], a1);
        a2 = fmaf(b2f((u16)k8[6]), qh[d+6], a2);
        a3 = fmaf(b2f((u16)k8[7]), qh[d+7], a3);
      }
      sc = (a0 + a1) + (a2 + a3);
    }
    float bm = sc;
#pragma unroll
    for (int off = 32; off; off >>= 1) bm = fmaxf(bm, __shfl_xor(bm, off));
    float mn = fmaxf(m, bm);
    float ef = __expf(m - mn);              // 0 on first chunk
    float p = (lane < nk) ? __expf(sc - mn) : 0.f;
    float ps = p;
#pragma unroll
    for (int off = 32; off; off >>= 1) ps += __shfl_xor(ps, off);
    s = s * ef + ps;
    m = mn;
    o0 *= ef; o1 *= ef; o2 *= ef; o3 *= ef;
    p_s[h][lane] = p;
    if (h == 0) s_s[lane] = (lane < nk) ? src : 0;  // src identical across heads
    __syncthreads();
    const u16* vcol = vb + h * HD + lane;
#pragma unroll
    for (int jj = 0; jj < 64; jj += 4) {
      float pa = p_s[h][jj],   pb = p_s[h][jj+1];
      float pc = p_s[h][jj+2], pd = p_s[h][jj+3];
      int sa = s_s[jj], sb = s_s[jj+1], scx = s_s[jj+2], sd = s_s[jj+3];
      o0 = fmaf(pa, b2f(vcol[(size_t)sa  * EMB]), o0);
      o1 = fmaf(pb, b2f(vcol[(size_t)sb  * EMB]), o1);
      o2 = fmaf(pc, b2f(vcol[(size_t)scx * EMB]), o2);
      o3 = fmaf(pd, b2f(vcol[(size_t)sd  * EMB]), o3);
    }
    __syncthreads();
  }
  float o = (o0 + o1) + (o2 + o3);
  float agg = o / (s + 1e-16f);
  y[(size_t)n * EMB + h * HD + lane] += agg;
}

// ---------------- instance norm + lrelu + sanitize ----------------
__global__ __launch_bounds__(256) void colstats_partial(const float* __restrict__ y, float* __restrict__ part) {
  int c = threadIdx.x;
  int r0 = blockIdx.x * 128;
  float s = 0.f, q = 0.f;
  for (int r = r0; r < r0 + 128; r++) {
    float v = y[(size_t)r * EMB + c];
    s += v; q = fmaf(v, v, q);
  }
  part[blockIdx.x * 512 + c] = s;
  part[blockIdx.x * 512 + 256 + c] = q;
}
__global__ __launch_bounds__(256) void colstats_final(const float* __restrict__ part, float* __restrict__ stats) {
  int c = threadIdx.x;
  float s = 0.f, q = 0.f;
  for (int b = 0; b < 32; b++) { s += part[b * 512 + c]; q += part[b * 512 + 256 + c]; }
  float mean = s * (1.f / 4096.f);
  float var  = q * (1.f / 4096.f) - mean * mean;
  stats[c] = mean;
  stats[256 + c] = rsqrtf(var + 1e-5f);
}
__global__ __launch_bounds__(256) void norm_apply(const float* __restrict__ y, const float* __restrict__ stats,
                                                  float* __restrict__ f, int colOff) {
  int c = threadIdx.x;
  float mean = stats[c], rstd = stats[256 + c];
  int r0 = blockIdx.x * 16;
  for (int r = r0; r < r0 + 16; r++) {
    float v = (y[(size_t)r * EMB + c] - mean) * rstd;
    v = (v > 0.f) ? v : 0.2f * v;
    v = sanitize_f(v);
    f[(size_t)r * 512 + colOff + c] = v;
  }
}

// ---------------- classifier tail ----------------
__global__ __launch_bounds__(256) void final_softmax(const float* __restrict__ f1, const float* __restrict__ W2,
                                                     const float* __restrict__ b2, float* __restrict__ out) {
  int w = threadIdx.x >> 6, lane = threadIdx.x & 63;
  int row = blockIdx.x * 4 + w;
  const float* fr = f1 + (size_t)row * 128;
  float x0 = fr[lane], x1 = fr[lane + 64];
  float p0 = x0 * W2[lane]       + x1 * W2[64 + lane];
  float p1 = x0 * W2[128 + lane] + x1 * W2[192 + lane];
#pragma unroll
  for (int off = 32; off; off >>= 1) { p0 += __shfl_xor(p0, off); p1 += __shfl_xor(p1, off); }
  if (lane == 0) {
    float l0 = p0 + b2[0], l1 = p1 + b2[1];
    float mx = fmaxf(l0, l1);
    float e0 = __expf(l0 - mx), e1 = __expf(l1 - mx);
    float inv = 1.f / (e0 + e1);
    out[(size_t)row * 2 + 0] = l0;
    out[(size_t)row * 2 + 1] = l1;
    out[8192 + (size_t)row * 2 + 0] = e0 * inv;
    out[8192 + (size_t)row * 2 + 1] = e1 * inv;
  }
}

extern "C" void kernel_launch(void* const* d_in, const int* in_sizes, int n_in,
                              void* d_out, int out_size, void* d_ws, size_t ws_size,
                              hipStream_t stream) {
  const float* img   = (const float*)d_in[2];
  const int*   adj   = (const int*)d_in[3];
  const float* W_img = (const float*)d_in[4];  const float* b_img = (const float*)d_in[5];
  const float* W_qkv = (const float*)d_in[6];  const float* b_qkv = (const float*)d_in[7];
  const float* W_o   = (const float*)d_in[8];  const float* b_o   = (const float*)d_in[9];
  const float* Wq_o  = (const float*)d_in[10]; const float* bq_o  = (const float*)d_in[11];
  const float* Wk_o  = (const float*)d_in[12]; const float* bk_o  = (const float*)d_in[13];
  const float* Wv_o  = (const float*)d_in[14]; const float* bv_o  = (const float*)d_in[15];
  const float* Ws_o  = (const float*)d_in[16]; const float* bs_o  = (const float*)d_in[17];
  const float* Wq_a  = (const float*)d_in[18]; const float* bq_a  = (const float*)d_in[19];
  const float* Wk_a  = (const float*)d_in[20]; const float* bk_a  = (const float*)d_in[21];
  const float* Wv_a  = (const float*)d_in[22]; const float* bv_a  = (const float*)d_in[23];
  const float* Ws_a  = (const float*)d_in[24]; const float* bs_a  = (const float*)d_in[25];
  const float* W_c1  = (const float*)d_in[26]; const float* b_c1  = (const float*)d_in[27];
  const float* W_c2  = (const float*)d_in[28]; const float* b_c2  = (const float*)d_in[29];

  char* ws = (char*)d_ws;
  float* h     = (float*)(ws + 0);                    // 4 MB
  float* hattn = (float*)(ws + (4ull << 20));         // 4 MB (aliased as qkb during mha)
  float* qkv   = (float*)(ws + (8ull << 20));         // 12 MB (later conv q f32 + k/v bf16)
  float* y     = (float*)(ws + (20ull << 20));        // 4 MB
  float* f     = (float*)(ws + (24ull << 20));        // 8 MB
  float* f1    = (float*)(ws + (32ull << 20));        // 2 MB (aliased as vtb during mha)
  int*   indptr= (int*)  (ws + (34ull << 20));
  int*   cursor= (int*)  (ws + (34ull << 20) + 20480);
  int*   esrc  = (int*)  (ws + (34ull << 20) + 40960);
  float* part  = (float*)(ws + (34ull << 20) + 40960 + (1ull << 20));
  float* stats = (float*)(ws + (34ull << 20) + 40960 + (1ull << 20) + 65536);

  u16* qkb = (u16*)hattn;   // dead after mha
  u16* vtb = (u16*)f1;      // dead after mha

  float* qb   = qkv;                         // 4 MB f32
  u16*   kb16 = (u16*)(ws + (12ull << 20));  // 2 MB bf16
  u16*   vb16 = (u16*)(ws + (14ull << 20));  // 2 MB bf16

  dim3 b256(256);

  // 1. h = img_feat @ W_img^T + b_img   (M=4096,N=256,K=2048)
  {
    GArgs ga;
    for (int i = 0; i < 4; i++)
      ga.t[i] = { W_img + (size_t)i * 64 * 2048, b_img + i * 64, h, i * 64, 256, 0 };
    gemm_mfma<0><<<dim3(64, 4), b256, 0, stream>>>(img, ga, 2048);
  }
  // 2. qkv = h @ W_qkv^T + b_qkv   (N=768,K=256)
  {
    GArgs ga;
    for (int i = 0; i < 12; i++)
      ga.t[i] = { W_qkv + (size_t)i * 64 * 256, b_qkv + i * 64, qkv, i * 64, 768, 0 };
    gemm_mfma<0><<<dim3(64, 12), b256, 0, stream>>>(h, ga, 256);
  }
  // 3. causal MHA (MFMA flash, split-K) -> y
  conv_qk<<<1024, b256, 0, stream>>>(qkv, qkb);
  conv_vt<<<256, b256, 0, stream>>>(qkv, vtb);
  mha_mfma2<<<1024, b256, 0, stream>>>(qkb, vtb, y);
  // 4. h_attn = sanitize(y @ W_o^T + b_o)
  {
    GArgs ga;
    for (int i = 0; i < 4; i++)
      ga.t[i] = { W_o + (size_t)i * 64 * 256, b_o + i * 64, hattn, i * 64, 256, 0 };
    gemm_mfma<1><<<dim3(64, 4), b256, 0, stream>>>(y, ga, 256);
  }
  // 5. CSR of video_adj_list grouped by dst
  zero_i32<<<16, b256, 0, stream>>>(cursor, NN);
  hist_dst<<<NE / 256, b256, 0, stream>>>(adj, cursor);
  scan4096<<<1, 1024, 0, stream>>>(cursor, indptr, cursor);
  scatter_edges<<<NE / 256, b256, 0, stream>>>(adj, cursor, esrc);

  // 6. conv path O: q/k/v/skip fused (N=1024,K=256), input h; k,v in bf16
  {
    const float* Wg[4] = { Wq_o, Wk_o, Wv_o, Ws_o };
    const float* bg[4] = { bq_o, bk_o, bv_o, bs_o };
    float*       og[4] = { qb, (float*)kb16, (float*)vb16, y };
    const int    bf[4] = { 0, 1, 1, 0 };
    GArgs ga;
    for (int i = 0; i < 16; i++) {
      int gdx = i >> 2, li = i & 3;
      ga.t[i] = { Wg[gdx] + (size_t)li * 64 * 256, bg[gdx] + li * 64, og[gdx], li * 64, 256, bf[gdx] };
    }
    gemm_mfma<0><<<dim3(64, 16), b256, 0, stream>>>(h, ga, 256);
  }
  conv_agg<<<NN, b256, 0, stream>>>(qb, kb16, vb16, indptr, esrc, y);
  colstats_partial<<<32, b256, 0, stream>>>(y, part);
  colstats_final<<<1, b256, 0, stream>>>(part, stats);
  norm_apply<<<256, b256, 0, stream>>>(y, stats, f, 0);

  // 7. conv path A: same, input hattn
  {
    const float* Wg[4] = { Wq_a, Wk_a, Wv_a, Ws_a };
    const float* bg[4] = { bq_a, bk_a, bv_a, bs_a };
    float*       og[4] = { qb, (float*)kb16, (float*)vb16, y };
    const int    bf[4] = { 0, 1, 1, 0 };
    GArgs ga;
    for (int i = 0; i < 16; i++) {
      int gdx = i >> 2, li = i & 3;
      ga.t[i] = { Wg[gdx] + (size_t)li * 64 * 256, bg[gdx] + li * 64, og[gdx], li * 64, 256, bf[gdx] };
    }
    gemm_mfma<0><<<dim3(64, 16), b256, 0, stream>>>(hattn, ga, 256);
  }
  conv_agg<<<NN, b256, 0, stream>>>(qb, kb16, vb16, indptr, esrc, y);
  colstats_partial<<<32, b256, 0, stream>>>(y, part);
  colstats_final<<<1, b256, 0, stream>>>(part, stats);
  norm_apply<<<256, b256, 0, stream>>>(y, stats, f, 256);

  // 8. f1 = lrelu(f @ W_c1^T + b_c1)   (N=128,K=512)
  {
    GArgs ga;
    for (int i = 0; i < 2; i++)
      ga.t[i] = { W_c1 + (size_t)i * 64 * 512, b_c1 + i * 64, f1, i * 64, 128, 0 };
    gemm_mfma<2><<<dim3(64, 2), b256, 0, stream>>>(f, ga, 512);
  }
  // 9. logits + softmax -> out (f32): [0:8192] logits, [8192:16384] probs
  final_softmax<<<NN / 4, b256, 0, stream>>>(f1, W_c2, b_c2, (float*)d_out);
}

// Round 9
// 381.775 us; speedup vs baseline: 1.2270x; 1.2262x over previous
//
#include <hip/hip_runtime.h>
#include <hip/hip_bf16.h>

typedef unsigned short u16;
typedef unsigned int   u32;
typedef __attribute__((ext_vector_type(8))) short short8;
typedef __attribute__((ext_vector_type(4))) float f32x4;

#define NN 4096        // nodes
#define NE 262144      // edges
#define EMB 256
#define NH 4
#define HD 64

__device__ __forceinline__ float4 load4f(const float* p) { return *reinterpret_cast<const float4*>(p); }
__device__ __forceinline__ float sanitize_f(float v) {
  v = (v != v) ? 0.f : v;                 // nan -> 0
  return fminf(fmaxf(v, -1000.f), 1000.f); // +-inf and clip -> +-1000
}
__device__ __forceinline__ u16 f2b_rne(float x) {          // f32 -> bf16 bits, round-nearest-even
  u32 b = __float_as_uint(x);
  b += 0x7fff + ((b >> 16) & 1);
  return (u16)(b >> 16);
}
__device__ __forceinline__ u32 pack2(float a, float b) {
  return (u32)f2b_rne(a) | ((u32)f2b_rne(b) << 16);
}
__device__ __forceinline__ float b2f(u16 u) { return __uint_as_float((u32)u << 16); }

// ================= generic MFMA GEMM: out = act(A[M,K] @ W^T + bias) =================
struct GTile {
  const float* W;     // 64 weight rows for this tile: [64][K]
  const float* bias;  // 64 entries
  float*       out;   // f32 or bf16 (obf16)
  int          colOff;
  int          ldOut;
  int          obf16; // 1: write bf16 (u16*)
};
struct GArgs { GTile t[16]; };

// 256 threads = 4 waves; block tile 64x64; wave tile 32x32 (2x2 frags of 16x16x32).
template<int ACT>   // 0 none, 1 sanitize, 2 lrelu(0.2)
__global__ __launch_bounds__(256) void gemm_mfma(const float* __restrict__ A, const GArgs ga, int K) {
  __shared__ short As[64 * 40];
  __shared__ short Bs[64 * 40];
  const int t = threadIdx.x;
  const int bm = blockIdx.x * 64;
  const GTile tl = ga.t[blockIdx.y];
  const int w = t >> 6, l = t & 63, g = l >> 4, r16 = l & 15;
  const int wr = w >> 1, wc = w & 1;
  const int lrow = t >> 2, lseg = (t & 3) * 8;

  const float* Ap = A + (size_t)(bm + lrow) * K + lseg;
  const float* Wp = tl.W + (size_t)lrow * K + lseg;

  f32x4 acc[2][2] = {{{0.f,0.f,0.f,0.f},{0.f,0.f,0.f,0.f}},{{0.f,0.f,0.f,0.f},{0.f,0.f,0.f,0.f}}};
  for (int k0 = 0; k0 < K; k0 += 32) {
    float4 a0 = load4f(Ap + k0), a1 = load4f(Ap + k0 + 4);
    float4 b0 = load4f(Wp + k0), b1 = load4f(Wp + k0 + 4);
    __syncthreads();
    *(uint4*)&As[lrow * 40 + lseg] =
        make_uint4(pack2(a0.x,a0.y), pack2(a0.z,a0.w), pack2(a1.x,a1.y), pack2(a1.z,a1.w));
    *(uint4*)&Bs[lrow * 40 + lseg] =
        make_uint4(pack2(b0.x,b0.y), pack2(b0.z,b0.w), pack2(b1.x,b1.y), pack2(b1.z,b1.w));
    __syncthreads();
    short8 af0 = *(const short8*)&As[(wr*32 +      r16) * 40 + 8*g];
    short8 af1 = *(const short8*)&As[(wr*32 + 16 + r16) * 40 + 8*g];
    short8 bf0 = *(const short8*)&Bs[(wc*32 +      r16) * 40 + 8*g];
    short8 bf1 = *(const short8*)&Bs[(wc*32 + 16 + r16) * 40 + 8*g];
    acc[0][0] = __builtin_amdgcn_mfma_f32_16x16x32_bf16(af0, bf0, acc[0][0], 0, 0, 0);
    acc[0][1] = __builtin_amdgcn_mfma_f32_16x16x32_bf16(af0, bf1, acc[0][1], 0, 0, 0);
    acc[1][0] = __builtin_amdgcn_mfma_f32_16x16x32_bf16(af1, bf0, acc[1][0], 0, 0, 0);
    acc[1][1] = __builtin_amdgcn_mfma_f32_16x16x32_bf16(af1, bf1, acc[1][1], 0, 0, 0);
  }
  const float bj[2] = { tl.bias[wc*32 + r16], tl.bias[wc*32 + 16 + r16] };
#pragma unroll
  for (int i = 0; i < 2; i++) {
#pragma unroll
    for (int j = 0; j < 2; j++) {
      int col = tl.colOff + wc*32 + 16*j + r16;
#pragma unroll
      for (int r = 0; r < 4; r++) {
        int row = bm + wr*32 + 16*i + 4*g + r;
        float v = acc[i][j][r] + bj[j];
        if (ACT == 1) v = sanitize_f(v);
        if (ACT == 2) v = (v > 0.f) ? v : 0.2f * v;
        if (tl.obf16) ((u16*)tl.out)[(size_t)row * tl.ldOut + col] = f2b_rne(v);
        else          tl.out[(size_t)row * tl.ldOut + col] = v;
      }
    }
  }
}

// ---------------- qkv f32 -> bf16 converts ----------------
__global__ __launch_bounds__(256) void conv_qk(const float* __restrict__ qkv, u16* __restrict__ qkb) {
  int i = (blockIdx.x * 256 + threadIdx.x) * 8;
  int n = i >> 9, c = i & 511;
  const float* p = qkv + (size_t)n * 768 + c;
  float4 a = load4f(p), b = load4f(p + 4);
  uint4 r = make_uint4(pack2(a.x, a.y), pack2(a.z, a.w), pack2(b.x, b.y), pack2(b.z, b.w));
  *(uint4*)&qkb[(size_t)n * 512 + c] = r;
}
__global__ __launch_bounds__(256) void conv_vt(const float* __restrict__ qkv, u16* __restrict__ vtb) {
  __shared__ u16 T[64][72];
  int t = threadIdx.x;
  int n0 = (blockIdx.x >> 2) * 64, c0 = (blockIdx.x & 3) * 64;
#pragma unroll
  for (int it = 0; it < 4; it++) {
    int nl = it * 16 + (t >> 4), c4 = (t & 15) * 4;
    float4 v = load4f(qkv + (size_t)(n0 + nl) * 768 + 512 + c0 + c4);
    T[nl][c4] = f2b_rne(v.x); T[nl][c4+1] = f2b_rne(v.y);
    T[nl][c4+2] = f2b_rne(v.z); T[nl][c4+3] = f2b_rne(v.w);
  }
  __syncthreads();
  int cl = t >> 2, chunk = t & 3;
  u16 buf[16];
#pragma unroll
  for (int j = 0; j < 16; j++) buf[j] = T[chunk * 16 + j][cl];
  *(uint4*)&vtb[(size_t)(c0 + cl) * 4096 + n0 + chunk * 16]     = *(uint4*)&buf[0];
  *(uint4*)&vtb[(size_t)(c0 + cl) * 4096 + n0 + chunk * 16 + 8] = *(uint4*)&buf[8];
}

// ---------------- causal MHA: MFMA flash, split-K over 4 waves ----------------
__global__ __launch_bounds__(256, 4) void mha_mfma2(const u16* __restrict__ qkb, const u16* __restrict__ vtb,
                                                    float* __restrict__ out) {
  __shared__ float Obuf[4][16][68];
  __shared__ float msh[4][16];
  __shared__ float ssh[4][16];
  const int bid  = blockIdx.x;
  const int h    = bid & 3;
  const int tile = 255 - (bid >> 2);
  const int q0   = tile * 16;
  const int w    = threadIdx.x >> 6;
  const int l    = threadIdx.x & 63;
  const int g    = l >> 4, r16 = l & 15;
  const int hofs = h * 64;

  const u16* qrow = qkb + (size_t)(q0 + r16) * 512 + hofs;
  short8 Qf0 = *(const short8*)&qrow[8 * g];
  short8 Qf1 = *(const short8*)&qrow[32 + 8 * g];

  f32x4 O0 = {0.f,0.f,0.f,0.f}, O1 = O0, O2 = O0, O3 = O0;
  float m = -INFINITY, ssum = 0.f;
  const int nkt = (q0 + 16 + 63) >> 6;

  for (int kt = w; kt < nkt; kt += 4) {
    const int k0 = kt * 64;
    f32x4 S0 = {0.f,0.f,0.f,0.f}, S1 = S0, S2 = S0, S3 = S0;
    {
      const u16* kb0 = qkb + (size_t)(k0 + r16) * 512 + 256 + hofs + 8 * g;
      short8 a0 = *(const short8*)&kb0[0];
      short8 b0 = *(const short8*)&kb0[32];
      const u16* kb1 = kb0 + (size_t)16 * 512;
      short8 a1 = *(const short8*)&kb1[0];
      short8 b1 = *(const short8*)&kb1[32];
      const u16* kb2 = kb1 + (size_t)16 * 512;
      short8 a2 = *(const short8*)&kb2[0];
      short8 b2 = *(const short8*)&kb2[32];
      const u16* kb3 = kb2 + (size_t)16 * 512;
      short8 a3 = *(const short8*)&kb3[0];
      short8 b3 = *(const short8*)&kb3[32];
      S0 = __builtin_amdgcn_mfma_f32_16x16x32_bf16(a0, Qf0, S0, 0, 0, 0);
      S1 = __builtin_amdgcn_mfma_f32_16x16x32_bf16(a1, Qf0, S1, 0, 0, 0);
      S2 = __builtin_amdgcn_mfma_f32_16x16x32_bf16(a2, Qf0, S2, 0, 0, 0);
      S3 = __builtin_amdgcn_mfma_f32_16x16x32_bf16(a3, Qf0, S3, 0, 0, 0);
      S0 = __builtin_amdgcn_mfma_f32_16x16x32_bf16(b0, Qf1, S0, 0, 0, 0);
      S1 = __builtin_amdgcn_mfma_f32_16x16x32_bf16(b1, Qf1, S1, 0, 0, 0);
      S2 = __builtin_amdgcn_mfma_f32_16x16x32_bf16(b2, Qf1, S2, 0, 0, 0);
      S3 = __builtin_amdgcn_mfma_f32_16x16x32_bf16(b3, Qf1, S3, 0, 0, 0);
    }
    float sc[4][4];
#pragma unroll
    for (int r = 0; r < 4; r++) {
      sc[0][r] = S0[r] * 0.125f; sc[1][r] = S1[r] * 0.125f;
      sc[2][r] = S2[r] * 0.125f; sc[3][r] = S3[r] * 0.125f;
    }
    if (kt == nkt - 1) {
#pragma unroll
      for (int mb = 0; mb < 4; mb++)
#pragma unroll
        for (int r = 0; r < 4; r++)
          if (k0 + 16 * mb + 4 * g + r > q0 + r16) sc[mb][r] = -INFINITY;
    }
    float tm = sc[0][0];
#pragma unroll
    for (int mb = 0; mb < 4; mb++)
#pragma unroll
      for (int r = 0; r < 4; r++) tm = fmaxf(tm, sc[mb][r]);
    tm = fmaxf(tm, __shfl_xor(tm, 16));
    tm = fmaxf(tm, __shfl_xor(tm, 32));
    float mn = fmaxf(m, tm);
    float ef = __expf(m - mn);
    float pv[4][4];
    float ps = 0.f;
#pragma unroll
    for (int mb = 0; mb < 4; mb++)
#pragma unroll
      for (int r = 0; r < 4; r++) { pv[mb][r] = __expf(sc[mb][r] - mn); ps += pv[mb][r]; }
    ps += __shfl_xor(ps, 16);
    ps += __shfl_xor(ps, 32);
    ssum = ssum * ef + ps;
    m = mn;
#pragma unroll
    for (int r = 0; r < 4; r++) {
      float efr = __shfl(ef, 4 * g + r);
      O0[r] *= efr; O1[r] *= efr; O2[r] *= efr; O3[r] *= efr;
    }
    short8 ap[2];
#pragma unroll
    for (int c = 0; c < 2; c++) {
#pragma unroll
      for (int jb = 0; jb < 2; jb++) {
        int x = 2 * g + jb;
        int hi = x >> 2;
        int src = r16 + 16 * (x & 3);
#pragma unroll
        for (int rs = 0; rs < 4; rs++) {
          float tl_ = __shfl(pv[2 * c][rs],     src);
          float th_ = __shfl(pv[2 * c + 1][rs], src);
          ap[c][jb * 4 + rs] = (short)f2b_rne(hi ? th_ : tl_);
        }
      }
    }
    {
      const u16* vb0 = vtb + (size_t)(hofs + r16) * 4096 + k0 + 8 * g;
#pragma unroll
      for (int c = 0; c < 2; c++) {
        short8 v0 = *(const short8*)&vb0[32 * c];
        short8 v1 = *(const short8*)&vb0[16 * 4096 + 32 * c];
        short8 v2 = *(const short8*)&vb0[32 * 4096 + 32 * c];
        short8 v3 = *(const short8*)&vb0[48 * 4096 + 32 * c];
        O0 = __builtin_amdgcn_mfma_f32_16x16x32_bf16(ap[c], v0, O0, 0, 0, 0);
        O1 = __builtin_amdgcn_mfma_f32_16x16x32_bf16(ap[c], v1, O1, 0, 0, 0);
        O2 = __builtin_amdgcn_mfma_f32_16x16x32_bf16(ap[c], v2, O2, 0, 0, 0);
        O3 = __builtin_amdgcn_mfma_f32_16x16x32_bf16(ap[c], v3, O3, 0, 0, 0);
      }
    }
  }

#pragma unroll
  for (int r = 0; r < 4; r++) {
    int q = 4 * g + r;
    Obuf[w][q][r16 +  0] = O0[r];
    Obuf[w][q][r16 + 16] = O1[r];
    Obuf[w][q][r16 + 32] = O2[r];
    Obuf[w][q][r16 + 48] = O3[r];
  }
  if (l < 16) { msh[w][l] = m; ssh[w][l] = ssum; }
  __syncthreads();

  int t = threadIdx.x;
  int q = t >> 4, dc = (t & 15) * 4;
  float M = fmaxf(fmaxf(msh[0][q], msh[1][q]), fmaxf(msh[2][q], msh[3][q]));
  float e0 = __expf(msh[0][q] - M), e1 = __expf(msh[1][q] - M);
  float e2 = __expf(msh[2][q] - M), e3 = __expf(msh[3][q] - M);
  float Stot = e0 * ssh[0][q] + e1 * ssh[1][q] + e2 * ssh[2][q] + e3 * ssh[3][q];
  float inv = 1.f / Stot;
  float4 res;
#pragma unroll
  for (int dd = 0; dd < 4; dd++) {
    float o = e0 * Obuf[0][q][dc+dd] + e1 * Obuf[1][q][dc+dd]
            + e2 * Obuf[2][q][dc+dd] + e3 * Obuf[3][q][dc+dd];
    ((float*)&res)[dd] = o * inv;
  }
  *(float4*)&out[(size_t)(q0 + q) * EMB + hofs + dc] = res;
}

// ---------------- CSR build ----------------
__global__ void zero_i32(int* p, int n) {
  int i = blockIdx.x * 256 + threadIdx.x;
  if (i < n) p[i] = 0;
}
__global__ void hist_dst(const int* __restrict__ adj, int* __restrict__ cnt) {
  int e = blockIdx.x * 256 + threadIdx.x;
  if (e < NE) atomicAdd(&cnt[adj[NE + e]], 1);
}
__global__ __launch_bounds__(1024) void scan4096(const int* __restrict__ cnt, int* __restrict__ indptr,
                                                 int* __restrict__ cursor) {
  int t = threadIdx.x;
  int4 c = *reinterpret_cast<const int4*>(cnt + t * 4);
  int s0 = c.x, s1 = s0 + c.y, s2 = s1 + c.z, s3 = s2 + c.w;
  int lane = t & 63, w = t >> 6;
  int x = s3;
#pragma unroll
  for (int off = 1; off < 64; off <<= 1) {
    int y = __shfl_up(x, off);
    if (lane >= off) x += y;
  }
  __shared__ int wsum[16];
  if (lane == 63) wsum[w] = x;
  __syncthreads();
  if (t == 0) {
    int acc = 0;
    for (int i = 0; i < 16; i++) { int tv = wsum[i]; wsum[i] = acc; acc += tv; }
  }
  __syncthreads();
  int b = wsum[w] + x - s3;
  indptr[t*4+0] = b;      indptr[t*4+1] = b + s0;
  indptr[t*4+2] = b + s1; indptr[t*4+3] = b + s2;
  cursor[t*4+0] = b;      cursor[t*4+1] = b + s0;
  cursor[t*4+2] = b + s1; cursor[t*4+3] = b + s2;
  if (t == 1023) indptr[4096] = b + s3;
}
__global__ void scatter_edges(const int* __restrict__ adj, int* __restrict__ cursor, int* __restrict__ esrc) {
  int e = blockIdx.x * 256 + threadIdx.x;
  if (e < NE) {
    int dst = adj[NE + e];
    int pos = atomicAdd(&cursor[dst], 1);
    esrc[pos] = adj[e];
  }
}

// ---------------- TransformerConv aggregation (bf16 K/V, LDS-staged P, 4-way ILP) ----------------
__global__ __launch_bounds__(256, 4) void conv_agg(const float* __restrict__ qb, const u16* __restrict__ kb,
                                                   const u16* __restrict__ vb, const int* __restrict__ indptr,
                                                   const int* __restrict__ esrc, float* __restrict__ y) {
  __shared__ float q_s[EMB];
  __shared__ float p_s[NH][64];
  __shared__ int   s_s[64];
  int n = blockIdx.x;
  int tid = threadIdx.x;
  int h = tid >> 6, lane = tid & 63;
  q_s[tid] = qb[(size_t)n * EMB + tid] * 0.125f;   // fold 1/sqrt(D) into q
  int start = indptr[n], end = indptr[n + 1];
  __syncthreads();
  const float* qh = &q_s[h * HD];
  float m = -INFINITY, s = 0.f;
  float o0 = 0.f, o1 = 0.f, o2 = 0.f, o3 = 0.f;
  for (int p0 = start; p0 < end; p0 += 64) {
    int nk = end - p0; if (nk > 64) nk = 64;
    float sc = -INFINITY;
    int src = 0;
    if (lane < nk) {
      src = esrc[p0 + lane];
      const u16* kr = kb + (size_t)src * EMB + h * HD;
      float a0 = 0.f, a1 = 0.f, a2 = 0.f, a3 = 0.f;
#pragma unroll
      for (int d = 0; d < HD; d += 8) {
        short8 k8 = *(const short8*)&kr[d];
        a0 = fmaf(b2f((u16)k8[0]), qh[d+0], a0);
        a1 = fmaf(b2f((u16)k8[1]), qh[d+1], a1);
        a2 = fmaf(b2f((u16)k8[2]), qh[d+2], a2);
        a3 = fmaf(b2f((u16)k8[3]), qh[d+3], a3);
        a0 = fmaf(b2f((u16)k8[4]), qh[d+4], a0);
        a1 = fmaf(b2f((u16)k8[5]), qh[d+5], a1);
        a2 = fmaf(b2f((u16)k8[6]), qh[d+6], a2);
        a3 = fmaf(b2f((u16)k8[7]), qh[d+7], a3);
      }
      sc = (a0 + a1) + (a2 + a3);
    }
    float bm = sc;
#pragma unroll
    for (int off = 32; off; off >>= 1) bm = fmaxf(bm, __shfl_xor(bm, off));
    float mn = fmaxf(m, bm);
    float ef = __expf(m - mn);              // 0 on first chunk
    float p = (lane < nk) ? __expf(sc - mn) : 0.f;
    float ps = p;
#pragma unroll
    for (int off = 32; off; off >>= 1) ps += __shfl_xor(ps, off);
    s = s * ef + ps;
    m = mn;
    o0 *= ef; o1 *= ef; o2 *= ef; o3 *= ef;
    p_s[h][lane] = p;
    if (h == 0) s_s[lane] = (lane < nk) ? src : 0;  // src identical across heads
    __syncthreads();
    const u16* vcol = vb + h * HD + lane;
    int nk4 = (nk + 3) & ~3;
    for (int jj = 0; jj < nk4; jj += 4) {
      float pa = p_s[h][jj],   pb = p_s[h][jj+1];
      float pc = p_s[h][jj+2], pd = p_s[h][jj+3];
      int sa = s_s[jj], sb = s_s[jj+1], scx = s_s[jj+2], sd = s_s[jj+3];
      o0 = fmaf(pa, b2f(vcol[(size_t)sa  * EMB]), o0);
      o1 = fmaf(pb, b2f(vcol[(size_t)sb  * EMB]), o1);
      o2 = fmaf(pc, b2f(vcol[(size_t)scx * EMB]), o2);
      o3 = fmaf(pd, b2f(vcol[(size_t)sd  * EMB]), o3);
    }
    __syncthreads();
  }
  float o = (o0 + o1) + (o2 + o3);
  float agg = o / (s + 1e-16f);
  y[(size_t)n * EMB + h * HD + lane] += agg;
}

// ---------------- instance norm + lrelu + sanitize ----------------
__global__ __launch_bounds__(256) void colstats_partial(const float* __restrict__ y, float* __restrict__ part) {
  int c = threadIdx.x;
  int r0 = blockIdx.x * 128;
  float s = 0.f, q = 0.f;
  for (int r = r0; r < r0 + 128; r++) {
    float v = y[(size_t)r * EMB + c];
    s += v; q = fmaf(v, v, q);
  }
  part[blockIdx.x * 512 + c] = s;
  part[blockIdx.x * 512 + 256 + c] = q;
}
__global__ __launch_bounds__(256) void colstats_final(const float* __restrict__ part, float* __restrict__ stats) {
  int c = threadIdx.x;
  float s = 0.f, q = 0.f;
  for (int b = 0; b < 32; b++) { s += part[b * 512 + c]; q += part[b * 512 + 256 + c]; }
  float mean = s * (1.f / 4096.f);
  float var  = q * (1.f / 4096.f) - mean * mean;
  stats[c] = mean;
  stats[256 + c] = rsqrtf(var + 1e-5f);
}
__global__ __launch_bounds__(256) void norm_apply(const float* __restrict__ y, const float* __restrict__ stats,
                                                  float* __restrict__ f, int colOff) {
  int c = threadIdx.x;
  float mean = stats[c], rstd = stats[256 + c];
  int r0 = blockIdx.x * 16;
  for (int r = r0; r < r0 + 16; r++) {
    float v = (y[(size_t)r * EMB + c] - mean) * rstd;
    v = (v > 0.f) ? v : 0.2f * v;
    v = sanitize_f(v);
    f[(size_t)r * 512 + colOff + c] = v;
  }
}

// ---------------- classifier tail ----------------
__global__ __launch_bounds__(256) void final_softmax(const float* __restrict__ f1, const float* __restrict__ W2,
                                                     const float* __restrict__ b2, float* __restrict__ out) {
  int w = threadIdx.x >> 6, lane = threadIdx.x & 63;
  int row = blockIdx.x * 4 + w;
  const float* fr = f1 + (size_t)row * 128;
  float x0 = fr[lane], x1 = fr[lane + 64];
  float p0 = x0 * W2[lane]       + x1 * W2[64 + lane];
  float p1 = x0 * W2[128 + lane] + x1 * W2[192 + lane];
#pragma unroll
  for (int off = 32; off; off >>= 1) { p0 += __shfl_xor(p0, off); p1 += __shfl_xor(p1, off); }
  if (lane == 0) {
    float l0 = p0 + b2[0], l1 = p1 + b2[1];
    float mx = fmaxf(l0, l1);
    float e0 = __expf(l0 - mx), e1 = __expf(l1 - mx);
    float inv = 1.f / (e0 + e1);
    out[(size_t)row * 2 + 0] = l0;
    out[(size_t)row * 2 + 1] = l1;
    out[8192 + (size_t)row * 2 + 0] = e0 * inv;
    out[8192 + (size_t)row * 2 + 1] = e1 * inv;
  }
}

extern "C" void kernel_launch(void* const* d_in, const int* in_sizes, int n_in,
                              void* d_out, int out_size, void* d_ws, size_t ws_size,
                              hipStream_t stream) {
  const float* img   = (const float*)d_in[2];
  const int*   adj   = (const int*)d_in[3];
  const float* W_img = (const float*)d_in[4];  const float* b_img = (const float*)d_in[5];
  const float* W_qkv = (const float*)d_in[6];  const float* b_qkv = (const float*)d_in[7];
  const float* W_o   = (const float*)d_in[8];  const float* b_o   = (const float*)d_in[9];
  const float* Wq_o  = (const float*)d_in[10]; const float* bq_o  = (const float*)d_in[11];
  const float* Wk_o  = (const float*)d_in[12]; const float* bk_o  = (const float*)d_in[13];
  const float* Wv_o  = (const float*)d_in[14]; const float* bv_o  = (const float*)d_in[15];
  const float* Ws_o  = (const float*)d_in[16]; const float* bs_o  = (const float*)d_in[17];
  const float* Wq_a  = (const float*)d_in[18]; const float* bq_a  = (const float*)d_in[19];
  const float* Wk_a  = (const float*)d_in[20]; const float* bk_a  = (const float*)d_in[21];
  const float* Wv_a  = (const float*)d_in[22]; const float* bv_a  = (const float*)d_in[23];
  const float* Ws_a  = (const float*)d_in[24]; const float* bs_a  = (const float*)d_in[25];
  const float* W_c1  = (const float*)d_in[26]; const float* b_c1  = (const float*)d_in[27];
  const float* W_c2  = (const float*)d_in[28]; const float* b_c2  = (const float*)d_in[29];

  char* ws = (char*)d_ws;
  float* h     = (float*)(ws + 0);                    // 4 MB
  float* hattn = (float*)(ws + (4ull << 20));         // 4 MB (aliased as qkb during mha)
  float* qkv   = (float*)(ws + (8ull << 20));         // 12 MB (later conv q f32 + k/v bf16)
  float* y     = (float*)(ws + (20ull << 20));        // 4 MB
  float* f     = (float*)(ws + (24ull << 20));        // 8 MB
  float* f1    = (float*)(ws + (32ull << 20));        // 2 MB (aliased as vtb during mha)
  int*   indptr= (int*)  (ws + (34ull << 20));
  int*   cursor= (int*)  (ws + (34ull << 20) + 20480);
  int*   esrc  = (int*)  (ws + (34ull << 20) + 40960);
  float* part  = (float*)(ws + (34ull << 20) + 40960 + (1ull << 20));
  float* stats = (float*)(ws + (34ull << 20) + 40960 + (1ull << 20) + 65536);

  u16* qkb = (u16*)hattn;   // dead after mha
  u16* vtb = (u16*)f1;      // dead after mha

  float* qb   = qkv;                         // 4 MB f32
  u16*   kb16 = (u16*)(ws + (12ull << 20));  // 2 MB bf16
  u16*   vb16 = (u16*)(ws + (14ull << 20));  // 2 MB bf16

  dim3 b256(256);

  // 1. h = img_feat @ W_img^T + b_img   (M=4096,N=256,K=2048)
  {
    GArgs ga;
    for (int i = 0; i < 4; i++)
      ga.t[i] = { W_img + (size_t)i * 64 * 2048, b_img + i * 64, h, i * 64, 256, 0 };
    gemm_mfma<0><<<dim3(64, 4), b256, 0, stream>>>(img, ga, 2048);
  }
  // 2. qkv = h @ W_qkv^T + b_qkv   (N=768,K=256)
  {
    GArgs ga;
    for (int i = 0; i < 12; i++)
      ga.t[i] = { W_qkv + (size_t)i * 64 * 256, b_qkv + i * 64, qkv, i * 64, 768, 0 };
    gemm_mfma<0><<<dim3(64, 12), b256, 0, stream>>>(h, ga, 256);
  }
  // 3. causal MHA (MFMA flash, split-K) -> y
  conv_qk<<<1024, b256, 0, stream>>>(qkv, qkb);
  conv_vt<<<256, b256, 0, stream>>>(qkv, vtb);
  mha_mfma2<<<1024, b256, 0, stream>>>(qkb, vtb, y);
  // 4. h_attn = sanitize(y @ W_o^T + b_o)
  {
    GArgs ga;
    for (int i = 0; i < 4; i++)
      ga.t[i] = { W_o + (size_t)i * 64 * 256, b_o + i * 64, hattn, i * 64, 256, 0 };
    gemm_mfma<1><<<dim3(64, 4), b256, 0, stream>>>(y, ga, 256);
  }
  // 5. CSR of video_adj_list grouped by dst
  zero_i32<<<16, b256, 0, stream>>>(cursor, NN);
  hist_dst<<<NE / 256, b256, 0, stream>>>(adj, cursor);
  scan4096<<<1, 1024, 0, stream>>>(cursor, indptr, cursor);
  scatter_edges<<<NE / 256, b256, 0, stream>>>(adj, cursor, esrc);

  // 6. conv path O: q/k/v/skip fused (N=1024,K=256), input h; k,v in bf16
  {
    const float* Wg[4] = { Wq_o, Wk_o, Wv_o, Ws_o };
    const float* bg[4] = { bq_o, bk_o, bv_o, bs_o };
    float*       og[4] = { qb, (float*)kb16, (float*)vb16, y };
    const int    bf[4] = { 0, 1, 1, 0 };
    GArgs ga;
    for (int i = 0; i < 16; i++) {
      int gdx = i >> 2, li = i & 3;
      ga.t[i] = { Wg[gdx] + (size_t)li * 64 * 256, bg[gdx] + li * 64, og[gdx], li * 64, 256, bf[gdx] };
    }
    gemm_mfma<0><<<dim3(64, 16), b256, 0, stream>>>(h, ga, 256);
  }
  conv_agg<<<NN, b256, 0, stream>>>(qb, kb16, vb16, indptr, esrc, y);
  colstats_partial<<<32, b256, 0, stream>>>(y, part);
  colstats_final<<<1, b256, 0, stream>>>(part, stats);
  norm_apply<<<256, b256, 0, stream>>>(y, stats, f, 0);

  // 7. conv path A: same, input hattn
  {
    const float* Wg[4] = { Wq_a, Wk_a, Wv_a, Ws_a };
    const float* bg[4] = { bq_a, bk_a, bv_a, bs_a };
    float*       og[4] = { qb, (float*)kb16, (float*)vb16, y };
    const int    bf[4] = { 0, 1, 1, 0 };
    GArgs ga;
    for (int i = 0; i < 16; i++) {
      int gdx = i >> 2, li = i & 3;
      ga.t[i] = { Wg[gdx] + (size_t)li * 64 * 256, bg[gdx] + li * 64, og[gdx], li * 64, 256, bf[gdx] };
    }
    gemm_mfma<0><<<dim3(64, 16), b256, 0, stream>>>(hattn, ga, 256);
  }
  conv_agg<<<NN, b256, 0, stream>>>(qb, kb16, vb16, indptr, esrc, y);
  colstats_partial<<<32, b256, 0, stream>>>(y, part);
  colstats_final<<<1, b256, 0, stream>>>(part, stats);
  norm_apply<<<256, b256, 0, stream>>>(y, stats, f, 256);

  // 8. f1 = lrelu(f @ W_c1^T + b_c1)   (N=128,K=512)
  {
    GArgs ga;
    for (int i = 0; i < 2; i++)
      ga.t[i] = { W_c1 + (size_t)i * 64 * 512, b_c1 + i * 64, f1, i * 64, 128, 0 };
    gemm_mfma<2><<<dim3(64, 2), b256, 0, stream>>>(f, ga, 512);
  }
  // 9. logits + softmax -> out (f32): [0:8192] logits, [8192:16384] probs
  final_softmax<<<NN / 4, b256, 0, stream>>>(f1, W_c2, b_c2, (float*)d_out);
}

// Round 10
// 342.278 us; speedup vs baseline: 1.3685x; 1.1154x over previous
//
#include <hip/hip_runtime.h>
#include <hip/hip_bf16.h>

typedef unsigned short u16;
typedef unsigned int   u32;
typedef __attribute__((ext_vector_type(8))) short short8;
typedef __attribute__((ext_vector_type(4))) float f32x4;

#define NN 4096        // nodes
#define NE 262144      // edges
#define EMB 256
#define NH 4
#define HD 64

__device__ __forceinline__ float4 load4f(const float* p) { return *reinterpret_cast<const float4*>(p); }
__device__ __forceinline__ float sanitize_f(float v) {
  v = (v != v) ? 0.f : v;                 // nan -> 0
  return fminf(fmaxf(v, -1000.f), 1000.f); // +-inf and clip -> +-1000
}
__device__ __forceinline__ u16 f2b_rne(float x) {          // f32 -> bf16 bits, round-nearest-even
  u32 b = __float_as_uint(x);
  b += 0x7fff + ((b >> 16) & 1);
  return (u16)(b >> 16);
}
__device__ __forceinline__ u32 pack2(float a, float b) {
  return (u32)f2b_rne(a) | ((u32)f2b_rne(b) << 16);
}
__device__ __forceinline__ float b2f(u16 u) { return __uint_as_float((u32)u << 16); }

// ================= generic MFMA GEMM: out = act(A[M,K] @ W^T + bias) =================
struct GTile {
  const float* W;     // 64 weight rows for this tile: [64][K]
  const float* bias;  // 64 entries
  float*       out;   // f32 or bf16 (obf16)
  int          colOff;
  int          ldOut;
  int          obf16; // 1: write bf16 (u16*)
};
struct GArgs { GTile t[16]; };

// 256 threads = 4 waves; block tile 64x64; wave tile 32x32 (2x2 frags of 16x16x32).
template<int ACT>   // 0 none, 1 sanitize, 2 lrelu(0.2)
__global__ __launch_bounds__(256) void gemm_mfma(const float* __restrict__ A, const GArgs ga, int K) {
  __shared__ short As[64 * 40];
  __shared__ short Bs[64 * 40];
  const int t = threadIdx.x;
  const int bm = blockIdx.x * 64;
  const GTile tl = ga.t[blockIdx.y];
  const int w = t >> 6, l = t & 63, g = l >> 4, r16 = l & 15;
  const int wr = w >> 1, wc = w & 1;
  const int lrow = t >> 2, lseg = (t & 3) * 8;

  const float* Ap = A + (size_t)(bm + lrow) * K + lseg;
  const float* Wp = tl.W + (size_t)lrow * K + lseg;

  f32x4 acc[2][2] = {{{0.f,0.f,0.f,0.f},{0.f,0.f,0.f,0.f}},{{0.f,0.f,0.f,0.f},{0.f,0.f,0.f,0.f}}};
  for (int k0 = 0; k0 < K; k0 += 32) {
    float4 a0 = load4f(Ap + k0), a1 = load4f(Ap + k0 + 4);
    float4 b0 = load4f(Wp + k0), b1 = load4f(Wp + k0 + 4);
    __syncthreads();
    *(uint4*)&As[lrow * 40 + lseg] =
        make_uint4(pack2(a0.x,a0.y), pack2(a0.z,a0.w), pack2(a1.x,a1.y), pack2(a1.z,a1.w));
    *(uint4*)&Bs[lrow * 40 + lseg] =
        make_uint4(pack2(b0.x,b0.y), pack2(b0.z,b0.w), pack2(b1.x,b1.y), pack2(b1.z,b1.w));
    __syncthreads();
    short8 af0 = *(const short8*)&As[(wr*32 +      r16) * 40 + 8*g];
    short8 af1 = *(const short8*)&As[(wr*32 + 16 + r16) * 40 + 8*g];
    short8 bf0 = *(const short8*)&Bs[(wc*32 +      r16) * 40 + 8*g];
    short8 bf1 = *(const short8*)&Bs[(wc*32 + 16 + r16) * 40 + 8*g];
    acc[0][0] = __builtin_amdgcn_mfma_f32_16x16x32_bf16(af0, bf0, acc[0][0], 0, 0, 0);
    acc[0][1] = __builtin_amdgcn_mfma_f32_16x16x32_bf16(af0, bf1, acc[0][1], 0, 0, 0);
    acc[1][0] = __builtin_amdgcn_mfma_f32_16x16x32_bf16(af1, bf0, acc[1][0], 0, 0, 0);
    acc[1][1] = __builtin_amdgcn_mfma_f32_16x16x32_bf16(af1, bf1, acc[1][1], 0, 0, 0);
  }
  const float bj[2] = { tl.bias[wc*32 + r16], tl.bias[wc*32 + 16 + r16] };
#pragma unroll
  for (int i = 0; i < 2; i++) {
#pragma unroll
    for (int j = 0; j < 2; j++) {
      int col = tl.colOff + wc*32 + 16*j + r16;
#pragma unroll
      for (int r = 0; r < 4; r++) {
        int row = bm + wr*32 + 16*i + 4*g + r;
        float v = acc[i][j][r] + bj[j];
        if (ACT == 1) v = sanitize_f(v);
        if (ACT == 2) v = (v > 0.f) ? v : 0.2f * v;
        if (tl.obf16) ((u16*)tl.out)[(size_t)row * tl.ldOut + col] = f2b_rne(v);
        else          tl.out[(size_t)row * tl.ldOut + col] = v;
      }
    }
  }
}

// ---------------- img GEMM split-K: K=2048 over 4 z-blocks of 512 ----------------
__global__ __launch_bounds__(256) void gemm_img_splitk(const float* __restrict__ A, const float* __restrict__ W,
                                                       float* __restrict__ part) {
  __shared__ short As[64 * 40];
  __shared__ short Bs[64 * 40];
  const int t = threadIdx.x;
  const int bm = blockIdx.x * 64, bn = blockIdx.y * 64, ks = blockIdx.z;
  const int w = t >> 6, l = t & 63, g = l >> 4, r16 = l & 15;
  const int wr = w >> 1, wc = w & 1;
  const int lrow = t >> 2, lseg = (t & 3) * 8;

  const float* Ap = A + (size_t)(bm + lrow) * 2048 + ks * 512 + lseg;
  const float* Wp = W + (size_t)(bn + lrow) * 2048 + ks * 512 + lseg;

  f32x4 acc[2][2] = {{{0.f,0.f,0.f,0.f},{0.f,0.f,0.f,0.f}},{{0.f,0.f,0.f,0.f},{0.f,0.f,0.f,0.f}}};
  for (int k0 = 0; k0 < 512; k0 += 32) {
    float4 a0 = load4f(Ap + k0), a1 = load4f(Ap + k0 + 4);
    float4 b0 = load4f(Wp + k0), b1 = load4f(Wp + k0 + 4);
    __syncthreads();
    *(uint4*)&As[lrow * 40 + lseg] =
        make_uint4(pack2(a0.x,a0.y), pack2(a0.z,a0.w), pack2(a1.x,a1.y), pack2(a1.z,a1.w));
    *(uint4*)&Bs[lrow * 40 + lseg] =
        make_uint4(pack2(b0.x,b0.y), pack2(b0.z,b0.w), pack2(b1.x,b1.y), pack2(b1.z,b1.w));
    __syncthreads();
    short8 af0 = *(const short8*)&As[(wr*32 +      r16) * 40 + 8*g];
    short8 af1 = *(const short8*)&As[(wr*32 + 16 + r16) * 40 + 8*g];
    short8 bf0 = *(const short8*)&Bs[(wc*32 +      r16) * 40 + 8*g];
    short8 bf1 = *(const short8*)&Bs[(wc*32 + 16 + r16) * 40 + 8*g];
    acc[0][0] = __builtin_amdgcn_mfma_f32_16x16x32_bf16(af0, bf0, acc[0][0], 0, 0, 0);
    acc[0][1] = __builtin_amdgcn_mfma_f32_16x16x32_bf16(af0, bf1, acc[0][1], 0, 0, 0);
    acc[1][0] = __builtin_amdgcn_mfma_f32_16x16x32_bf16(af1, bf0, acc[1][0], 0, 0, 0);
    acc[1][1] = __builtin_amdgcn_mfma_f32_16x16x32_bf16(af1, bf1, acc[1][1], 0, 0, 0);
  }
  float* op = part + (size_t)ks * (NN * 256);
#pragma unroll
  for (int i = 0; i < 2; i++) {
#pragma unroll
    for (int j = 0; j < 2; j++) {
      int col = bn + wc*32 + 16*j + r16;
#pragma unroll
      for (int r = 0; r < 4; r++) {
        int row = bm + wr*32 + 16*i + 4*g + r;
        op[(size_t)row * 256 + col] = acc[i][j][r];
      }
    }
  }
}
__global__ __launch_bounds__(256) void gemm_img_reduce(const float* __restrict__ part,
                                                       const float* __restrict__ bias,
                                                       float* __restrict__ h) {
  int idx = blockIdx.x * 256 + threadIdx.x;   // 262144 threads, 4 floats each
  int row = idx >> 6, c4 = (idx & 63) * 4;
  size_t o = (size_t)row * 256 + c4;
  float4 s = load4f(part + o);
  float4 p1 = load4f(part + 1048576 + o);
  float4 p2 = load4f(part + 2097152 + o);
  float4 p3 = load4f(part + 3145728 + o);
  float4 bb = load4f(bias + c4);
  s.x += p1.x + p2.x + p3.x + bb.x;
  s.y += p1.y + p2.y + p3.y + bb.y;
  s.z += p1.z + p2.z + p3.z + bb.z;
  s.w += p1.w + p2.w + p3.w + bb.w;
  *(float4*)&h[o] = s;
}

// ---------------- qkv f32 -> bf16 converts ----------------
__global__ __launch_bounds__(256) void conv_qk(const float* __restrict__ qkv, u16* __restrict__ qkb) {
  int i = (blockIdx.x * 256 + threadIdx.x) * 8;
  int n = i >> 9, c = i & 511;
  const float* p = qkv + (size_t)n * 768 + c;
  float4 a = load4f(p), b = load4f(p + 4);
  uint4 r = make_uint4(pack2(a.x, a.y), pack2(a.z, a.w), pack2(b.x, b.y), pack2(b.z, b.w));
  *(uint4*)&qkb[(size_t)n * 512 + c] = r;
}
__global__ __launch_bounds__(256) void conv_vt(const float* __restrict__ qkv, u16* __restrict__ vtb) {
  __shared__ u16 T[64][72];
  int t = threadIdx.x;
  int n0 = (blockIdx.x >> 2) * 64, c0 = (blockIdx.x & 3) * 64;
#pragma unroll
  for (int it = 0; it < 4; it++) {
    int nl = it * 16 + (t >> 4), c4 = (t & 15) * 4;
    float4 v = load4f(qkv + (size_t)(n0 + nl) * 768 + 512 + c0 + c4);
    T[nl][c4] = f2b_rne(v.x); T[nl][c4+1] = f2b_rne(v.y);
    T[nl][c4+2] = f2b_rne(v.z); T[nl][c4+3] = f2b_rne(v.w);
  }
  __syncthreads();
  int cl = t >> 2, chunk = t & 3;
  u16 buf[16];
#pragma unroll
  for (int j = 0; j < 16; j++) buf[j] = T[chunk * 16 + j][cl];
  *(uint4*)&vtb[(size_t)(c0 + cl) * 4096 + n0 + chunk * 16]     = *(uint4*)&buf[0];
  *(uint4*)&vtb[(size_t)(c0 + cl) * 4096 + n0 + chunk * 16 + 8] = *(uint4*)&buf[8];
}

// ---------------- causal MHA: MFMA flash, split-K over 4 waves x 2 blocks ----------------
// grid 2048: ks = bid&1, h = (bid>>1)&3, tile = 255-(bid>>3).
// Block covers k-tiles kt with kt%2==ks; writes unnormalized partial (O, m, s).
__global__ __launch_bounds__(256, 4) void mha_mfma2(const u16* __restrict__ qkb, const u16* __restrict__ vtb,
                                                    float* __restrict__ Opart, float* __restrict__ mspart) {
  __shared__ float Obuf[4][16][68];
  __shared__ float msh[4][16];
  __shared__ float ssh[4][16];
  const int bid  = blockIdx.x;
  const int ks   = bid & 1;
  const int h    = (bid >> 1) & 3;
  const int tile = 255 - (bid >> 3);
  const int q0   = tile * 16;
  const int w    = threadIdx.x >> 6;
  const int l    = threadIdx.x & 63;
  const int g    = l >> 4, r16 = l & 15;
  const int hofs = h * 64;

  const u16* qrow = qkb + (size_t)(q0 + r16) * 512 + hofs;
  short8 Qf0 = *(const short8*)&qrow[8 * g];
  short8 Qf1 = *(const short8*)&qrow[32 + 8 * g];

  f32x4 O0 = {0.f,0.f,0.f,0.f}, O1 = O0, O2 = O0, O3 = O0;
  float m = -INFINITY, ssum = 0.f;
  const int nkt = (q0 + 16 + 63) >> 6;

  for (int kt = ks + 2 * w; kt < nkt; kt += 8) {
    const int k0 = kt * 64;
    f32x4 S0 = {0.f,0.f,0.f,0.f}, S1 = S0, S2 = S0, S3 = S0;
    {
      const u16* kb0 = qkb + (size_t)(k0 + r16) * 512 + 256 + hofs + 8 * g;
      short8 a0 = *(const short8*)&kb0[0];
      short8 b0 = *(const short8*)&kb0[32];
      const u16* kb1 = kb0 + (size_t)16 * 512;
      short8 a1 = *(const short8*)&kb1[0];
      short8 b1 = *(const short8*)&kb1[32];
      const u16* kb2 = kb1 + (size_t)16 * 512;
      short8 a2 = *(const short8*)&kb2[0];
      short8 b2 = *(const short8*)&kb2[32];
      const u16* kb3 = kb2 + (size_t)16 * 512;
      short8 a3 = *(const short8*)&kb3[0];
      short8 b3 = *(const short8*)&kb3[32];
      S0 = __builtin_amdgcn_mfma_f32_16x16x32_bf16(a0, Qf0, S0, 0, 0, 0);
      S1 = __builtin_amdgcn_mfma_f32_16x16x32_bf16(a1, Qf0, S1, 0, 0, 0);
      S2 = __builtin_amdgcn_mfma_f32_16x16x32_bf16(a2, Qf0, S2, 0, 0, 0);
      S3 = __builtin_amdgcn_mfma_f32_16x16x32_bf16(a3, Qf0, S3, 0, 0, 0);
      S0 = __builtin_amdgcn_mfma_f32_16x16x32_bf16(b0, Qf1, S0, 0, 0, 0);
      S1 = __builtin_amdgcn_mfma_f32_16x16x32_bf16(b1, Qf1, S1, 0, 0, 0);
      S2 = __builtin_amdgcn_mfma_f32_16x16x32_bf16(b2, Qf1, S2, 0, 0, 0);
      S3 = __builtin_amdgcn_mfma_f32_16x16x32_bf16(b3, Qf1, S3, 0, 0, 0);
    }
    float sc[4][4];
#pragma unroll
    for (int r = 0; r < 4; r++) {
      sc[0][r] = S0[r] * 0.125f; sc[1][r] = S1[r] * 0.125f;
      sc[2][r] = S2[r] * 0.125f; sc[3][r] = S3[r] * 0.125f;
    }
    if (kt == nkt - 1) {
#pragma unroll
      for (int mb = 0; mb < 4; mb++)
#pragma unroll
        for (int r = 0; r < 4; r++)
          if (k0 + 16 * mb + 4 * g + r > q0 + r16) sc[mb][r] = -INFINITY;
    }
    float tm = sc[0][0];
#pragma unroll
    for (int mb = 0; mb < 4; mb++)
#pragma unroll
      for (int r = 0; r < 4; r++) tm = fmaxf(tm, sc[mb][r]);
    tm = fmaxf(tm, __shfl_xor(tm, 16));
    tm = fmaxf(tm, __shfl_xor(tm, 32));
    float mn = fmaxf(m, tm);
    float ef = __expf(m - mn);
    float pv[4][4];
    float ps = 0.f;
#pragma unroll
    for (int mb = 0; mb < 4; mb++)
#pragma unroll
      for (int r = 0; r < 4; r++) { pv[mb][r] = __expf(sc[mb][r] - mn); ps += pv[mb][r]; }
    ps += __shfl_xor(ps, 16);
    ps += __shfl_xor(ps, 32);
    ssum = ssum * ef + ps;
    m = mn;
#pragma unroll
    for (int r = 0; r < 4; r++) {
      float efr = __shfl(ef, 4 * g + r);
      O0[r] *= efr; O1[r] *= efr; O2[r] *= efr; O3[r] *= efr;
    }
    short8 ap[2];
#pragma unroll
    for (int c = 0; c < 2; c++) {
#pragma unroll
      for (int jb = 0; jb < 2; jb++) {
        int x = 2 * g + jb;
        int hi = x >> 2;
        int src = r16 + 16 * (x & 3);
#pragma unroll
        for (int rs = 0; rs < 4; rs++) {
          float tl_ = __shfl(pv[2 * c][rs],     src);
          float th_ = __shfl(pv[2 * c + 1][rs], src);
          ap[c][jb * 4 + rs] = (short)f2b_rne(hi ? th_ : tl_);
        }
      }
    }
    {
      const u16* vb0 = vtb + (size_t)(hofs + r16) * 4096 + k0 + 8 * g;
#pragma unroll
      for (int c = 0; c < 2; c++) {
        short8 v0 = *(const short8*)&vb0[32 * c];
        short8 v1 = *(const short8*)&vb0[16 * 4096 + 32 * c];
        short8 v2 = *(const short8*)&vb0[32 * 4096 + 32 * c];
        short8 v3 = *(const short8*)&vb0[48 * 4096 + 32 * c];
        O0 = __builtin_amdgcn_mfma_f32_16x16x32_bf16(ap[c], v0, O0, 0, 0, 0);
        O1 = __builtin_amdgcn_mfma_f32_16x16x32_bf16(ap[c], v1, O1, 0, 0, 0);
        O2 = __builtin_amdgcn_mfma_f32_16x16x32_bf16(ap[c], v2, O2, 0, 0, 0);
        O3 = __builtin_amdgcn_mfma_f32_16x16x32_bf16(ap[c], v3, O3, 0, 0, 0);
      }
    }
  }

#pragma unroll
  for (int r = 0; r < 4; r++) {
    int q = 4 * g + r;
    Obuf[w][q][r16 +  0] = O0[r];
    Obuf[w][q][r16 + 16] = O1[r];
    Obuf[w][q][r16 + 32] = O2[r];
    Obuf[w][q][r16 + 48] = O3[r];
  }
  if (l < 16) { msh[w][l] = m; ssh[w][l] = ssum; }
  __syncthreads();

  // merge the 4 wave-partials into an UNNORMALIZED block partial (O at max M, plus m,s)
  int t = threadIdx.x;
  int q = t >> 4, dc = (t & 15) * 4;
  float M = fmaxf(fmaxf(msh[0][q], msh[1][q]), fmaxf(msh[2][q], msh[3][q]));
  float e0, e1, e2, e3;
  if (M == -INFINITY) { e0 = e1 = e2 = e3 = 0.f; }   // empty stripe (ks=1, tiny tile)
  else {
    e0 = __expf(msh[0][q] - M); e1 = __expf(msh[1][q] - M);
    e2 = __expf(msh[2][q] - M); e3 = __expf(msh[3][q] - M);
  }
  float4 res;
#pragma unroll
  for (int dd = 0; dd < 4; dd++) {
    ((float*)&res)[dd] = e0 * Obuf[0][q][dc+dd] + e1 * Obuf[1][q][dc+dd]
                       + e2 * Obuf[2][q][dc+dd] + e3 * Obuf[3][q][dc+dd];
  }
  *(float4*)&Opart[(size_t)bid * 1024 + q * 64 + dc] = res;
  if (t < 16) {
    float Mq = fmaxf(fmaxf(msh[0][t], msh[1][t]), fmaxf(msh[2][t], msh[3][t]));
    float Sq = 0.f;
    if (Mq != -INFINITY)
      Sq = __expf(msh[0][t] - Mq) * ssh[0][t] + __expf(msh[1][t] - Mq) * ssh[1][t]
         + __expf(msh[2][t] - Mq) * ssh[2][t] + __expf(msh[3][t] - Mq) * ssh[3][t];
    mspart[bid * 32 + t] = Mq;
    mspart[bid * 32 + 16 + t] = Sq;
  }
}

// merge 2 block-partials -> normalized output
__global__ __launch_bounds__(256) void mha_merge(const float* __restrict__ Opart, const float* __restrict__ mspart,
                                                 float* __restrict__ out) {
  int mb = blockIdx.x;                 // (255-tile)*4 + h
  int h = mb & 3, tile = 255 - (mb >> 2);
  int q0 = tile * 16, hofs = h * 64;
  int t = threadIdx.x, q = t >> 4, dc = (t & 15) * 4;
  int p0 = 2 * mb, p1 = 2 * mb + 1;
  float m0 = mspart[p0 * 32 + q],      m1 = mspart[p1 * 32 + q];
  float s0 = mspart[p0 * 32 + 16 + q], s1 = mspart[p1 * 32 + 16 + q];
  float M = fmaxf(m0, m1);             // m0 always finite (kt=0 in stripe 0)
  float e0 = __expf(m0 - M);
  float e1 = (m1 == -INFINITY) ? 0.f : __expf(m1 - M);
  float S = e0 * s0 + e1 * s1;
  float inv = 1.f / S;
  float4 a = load4f(&Opart[(size_t)p0 * 1024 + q * 64 + dc]);
  float4 b = load4f(&Opart[(size_t)p1 * 1024 + q * 64 + dc]);
  float4 r;
  r.x = (e0 * a.x + e1 * b.x) * inv;
  r.y = (e0 * a.y + e1 * b.y) * inv;
  r.z = (e0 * a.z + e1 * b.z) * inv;
  r.w = (e0 * a.w + e1 * b.w) * inv;
  *(float4*)&out[(size_t)(q0 + q) * EMB + hofs + dc] = r;
}

// ---------------- CSR build ----------------
__global__ void zero_i32(int* p, int n) {
  int i = blockIdx.x * 256 + threadIdx.x;
  if (i < n) p[i] = 0;
}
__global__ void hist_dst(const int* __restrict__ adj, int* __restrict__ cnt) {
  int e = blockIdx.x * 256 + threadIdx.x;
  if (e < NE) atomicAdd(&cnt[adj[NE + e]], 1);
}
__global__ __launch_bounds__(1024) void scan4096(const int* __restrict__ cnt, int* __restrict__ indptr,
                                                 int* __restrict__ cursor) {
  int t = threadIdx.x;
  int4 c = *reinterpret_cast<const int4*>(cnt + t * 4);
  int s0 = c.x, s1 = s0 + c.y, s2 = s1 + c.z, s3 = s2 + c.w;
  int lane = t & 63, w = t >> 6;
  int x = s3;
#pragma unroll
  for (int off = 1; off < 64; off <<= 1) {
    int y = __shfl_up(x, off);
    if (lane >= off) x += y;
  }
  __shared__ int wsum[16];
  if (lane == 63) wsum[w] = x;
  __syncthreads();
  if (t == 0) {
    int acc = 0;
    for (int i = 0; i < 16; i++) { int tv = wsum[i]; wsum[i] = acc; acc += tv; }
  }
  __syncthreads();
  int b = wsum[w] + x - s3;
  indptr[t*4+0] = b;      indptr[t*4+1] = b + s0;
  indptr[t*4+2] = b + s1; indptr[t*4+3] = b + s2;
  cursor[t*4+0] = b;      cursor[t*4+1] = b + s0;
  cursor[t*4+2] = b + s1; cursor[t*4+3] = b + s2;
  if (t == 1023) indptr[4096] = b + s3;
}
__global__ void scatter_edges(const int* __restrict__ adj, int* __restrict__ cursor, int* __restrict__ esrc) {
  int e = blockIdx.x * 256 + threadIdx.x;
  if (e < NE) {
    int dst = adj[NE + e];
    int pos = atomicAdd(&cursor[dst], 1);
    esrc[pos] = adj[e];
  }
}

// ---------------- TransformerConv aggregation (bf16 K/V, LDS-staged P, 4-way ILP) ----------------
__global__ __launch_bounds__(256, 4) void conv_agg(const float* __restrict__ qb, const u16* __restrict__ kb,
                                                   const u16* __restrict__ vb, const int* __restrict__ indptr,
                                                   const int* __restrict__ esrc, float* __restrict__ y) {
  __shared__ float q_s[EMB];
  __shared__ float p_s[NH][64];
  __shared__ int   s_s[64];
  int n = blockIdx.x;
  int tid = threadIdx.x;
  int h = tid >> 6, lane = tid & 63;
  q_s[tid] = qb[(size_t)n * EMB + tid] * 0.125f;   // fold 1/sqrt(D) into q
  int start = indptr[n], end = indptr[n + 1];
  __syncthreads();
  const float* qh = &q_s[h * HD];
  float m = -INFINITY, s = 0.f;
  float o0 = 0.f, o1 = 0.f, o2 = 0.f, o3 = 0.f;
  for (int p0 = start; p0 < end; p0 += 64) {
    int nk = end - p0; if (nk > 64) nk = 64;
    float sc = -INFINITY;
    int src = 0;
    if (lane < nk) {
      src = esrc[p0 + lane];
      const u16* kr = kb + (size_t)src * EMB + h * HD;
      float a0 = 0.f, a1 = 0.f, a2 = 0.f, a3 = 0.f;
#pragma unroll
      for (int d = 0; d < HD; d += 8) {
        short8 k8 = *(const short8*)&kr[d];
        a0 = fmaf(b2f((u16)k8[0]), qh[d+0], a0);
        a1 = fmaf(b2f((u16)k8[1]), qh[d+1], a1);
        a2 = fmaf(b2f((u16)k8[2]), qh[d+2], a2);
        a3 = fmaf(b2f((u16)k8[3]), qh[d+3], a3);
        a0 = fmaf(b2f((u16)k8[4]), qh[d+4], a0);
        a1 = fmaf(b2f((u16)k8[5]), qh[d+5], a1);
        a2 = fmaf(b2f((u16)k8[6]), qh[d+6], a2);
        a3 = fmaf(b2f((u16)k8[7]), qh[d+7], a3);
      }
      sc = (a0 + a1) + (a2 + a3);
    }
    float bm = sc;
#pragma unroll
    for (int off = 32; off; off >>= 1) bm = fmaxf(bm, __shfl_xor(bm, off));
    float mn = fmaxf(m, bm);
    float ef = __expf(m - mn);              // 0 on first chunk
    float p = (lane < nk) ? __expf(sc - mn) : 0.f;
    float ps = p;
#pragma unroll
    for (int off = 32; off; off >>= 1) ps += __shfl_xor(ps, off);
    s = s * ef + ps;
    m = mn;
    o0 *= ef; o1 *= ef; o2 *= ef; o3 *= ef;
    p_s[h][lane] = p;
    if (h == 0) s_s[lane] = (lane < nk) ? src : 0;  // src identical across heads
    __syncthreads();
    const u16* vcol = vb + h * HD + lane;
    int nk4 = (nk + 3) & ~3;
    for (int jj = 0; jj < nk4; jj += 4) {
      float pa = p_s[h][jj],   pb = p_s[h][jj+1];
      float pc = p_s[h][jj+2], pd = p_s[h][jj+3];
      int sa = s_s[jj], sb = s_s[jj+1], scx = s_s[jj+2], sd = s_s[jj+3];
      o0 = fmaf(pa, b2f(vcol[(size_t)sa  * EMB]), o0);
      o1 = fmaf(pb, b2f(vcol[(size_t)sb  * EMB]), o1);
      o2 = fmaf(pc, b2f(vcol[(size_t)scx * EMB]), o2);
      o3 = fmaf(pd, b2f(vcol[(size_t)sd  * EMB]), o3);
    }
    __syncthreads();
  }
  float o = (o0 + o1) + (o2 + o3);
  float agg = o / (s + 1e-16f);
  y[(size_t)n * EMB + h * HD + lane] += agg;
}

// ---------------- instance norm + lrelu + sanitize ----------------
__global__ __launch_bounds__(256) void colstats_partial(const float* __restrict__ y, float* __restrict__ part) {
  int c = threadIdx.x;
  int r0 = blockIdx.x * 128;
  float s = 0.f, q = 0.f;
  for (int r = r0; r < r0 + 128; r++) {
    float v = y[(size_t)r * EMB + c];
    s += v; q = fmaf(v, v, q);
  }
  part[blockIdx.x * 512 + c] = s;
  part[blockIdx.x * 512 + 256 + c] = q;
}
__global__ __launch_bounds__(256) void colstats_final(const float* __restrict__ part, float* __restrict__ stats) {
  int c = threadIdx.x;
  float s = 0.f, q = 0.f;
  for (int b = 0; b < 32; b++) { s += part[b * 512 + c]; q += part[b * 512 + 256 + c]; }
  float mean = s * (1.f / 4096.f);
  float var  = q * (1.f / 4096.f) - mean * mean;
  stats[c] = mean;
  stats[256 + c] = rsqrtf(var + 1e-5f);
}
__global__ __launch_bounds__(256) void norm_apply(const float* __restrict__ y, const float* __restrict__ stats,
                                                  float* __restrict__ f, int colOff) {
  int c = threadIdx.x;
  float mean = stats[c], rstd = stats[256 + c];
  int r0 = blockIdx.x * 16;
  for (int r = r0; r < r0 + 16; r++) {
    float v = (y[(size_t)r * EMB + c] - mean) * rstd;
    v = (v > 0.f) ? v : 0.2f * v;
    v = sanitize_f(v);
    f[(size_t)r * 512 + colOff + c] = v;
  }
}

// ---------------- classifier tail ----------------
__global__ __launch_bounds__(256) void final_softmax(const float* __restrict__ f1, const float* __restrict__ W2,
                                                     const float* __restrict__ b2, float* __restrict__ out) {
  int w = threadIdx.x >> 6, lane = threadIdx.x & 63;
  int row = blockIdx.x * 4 + w;
  const float* fr = f1 + (size_t)row * 128;
  float x0 = fr[lane], x1 = fr[lane + 64];
  float p0 = x0 * W2[lane]       + x1 * W2[64 + lane];
  float p1 = x0 * W2[128 + lane] + x1 * W2[192 + lane];
#pragma unroll
  for (int off = 32; off; off >>= 1) { p0 += __shfl_xor(p0, off); p1 += __shfl_xor(p1, off); }
  if (lane == 0) {
    float l0 = p0 + b2[0], l1 = p1 + b2[1];
    float mx = fmaxf(l0, l1);
    float e0 = __expf(l0 - mx), e1 = __expf(l1 - mx);
    float inv = 1.f / (e0 + e1);
    out[(size_t)row * 2 + 0] = l0;
    out[(size_t)row * 2 + 1] = l1;
    out[8192 + (size_t)row * 2 + 0] = e0 * inv;
    out[8192 + (size_t)row * 2 + 1] = e1 * inv;
  }
}

extern "C" void kernel_launch(void* const* d_in, const int* in_sizes, int n_in,
                              void* d_out, int out_size, void* d_ws, size_t ws_size,
                              hipStream_t stream) {
  const float* img   = (const float*)d_in[2];
  const int*   adj   = (const int*)d_in[3];
  const float* W_img = (const float*)d_in[4];  const float* b_img = (const float*)d_in[5];
  const float* W_qkv = (const float*)d_in[6];  const float* b_qkv = (const float*)d_in[7];
  const float* W_o   = (const float*)d_in[8];  const float* b_o   = (const float*)d_in[9];
  const float* Wq_o  = (const float*)d_in[10]; const float* bq_o  = (const float*)d_in[11];
  const float* Wk_o  = (const float*)d_in[12]; const float* bk_o  = (const float*)d_in[13];
  const float* Wv_o  = (const float*)d_in[14]; const float* bv_o  = (const float*)d_in[15];
  const float* Ws_o  = (const float*)d_in[16]; const float* bs_o  = (const float*)d_in[17];
  const float* Wq_a  = (const float*)d_in[18]; const float* bq_a  = (const float*)d_in[19];
  const float* Wk_a  = (const float*)d_in[20]; const float* bk_a  = (const float*)d_in[21];
  const float* Wv_a  = (const float*)d_in[22]; const float* bv_a  = (const float*)d_in[23];
  const float* Ws_a  = (const float*)d_in[24]; const float* bs_a  = (const float*)d_in[25];
  const float* W_c1  = (const float*)d_in[26]; const float* b_c1  = (const float*)d_in[27];
  const float* W_c2  = (const float*)d_in[28]; const float* b_c2  = (const float*)d_in[29];

  char* ws = (char*)d_ws;
  float* h     = (float*)(ws + 0);                    // 4 MB
  float* hattn = (float*)(ws + (4ull << 20));         // 4 MB (aliased as qkb during mha)
  float* qkv   = (float*)(ws + (8ull << 20));         // 12 MB (img-splitk partials before step 2)
  float* y     = (float*)(ws + (20ull << 20));        // 4 MB  (img-splitk partial #4 before step 2)
  float* f     = (float*)(ws + (24ull << 20));        // 8 MB  (mha O-partials during step 3)
  float* f1    = (float*)(ws + (32ull << 20));        // 2 MB (aliased as vtb during mha)
  int*   indptr= (int*)  (ws + (34ull << 20));
  int*   cursor= (int*)  (ws + (34ull << 20) + 20480);
  int*   esrc  = (int*)  (ws + (34ull << 20) + 40960);  // 1 MB (mha m/s partials during step 3)
  float* part  = (float*)(ws + (34ull << 20) + 40960 + (1ull << 20));
  float* stats = (float*)(ws + (34ull << 20) + 40960 + (1ull << 20) + 65536);

  u16* qkb = (u16*)hattn;   // dead after mha
  u16* vtb = (u16*)f1;      // dead after mha

  float* imgpart = qkv;          // 16 MB contiguous (qkv 12MB + y 4MB), free during step 1
  float* Opart   = f;            // 8 MB, free during step 3
  float* mspart  = (float*)esrc; // 256 KB, free during step 3 (CSR built later)

  float* qb   = qkv;                         // 4 MB f32
  u16*   kb16 = (u16*)(ws + (12ull << 20));  // 2 MB bf16
  u16*   vb16 = (u16*)(ws + (14ull << 20));  // 2 MB bf16

  dim3 b256(256);

  // 1. h = img_feat @ W_img^T + b_img   (M=4096,N=256,K=2048) split-K x4
  gemm_img_splitk<<<dim3(64, 4, 4), b256, 0, stream>>>(img, W_img, imgpart);
  gemm_img_reduce<<<1024, b256, 0, stream>>>(imgpart, b_img, h);
  // 2. qkv = h @ W_qkv^T + b_qkv   (N=768,K=256)
  {
    GArgs ga;
    for (int i = 0; i < 12; i++)
      ga.t[i] = { W_qkv + (size_t)i * 64 * 256, b_qkv + i * 64, qkv, i * 64, 768, 0 };
    gemm_mfma<0><<<dim3(64, 12), b256, 0, stream>>>(h, ga, 256);
  }
  // 3. causal MHA (MFMA flash, split-K x (4 waves x 2 blocks)) -> y
  conv_qk<<<1024, b256, 0, stream>>>(qkv, qkb);
  conv_vt<<<256, b256, 0, stream>>>(qkv, vtb);
  mha_mfma2<<<2048, b256, 0, stream>>>(qkb, vtb, Opart, mspart);
  mha_merge<<<1024, b256, 0, stream>>>(Opart, mspart, y);
  // 4. h_attn = sanitize(y @ W_o^T + b_o)
  {
    GArgs ga;
    for (int i = 0; i < 4; i++)
      ga.t[i] = { W_o + (size_t)i * 64 * 256, b_o + i * 64, hattn, i * 64, 256, 0 };
    gemm_mfma<1><<<dim3(64, 4), b256, 0, stream>>>(y, ga, 256);
  }
  // 5. CSR of video_adj_list grouped by dst
  zero_i32<<<16, b256, 0, stream>>>(cursor, NN);
  hist_dst<<<NE / 256, b256, 0, stream>>>(adj, cursor);
  scan4096<<<1, 1024, 0, stream>>>(cursor, indptr, cursor);
  scatter_edges<<<NE / 256, b256, 0, stream>>>(adj, cursor, esrc);

  // 6. conv path O: q/k/v/skip fused (N=1024,K=256), input h; k,v in bf16
  {
    const float* Wg[4] = { Wq_o, Wk_o, Wv_o, Ws_o };
    const float* bg[4] = { bq_o, bk_o, bv_o, bs_o };
    float*       og[4] = { qb, (float*)kb16, (float*)vb16, y };
    const int    bf[4] = { 0, 1, 1, 0 };
    GArgs ga;
    for (int i = 0; i < 16; i++) {
      int gdx = i >> 2, li = i & 3;
      ga.t[i] = { Wg[gdx] + (size_t)li * 64 * 256, bg[gdx] + li * 64, og[gdx], li * 64, 256, bf[gdx] };
    }
    gemm_mfma<0><<<dim3(64, 16), b256, 0, stream>>>(h, ga, 256);
  }
  conv_agg<<<NN, b256, 0, stream>>>(qb, kb16, vb16, indptr, esrc, y);
  colstats_partial<<<32, b256, 0, stream>>>(y, part);
  colstats_final<<<1, b256, 0, stream>>>(part, stats);
  norm_apply<<<256, b256, 0, stream>>>(y, stats, f, 0);

  // 7. conv path A: same, input hattn
  {
    const float* Wg[4] = { Wq_a, Wk_a, Wv_a, Ws_a };
    const float* bg[4] = { bq_a, bk_a, bv_a, bs_a };
    float*       og[4] = { qb, (float*)kb16, (float*)vb16, y };
    const int    bf[4] = { 0, 1, 1, 0 };
    GArgs ga;
    for (int i = 0; i < 16; i++) {
      int gdx = i >> 2, li = i & 3;
      ga.t[i] = { Wg[gdx] + (size_t)li * 64 * 256, bg[gdx] + li * 64, og[gdx], li * 64, 256, bf[gdx] };
    }
    gemm_mfma<0><<<dim3(64, 16), b256, 0, stream>>>(hattn, ga, 256);
  }
  conv_agg<<<NN, b256, 0, stream>>>(qb, kb16, vb16, indptr, esrc, y);
  colstats_partial<<<32, b256, 0, stream>>>(y, part);
  colstats_final<<<1, b256, 0, stream>>>(part, stats);
  norm_apply<<<256, b256, 0, stream>>>(y, stats, f, 256);

  // 8. f1 = lrelu(f @ W_c1^T + b_c1)   (N=128,K=512)
  {
    GArgs ga;
    for (int i = 0; i < 2; i++)
      ga.t[i] = { W_c1 + (size_t)i * 64 * 512, b_c1 + i * 64, f1, i * 64, 128, 0 };
    gemm_mfma<2><<<dim3(64, 2), b256, 0, stream>>>(f, ga, 512);
  }
  // 9. logits + softmax -> out (f32): [0:8192] logits, [8192:16384] probs
  final_softmax<<<NN / 4, b256, 0, stream>>>(f1, W_c2, b_c2, (float*)d_out);
}

// Round 11
// 335.112 us; speedup vs baseline: 1.3978x; 1.0214x over previous
//
#include <hip/hip_runtime.h>
#include <hip/hip_bf16.h>

typedef unsigned short u16;
typedef unsigned int   u32;
typedef __attribute__((ext_vector_type(8))) short short8;
typedef __attribute__((ext_vector_type(4))) float f32x4;

#define NN 4096        // nodes
#define NE 262144      // edges
#define EMB 256
#define NH 4
#define HD 64

__device__ __forceinline__ float4 load4f(const float* p) { return *reinterpret_cast<const float4*>(p); }
__device__ __forceinline__ float sanitize_f(float v) {
  v = (v != v) ? 0.f : v;                 // nan -> 0
  return fminf(fmaxf(v, -1000.f), 1000.f); // +-inf and clip -> +-1000
}
__device__ __forceinline__ u16 f2b_rne(float x) {          // f32 -> bf16 bits, round-nearest-even
  u32 b = __float_as_uint(x);
  b += 0x7fff + ((b >> 16) & 1);
  return (u16)(b >> 16);
}
__device__ __forceinline__ u32 pack2(float a, float b) {
  return (u32)f2b_rne(a) | ((u32)f2b_rne(b) << 16);
}
__device__ __forceinline__ float b2f(u16 u) { return __uint_as_float((u32)u << 16); }

// ================= generic MFMA GEMM: out = act(A[M,K] @ W^T + bias) =================
struct GTile {
  const float* W;     // 64 weight rows for this tile: [64][K]
  const float* bias;  // 64 entries
  float*       out;   // f32 / bf16 / bf16-transposed
  int          colOff;
  int          ldOut;
  int          obf16; // 0: f32 row-major; 1: bf16 row-major; 2: bf16 TRANSPOSED out[col*ldOut+row]
};
struct GArgs { GTile t[16]; };

// 256 threads = 4 waves; block tile 64x64; wave tile 32x32 (2x2 frags of 16x16x32).
template<int ACT>   // 0 none, 1 sanitize, 2 lrelu(0.2)
__global__ __launch_bounds__(256) void gemm_mfma(const float* __restrict__ A, const GArgs ga, int K) {
  __shared__ short As[64 * 40];
  __shared__ short Bs[64 * 40];
  const int t = threadIdx.x;
  const int bm = blockIdx.x * 64;
  const GTile tl = ga.t[blockIdx.y];
  const int w = t >> 6, l = t & 63, g = l >> 4, r16 = l & 15;
  const int wr = w >> 1, wc = w & 1;
  const int lrow = t >> 2, lseg = (t & 3) * 8;

  const float* Ap = A + (size_t)(bm + lrow) * K + lseg;
  const float* Wp = tl.W + (size_t)lrow * K + lseg;

  f32x4 acc[2][2] = {{{0.f,0.f,0.f,0.f},{0.f,0.f,0.f,0.f}},{{0.f,0.f,0.f,0.f},{0.f,0.f,0.f,0.f}}};
  for (int k0 = 0; k0 < K; k0 += 32) {
    float4 a0 = load4f(Ap + k0), a1 = load4f(Ap + k0 + 4);
    float4 b0 = load4f(Wp + k0), b1 = load4f(Wp + k0 + 4);
    __syncthreads();
    *(uint4*)&As[lrow * 40 + lseg] =
        make_uint4(pack2(a0.x,a0.y), pack2(a0.z,a0.w), pack2(a1.x,a1.y), pack2(a1.z,a1.w));
    *(uint4*)&Bs[lrow * 40 + lseg] =
        make_uint4(pack2(b0.x,b0.y), pack2(b0.z,b0.w), pack2(b1.x,b1.y), pack2(b1.z,b1.w));
    __syncthreads();
    short8 af0 = *(const short8*)&As[(wr*32 +      r16) * 40 + 8*g];
    short8 af1 = *(const short8*)&As[(wr*32 + 16 + r16) * 40 + 8*g];
    short8 bf0 = *(const short8*)&Bs[(wc*32 +      r16) * 40 + 8*g];
    short8 bf1 = *(const short8*)&Bs[(wc*32 + 16 + r16) * 40 + 8*g];
    acc[0][0] = __builtin_amdgcn_mfma_f32_16x16x32_bf16(af0, bf0, acc[0][0], 0, 0, 0);
    acc[0][1] = __builtin_amdgcn_mfma_f32_16x16x32_bf16(af0, bf1, acc[0][1], 0, 0, 0);
    acc[1][0] = __builtin_amdgcn_mfma_f32_16x16x32_bf16(af1, bf0, acc[1][0], 0, 0, 0);
    acc[1][1] = __builtin_amdgcn_mfma_f32_16x16x32_bf16(af1, bf1, acc[1][1], 0, 0, 0);
  }
  const float bj[2] = { tl.bias[wc*32 + r16], tl.bias[wc*32 + 16 + r16] };
#pragma unroll
  for (int i = 0; i < 2; i++) {
#pragma unroll
    for (int j = 0; j < 2; j++) {
      int col  = tl.colOff + wc*32 + 16*j + r16;
      int row0 = bm + wr*32 + 16*i + 4*g;
      if (tl.obf16 == 2) {           // transposed bf16: out[col*ldOut + row], 4 consecutive rows
        u16 pk[4];
#pragma unroll
        for (int r = 0; r < 4; r++) pk[r] = f2b_rne(acc[i][j][r] + bj[j]);
        *(uint2*)((u16*)tl.out + (size_t)col * tl.ldOut + row0) = *(uint2*)pk;
      } else {
#pragma unroll
        for (int r = 0; r < 4; r++) {
          float v = acc[i][j][r] + bj[j];
          if (ACT == 1) v = sanitize_f(v);
          if (ACT == 2) v = (v > 0.f) ? v : 0.2f * v;
          if (tl.obf16) ((u16*)tl.out)[(size_t)(row0 + r) * tl.ldOut + col] = f2b_rne(v);
          else          tl.out[(size_t)(row0 + r) * tl.ldOut + col] = v;
        }
      }
    }
  }
}

// ---------------- img GEMM split-K: K=2048 over 4 z-blocks of 512 ----------------
__global__ __launch_bounds__(256) void gemm_img_splitk(const float* __restrict__ A, const float* __restrict__ W,
                                                       float* __restrict__ part) {
  __shared__ short As[64 * 40];
  __shared__ short Bs[64 * 40];
  const int t = threadIdx.x;
  const int bm = blockIdx.x * 64, bn = blockIdx.y * 64, ks = blockIdx.z;
  const int w = t >> 6, l = t & 63, g = l >> 4, r16 = l & 15;
  const int wr = w >> 1, wc = w & 1;
  const int lrow = t >> 2, lseg = (t & 3) * 8;

  const float* Ap = A + (size_t)(bm + lrow) * 2048 + ks * 512 + lseg;
  const float* Wp = W + (size_t)(bn + lrow) * 2048 + ks * 512 + lseg;

  f32x4 acc[2][2] = {{{0.f,0.f,0.f,0.f},{0.f,0.f,0.f,0.f}},{{0.f,0.f,0.f,0.f},{0.f,0.f,0.f,0.f}}};
  for (int k0 = 0; k0 < 512; k0 += 32) {
    float4 a0 = load4f(Ap + k0), a1 = load4f(Ap + k0 + 4);
    float4 b0 = load4f(Wp + k0), b1 = load4f(Wp + k0 + 4);
    __syncthreads();
    *(uint4*)&As[lrow * 40 + lseg] =
        make_uint4(pack2(a0.x,a0.y), pack2(a0.z,a0.w), pack2(a1.x,a1.y), pack2(a1.z,a1.w));
    *(uint4*)&Bs[lrow * 40 + lseg] =
        make_uint4(pack2(b0.x,b0.y), pack2(b0.z,b0.w), pack2(b1.x,b1.y), pack2(b1.z,b1.w));
    __syncthreads();
    short8 af0 = *(const short8*)&As[(wr*32 +      r16) * 40 + 8*g];
    short8 af1 = *(const short8*)&As[(wr*32 + 16 + r16) * 40 + 8*g];
    short8 bf0 = *(const short8*)&Bs[(wc*32 +      r16) * 40 + 8*g];
    short8 bf1 = *(const short8*)&Bs[(wc*32 + 16 + r16) * 40 + 8*g];
    acc[0][0] = __builtin_amdgcn_mfma_f32_16x16x32_bf16(af0, bf0, acc[0][0], 0, 0, 0);
    acc[0][1] = __builtin_amdgcn_mfma_f32_16x16x32_bf16(af0, bf1, acc[0][1], 0, 0, 0);
    acc[1][0] = __builtin_amdgcn_mfma_f32_16x16x32_bf16(af1, bf0, acc[1][0], 0, 0, 0);
    acc[1][1] = __builtin_amdgcn_mfma_f32_16x16x32_bf16(af1, bf1, acc[1][1], 0, 0, 0);
  }
  float* op = part + (size_t)ks * (NN * 256);
#pragma unroll
  for (int i = 0; i < 2; i++) {
#pragma unroll
    for (int j = 0; j < 2; j++) {
      int col = bn + wc*32 + 16*j + r16;
#pragma unroll
      for (int r = 0; r < 4; r++) {
        int row = bm + wr*32 + 16*i + 4*g + r;
        op[(size_t)row * 256 + col] = acc[i][j][r];
      }
    }
  }
}
__global__ __launch_bounds__(256) void gemm_img_reduce(const float* __restrict__ part,
                                                       const float* __restrict__ bias,
                                                       float* __restrict__ h) {
  int idx = blockIdx.x * 256 + threadIdx.x;   // 262144 threads, 4 floats each
  int row = idx >> 6, c4 = (idx & 63) * 4;
  size_t o = (size_t)row * 256 + c4;
  float4 s = load4f(part + o);
  float4 p1 = load4f(part + 1048576 + o);
  float4 p2 = load4f(part + 2097152 + o);
  float4 p3 = load4f(part + 3145728 + o);
  float4 bb = load4f(bias + c4);
  s.x += p1.x + p2.x + p3.x + bb.x;
  s.y += p1.y + p2.y + p3.y + bb.y;
  s.z += p1.z + p2.z + p3.z + bb.z;
  s.w += p1.w + p2.w + p3.w + bb.w;
  *(float4*)&h[o] = s;
}

// ---------------- causal MHA: MFMA flash, split-K over 4 waves x 2 blocks ----------------
// grid 2048: ks = bid&1, h = (bid>>1)&3, tile = 255-(bid>>3).
__global__ __launch_bounds__(256, 4) void mha_mfma2(const u16* __restrict__ qkb, const u16* __restrict__ vtb,
                                                    float* __restrict__ Opart, float* __restrict__ mspart) {
  __shared__ float Obuf[4][16][68];
  __shared__ float msh[4][16];
  __shared__ float ssh[4][16];
  const int bid  = blockIdx.x;
  const int ks   = bid & 1;
  const int h    = (bid >> 1) & 3;
  const int tile = 255 - (bid >> 3);
  const int q0   = tile * 16;
  const int w    = threadIdx.x >> 6;
  const int l    = threadIdx.x & 63;
  const int g    = l >> 4, r16 = l & 15;
  const int hofs = h * 64;

  const u16* qrow = qkb + (size_t)(q0 + r16) * 512 + hofs;
  short8 Qf0 = *(const short8*)&qrow[8 * g];
  short8 Qf1 = *(const short8*)&qrow[32 + 8 * g];

  f32x4 O0 = {0.f,0.f,0.f,0.f}, O1 = O0, O2 = O0, O3 = O0;
  float m = -INFINITY, ssum = 0.f;
  const int nkt = (q0 + 16 + 63) >> 6;

  for (int kt = ks + 2 * w; kt < nkt; kt += 8) {
    const int k0 = kt * 64;
    // ---- issue ALL loads up front: K (needed first) and V (needed after softmax) ----
    const u16* kb0 = qkb + (size_t)(k0 + r16) * 512 + 256 + hofs + 8 * g;
    short8 a0 = *(const short8*)&kb0[0];
    short8 b0 = *(const short8*)&kb0[32];
    const u16* kb1 = kb0 + (size_t)16 * 512;
    short8 a1 = *(const short8*)&kb1[0];
    short8 b1 = *(const short8*)&kb1[32];
    const u16* kb2 = kb1 + (size_t)16 * 512;
    short8 a2 = *(const short8*)&kb2[0];
    short8 b2 = *(const short8*)&kb2[32];
    const u16* kb3 = kb2 + (size_t)16 * 512;
    short8 a3 = *(const short8*)&kb3[0];
    short8 b3 = *(const short8*)&kb3[32];
    const u16* vb0 = vtb + (size_t)(hofs + r16) * 4096 + k0 + 8 * g;
    short8 V00 = *(const short8*)&vb0[0];
    short8 V01 = *(const short8*)&vb0[32];
    short8 V10 = *(const short8*)&vb0[16 * 4096];
    short8 V11 = *(const short8*)&vb0[16 * 4096 + 32];
    short8 V20 = *(const short8*)&vb0[32 * 4096];
    short8 V21 = *(const short8*)&vb0[32 * 4096 + 32];
    short8 V30 = *(const short8*)&vb0[48 * 4096];
    short8 V31 = *(const short8*)&vb0[48 * 4096 + 32];

    f32x4 S0 = {0.f,0.f,0.f,0.f}, S1 = S0, S2 = S0, S3 = S0;
    S0 = __builtin_amdgcn_mfma_f32_16x16x32_bf16(a0, Qf0, S0, 0, 0, 0);
    S1 = __builtin_amdgcn_mfma_f32_16x16x32_bf16(a1, Qf0, S1, 0, 0, 0);
    S2 = __builtin_amdgcn_mfma_f32_16x16x32_bf16(a2, Qf0, S2, 0, 0, 0);
    S3 = __builtin_amdgcn_mfma_f32_16x16x32_bf16(a3, Qf0, S3, 0, 0, 0);
    S0 = __builtin_amdgcn_mfma_f32_16x16x32_bf16(b0, Qf1, S0, 0, 0, 0);
    S1 = __builtin_amdgcn_mfma_f32_16x16x32_bf16(b1, Qf1, S1, 0, 0, 0);
    S2 = __builtin_amdgcn_mfma_f32_16x16x32_bf16(b2, Qf1, S2, 0, 0, 0);
    S3 = __builtin_amdgcn_mfma_f32_16x16x32_bf16(b3, Qf1, S3, 0, 0, 0);

    float sc[4][4];
#pragma unroll
    for (int r = 0; r < 4; r++) {
      sc[0][r] = S0[r] * 0.125f; sc[1][r] = S1[r] * 0.125f;
      sc[2][r] = S2[r] * 0.125f; sc[3][r] = S3[r] * 0.125f;
    }
    if (kt == nkt - 1) {
#pragma unroll
      for (int mb = 0; mb < 4; mb++)
#pragma unroll
        for (int r = 0; r < 4; r++)
          if (k0 + 16 * mb + 4 * g + r > q0 + r16) sc[mb][r] = -INFINITY;
    }
    float tm = sc[0][0];
#pragma unroll
    for (int mb = 0; mb < 4; mb++)
#pragma unroll
      for (int r = 0; r < 4; r++) tm = fmaxf(tm, sc[mb][r]);
    tm = fmaxf(tm, __shfl_xor(tm, 16));
    tm = fmaxf(tm, __shfl_xor(tm, 32));
    float mn = fmaxf(m, tm);
    float ef = __expf(m - mn);
    float pv[4][4];
    float ps = 0.f;
#pragma unroll
    for (int mb = 0; mb < 4; mb++)
#pragma unroll
      for (int r = 0; r < 4; r++) { pv[mb][r] = __expf(sc[mb][r] - mn); ps += pv[mb][r]; }
    ps += __shfl_xor(ps, 16);
    ps += __shfl_xor(ps, 32);
    ssum = ssum * ef + ps;
    m = mn;
#pragma unroll
    for (int r = 0; r < 4; r++) {
      float efr = __shfl(ef, 4 * g + r);
      O0[r] *= efr; O1[r] *= efr; O2[r] *= efr; O3[r] *= efr;
    }
    // ---- P A-fragments via PACKED shuffles (16 shfls, not 32) ----
    // pk[c][rs] = bf16pair(pv[2c][rs], pv[2c+1][rs]); dest picks hi/lo half.
    u32 pk[2][4];
#pragma unroll
    for (int c = 0; c < 2; c++)
#pragma unroll
      for (int rs = 0; rs < 4; rs++) pk[c][rs] = pack2(pv[2 * c][rs], pv[2 * c + 1][rs]);
    short8 ap[2];
#pragma unroll
    for (int c = 0; c < 2; c++) {
#pragma unroll
      for (int jb = 0; jb < 2; jb++) {
        int x = 2 * g + jb;
        int hi = x >> 2;
        int src = r16 + 16 * (x & 3);
#pragma unroll
        for (int rs = 0; rs < 4; rs++) {
          u32 v = __shfl(pk[c][rs], src);
          ap[c][jb * 4 + rs] = (short)(hi ? (v >> 16) : (v & 0xffff));
        }
      }
    }
    O0 = __builtin_amdgcn_mfma_f32_16x16x32_bf16(ap[0], V00, O0, 0, 0, 0);
    O1 = __builtin_amdgcn_mfma_f32_16x16x32_bf16(ap[0], V10, O1, 0, 0, 0);
    O2 = __builtin_amdgcn_mfma_f32_16x16x32_bf16(ap[0], V20, O2, 0, 0, 0);
    O3 = __builtin_amdgcn_mfma_f32_16x16x32_bf16(ap[0], V30, O3, 0, 0, 0);
    O0 = __builtin_amdgcn_mfma_f32_16x16x32_bf16(ap[1], V01, O0, 0, 0, 0);
    O1 = __builtin_amdgcn_mfma_f32_16x16x32_bf16(ap[1], V11, O1, 0, 0, 0);
    O2 = __builtin_amdgcn_mfma_f32_16x16x32_bf16(ap[1], V21, O2, 0, 0, 0);
    O3 = __builtin_amdgcn_mfma_f32_16x16x32_bf16(ap[1], V31, O3, 0, 0, 0);
  }

#pragma unroll
  for (int r = 0; r < 4; r++) {
    int q = 4 * g + r;
    Obuf[w][q][r16 +  0] = O0[r];
    Obuf[w][q][r16 + 16] = O1[r];
    Obuf[w][q][r16 + 32] = O2[r];
    Obuf[w][q][r16 + 48] = O3[r];
  }
  if (l < 16) { msh[w][l] = m; ssh[w][l] = ssum; }
  __syncthreads();

  // merge the 4 wave-partials into an UNNORMALIZED block partial (O at max M, plus m,s)
  int t = threadIdx.x;
  int q = t >> 4, dc = (t & 15) * 4;
  float M = fmaxf(fmaxf(msh[0][q], msh[1][q]), fmaxf(msh[2][q], msh[3][q]));
  float e0, e1, e2, e3;
  if (M == -INFINITY) { e0 = e1 = e2 = e3 = 0.f; }   // empty stripe (ks=1, tiny tile)
  else {
    e0 = __expf(msh[0][q] - M); e1 = __expf(msh[1][q] - M);
    e2 = __expf(msh[2][q] - M); e3 = __expf(msh[3][q] - M);
  }
  float4 res;
#pragma unroll
  for (int dd = 0; dd < 4; dd++) {
    ((float*)&res)[dd] = e0 * Obuf[0][q][dc+dd] + e1 * Obuf[1][q][dc+dd]
                       + e2 * Obuf[2][q][dc+dd] + e3 * Obuf[3][q][dc+dd];
  }
  *(float4*)&Opart[(size_t)bid * 1024 + q * 64 + dc] = res;
  if (t < 16) {
    float Mq = fmaxf(fmaxf(msh[0][t], msh[1][t]), fmaxf(msh[2][t], msh[3][t]));
    float Sq = 0.f;
    if (Mq != -INFINITY)
      Sq = __expf(msh[0][t] - Mq) * ssh[0][t] + __expf(msh[1][t] - Mq) * ssh[1][t]
         + __expf(msh[2][t] - Mq) * ssh[2][t] + __expf(msh[3][t] - Mq) * ssh[3][t];
    mspart[bid * 32 + t] = Mq;
    mspart[bid * 32 + 16 + t] = Sq;
  }
}

// merge 2 block-partials -> normalized output
__global__ __launch_bounds__(256) void mha_merge(const float* __restrict__ Opart, const float* __restrict__ mspart,
                                                 float* __restrict__ out) {
  int mb = blockIdx.x;                 // (255-tile)*4 + h
  int h = mb & 3, tile = 255 - (mb >> 2);
  int q0 = tile * 16, hofs = h * 64;
  int t = threadIdx.x, q = t >> 4, dc = (t & 15) * 4;
  int p0 = 2 * mb, p1 = 2 * mb + 1;
  float m0 = mspart[p0 * 32 + q],      m1 = mspart[p1 * 32 + q];
  float s0 = mspart[p0 * 32 + 16 + q], s1 = mspart[p1 * 32 + 16 + q];
  float M = fmaxf(m0, m1);             // m0 always finite (kt=0 in stripe 0)
  float e0 = __expf(m0 - M);
  float e1 = (m1 == -INFINITY) ? 0.f : __expf(m1 - M);
  float S = e0 * s0 + e1 * s1;
  float inv = 1.f / S;
  float4 a = load4f(&Opart[(size_t)p0 * 1024 + q * 64 + dc]);
  float4 b = load4f(&Opart[(size_t)p1 * 1024 + q * 64 + dc]);
  float4 r;
  r.x = (e0 * a.x + e1 * b.x) * inv;
  r.y = (e0 * a.y + e1 * b.y) * inv;
  r.z = (e0 * a.z + e1 * b.z) * inv;
  r.w = (e0 * a.w + e1 * b.w) * inv;
  *(float4*)&out[(size_t)(q0 + q) * EMB + hofs + dc] = r;
}

// ---------------- CSR build ----------------
__global__ void zero_i32(int* p, int n) {
  int i = blockIdx.x * 256 + threadIdx.x;
  if (i < n) p[i] = 0;
}
__global__ void hist_dst(const int* __restrict__ adj, int* __restrict__ cnt) {
  int e = blockIdx.x * 256 + threadIdx.x;
  if (e < NE) atomicAdd(&cnt[adj[NE + e]], 1);
}
__global__ __launch_bounds__(1024) void scan4096(const int* __restrict__ cnt, int* __restrict__ indptr,
                                                 int* __restrict__ cursor) {
  int t = threadIdx.x;
  int4 c = *reinterpret_cast<const int4*>(cnt + t * 4);
  int s0 = c.x, s1 = s0 + c.y, s2 = s1 + c.z, s3 = s2 + c.w;
  int lane = t & 63, w = t >> 6;
  int x = s3;
#pragma unroll
  for (int off = 1; off < 64; off <<= 1) {
    int y = __shfl_up(x, off);
    if (lane >= off) x += y;
  }
  __shared__ int wsum[16];
  if (lane == 63) wsum[w] = x;
  __syncthreads();
  if (t == 0) {
    int acc = 0;
    for (int i = 0; i < 16; i++) { int tv = wsum[i]; wsum[i] = acc; acc += tv; }
  }
  __syncthreads();
  int b = wsum[w] + x - s3;
  indptr[t*4+0] = b;      indptr[t*4+1] = b + s0;
  indptr[t*4+2] = b + s1; indptr[t*4+3] = b + s2;
  cursor[t*4+0] = b;      cursor[t*4+1] = b + s0;
  cursor[t*4+2] = b + s1; cursor[t*4+3] = b + s2;
  if (t == 1023) indptr[4096] = b + s3;
}
__global__ void scatter_edges(const int* __restrict__ adj, int* __restrict__ cursor, int* __restrict__ esrc) {
  int e = blockIdx.x * 256 + threadIdx.x;
  if (e < NE) {
    int dst = adj[NE + e];
    int pos = atomicAdd(&cursor[dst], 1);
    esrc[pos] = adj[e];
  }
}

// ---------------- TransformerConv aggregation (bf16 K/V, LDS-staged P, 4-way ILP) ----------------
__global__ __launch_bounds__(256, 4) void conv_agg(const float* __restrict__ qb, const u16* __restrict__ kb,
                                                   const u16* __restrict__ vb, const int* __restrict__ indptr,
                                                   const int* __restrict__ esrc, float* __restrict__ y) {
  __shared__ float q_s[EMB];
  __shared__ float p_s[NH][64];
  __shared__ int   s_s[64];
  int n = blockIdx.x;
  int tid = threadIdx.x;
  int h = tid >> 6, lane = tid & 63;
  q_s[tid] = qb[(size_t)n * EMB + tid] * 0.125f;   // fold 1/sqrt(D) into q
  int start = indptr[n], end = indptr[n + 1];
  __syncthreads();
  const float* qh = &q_s[h * HD];
  float m = -INFINITY, s = 0.f;
  float o0 = 0.f, o1 = 0.f, o2 = 0.f, o3 = 0.f;
  for (int p0 = start; p0 < end; p0 += 64) {
    int nk = end - p0; if (nk > 64) nk = 64;
    float sc = -INFINITY;
    int src = 0;
    if (lane < nk) {
      src = esrc[p0 + lane];
      const u16* kr = kb + (size_t)src * EMB + h * HD;
      float a0 = 0.f, a1 = 0.f, a2 = 0.f, a3 = 0.f;
#pragma unroll
      for (int d = 0; d < HD; d += 8) {
        short8 k8 = *(const short8*)&kr[d];
        a0 = fmaf(b2f((u16)k8[0]), qh[d+0], a0);
        a1 = fmaf(b2f((u16)k8[1]), qh[d+1], a1);
        a2 = fmaf(b2f((u16)k8[2]), qh[d+2], a2);
        a3 = fmaf(b2f((u16)k8[3]), qh[d+3], a3);
        a0 = fmaf(b2f((u16)k8[4]), qh[d+4], a0);
        a1 = fmaf(b2f((u16)k8[5]), qh[d+5], a1);
        a2 = fmaf(b2f((u16)k8[6]), qh[d+6], a2);
        a3 = fmaf(b2f((u16)k8[7]), qh[d+7], a3);
      }
      sc = (a0 + a1) + (a2 + a3);
    }
    float bm = sc;
#pragma unroll
    for (int off = 32; off; off >>= 1) bm = fmaxf(bm, __shfl_xor(bm, off));
    float mn = fmaxf(m, bm);
    float ef = __expf(m - mn);              // 0 on first chunk
    float p = (lane < nk) ? __expf(sc - mn) : 0.f;
    float ps = p;
#pragma unroll
    for (int off = 32; off; off >>= 1) ps += __shfl_xor(ps, off);
    s = s * ef + ps;
    m = mn;
    o0 *= ef; o1 *= ef; o2 *= ef; o3 *= ef;
    p_s[h][lane] = p;
    if (h == 0) s_s[lane] = (lane < nk) ? src : 0;  // src identical across heads
    __syncthreads();
    const u16* vcol = vb + h * HD + lane;
    int nk4 = (nk + 3) & ~3;
    for (int jj = 0; jj < nk4; jj += 4) {
      float pa = p_s[h][jj],   pb = p_s[h][jj+1];
      float pc = p_s[h][jj+2], pd = p_s[h][jj+3];
      int sa = s_s[jj], sb = s_s[jj+1], scx = s_s[jj+2], sd = s_s[jj+3];
      o0 = fmaf(pa, b2f(vcol[(size_t)sa  * EMB]), o0);
      o1 = fmaf(pb, b2f(vcol[(size_t)sb  * EMB]), o1);
      o2 = fmaf(pc, b2f(vcol[(size_t)scx * EMB]), o2);
      o3 = fmaf(pd, b2f(vcol[(size_t)sd  * EMB]), o3);
    }
    __syncthreads();
  }
  float o = (o0 + o1) + (o2 + o3);
  float agg = o / (s + 1e-16f);
  y[(size_t)n * EMB + h * HD + lane] += agg;
}

// ---------------- instance norm + lrelu + sanitize ----------------
__global__ __launch_bounds__(256) void colstats_partial(const float* __restrict__ y, float* __restrict__ part) {
  int c = threadIdx.x;
  int r0 = blockIdx.x * 128;
  float s = 0.f, q = 0.f;
  for (int r = r0; r < r0 + 128; r++) {
    float v = y[(size_t)r * EMB + c];
    s += v; q = fmaf(v, v, q);
  }
  part[blockIdx.x * 512 + c] = s;
  part[blockIdx.x * 512 + 256 + c] = q;
}
__global__ __launch_bounds__(256) void colstats_final(const float* __restrict__ part, float* __restrict__ stats) {
  int c = threadIdx.x;
  float s = 0.f, q = 0.f;
  for (int b = 0; b < 32; b++) { s += part[b * 512 + c]; q += part[b * 512 + 256 + c]; }
  float mean = s * (1.f / 4096.f);
  float var  = q * (1.f / 4096.f) - mean * mean;
  stats[c] = mean;
  stats[256 + c] = rsqrtf(var + 1e-5f);
}
__global__ __launch_bounds__(256) void norm_apply(const float* __restrict__ y, const float* __restrict__ stats,
                                                  float* __restrict__ f, int colOff) {
  int c = threadIdx.x;
  float mean = stats[c], rstd = stats[256 + c];
  int r0 = blockIdx.x * 16;
  for (int r = r0; r < r0 + 16; r++) {
    float v = (y[(size_t)r * EMB + c] - mean) * rstd;
    v = (v > 0.f) ? v : 0.2f * v;
    v = sanitize_f(v);
    f[(size_t)r * 512 + colOff + c] = v;
  }
}

// ---------------- classifier tail ----------------
__global__ __launch_bounds__(256) void final_softmax(const float* __restrict__ f1, const float* __restrict__ W2,
                                                     const float* __restrict__ b2, float* __restrict__ out) {
  int w = threadIdx.x >> 6, lane = threadIdx.x & 63;
  int row = blockIdx.x * 4 + w;
  const float* fr = f1 + (size_t)row * 128;
  float x0 = fr[lane], x1 = fr[lane + 64];
  float p0 = x0 * W2[lane]       + x1 * W2[64 + lane];
  float p1 = x0 * W2[128 + lane] + x1 * W2[192 + lane];
#pragma unroll
  for (int off = 32; off; off >>= 1) { p0 += __shfl_xor(p0, off); p1 += __shfl_xor(p1, off); }
  if (lane == 0) {
    float l0 = p0 + b2[0], l1 = p1 + b2[1];
    float mx = fmaxf(l0, l1);
    float e0 = __expf(l0 - mx), e1 = __expf(l1 - mx);
    float inv = 1.f / (e0 + e1);
    out[(size_t)row * 2 + 0] = l0;
    out[(size_t)row * 2 + 1] = l1;
    out[8192 + (size_t)row * 2 + 0] = e0 * inv;
    out[8192 + (size_t)row * 2 + 1] = e1 * inv;
  }
}

extern "C" void kernel_launch(void* const* d_in, const int* in_sizes, int n_in,
                              void* d_out, int out_size, void* d_ws, size_t ws_size,
                              hipStream_t stream) {
  const float* img   = (const float*)d_in[2];
  const int*   adj   = (const int*)d_in[3];
  const float* W_img = (const float*)d_in[4];  const float* b_img = (const float*)d_in[5];
  const float* W_qkv = (const float*)d_in[6];  const float* b_qkv = (const float*)d_in[7];
  const float* W_o   = (const float*)d_in[8];  const float* b_o   = (const float*)d_in[9];
  const float* Wq_o  = (const float*)d_in[10]; const float* bq_o  = (const float*)d_in[11];
  const float* Wk_o  = (const float*)d_in[12]; const float* bk_o  = (const float*)d_in[13];
  const float* Wv_o  = (const float*)d_in[14]; const float* bv_o  = (const float*)d_in[15];
  const float* Ws_o  = (const float*)d_in[16]; const float* bs_o  = (const float*)d_in[17];
  const float* Wq_a  = (const float*)d_in[18]; const float* bq_a  = (const float*)d_in[19];
  const float* Wk_a  = (const float*)d_in[20]; const float* bk_a  = (const float*)d_in[21];
  const float* Wv_a  = (const float*)d_in[22]; const float* bv_a  = (const float*)d_in[23];
  const float* Ws_a  = (const float*)d_in[24]; const float* bs_a  = (const float*)d_in[25];
  const float* W_c1  = (const float*)d_in[26]; const float* b_c1  = (const float*)d_in[27];
  const float* W_c2  = (const float*)d_in[28]; const float* b_c2  = (const float*)d_in[29];

  char* ws = (char*)d_ws;
  float* h     = (float*)(ws + 0);                    // 4 MB
  float* hattn = (float*)(ws + (4ull << 20));         // 4 MB (aliased as qkb during mha)
  float* qkv   = (float*)(ws + (8ull << 20));         // 12 MB (img-splitk partials; conv qb later)
  float* y     = (float*)(ws + (20ull << 20));        // 4 MB  (img-splitk partial #4)
  float* f     = (float*)(ws + (24ull << 20));        // 8 MB  (mha O-partials during step 3)
  float* f1    = (float*)(ws + (32ull << 20));        // 2 MB (aliased as vtb during mha)
  int*   indptr= (int*)  (ws + (34ull << 20));
  int*   cursor= (int*)  (ws + (34ull << 20) + 20480);
  int*   esrc  = (int*)  (ws + (34ull << 20) + 40960);  // 1 MB (mha m/s partials during step 3)
  float* part  = (float*)(ws + (34ull << 20) + 40960 + (1ull << 20));
  float* stats = (float*)(ws + (34ull << 20) + 40960 + (1ull << 20) + 65536);

  u16* qkb = (u16*)hattn;   // 4 MB, dead after mha (hattn written at step 4)
  u16* vtb = (u16*)f1;      // 2 MB, dead after mha (f1 written at step 8)

  float* imgpart = qkv;          // 16 MB contiguous (qkv 12MB + y 4MB), free during step 1
  float* Opart   = f;            // 8 MB, free during step 3
  float* mspart  = (float*)esrc; // 256 KB, free during step 3 (CSR built later)

  float* qb   = qkv;                         // 4 MB f32
  u16*   kb16 = (u16*)(ws + (12ull << 20));  // 2 MB bf16
  u16*   vb16 = (u16*)(ws + (14ull << 20));  // 2 MB bf16

  dim3 b256(256);

  // 1. h = img_feat @ W_img^T + b_img   (M=4096,N=256,K=2048) split-K x4
  gemm_img_splitk<<<dim3(64, 4, 4), b256, 0, stream>>>(img, W_img, imgpart);
  gemm_img_reduce<<<1024, b256, 0, stream>>>(imgpart, b_img, h);
  // 2. qkv GEMM writes mha-ready buffers directly: Q|K -> qkb (bf16), V -> vtb (bf16 transposed)
  {
    GArgs ga;
    for (int i = 0; i < 8; i++)
      ga.t[i]  = { W_qkv + (size_t)i * 64 * 256, b_qkv + i * 64, (float*)qkb, i * 64, 512, 1 };
    for (int i = 8; i < 12; i++)
      ga.t[i]  = { W_qkv + (size_t)i * 64 * 256, b_qkv + i * 64, (float*)vtb, (i - 8) * 64, 4096, 2 };
    gemm_mfma<0><<<dim3(64, 12), b256, 0, stream>>>(h, ga, 256);
  }
  // 3. causal MHA (MFMA flash, split-K x (4 waves x 2 blocks)) -> y
  mha_mfma2<<<2048, b256, 0, stream>>>(qkb, vtb, Opart, mspart);
  mha_merge<<<1024, b256, 0, stream>>>(Opart, mspart, y);
  // 4. h_attn = sanitize(y @ W_o^T + b_o)
  {
    GArgs ga;
    for (int i = 0; i < 4; i++)
      ga.t[i] = { W_o + (size_t)i * 64 * 256, b_o + i * 64, hattn, i * 64, 256, 0 };
    gemm_mfma<1><<<dim3(64, 4), b256, 0, stream>>>(y, ga, 256);
  }
  // 5. CSR of video_adj_list grouped by dst
  zero_i32<<<16, b256, 0, stream>>>(cursor, NN);
  hist_dst<<<NE / 256, b256, 0, stream>>>(adj, cursor);
  scan4096<<<1, 1024, 0, stream>>>(cursor, indptr, cursor);
  scatter_edges<<<NE / 256, b256, 0, stream>>>(adj, cursor, esrc);

  // 6. conv path O: q/k/v/skip fused (N=1024,K=256), input h; k,v in bf16
  {
    const float* Wg[4] = { Wq_o, Wk_o, Wv_o, Ws_o };
    const float* bg[4] = { bq_o, bk_o, bv_o, bs_o };
    float*       og[4] = { qb, (float*)kb16, (float*)vb16, y };
    const int    bf[4] = { 0, 1, 1, 0 };
    GArgs ga;
    for (int i = 0; i < 16; i++) {
      int gdx = i >> 2, li = i & 3;
      ga.t[i] = { Wg[gdx] + (size_t)li * 64 * 256, bg[gdx] + li * 64, og[gdx], li * 64, 256, bf[gdx] };
    }
    gemm_mfma<0><<<dim3(64, 16), b256, 0, stream>>>(h, ga, 256);
  }
  conv_agg<<<NN, b256, 0, stream>>>(qb, kb16, vb16, indptr, esrc, y);
  colstats_partial<<<32, b256, 0, stream>>>(y, part);
  colstats_final<<<1, b256, 0, stream>>>(part, stats);
  norm_apply<<<256, b256, 0, stream>>>(y, stats, f, 0);

  // 7. conv path A: same, input hattn
  {
    const float* Wg[4] = { Wq_a, Wk_a, Wv_a, Ws_a };
    const float* bg[4] = { bq_a, bk_a, bv_a, bs_a };
    float*       og[4] = { qb, (float*)kb16, (float*)vb16, y };
    const int    bf[4] = { 0, 1, 1, 0 };
    GArgs ga;
    for (int i = 0; i < 16; i++) {
      int gdx = i >> 2, li = i & 3;
      ga.t[i] = { Wg[gdx] + (size_t)li * 64 * 256, bg[gdx] + li * 64, og[gdx], li * 64, 256, bf[gdx] };
    }
    gemm_mfma<0><<<dim3(64, 16), b256, 0, stream>>>(hattn, ga, 256);
  }
  conv_agg<<<NN, b256, 0, stream>>>(qb, kb16, vb16, indptr, esrc, y);
  colstats_partial<<<32, b256, 0, stream>>>(y, part);
  colstats_final<<<1, b256, 0, stream>>>(part, stats);
  norm_apply<<<256, b256, 0, stream>>>(y, stats, f, 256);

  // 8. f1 = lrelu(f @ W_c1^T + b_c1)   (N=128,K=512)
  {
    GArgs ga;
    for (int i = 0; i < 2; i++)
      ga.t[i] = { W_c1 + (size_t)i * 64 * 512, b_c1 + i * 64, f1, i * 64, 128, 0 };
    gemm_mfma<2><<<dim3(64, 2), b256, 0, stream>>>(f, ga, 512);
  }
  // 9. logits + softmax -> out (f32): [0:8192] logits, [8192:16384] probs
  final_softmax<<<NN / 4, b256, 0, stream>>>(f1, W_c2, b_c2, (float*)d_out);
}

// Round 12
// 312.711 us; speedup vs baseline: 1.4979x; 1.0716x over previous
//
#include <hip/hip_runtime.h>
#include <hip/hip_bf16.h>

typedef unsigned short u16;
typedef unsigned int   u32;
typedef __attribute__((ext_vector_type(8))) short short8;
typedef __attribute__((ext_vector_type(4))) float f32x4;

#define NN 4096        // nodes
#define NE 262144      // edges
#define EMB 256
#define NH 4
#define HD 64

__device__ __forceinline__ float4 load4f(const float* p) { return *reinterpret_cast<const float4*>(p); }
__device__ __forceinline__ float sanitize_f(float v) {
  v = (v != v) ? 0.f : v;                 // nan -> 0
  return fminf(fmaxf(v, -1000.f), 1000.f); // +-inf and clip -> +-1000
}
__device__ __forceinline__ u16 f2b_rne(float x) {          // f32 -> bf16 bits, round-nearest-even
  u32 b = __float_as_uint(x);
  b += 0x7fff + ((b >> 16) & 1);
  return (u16)(b >> 16);
}
__device__ __forceinline__ u32 pack2(float a, float b) {
  return (u32)f2b_rne(a) | ((u32)f2b_rne(b) << 16);
}
__device__ __forceinline__ float b2f(u16 u) { return __uint_as_float((u32)u << 16); }

// ================= generic MFMA GEMM: out = act(A[M,K] @ W^T + bias) =================
struct GTile {
  const float* W;     // 64 weight rows for this tile: [64][K]
  const float* bias;  // 64 entries
  float*       out;   // f32 / bf16 / bf16-transposed
  int          colOff;
  int          ldOut;
  int          obf16; // 0: f32 row-major; 1: bf16 row-major; 2: bf16 TRANSPOSED out[col*ldOut+row]
};
struct GArgs { GTile t[16]; };

// 256 threads = 4 waves; block tile 64x64; wave tile 32x32 (2x2 frags of 16x16x32).
template<int ACT>   // 0 none, 1 sanitize, 2 lrelu(0.2)
__global__ __launch_bounds__(256) void gemm_mfma(const float* __restrict__ A, const GArgs ga, int K) {
  __shared__ short As[64 * 40];
  __shared__ short Bs[64 * 40];
  const int t = threadIdx.x;
  const int bm = blockIdx.x * 64;
  const GTile tl = ga.t[blockIdx.y];
  const int w = t >> 6, l = t & 63, g = l >> 4, r16 = l & 15;
  const int wr = w >> 1, wc = w & 1;
  const int lrow = t >> 2, lseg = (t & 3) * 8;

  const float* Ap = A + (size_t)(bm + lrow) * K + lseg;
  const float* Wp = tl.W + (size_t)lrow * K + lseg;

  f32x4 acc[2][2] = {{{0.f,0.f,0.f,0.f},{0.f,0.f,0.f,0.f}},{{0.f,0.f,0.f,0.f},{0.f,0.f,0.f,0.f}}};
  for (int k0 = 0; k0 < K; k0 += 32) {
    float4 a0 = load4f(Ap + k0), a1 = load4f(Ap + k0 + 4);
    float4 b0 = load4f(Wp + k0), b1 = load4f(Wp + k0 + 4);
    __syncthreads();
    *(uint4*)&As[lrow * 40 + lseg] =
        make_uint4(pack2(a0.x,a0.y), pack2(a0.z,a0.w), pack2(a1.x,a1.y), pack2(a1.z,a1.w));
    *(uint4*)&Bs[lrow * 40 + lseg] =
        make_uint4(pack2(b0.x,b0.y), pack2(b0.z,b0.w), pack2(b1.x,b1.y), pack2(b1.z,b1.w));
    __syncthreads();
    short8 af0 = *(const short8*)&As[(wr*32 +      r16) * 40 + 8*g];
    short8 af1 = *(const short8*)&As[(wr*32 + 16 + r16) * 40 + 8*g];
    short8 bf0 = *(const short8*)&Bs[(wc*32 +      r16) * 40 + 8*g];
    short8 bf1 = *(const short8*)&Bs[(wc*32 + 16 + r16) * 40 + 8*g];
    acc[0][0] = __builtin_amdgcn_mfma_f32_16x16x32_bf16(af0, bf0, acc[0][0], 0, 0, 0);
    acc[0][1] = __builtin_amdgcn_mfma_f32_16x16x32_bf16(af0, bf1, acc[0][1], 0, 0, 0);
    acc[1][0] = __builtin_amdgcn_mfma_f32_16x16x32_bf16(af1, bf0, acc[1][0], 0, 0, 0);
    acc[1][1] = __builtin_amdgcn_mfma_f32_16x16x32_bf16(af1, bf1, acc[1][1], 0, 0, 0);
  }
  const float bj[2] = { tl.bias[wc*32 + r16], tl.bias[wc*32 + 16 + r16] };
#pragma unroll
  for (int i = 0; i < 2; i++) {
#pragma unroll
    for (int j = 0; j < 2; j++) {
      int col  = tl.colOff + wc*32 + 16*j + r16;
      int row0 = bm + wr*32 + 16*i + 4*g;
      if (tl.obf16 == 2) {           // transposed bf16: out[col*ldOut + row], 4 consecutive rows
        u16 pk[4];
#pragma unroll
        for (int r = 0; r < 4; r++) pk[r] = f2b_rne(acc[i][j][r] + bj[j]);
        *(uint2*)((u16*)tl.out + (size_t)col * tl.ldOut + row0) = *(uint2*)pk;
      } else {
#pragma unroll
        for (int r = 0; r < 4; r++) {
          float v = acc[i][j][r] + bj[j];
          if (ACT == 1) v = sanitize_f(v);
          if (ACT == 2) v = (v > 0.f) ? v : 0.2f * v;
          if (tl.obf16) ((u16*)tl.out)[(size_t)(row0 + r) * tl.ldOut + col] = f2b_rne(v);
          else          tl.out[(size_t)(row0 + r) * tl.ldOut + col] = v;
        }
      }
    }
  }
}

// ---------------- img GEMM split-K: K=2048 over 4 z-blocks of 512 ----------------
__global__ __launch_bounds__(256) void gemm_img_splitk(const float* __restrict__ A, const float* __restrict__ W,
                                                       float* __restrict__ part) {
  __shared__ short As[64 * 40];
  __shared__ short Bs[64 * 40];
  const int t = threadIdx.x;
  const int bm = blockIdx.x * 64, bn = blockIdx.y * 64, ks = blockIdx.z;
  const int w = t >> 6, l = t & 63, g = l >> 4, r16 = l & 15;
  const int wr = w >> 1, wc = w & 1;
  const int lrow = t >> 2, lseg = (t & 3) * 8;

  const float* Ap = A + (size_t)(bm + lrow) * 2048 + ks * 512 + lseg;
  const float* Wp = W + (size_t)(bn + lrow) * 2048 + ks * 512 + lseg;

  f32x4 acc[2][2] = {{{0.f,0.f,0.f,0.f},{0.f,0.f,0.f,0.f}},{{0.f,0.f,0.f,0.f},{0.f,0.f,0.f,0.f}}};
  for (int k0 = 0; k0 < 512; k0 += 32) {
    float4 a0 = load4f(Ap + k0), a1 = load4f(Ap + k0 + 4);
    float4 b0 = load4f(Wp + k0), b1 = load4f(Wp + k0 + 4);
    __syncthreads();
    *(uint4*)&As[lrow * 40 + lseg] =
        make_uint4(pack2(a0.x,a0.y), pack2(a0.z,a0.w), pack2(a1.x,a1.y), pack2(a1.z,a1.w));
    *(uint4*)&Bs[lrow * 40 + lseg] =
        make_uint4(pack2(b0.x,b0.y), pack2(b0.z,b0.w), pack2(b1.x,b1.y), pack2(b1.z,b1.w));
    __syncthreads();
    short8 af0 = *(const short8*)&As[(wr*32 +      r16) * 40 + 8*g];
    short8 af1 = *(const short8*)&As[(wr*32 + 16 + r16) * 40 + 8*g];
    short8 bf0 = *(const short8*)&Bs[(wc*32 +      r16) * 40 + 8*g];
    short8 bf1 = *(const short8*)&Bs[(wc*32 + 16 + r16) * 40 + 8*g];
    acc[0][0] = __builtin_amdgcn_mfma_f32_16x16x32_bf16(af0, bf0, acc[0][0], 0, 0, 0);
    acc[0][1] = __builtin_amdgcn_mfma_f32_16x16x32_bf16(af0, bf1, acc[0][1], 0, 0, 0);
    acc[1][0] = __builtin_amdgcn_mfma_f32_16x16x32_bf16(af1, bf0, acc[1][0], 0, 0, 0);
    acc[1][1] = __builtin_amdgcn_mfma_f32_16x16x32_bf16(af1, bf1, acc[1][1], 0, 0, 0);
  }
  float* op = part + (size_t)ks * (NN * 256);
#pragma unroll
  for (int i = 0; i < 2; i++) {
#pragma unroll
    for (int j = 0; j < 2; j++) {
      int col = bn + wc*32 + 16*j + r16;
#pragma unroll
      for (int r = 0; r < 4; r++) {
        int row = bm + wr*32 + 16*i + 4*g + r;
        op[(size_t)row * 256 + col] = acc[i][j][r];
      }
    }
  }
}
__global__ __launch_bounds__(256) void gemm_img_reduce(const float* __restrict__ part,
                                                       const float* __restrict__ bias,
                                                       float* __restrict__ h) {
  int idx = blockIdx.x * 256 + threadIdx.x;   // 262144 threads, 4 floats each
  int row = idx >> 6, c4 = (idx & 63) * 4;
  size_t o = (size_t)row * 256 + c4;
  float4 s = load4f(part + o);
  float4 p1 = load4f(part + 1048576 + o);
  float4 p2 = load4f(part + 2097152 + o);
  float4 p3 = load4f(part + 3145728 + o);
  float4 bb = load4f(bias + c4);
  s.x += p1.x + p2.x + p3.x + bb.x;
  s.y += p1.y + p2.y + p3.y + bb.y;
  s.z += p1.z + p2.z + p3.z + bb.z;
  s.w += p1.w + p2.w + p3.w + bb.w;
  *(float4*)&h[o] = s;
}

// ---------------- causal MHA v3: 64-q blocks, LDS-shared K/V, pipelined, split-K x2 ----------------
// grid 512: ks = bid&1, h = (bid>>1)&3, T = 63-(bid>>3) (64-row q-tile; long first).
// 4 waves own disjoint 16-q sub-tiles; all share the LDS K/V tile. Partials merged by mha_merge3.
#define KSTR 72   // LDS row stride in shorts (64 data + 8 pad; 2-way reads = free)
__global__ __launch_bounds__(256, 4) void mha_mfma3(const u16* __restrict__ qkb, const u16* __restrict__ vtb,
                                                    float* __restrict__ Opart, float* __restrict__ mspart) {
  __shared__ u16 Ks[64 * KSTR];
  __shared__ u16 Vs[64 * KSTR];
  const int bid = blockIdx.x;
  const int ks  = bid & 1;
  const int hh  = (bid >> 1) & 3;
  const int T   = 63 - (bid >> 3);
  const int q0  = T * 64;
  const int t   = threadIdx.x;
  const int w   = t >> 6, l = t & 63, g = l >> 4, r16 = l & 15;
  const int hofs = hh * 64;
  const int lrow = t >> 3, lc8 = (t & 7) * 8;   // staging: 32 rows x 64 cols per pass

  // Q B-fragments for this wave's 16 q rows (col=q=r16, dims 8g+j / 32+8g+j)
  const u16* qrow = qkb + (size_t)(q0 + 16 * w + r16) * 512 + hofs;
  short8 Qf0 = *(const short8*)&qrow[8 * g];
  short8 Qf1 = *(const short8*)&qrow[32 + 8 * g];

  f32x4 O0 = {0.f,0.f,0.f,0.f}, O1 = O0, O2 = O0, O3 = O0;
  float m = -INFINITY, ssum = 0.f;

  uint4 rk0, rk1, rv0, rv1;
  if (ks <= T) {
    int k0 = ks * 64;
    rk0 = *(const uint4*)&qkb[(size_t)(k0 + lrow) * 512 + 256 + hofs + lc8];
    rk1 = *(const uint4*)&qkb[(size_t)(k0 + 32 + lrow) * 512 + 256 + hofs + lc8];
    rv0 = *(const uint4*)&vtb[(size_t)(hofs + lrow) * 4096 + k0 + lc8];
    rv1 = *(const uint4*)&vtb[(size_t)(hofs + 32 + lrow) * 4096 + k0 + lc8];
  }
  for (int kt = ks; kt <= T; kt += 2) {
    __syncthreads();                       // previous compute done reading LDS
    *(uint4*)&Ks[lrow * KSTR + lc8]        = rk0;
    *(uint4*)&Ks[(32 + lrow) * KSTR + lc8] = rk1;
    *(uint4*)&Vs[lrow * KSTR + lc8]        = rv0;
    *(uint4*)&Vs[(32 + lrow) * KSTR + lc8] = rv1;
    __syncthreads();
    if (kt + 2 <= T) {                     // prefetch next stripe tile (hidden under compute)
      int k2 = (kt + 2) * 64;
      rk0 = *(const uint4*)&qkb[(size_t)(k2 + lrow) * 512 + 256 + hofs + lc8];
      rk1 = *(const uint4*)&qkb[(size_t)(k2 + 32 + lrow) * 512 + 256 + hofs + lc8];
      rv0 = *(const uint4*)&vtb[(size_t)(hofs + lrow) * 4096 + k2 + lc8];
      rv1 = *(const uint4*)&vtb[(size_t)(hofs + 32 + lrow) * 4096 + k2 + lc8];
    }
    // ---- S^T[64k][16q] from LDS K + reg Q ----
    f32x4 S0 = {0.f,0.f,0.f,0.f}, S1 = S0, S2 = S0, S3 = S0;
    {
      short8 a0 = *(const short8*)&Ks[(r16)      * KSTR + 8*g];
      short8 a1 = *(const short8*)&Ks[(16 + r16) * KSTR + 8*g];
      short8 a2 = *(const short8*)&Ks[(32 + r16) * KSTR + 8*g];
      short8 a3 = *(const short8*)&Ks[(48 + r16) * KSTR + 8*g];
      S0 = __builtin_amdgcn_mfma_f32_16x16x32_bf16(a0, Qf0, S0, 0, 0, 0);
      S1 = __builtin_amdgcn_mfma_f32_16x16x32_bf16(a1, Qf0, S1, 0, 0, 0);
      S2 = __builtin_amdgcn_mfma_f32_16x16x32_bf16(a2, Qf0, S2, 0, 0, 0);
      S3 = __builtin_amdgcn_mfma_f32_16x16x32_bf16(a3, Qf0, S3, 0, 0, 0);
      short8 b0 = *(const short8*)&Ks[(r16)      * KSTR + 32 + 8*g];
      short8 b1 = *(const short8*)&Ks[(16 + r16) * KSTR + 32 + 8*g];
      short8 b2 = *(const short8*)&Ks[(32 + r16) * KSTR + 32 + 8*g];
      short8 b3 = *(const short8*)&Ks[(48 + r16) * KSTR + 32 + 8*g];
      S0 = __builtin_amdgcn_mfma_f32_16x16x32_bf16(b0, Qf1, S0, 0, 0, 0);
      S1 = __builtin_amdgcn_mfma_f32_16x16x32_bf16(b1, Qf1, S1, 0, 0, 0);
      S2 = __builtin_amdgcn_mfma_f32_16x16x32_bf16(b2, Qf1, S2, 0, 0, 0);
      S3 = __builtin_amdgcn_mfma_f32_16x16x32_bf16(b3, Qf1, S3, 0, 0, 0);
    }
    float sc[4][4];
#pragma unroll
    for (int r = 0; r < 4; r++) {
      sc[0][r] = S0[r] * 0.125f; sc[1][r] = S1[r] * 0.125f;
      sc[2][r] = S2[r] * 0.125f; sc[3][r] = S3[r] * 0.125f;
    }
    if (kt == T) {    // causal mask: k_local 16mb+4g+r vs q_local 16w+r16 (same 64-block)
#pragma unroll
      for (int mb = 0; mb < 4; mb++)
#pragma unroll
        for (int r = 0; r < 4; r++)
          if (16 * mb + 4 * g + r > 16 * w + r16) sc[mb][r] = -INFINITY;
    }
    float tm = sc[0][0];
#pragma unroll
    for (int mb = 0; mb < 4; mb++)
#pragma unroll
      for (int r = 0; r < 4; r++) tm = fmaxf(tm, sc[mb][r]);
    tm = fmaxf(tm, __shfl_xor(tm, 16));
    tm = fmaxf(tm, __shfl_xor(tm, 32));
    float mn = fmaxf(m, tm);                  // tm finite (diagonal survives) -> mn finite
    float ef = __expf(m - mn);
    float pv[4][4];
    float ps = 0.f;
#pragma unroll
    for (int mb = 0; mb < 4; mb++)
#pragma unroll
      for (int r = 0; r < 4; r++) { pv[mb][r] = __expf(sc[mb][r] - mn); ps += pv[mb][r]; }
    ps += __shfl_xor(ps, 16);
    ps += __shfl_xor(ps, 32);
    ssum = ssum * ef + ps;
    m = mn;
#pragma unroll
    for (int r = 0; r < 4; r++) {
      float efr = __shfl(ef, 4 * g + r);
      O0[r] *= efr; O1[r] *= efr; O2[r] *= efr; O3[r] *= efr;
    }
    // ---- P A-fragments via packed shuffles (16) ----
    u32 pk[2][4];
#pragma unroll
    for (int c = 0; c < 2; c++)
#pragma unroll
      for (int rs = 0; rs < 4; rs++) pk[c][rs] = pack2(pv[2 * c][rs], pv[2 * c + 1][rs]);
    short8 ap[2];
#pragma unroll
    for (int c = 0; c < 2; c++) {
#pragma unroll
      for (int jb = 0; jb < 2; jb++) {
        int x = 2 * g + jb;
        int hi = x >> 2;
        int src = r16 + 16 * (x & 3);
#pragma unroll
        for (int rs = 0; rs < 4; rs++) {
          u32 v = __shfl(pk[c][rs], src);
          ap[c][jb * 4 + rs] = (short)(hi ? (v >> 16) : (v & 0xffff));
        }
      }
    }
    // ---- O += P @ V from LDS V^T ----
    {
      short8 V00 = *(const short8*)&Vs[(r16)      * KSTR + 8*g];
      short8 V10 = *(const short8*)&Vs[(16 + r16) * KSTR + 8*g];
      short8 V20 = *(const short8*)&Vs[(32 + r16) * KSTR + 8*g];
      short8 V30 = *(const short8*)&Vs[(48 + r16) * KSTR + 8*g];
      O0 = __builtin_amdgcn_mfma_f32_16x16x32_bf16(ap[0], V00, O0, 0, 0, 0);
      O1 = __builtin_amdgcn_mfma_f32_16x16x32_bf16(ap[0], V10, O1, 0, 0, 0);
      O2 = __builtin_amdgcn_mfma_f32_16x16x32_bf16(ap[0], V20, O2, 0, 0, 0);
      O3 = __builtin_amdgcn_mfma_f32_16x16x32_bf16(ap[0], V30, O3, 0, 0, 0);
      short8 V01 = *(const short8*)&Vs[(r16)      * KSTR + 32 + 8*g];
      short8 V11 = *(const short8*)&Vs[(16 + r16) * KSTR + 32 + 8*g];
      short8 V21 = *(const short8*)&Vs[(32 + r16) * KSTR + 32 + 8*g];
      short8 V31 = *(const short8*)&Vs[(48 + r16) * KSTR + 32 + 8*g];
      O0 = __builtin_amdgcn_mfma_f32_16x16x32_bf16(ap[1], V01, O0, 0, 0, 0);
      O1 = __builtin_amdgcn_mfma_f32_16x16x32_bf16(ap[1], V11, O1, 0, 0, 0);
      O2 = __builtin_amdgcn_mfma_f32_16x16x32_bf16(ap[1], V21, O2, 0, 0, 0);
      O3 = __builtin_amdgcn_mfma_f32_16x16x32_bf16(ap[1], V31, O3, 0, 0, 0);
    }
  }

  // ---- write unnormalized wave partials (waves own disjoint q rows; no intra-block merge) ----
  size_t ob = (size_t)bid * 4096;
#pragma unroll
  for (int r = 0; r < 4; r++) {
    int q = 16 * w + 4 * g + r;
    Opart[ob + q * 64 + r16]      = O0[r];
    Opart[ob + q * 64 + 16 + r16] = O1[r];
    Opart[ob + q * 64 + 32 + r16] = O2[r];
    Opart[ob + q * 64 + 48 + r16] = O3[r];
  }
  if (l < 16) {
    mspart[bid * 128 + 16 * w + l]      = m;
    mspart[bid * 128 + 64 + 16 * w + l] = ssum;
  }
}

// merge 2 stripe-partials -> normalized output. grid 256: T = mb>>2, h = mb&3.
__global__ __launch_bounds__(256) void mha_merge3(const float* __restrict__ Opart, const float* __restrict__ mspart,
                                                  float* __restrict__ out) {
  int mb = blockIdx.x;
  int h = mb & 3, T = mb >> 2;
  int bid0 = ((63 - T) << 3) | (h << 1);
  int bid1 = bid0 | 1;
  int t = threadIdx.x;
  int q = t >> 2, dbase = (t & 3) * 16;
  float m0 = mspart[bid0 * 128 + q],      m1 = mspart[bid1 * 128 + q];
  float s0 = mspart[bid0 * 128 + 64 + q], s1 = mspart[bid1 * 128 + 64 + q];
  float M = fmaxf(m0, m1);                 // m0 always finite (stripe 0 has kt=0)
  float e0 = __expf(m0 - M);
  float e1 = (m1 == -INFINITY) ? 0.f : __expf(m1 - M);
  float inv = 1.f / (e0 * s0 + e1 * s1);
  const float* A = Opart + (size_t)bid0 * 4096 + q * 64 + dbase;
  const float* B = Opart + (size_t)bid1 * 4096 + q * 64 + dbase;
  float* Y = out + (size_t)(T * 64 + q) * EMB + h * 64 + dbase;
#pragma unroll
  for (int i = 0; i < 4; i++) {
    float4 a = load4f(A + 4 * i), b = load4f(B + 4 * i);
    float4 r;
    r.x = (e0 * a.x + e1 * b.x) * inv;
    r.y = (e0 * a.y + e1 * b.y) * inv;
    r.z = (e0 * a.z + e1 * b.z) * inv;
    r.w = (e0 * a.w + e1 * b.w) * inv;
    *(float4*)(Y + 4 * i) = r;
  }
}

// ---------------- CSR build ----------------
__global__ void zero_i32(int* p, int n) {
  int i = blockIdx.x * 256 + threadIdx.x;
  if (i < n) p[i] = 0;
}
__global__ void hist_dst(const int* __restrict__ adj, int* __restrict__ cnt) {
  int e = blockIdx.x * 256 + threadIdx.x;
  if (e < NE) atomicAdd(&cnt[adj[NE + e]], 1);
}
__global__ __launch_bounds__(1024) void scan4096(const int* __restrict__ cnt, int* __restrict__ indptr,
                                                 int* __restrict__ cursor) {
  int t = threadIdx.x;
  int4 c = *reinterpret_cast<const int4*>(cnt + t * 4);
  int s0 = c.x, s1 = s0 + c.y, s2 = s1 + c.z, s3 = s2 + c.w;
  int lane = t & 63, w = t >> 6;
  int x = s3;
#pragma unroll
  for (int off = 1; off < 64; off <<= 1) {
    int y = __shfl_up(x, off);
    if (lane >= off) x += y;
  }
  __shared__ int wsum[16];
  if (lane == 63) wsum[w] = x;
  __syncthreads();
  if (t == 0) {
    int acc = 0;
    for (int i = 0; i < 16; i++) { int tv = wsum[i]; wsum[i] = acc; acc += tv; }
  }
  __syncthreads();
  int b = wsum[w] + x - s3;
  indptr[t*4+0] = b;      indptr[t*4+1] = b + s0;
  indptr[t*4+2] = b + s1; indptr[t*4+3] = b + s2;
  cursor[t*4+0] = b;      cursor[t*4+1] = b + s0;
  cursor[t*4+2] = b + s1; cursor[t*4+3] = b + s2;
  if (t == 1023) indptr[4096] = b + s3;
}
__global__ void scatter_edges(const int* __restrict__ adj, int* __restrict__ cursor, int* __restrict__ esrc) {
  int e = blockIdx.x * 256 + threadIdx.x;
  if (e < NE) {
    int dst = adj[NE + e];
    int pos = atomicAdd(&cursor[dst], 1);
    esrc[pos] = adj[e];
  }
}

// ---------------- TransformerConv aggregation (bf16 K/V, LDS-staged P, 4-way ILP) ----------------
__global__ __launch_bounds__(256, 4) void conv_agg(const float* __restrict__ qb, const u16* __restrict__ kb,
                                                   const u16* __restrict__ vb, const int* __restrict__ indptr,
                                                   const int* __restrict__ esrc, float* __restrict__ y) {
  __shared__ float q_s[EMB];
  __shared__ float p_s[NH][64];
  __shared__ int   s_s[64];
  int n = blockIdx.x;
  int tid = threadIdx.x;
  int h = tid >> 6, lane = tid & 63;
  q_s[tid] = qb[(size_t)n * EMB + tid] * 0.125f;   // fold 1/sqrt(D) into q
  int start = indptr[n], end = indptr[n + 1];
  __syncthreads();
  const float* qh = &q_s[h * HD];
  float m = -INFINITY, s = 0.f;
  float o0 = 0.f, o1 = 0.f, o2 = 0.f, o3 = 0.f;
  for (int p0 = start; p0 < end; p0 += 64) {
    int nk = end - p0; if (nk > 64) nk = 64;
    float sc = -INFINITY;
    int src = 0;
    if (lane < nk) {
      src = esrc[p0 + lane];
      const u16* kr = kb + (size_t)src * EMB + h * HD;
      float a0 = 0.f, a1 = 0.f, a2 = 0.f, a3 = 0.f;
#pragma unroll
      for (int d = 0; d < HD; d += 8) {
        short8 k8 = *(const short8*)&kr[d];
        a0 = fmaf(b2f((u16)k8[0]), qh[d+0], a0);
        a1 = fmaf(b2f((u16)k8[1]), qh[d+1], a1);
        a2 = fmaf(b2f((u16)k8[2]), qh[d+2], a2);
        a3 = fmaf(b2f((u16)k8[3]), qh[d+3], a3);
        a0 = fmaf(b2f((u16)k8[4]), qh[d+4], a0);
        a1 = fmaf(b2f((u16)k8[5]), qh[d+5], a1);
        a2 = fmaf(b2f((u16)k8[6]), qh[d+6], a2);
        a3 = fmaf(b2f((u16)k8[7]), qh[d+7], a3);
      }
      sc = (a0 + a1) + (a2 + a3);
    }
    float bm = sc;
#pragma unroll
    for (int off = 32; off; off >>= 1) bm = fmaxf(bm, __shfl_xor(bm, off));
    float mn = fmaxf(m, bm);
    float ef = __expf(m - mn);              // 0 on first chunk
    float p = (lane < nk) ? __expf(sc - mn) : 0.f;
    float ps = p;
#pragma unroll
    for (int off = 32; off; off >>= 1) ps += __shfl_xor(ps, off);
    s = s * ef + ps;
    m = mn;
    o0 *= ef; o1 *= ef; o2 *= ef; o3 *= ef;
    p_s[h][lane] = p;
    if (h == 0) s_s[lane] = (lane < nk) ? src : 0;  // src identical across heads
    __syncthreads();
    const u16* vcol = vb + h * HD + lane;
    int nk4 = (nk + 3) & ~3;
    for (int jj = 0; jj < nk4; jj += 4) {
      float pa = p_s[h][jj],   pb = p_s[h][jj+1];
      float pc = p_s[h][jj+2], pd = p_s[h][jj+3];
      int sa = s_s[jj], sb = s_s[jj+1], scx = s_s[jj+2], sd = s_s[jj+3];
      o0 = fmaf(pa, b2f(vcol[(size_t)sa  * EMB]), o0);
      o1 = fmaf(pb, b2f(vcol[(size_t)sb  * EMB]), o1);
      o2 = fmaf(pc, b2f(vcol[(size_t)scx * EMB]), o2);
      o3 = fmaf(pd, b2f(vcol[(size_t)sd  * EMB]), o3);
    }
    __syncthreads();
  }
  float o = (o0 + o1) + (o2 + o3);
  float agg = o / (s + 1e-16f);
  y[(size_t)n * EMB + h * HD + lane] += agg;
}

// ---------------- instance norm + lrelu + sanitize ----------------
__global__ __launch_bounds__(256) void colstats_partial(const float* __restrict__ y, float* __restrict__ part) {
  int c = threadIdx.x;
  int r0 = blockIdx.x * 128;
  float s = 0.f, q = 0.f;
  for (int r = r0; r < r0 + 128; r++) {
    float v = y[(size_t)r * EMB + c];
    s += v; q = fmaf(v, v, q);
  }
  part[blockIdx.x * 512 + c] = s;
  part[blockIdx.x * 512 + 256 + c] = q;
}
__global__ __launch_bounds__(256) void colstats_final(const float* __restrict__ part, float* __restrict__ stats) {
  int c = threadIdx.x;
  float s = 0.f, q = 0.f;
  for (int b = 0; b < 32; b++) { s += part[b * 512 + c]; q += part[b * 512 + 256 + c]; }
  float mean = s * (1.f / 4096.f);
  float var  = q * (1.f / 4096.f) - mean * mean;
  stats[c] = mean;
  stats[256 + c] = rsqrtf(var + 1e-5f);
}
__global__ __launch_bounds__(256) void norm_apply(const float* __restrict__ y, const float* __restrict__ stats,
                                                  float* __restrict__ f, int colOff) {
  int c = threadIdx.x;
  float mean = stats[c], rstd = stats[256 + c];
  int r0 = blockIdx.x * 16;
  for (int r = r0; r < r0 + 16; r++) {
    float v = (y[(size_t)r * EMB + c] - mean) * rstd;
    v = (v > 0.f) ? v : 0.2f * v;
    v = sanitize_f(v);
    f[(size_t)r * 512 + colOff + c] = v;
  }
}

// ---------------- classifier tail ----------------
__global__ __launch_bounds__(256) void final_softmax(const float* __restrict__ f1, const float* __restrict__ W2,
                                                     const float* __restrict__ b2, float* __restrict__ out) {
  int w = threadIdx.x >> 6, lane = threadIdx.x & 63;
  int row = blockIdx.x * 4 + w;
  const float* fr = f1 + (size_t)row * 128;
  float x0 = fr[lane], x1 = fr[lane + 64];
  float p0 = x0 * W2[lane]       + x1 * W2[64 + lane];
  float p1 = x0 * W2[128 + lane] + x1 * W2[192 + lane];
#pragma unroll
  for (int off = 32; off; off >>= 1) { p0 += __shfl_xor(p0, off); p1 += __shfl_xor(p1, off); }
  if (lane == 0) {
    float l0 = p0 + b2[0], l1 = p1 + b2[1];
    float mx = fmaxf(l0, l1);
    float e0 = __expf(l0 - mx), e1 = __expf(l1 - mx);
    float inv = 1.f / (e0 + e1);
    out[(size_t)row * 2 + 0] = l0;
    out[(size_t)row * 2 + 1] = l1;
    out[8192 + (size_t)row * 2 + 0] = e0 * inv;
    out[8192 + (size_t)row * 2 + 1] = e1 * inv;
  }
}

extern "C" void kernel_launch(void* const* d_in, const int* in_sizes, int n_in,
                              void* d_out, int out_size, void* d_ws, size_t ws_size,
                              hipStream_t stream) {
  const float* img   = (const float*)d_in[2];
  const int*   adj   = (const int*)d_in[3];
  const float* W_img = (const float*)d_in[4];  const float* b_img = (const float*)d_in[5];
  const float* W_qkv = (const float*)d_in[6];  const float* b_qkv = (const float*)d_in[7];
  const float* W_o   = (const float*)d_in[8];  const float* b_o   = (const float*)d_in[9];
  const float* Wq_o  = (const float*)d_in[10]; const float* bq_o  = (const float*)d_in[11];
  const float* Wk_o  = (const float*)d_in[12]; const float* bk_o  = (const float*)d_in[13];
  const float* Wv_o  = (const float*)d_in[14]; const float* bv_o  = (const float*)d_in[15];
  const float* Ws_o  = (const float*)d_in[16]; const float* bs_o  = (const float*)d_in[17];
  const float* Wq_a  = (const float*)d_in[18]; const float* bq_a  = (const float*)d_in[19];
  const float* Wk_a  = (const float*)d_in[20]; const float* bk_a  = (const float*)d_in[21];
  const float* Wv_a  = (const float*)d_in[22]; const float* bv_a  = (const float*)d_in[23];
  const float* Ws_a  = (const float*)d_in[24]; const float* bs_a  = (const float*)d_in[25];
  const float* W_c1  = (const float*)d_in[26]; const float* b_c1  = (const float*)d_in[27];
  const float* W_c2  = (const float*)d_in[28]; const float* b_c2  = (const float*)d_in[29];

  char* ws = (char*)d_ws;
  float* h     = (float*)(ws + 0);                    // 4 MB
  float* hattn = (float*)(ws + (4ull << 20));         // 4 MB (aliased as qkb during mha)
  float* qkv   = (float*)(ws + (8ull << 20));         // 12 MB (img-splitk partials; conv qb later)
  float* y     = (float*)(ws + (20ull << 20));        // 4 MB  (img-splitk partial #4)
  float* f     = (float*)(ws + (24ull << 20));        // 8 MB  (mha O-partials during step 3)
  float* f1    = (float*)(ws + (32ull << 20));        // 2 MB (aliased as vtb during mha)
  int*   indptr= (int*)  (ws + (34ull << 20));
  int*   cursor= (int*)  (ws + (34ull << 20) + 20480);
  int*   esrc  = (int*)  (ws + (34ull << 20) + 40960);  // 1 MB (mha m/s partials during step 3)
  float* part  = (float*)(ws + (34ull << 20) + 40960 + (1ull << 20));
  float* stats = (float*)(ws + (34ull << 20) + 40960 + (1ull << 20) + 65536);

  u16* qkb = (u16*)hattn;   // 4 MB, dead after mha (hattn written at step 4)
  u16* vtb = (u16*)f1;      // 2 MB, dead after mha (f1 written at step 8)

  float* imgpart = qkv;          // 16 MB contiguous (qkv 12MB + y 4MB), free during step 1
  float* Opart   = f;            // 8 MB (512 blocks x 4096 floats), free during step 3
  float* mspart  = (float*)esrc; // 256 KB, free during step 3 (CSR built later)

  float* qb   = qkv;                         // 4 MB f32
  u16*   kb16 = (u16*)(ws + (12ull << 20));  // 2 MB bf16
  u16*   vb16 = (u16*)(ws + (14ull << 20));  // 2 MB bf16

  dim3 b256(256);

  // 1. h = img_feat @ W_img^T + b_img   (M=4096,N=256,K=2048) split-K x4
  gemm_img_splitk<<<dim3(64, 4, 4), b256, 0, stream>>>(img, W_img, imgpart);
  gemm_img_reduce<<<1024, b256, 0, stream>>>(imgpart, b_img, h);
  // 2. qkv GEMM writes mha-ready buffers directly: Q|K -> qkb (bf16), V -> vtb (bf16 transposed)
  {
    GArgs ga;
    for (int i = 0; i < 8; i++)
      ga.t[i]  = { W_qkv + (size_t)i * 64 * 256, b_qkv + i * 64, (float*)qkb, i * 64, 512, 1 };
    for (int i = 8; i < 12; i++)
      ga.t[i]  = { W_qkv + (size_t)i * 64 * 256, b_qkv + i * 64, (float*)vtb, (i - 8) * 64, 4096, 2 };
    gemm_mfma<0><<<dim3(64, 12), b256, 0, stream>>>(h, ga, 256);
  }
  // 3. causal MHA v3 (64q blocks, LDS K/V, split-K x2) -> y
  mha_mfma3<<<512, b256, 0, stream>>>(qkb, vtb, Opart, mspart);
  mha_merge3<<<256, b256, 0, stream>>>(Opart, mspart, y);
  // 4. h_attn = sanitize(y @ W_o^T + b_o)
  {
    GArgs ga;
    for (int i = 0; i < 4; i++)
      ga.t[i] = { W_o + (size_t)i * 64 * 256, b_o + i * 64, hattn, i * 64, 256, 0 };
    gemm_mfma<1><<<dim3(64, 4), b256, 0, stream>>>(y, ga, 256);
  }
  // 5. CSR of video_adj_list grouped by dst
  zero_i32<<<16, b256, 0, stream>>>(cursor, NN);
  hist_dst<<<NE / 256, b256, 0, stream>>>(adj, cursor);
  scan4096<<<1, 1024, 0, stream>>>(cursor, indptr, cursor);
  scatter_edges<<<NE / 256, b256, 0, stream>>>(adj, cursor, esrc);

  // 6. conv path O: q/k/v/skip fused (N=1024,K=256), input h; k,v in bf16
  {
    const float* Wg[4] = { Wq_o, Wk_o, Wv_o, Ws_o };
    const float* bg[4] = { bq_o, bk_o, bv_o, bs_o };
    float*       og[4] = { qb, (float*)kb16, (float*)vb16, y };
    const int    bf[4] = { 0, 1, 1, 0 };
    GArgs ga;
    for (int i = 0; i < 16; i++) {
      int gdx = i >> 2, li = i & 3;
      ga.t[i] = { Wg[gdx] + (size_t)li * 64 * 256, bg[gdx] + li * 64, og[gdx], li * 64, 256, bf[gdx] };
    }
    gemm_mfma<0><<<dim3(64, 16), b256, 0, stream>>>(h, ga, 256);
  }
  conv_agg<<<NN, b256, 0, stream>>>(qb, kb16, vb16, indptr, esrc, y);
  colstats_partial<<<32, b256, 0, stream>>>(y, part);
  colstats_final<<<1, b256, 0, stream>>>(part, stats);
  norm_apply<<<256, b256, 0, stream>>>(y, stats, f, 0);

  // 7. conv path A: same, input hattn
  {
    const float* Wg[4] = { Wq_a, Wk_a, Wv_a, Ws_a };
    const float* bg[4] = { bq_a, bk_a, bv_a, bs_a };
    float*       og[4] = { qb, (float*)kb16, (float*)vb16, y };
    const int    bf[4] = { 0, 1, 1, 0 };
    GArgs ga;
    for (int i = 0; i < 16; i++) {
      int gdx = i >> 2, li = i & 3;
      ga.t[i] = { Wg[gdx] + (size_t)li * 64 * 256, bg[gdx] + li * 64, og[gdx], li * 64, 256, bf[gdx] };
    }
    gemm_mfma<0><<<dim3(64, 16), b256, 0, stream>>>(hattn, ga, 256);
  }
  conv_agg<<<NN, b256, 0, stream>>>(qb, kb16, vb16, indptr, esrc, y);
  colstats_partial<<<32, b256, 0, stream>>>(y, part);
  colstats_final<<<1, b256, 0, stream>>>(part, stats);
  norm_apply<<<256, b256, 0, stream>>>(y, stats, f, 256);

  // 8. f1 = lrelu(f @ W_c1^T + b_c1)   (N=128,K=512)
  {
    GArgs ga;
    for (int i = 0; i < 2; i++)
      ga.t[i] = { W_c1 + (size_t)i * 64 * 512, b_c1 + i * 64, f1, i * 64, 128, 0 };
    gemm_mfma<2><<<dim3(64, 2), b256, 0, stream>>>(f, ga, 512);
  }
  // 9. logits + softmax -> out (f32): [0:8192] logits, [8192:16384] probs
  final_softmax<<<NN / 4, b256, 0, stream>>>(f1, W_c2, b_c2, (float*)d_out);
}

// Round 13
// 281.572 us; speedup vs baseline: 1.6636x; 1.1106x over previous
//
#include <hip/hip_runtime.h>
#include <hip/hip_bf16.h>

typedef unsigned short u16;
typedef unsigned int   u32;
typedef __attribute__((ext_vector_type(8))) short short8;
typedef __attribute__((ext_vector_type(4))) float f32x4;

#define NN 4096        // nodes
#define NE 262144      // edges
#define EMB 256
#define NH 4
#define HD 64

__device__ __forceinline__ float4 load4f(const float* p) { return *reinterpret_cast<const float4*>(p); }
__device__ __forceinline__ float sanitize_f(float v) {
  v = (v != v) ? 0.f : v;                 // nan -> 0
  return fminf(fmaxf(v, -1000.f), 1000.f); // +-inf and clip -> +-1000
}
__device__ __forceinline__ u16 f2b_rne(float x) {          // f32 -> bf16 bits, round-nearest-even
  u32 b = __float_as_uint(x);
  b += 0x7fff + ((b >> 16) & 1);
  return (u16)(b >> 16);
}
__device__ __forceinline__ u32 pack2(float a, float b) {
  return (u32)f2b_rne(a) | ((u32)f2b_rne(b) << 16);
}
__device__ __forceinline__ float b2f(u16 u) { return __uint_as_float((u32)u << 16); }

// ================= generic MFMA GEMM: out = act(A[M,K] @ W^T + bias) =================
struct GTile {
  const float* W;     // 64 weight rows for this tile: [64][K]
  const float* bias;  // 64 entries
  float*       out;   // f32 / bf16 / bf16-transposed
  int          colOff;
  int          ldOut;
  int          obf16; // 0: f32 row-major; 1: bf16 row-major; 2: bf16 TRANSPOSED out[col*ldOut+row]
};
struct GArgs { GTile t[16]; };

// 256 threads = 4 waves; block tile 64x64; wave tile 32x32 (2x2 frags of 16x16x32).
template<int ACT>   // 0 none, 1 sanitize, 2 lrelu(0.2)
__global__ __launch_bounds__(256) void gemm_mfma(const float* __restrict__ A, const GArgs ga, int K) {
  __shared__ short As[64 * 40];
  __shared__ short Bs[64 * 40];
  const int t = threadIdx.x;
  const int bm = blockIdx.x * 64;
  const GTile tl = ga.t[blockIdx.y];
  const int w = t >> 6, l = t & 63, g = l >> 4, r16 = l & 15;
  const int wr = w >> 1, wc = w & 1;
  const int lrow = t >> 2, lseg = (t & 3) * 8;

  const float* Ap = A + (size_t)(bm + lrow) * K + lseg;
  const float* Wp = tl.W + (size_t)lrow * K + lseg;

  f32x4 acc[2][2] = {{{0.f,0.f,0.f,0.f},{0.f,0.f,0.f,0.f}},{{0.f,0.f,0.f,0.f},{0.f,0.f,0.f,0.f}}};
  for (int k0 = 0; k0 < K; k0 += 32) {
    float4 a0 = load4f(Ap + k0), a1 = load4f(Ap + k0 + 4);
    float4 b0 = load4f(Wp + k0), b1 = load4f(Wp + k0 + 4);
    __syncthreads();
    *(uint4*)&As[lrow * 40 + lseg] =
        make_uint4(pack2(a0.x,a0.y), pack2(a0.z,a0.w), pack2(a1.x,a1.y), pack2(a1.z,a1.w));
    *(uint4*)&Bs[lrow * 40 + lseg] =
        make_uint4(pack2(b0.x,b0.y), pack2(b0.z,b0.w), pack2(b1.x,b1.y), pack2(b1.z,b1.w));
    __syncthreads();
    short8 af0 = *(const short8*)&As[(wr*32 +      r16) * 40 + 8*g];
    short8 af1 = *(const short8*)&As[(wr*32 + 16 + r16) * 40 + 8*g];
    short8 bf0 = *(const short8*)&Bs[(wc*32 +      r16) * 40 + 8*g];
    short8 bf1 = *(const short8*)&Bs[(wc*32 + 16 + r16) * 40 + 8*g];
    acc[0][0] = __builtin_amdgcn_mfma_f32_16x16x32_bf16(af0, bf0, acc[0][0], 0, 0, 0);
    acc[0][1] = __builtin_amdgcn_mfma_f32_16x16x32_bf16(af0, bf1, acc[0][1], 0, 0, 0);
    acc[1][0] = __builtin_amdgcn_mfma_f32_16x16x32_bf16(af1, bf0, acc[1][0], 0, 0, 0);
    acc[1][1] = __builtin_amdgcn_mfma_f32_16x16x32_bf16(af1, bf1, acc[1][1], 0, 0, 0);
  }
  const float bj[2] = { tl.bias[wc*32 + r16], tl.bias[wc*32 + 16 + r16] };
#pragma unroll
  for (int i = 0; i < 2; i++) {
#pragma unroll
    for (int j = 0; j < 2; j++) {
      int col  = tl.colOff + wc*32 + 16*j + r16;
      int row0 = bm + wr*32 + 16*i + 4*g;
      if (tl.obf16 == 2) {           // transposed bf16: out[col*ldOut + row], 4 consecutive rows
        u16 pk[4];
#pragma unroll
        for (int r = 0; r < 4; r++) pk[r] = f2b_rne(acc[i][j][r] + bj[j]);
        *(uint2*)((u16*)tl.out + (size_t)col * tl.ldOut + row0) = *(uint2*)pk;
      } else {
#pragma unroll
        for (int r = 0; r < 4; r++) {
          float v = acc[i][j][r] + bj[j];
          if (ACT == 1) v = sanitize_f(v);
          if (ACT == 2) v = (v > 0.f) ? v : 0.2f * v;
          if (tl.obf16) ((u16*)tl.out)[(size_t)(row0 + r) * tl.ldOut + col] = f2b_rne(v);
          else          tl.out[(size_t)(row0 + r) * tl.ldOut + col] = v;
        }
      }
    }
  }
}

// ---------------- img GEMM split-K: K=2048 over 4 z-blocks of 512 ----------------
__global__ __launch_bounds__(256) void gemm_img_splitk(const float* __restrict__ A, const float* __restrict__ W,
                                                       float* __restrict__ part) {
  __shared__ short As[64 * 40];
  __shared__ short Bs[64 * 40];
  const int t = threadIdx.x;
  const int bm = blockIdx.x * 64, bn = blockIdx.y * 64, ks = blockIdx.z;
  const int w = t >> 6, l = t & 63, g = l >> 4, r16 = l & 15;
  const int wr = w >> 1, wc = w & 1;
  const int lrow = t >> 2, lseg = (t & 3) * 8;

  const float* Ap = A + (size_t)(bm + lrow) * 2048 + ks * 512 + lseg;
  const float* Wp = W + (size_t)(bn + lrow) * 2048 + ks * 512 + lseg;

  f32x4 acc[2][2] = {{{0.f,0.f,0.f,0.f},{0.f,0.f,0.f,0.f}},{{0.f,0.f,0.f,0.f},{0.f,0.f,0.f,0.f}}};
  for (int k0 = 0; k0 < 512; k0 += 32) {
    float4 a0 = load4f(Ap + k0), a1 = load4f(Ap + k0 + 4);
    float4 b0 = load4f(Wp + k0), b1 = load4f(Wp + k0 + 4);
    __syncthreads();
    *(uint4*)&As[lrow * 40 + lseg] =
        make_uint4(pack2(a0.x,a0.y), pack2(a0.z,a0.w), pack2(a1.x,a1.y), pack2(a1.z,a1.w));
    *(uint4*)&Bs[lrow * 40 + lseg] =
        make_uint4(pack2(b0.x,b0.y), pack2(b0.z,b0.w), pack2(b1.x,b1.y), pack2(b1.z,b1.w));
    __syncthreads();
    short8 af0 = *(const short8*)&As[(wr*32 +      r16) * 40 + 8*g];
    short8 af1 = *(const short8*)&As[(wr*32 + 16 + r16) * 40 + 8*g];
    short8 bf0 = *(const short8*)&Bs[(wc*32 +      r16) * 40 + 8*g];
    short8 bf1 = *(const short8*)&Bs[(wc*32 + 16 + r16) * 40 + 8*g];
    acc[0][0] = __builtin_amdgcn_mfma_f32_16x16x32_bf16(af0, bf0, acc[0][0], 0, 0, 0);
    acc[0][1] = __builtin_amdgcn_mfma_f32_16x16x32_bf16(af0, bf1, acc[0][1], 0, 0, 0);
    acc[1][0] = __builtin_amdgcn_mfma_f32_16x16x32_bf16(af1, bf0, acc[1][0], 0, 0, 0);
    acc[1][1] = __builtin_amdgcn_mfma_f32_16x16x32_bf16(af1, bf1, acc[1][1], 0, 0, 0);
  }
  float* op = part + (size_t)ks * (NN * 256);
#pragma unroll
  for (int i = 0; i < 2; i++) {
#pragma unroll
    for (int j = 0; j < 2; j++) {
      int col = bn + wc*32 + 16*j + r16;
#pragma unroll
      for (int r = 0; r < 4; r++) {
        int row = bm + wr*32 + 16*i + 4*g + r;
        op[(size_t)row * 256 + col] = acc[i][j][r];
      }
    }
  }
}
__global__ __launch_bounds__(256) void gemm_img_reduce(const float* __restrict__ part,
                                                       const float* __restrict__ bias,
                                                       float* __restrict__ h) {
  int idx = blockIdx.x * 256 + threadIdx.x;   // 262144 threads, 4 floats each
  int row = idx >> 6, c4 = (idx & 63) * 4;
  size_t o = (size_t)row * 256 + c4;
  float4 s = load4f(part + o);
  float4 p1 = load4f(part + 1048576 + o);
  float4 p2 = load4f(part + 2097152 + o);
  float4 p3 = load4f(part + 3145728 + o);
  float4 bb = load4f(bias + c4);
  s.x += p1.x + p2.x + p3.x + bb.x;
  s.y += p1.y + p2.y + p3.y + bb.y;
  s.z += p1.z + p2.z + p3.z + bb.z;
  s.w += p1.w + p2.w + p3.w + bb.w;
  *(float4*)&h[o] = s;
}

// ---------------- causal MHA v3: 64-q blocks, LDS-shared K/V, pipelined, split-K x2 ----------------
#define KSTR 72   // LDS row stride in shorts (64 data + 8 pad; 2-way reads = free)
__global__ __launch_bounds__(256, 4) void mha_mfma3(const u16* __restrict__ qkb, const u16* __restrict__ vtb,
                                                    float* __restrict__ Opart, float* __restrict__ mspart) {
  __shared__ u16 Ks[64 * KSTR];
  __shared__ u16 Vs[64 * KSTR];
  const int bid = blockIdx.x;
  const int ks  = bid & 1;
  const int hh  = (bid >> 1) & 3;
  const int T   = 63 - (bid >> 3);
  const int q0  = T * 64;
  const int t   = threadIdx.x;
  const int w   = t >> 6, l = t & 63, g = l >> 4, r16 = l & 15;
  const int hofs = hh * 64;
  const int lrow = t >> 3, lc8 = (t & 7) * 8;   // staging: 32 rows x 64 cols per pass

  const u16* qrow = qkb + (size_t)(q0 + 16 * w + r16) * 512 + hofs;
  short8 Qf0 = *(const short8*)&qrow[8 * g];
  short8 Qf1 = *(const short8*)&qrow[32 + 8 * g];

  f32x4 O0 = {0.f,0.f,0.f,0.f}, O1 = O0, O2 = O0, O3 = O0;
  float m = -INFINITY, ssum = 0.f;

  uint4 rk0, rk1, rv0, rv1;
  if (ks <= T) {
    int k0 = ks * 64;
    rk0 = *(const uint4*)&qkb[(size_t)(k0 + lrow) * 512 + 256 + hofs + lc8];
    rk1 = *(const uint4*)&qkb[(size_t)(k0 + 32 + lrow) * 512 + 256 + hofs + lc8];
    rv0 = *(const uint4*)&vtb[(size_t)(hofs + lrow) * 4096 + k0 + lc8];
    rv1 = *(const uint4*)&vtb[(size_t)(hofs + 32 + lrow) * 4096 + k0 + lc8];
  }
  for (int kt = ks; kt <= T; kt += 2) {
    __syncthreads();
    *(uint4*)&Ks[lrow * KSTR + lc8]        = rk0;
    *(uint4*)&Ks[(32 + lrow) * KSTR + lc8] = rk1;
    *(uint4*)&Vs[lrow * KSTR + lc8]        = rv0;
    *(uint4*)&Vs[(32 + lrow) * KSTR + lc8] = rv1;
    __syncthreads();
    if (kt + 2 <= T) {
      int k2 = (kt + 2) * 64;
      rk0 = *(const uint4*)&qkb[(size_t)(k2 + lrow) * 512 + 256 + hofs + lc8];
      rk1 = *(const uint4*)&qkb[(size_t)(k2 + 32 + lrow) * 512 + 256 + hofs + lc8];
      rv0 = *(const uint4*)&vtb[(size_t)(hofs + lrow) * 4096 + k2 + lc8];
      rv1 = *(const uint4*)&vtb[(size_t)(hofs + 32 + lrow) * 4096 + k2 + lc8];
    }
    f32x4 S0 = {0.f,0.f,0.f,0.f}, S1 = S0, S2 = S0, S3 = S0;
    {
      short8 a0 = *(const short8*)&Ks[(r16)      * KSTR + 8*g];
      short8 a1 = *(const short8*)&Ks[(16 + r16) * KSTR + 8*g];
      short8 a2 = *(const short8*)&Ks[(32 + r16) * KSTR + 8*g];
      short8 a3 = *(const short8*)&Ks[(48 + r16) * KSTR + 8*g];
      S0 = __builtin_amdgcn_mfma_f32_16x16x32_bf16(a0, Qf0, S0, 0, 0, 0);
      S1 = __builtin_amdgcn_mfma_f32_16x16x32_bf16(a1, Qf0, S1, 0, 0, 0);
      S2 = __builtin_amdgcn_mfma_f32_16x16x32_bf16(a2, Qf0, S2, 0, 0, 0);
      S3 = __builtin_amdgcn_mfma_f32_16x16x32_bf16(a3, Qf0, S3, 0, 0, 0);
      short8 b0 = *(const short8*)&Ks[(r16)      * KSTR + 32 + 8*g];
      short8 b1 = *(const short8*)&Ks[(16 + r16) * KSTR + 32 + 8*g];
      short8 b2 = *(const short8*)&Ks[(32 + r16) * KSTR + 32 + 8*g];
      short8 b3 = *(const short8*)&Ks[(48 + r16) * KSTR + 32 + 8*g];
      S0 = __builtin_amdgcn_mfma_f32_16x16x32_bf16(b0, Qf1, S0, 0, 0, 0);
      S1 = __builtin_amdgcn_mfma_f32_16x16x32_bf16(b1, Qf1, S1, 0, 0, 0);
      S2 = __builtin_amdgcn_mfma_f32_16x16x32_bf16(b2, Qf1, S2, 0, 0, 0);
      S3 = __builtin_amdgcn_mfma_f32_16x16x32_bf16(b3, Qf1, S3, 0, 0, 0);
    }
    float sc[4][4];
#pragma unroll
    for (int r = 0; r < 4; r++) {
      sc[0][r] = S0[r] * 0.125f; sc[1][r] = S1[r] * 0.125f;
      sc[2][r] = S2[r] * 0.125f; sc[3][r] = S3[r] * 0.125f;
    }
    if (kt == T) {
#pragma unroll
      for (int mb = 0; mb < 4; mb++)
#pragma unroll
        for (int r = 0; r < 4; r++)
          if (16 * mb + 4 * g + r > 16 * w + r16) sc[mb][r] = -INFINITY;
    }
    float tm = sc[0][0];
#pragma unroll
    for (int mb = 0; mb < 4; mb++)
#pragma unroll
      for (int r = 0; r < 4; r++) tm = fmaxf(tm, sc[mb][r]);
    tm = fmaxf(tm, __shfl_xor(tm, 16));
    tm = fmaxf(tm, __shfl_xor(tm, 32));
    float mn = fmaxf(m, tm);
    float ef = __expf(m - mn);
    float pv[4][4];
    float ps = 0.f;
#pragma unroll
    for (int mb = 0; mb < 4; mb++)
#pragma unroll
      for (int r = 0; r < 4; r++) { pv[mb][r] = __expf(sc[mb][r] - mn); ps += pv[mb][r]; }
    ps += __shfl_xor(ps, 16);
    ps += __shfl_xor(ps, 32);
    ssum = ssum * ef + ps;
    m = mn;
#pragma unroll
    for (int r = 0; r < 4; r++) {
      float efr = __shfl(ef, 4 * g + r);
      O0[r] *= efr; O1[r] *= efr; O2[r] *= efr; O3[r] *= efr;
    }
    u32 pk[2][4];
#pragma unroll
    for (int c = 0; c < 2; c++)
#pragma unroll
      for (int rs = 0; rs < 4; rs++) pk[c][rs] = pack2(pv[2 * c][rs], pv[2 * c + 1][rs]);
    short8 ap[2];
#pragma unroll
    for (int c = 0; c < 2; c++) {
#pragma unroll
      for (int jb = 0; jb < 2; jb++) {
        int x = 2 * g + jb;
        int hi = x >> 2;
        int src = r16 + 16 * (x & 3);
#pragma unroll
        for (int rs = 0; rs < 4; rs++) {
          u32 v = __shfl(pk[c][rs], src);
          ap[c][jb * 4 + rs] = (short)(hi ? (v >> 16) : (v & 0xffff));
        }
      }
    }
    {
      short8 V00 = *(const short8*)&Vs[(r16)      * KSTR + 8*g];
      short8 V10 = *(const short8*)&Vs[(16 + r16) * KSTR + 8*g];
      short8 V20 = *(const short8*)&Vs[(32 + r16) * KSTR + 8*g];
      short8 V30 = *(const short8*)&Vs[(48 + r16) * KSTR + 8*g];
      O0 = __builtin_amdgcn_mfma_f32_16x16x32_bf16(ap[0], V00, O0, 0, 0, 0);
      O1 = __builtin_amdgcn_mfma_f32_16x16x32_bf16(ap[0], V10, O1, 0, 0, 0);
      O2 = __builtin_amdgcn_mfma_f32_16x16x32_bf16(ap[0], V20, O2, 0, 0, 0);
      O3 = __builtin_amdgcn_mfma_f32_16x16x32_bf16(ap[0], V30, O3, 0, 0, 0);
      short8 V01 = *(const short8*)&Vs[(r16)      * KSTR + 32 + 8*g];
      short8 V11 = *(const short8*)&Vs[(16 + r16) * KSTR + 32 + 8*g];
      short8 V21 = *(const short8*)&Vs[(32 + r16) * KSTR + 32 + 8*g];
      short8 V31 = *(const short8*)&Vs[(48 + r16) * KSTR + 32 + 8*g];
      O0 = __builtin_amdgcn_mfma_f32_16x16x32_bf16(ap[1], V01, O0, 0, 0, 0);
      O1 = __builtin_amdgcn_mfma_f32_16x16x32_bf16(ap[1], V11, O1, 0, 0, 0);
      O2 = __builtin_amdgcn_mfma_f32_16x16x32_bf16(ap[1], V21, O2, 0, 0, 0);
      O3 = __builtin_amdgcn_mfma_f32_16x16x32_bf16(ap[1], V31, O3, 0, 0, 0);
    }
  }

  size_t ob = (size_t)bid * 4096;
#pragma unroll
  for (int r = 0; r < 4; r++) {
    int q = 16 * w + 4 * g + r;
    Opart[ob + q * 64 + r16]      = O0[r];
    Opart[ob + q * 64 + 16 + r16] = O1[r];
    Opart[ob + q * 64 + 32 + r16] = O2[r];
    Opart[ob + q * 64 + 48 + r16] = O3[r];
  }
  if (l < 16) {
    mspart[bid * 128 + 16 * w + l]      = m;
    mspart[bid * 128 + 64 + 16 * w + l] = ssum;
  }
}

// merge 2 stripe-partials -> normalized output. grid 256: T = mb>>2, h = mb&3.
__global__ __launch_bounds__(256) void mha_merge3(const float* __restrict__ Opart, const float* __restrict__ mspart,
                                                  float* __restrict__ out) {
  int mb = blockIdx.x;
  int h = mb & 3, T = mb >> 2;
  int bid0 = ((63 - T) << 3) | (h << 1);
  int bid1 = bid0 | 1;
  int t = threadIdx.x;
  int q = t >> 2, dbase = (t & 3) * 16;
  float m0 = mspart[bid0 * 128 + q],      m1 = mspart[bid1 * 128 + q];
  float s0 = mspart[bid0 * 128 + 64 + q], s1 = mspart[bid1 * 128 + 64 + q];
  float M = fmaxf(m0, m1);
  float e0 = __expf(m0 - M);
  float e1 = (m1 == -INFINITY) ? 0.f : __expf(m1 - M);
  float inv = 1.f / (e0 * s0 + e1 * s1);
  const float* A = Opart + (size_t)bid0 * 4096 + q * 64 + dbase;
  const float* B = Opart + (size_t)bid1 * 4096 + q * 64 + dbase;
  float* Y = out + (size_t)(T * 64 + q) * EMB + h * 64 + dbase;
#pragma unroll
  for (int i = 0; i < 4; i++) {
    float4 a = load4f(A + 4 * i), b = load4f(B + 4 * i);
    float4 r;
    r.x = (e0 * a.x + e1 * b.x) * inv;
    r.y = (e0 * a.y + e1 * b.y) * inv;
    r.z = (e0 * a.z + e1 * b.z) * inv;
    r.w = (e0 * a.w + e1 * b.w) * inv;
    *(float4*)(Y + 4 * i) = r;
  }
}

// ---------------- CSR build ----------------
__global__ void zero_i32(int* p, int n) {
  int i = blockIdx.x * 256 + threadIdx.x;
  if (i < n) p[i] = 0;
}
__global__ void hist_dst(const int* __restrict__ adj, int* __restrict__ cnt) {
  int e = blockIdx.x * 256 + threadIdx.x;
  if (e < NE) atomicAdd(&cnt[adj[NE + e]], 1);
}
__global__ __launch_bounds__(1024) void scan4096(const int* __restrict__ cnt, int* __restrict__ indptr,
                                                 int* __restrict__ cursor) {
  int t = threadIdx.x;
  int4 c = *reinterpret_cast<const int4*>(cnt + t * 4);
  int s0 = c.x, s1 = s0 + c.y, s2 = s1 + c.z, s3 = s2 + c.w;
  int lane = t & 63, w = t >> 6;
  int x = s3;
#pragma unroll
  for (int off = 1; off < 64; off <<= 1) {
    int y = __shfl_up(x, off);
    if (lane >= off) x += y;
  }
  __shared__ int wsum[16];
  if (lane == 63) wsum[w] = x;
  __syncthreads();
  if (t == 0) {
    int acc = 0;
    for (int i = 0; i < 16; i++) { int tv = wsum[i]; wsum[i] = acc; acc += tv; }
  }
  __syncthreads();
  int b = wsum[w] + x - s3;
  indptr[t*4+0] = b;      indptr[t*4+1] = b + s0;
  indptr[t*4+2] = b + s1; indptr[t*4+3] = b + s2;
  cursor[t*4+0] = b;      cursor[t*4+1] = b + s0;
  cursor[t*4+2] = b + s1; cursor[t*4+3] = b + s2;
  if (t == 1023) indptr[4096] = b + s3;
}
__global__ void scatter_edges(const int* __restrict__ adj, int* __restrict__ cursor, int* __restrict__ esrc) {
  int e = blockIdx.x * 256 + threadIdx.x;
  if (e < NE) {
    int dst = adj[NE + e];
    int pos = atomicAdd(&cursor[dst], 1);
    esrc[pos] = adj[e];
  }
}

// ---------------- TransformerConv aggregation: cooperative K-row gather + octet dot ----------------
// 8 consecutive lanes load one edge's 128B K-segment (16B/lane) -> 4x fewer divergent lines.
__global__ __launch_bounds__(256, 4) void conv_agg(const float* __restrict__ qb, const u16* __restrict__ kb,
                                                   const u16* __restrict__ vb, const int* __restrict__ indptr,
                                                   const int* __restrict__ esrc, float* __restrict__ y) {
  __shared__ float q_s[EMB];
  __shared__ float sc_s[NH][64];
  __shared__ float p_s[NH][64];
  __shared__ int   s_s[64];
  int n = blockIdx.x;
  int tid = threadIdx.x;
  int h = tid >> 6, lane = tid & 63;
  int lr8 = lane >> 3;            // row within octet-group (0..7)
  int lseg = (lane & 7) * 8;      // dim octet base
  q_s[tid] = qb[(size_t)n * EMB + tid] * 0.125f;   // fold 1/sqrt(D) into q
  int start = indptr[n], end = indptr[n + 1];
  __syncthreads();
  const float* qh = &q_s[h * HD];
  float q8[8];
#pragma unroll
  for (int j = 0; j < 8; j++) q8[j] = qh[lseg + j];
  float m = -INFINITY, s = 0.f;
  float o0 = 0.f, o1 = 0.f, o2 = 0.f, o3 = 0.f;
  for (int p0 = start; p0 < end; p0 += 64) {
    int nk = end - p0; if (nk > 64) nk = 64;
    if (h == 0) s_s[lane] = (lane < nk) ? esrc[p0 + lane] : 0;
    __syncthreads();                               // s_s visible to all waves
    // ---- scores: 8 passes, 8 lanes cooperate per edge row ----
#pragma unroll
    for (int pass = 0; pass < 8; pass++) {
      int row = pass * 8 + lr8;
      int src = s_s[row];                          // broadcast (8 lanes same addr)
      short8 k8 = *(const short8*)&kb[(size_t)src * EMB + h * HD + lseg];
      float a0 = fmaf(b2f((u16)k8[0]), q8[0], 0.f);
      float a1 = fmaf(b2f((u16)k8[1]), q8[1], 0.f);
      a0 = fmaf(b2f((u16)k8[2]), q8[2], a0);
      a1 = fmaf(b2f((u16)k8[3]), q8[3], a1);
      a0 = fmaf(b2f((u16)k8[4]), q8[4], a0);
      a1 = fmaf(b2f((u16)k8[5]), q8[5], a1);
      a0 = fmaf(b2f((u16)k8[6]), q8[6], a0);
      a1 = fmaf(b2f((u16)k8[7]), q8[7], a1);
      float acc = a0 + a1;
      acc += __shfl_xor(acc, 1);
      acc += __shfl_xor(acc, 2);
      acc += __shfl_xor(acc, 4);
      if ((lane & 7) == 0) sc_s[h][row] = (row < nk) ? acc : -INFINITY;
    }
    float sc = sc_s[h][lane];                      // same-wave LDS RAW: compiler waits lgkmcnt
    float bm = sc;
#pragma unroll
    for (int off = 32; off; off >>= 1) bm = fmaxf(bm, __shfl_xor(bm, off));
    float mn = fmaxf(m, bm);
    float ef = __expf(m - mn);                     // 0 on first chunk
    float p = __expf(sc - mn);                     // 0 for masked rows (sc=-inf)
    float ps = p;
#pragma unroll
    for (int off = 32; off; off >>= 1) ps += __shfl_xor(ps, off);
    s = s * ef + ps;
    m = mn;
    o0 *= ef; o1 *= ef; o2 *= ef; o3 *= ef;
    p_s[h][lane] = p;
    const u16* vcol = vb + h * HD + lane;
    int nk4 = (nk + 3) & ~3;
    for (int jj = 0; jj < nk4; jj += 4) {
      float pa = p_s[h][jj],   pb = p_s[h][jj+1];
      float pc = p_s[h][jj+2], pd = p_s[h][jj+3];
      int sa = s_s[jj], sb = s_s[jj+1], scx = s_s[jj+2], sd = s_s[jj+3];
      o0 = fmaf(pa, b2f(vcol[(size_t)sa  * EMB]), o0);
      o1 = fmaf(pb, b2f(vcol[(size_t)sb  * EMB]), o1);
      o2 = fmaf(pc, b2f(vcol[(size_t)scx * EMB]), o2);
      o3 = fmaf(pd, b2f(vcol[(size_t)sd  * EMB]), o3);
    }
    __syncthreads();                               // protect s_s before next chunk overwrite
  }
  float o = (o0 + o1) + (o2 + o3);
  float agg = o / (s + 1e-16f);
  y[(size_t)n * EMB + h * HD + lane] += agg;
}

// ---------------- instance norm + lrelu + sanitize ----------------
__global__ __launch_bounds__(256) void colstats_partial(const float* __restrict__ y, float* __restrict__ part) {
  int c = threadIdx.x;
  int r0 = blockIdx.x * 128;
  float s = 0.f, q = 0.f;
  for (int r = r0; r < r0 + 128; r++) {
    float v = y[(size_t)r * EMB + c];
    s += v; q = fmaf(v, v, q);
  }
  part[blockIdx.x * 512 + c] = s;
  part[blockIdx.x * 512 + 256 + c] = q;
}
__global__ __launch_bounds__(256) void colstats_final(const float* __restrict__ part, float* __restrict__ stats) {
  int c = threadIdx.x;
  float s = 0.f, q = 0.f;
  for (int b = 0; b < 32; b++) { s += part[b * 512 + c]; q += part[b * 512 + 256 + c]; }
  float mean = s * (1.f / 4096.f);
  float var  = q * (1.f / 4096.f) - mean * mean;
  stats[c] = mean;
  stats[256 + c] = rsqrtf(var + 1e-5f);
}
__global__ __launch_bounds__(256) void norm_apply(const float* __restrict__ y, const float* __restrict__ stats,
                                                  float* __restrict__ f, int colOff) {
  int c = threadIdx.x;
  float mean = stats[c], rstd = stats[256 + c];
  int r0 = blockIdx.x * 16;
  for (int r = r0; r < r0 + 16; r++) {
    float v = (y[(size_t)r * EMB + c] - mean) * rstd;
    v = (v > 0.f) ? v : 0.2f * v;
    v = sanitize_f(v);
    f[(size_t)r * 512 + colOff + c] = v;
  }
}

// ---------------- classifier tail ----------------
__global__ __launch_bounds__(256) void final_softmax(const float* __restrict__ f1, const float* __restrict__ W2,
                                                     const float* __restrict__ b2, float* __restrict__ out) {
  int w = threadIdx.x >> 6, lane = threadIdx.x & 63;
  int row = blockIdx.x * 4 + w;
  const float* fr = f1 + (size_t)row * 128;
  float x0 = fr[lane], x1 = fr[lane + 64];
  float p0 = x0 * W2[lane]       + x1 * W2[64 + lane];
  float p1 = x0 * W2[128 + lane] + x1 * W2[192 + lane];
#pragma unroll
  for (int off = 32; off; off >>= 1) { p0 += __shfl_xor(p0, off); p1 += __shfl_xor(p1, off); }
  if (lane == 0) {
    float l0 = p0 + b2[0], l1 = p1 + b2[1];
    float mx = fmaxf(l0, l1);
    float e0 = __expf(l0 - mx), e1 = __expf(l1 - mx);
    float inv = 1.f / (e0 + e1);
    out[(size_t)row * 2 + 0] = l0;
    out[(size_t)row * 2 + 1] = l1;
    out[8192 + (size_t)row * 2 + 0] = e0 * inv;
    out[8192 + (size_t)row * 2 + 1] = e1 * inv;
  }
}

extern "C" void kernel_launch(void* const* d_in, const int* in_sizes, int n_in,
                              void* d_out, int out_size, void* d_ws, size_t ws_size,
                              hipStream_t stream) {
  const float* img   = (const float*)d_in[2];
  const int*   adj   = (const int*)d_in[3];
  const float* W_img = (const float*)d_in[4];  const float* b_img = (const float*)d_in[5];
  const float* W_qkv = (const float*)d_in[6];  const float* b_qkv = (const float*)d_in[7];
  const float* W_o   = (const float*)d_in[8];  const float* b_o   = (const float*)d_in[9];
  const float* Wq_o  = (const float*)d_in[10]; const float* bq_o  = (const float*)d_in[11];
  const float* Wk_o  = (const float*)d_in[12]; const float* bk_o  = (const float*)d_in[13];
  const float* Wv_o  = (const float*)d_in[14]; const float* bv_o  = (const float*)d_in[15];
  const float* Ws_o  = (const float*)d_in[16]; const float* bs_o  = (const float*)d_in[17];
  const float* Wq_a  = (const float*)d_in[18]; const float* bq_a  = (const float*)d_in[19];
  const float* Wk_a  = (const float*)d_in[20]; const float* bk_a  = (const float*)d_in[21];
  const float* Wv_a  = (const float*)d_in[22]; const float* bv_a  = (const float*)d_in[23];
  const float* Ws_a  = (const float*)d_in[24]; const float* bs_a  = (const float*)d_in[25];
  const float* W_c1  = (const float*)d_in[26]; const float* b_c1  = (const float*)d_in[27];
  const float* W_c2  = (const float*)d_in[28]; const float* b_c2  = (const float*)d_in[29];

  char* ws = (char*)d_ws;
  float* h     = (float*)(ws + 0);                    // 4 MB
  float* hattn = (float*)(ws + (4ull << 20));         // 4 MB (aliased as qkb during mha)
  float* qkv   = (float*)(ws + (8ull << 20));         // 12 MB (img-splitk partials; conv qb later)
  float* y     = (float*)(ws + (20ull << 20));        // 4 MB  (img-splitk partial #4)
  float* f     = (float*)(ws + (24ull << 20));        // 8 MB  (mha O-partials during step 3)
  float* f1    = (float*)(ws + (32ull << 20));        // 2 MB (aliased as vtb during mha)
  int*   indptr= (int*)  (ws + (34ull << 20));
  int*   cursor= (int*)  (ws + (34ull << 20) + 20480);
  int*   esrc  = (int*)  (ws + (34ull << 20) + 40960);  // 1 MB (mha m/s partials during step 3)
  float* part  = (float*)(ws + (34ull << 20) + 40960 + (1ull << 20));
  float* stats = (float*)(ws + (34ull << 20) + 40960 + (1ull << 20) + 65536);

  u16* qkb = (u16*)hattn;   // 4 MB, dead after mha (hattn written at step 4)
  u16* vtb = (u16*)f1;      // 2 MB, dead after mha (f1 written at step 8)

  float* imgpart = qkv;          // 16 MB contiguous (qkv 12MB + y 4MB), free during step 1
  float* Opart   = f;            // 8 MB (512 blocks x 4096 floats), free during step 3
  float* mspart  = (float*)esrc; // 256 KB, free during step 3 (CSR built later)

  float* qb   = qkv;                         // 4 MB f32
  u16*   kb16 = (u16*)(ws + (12ull << 20));  // 2 MB bf16
  u16*   vb16 = (u16*)(ws + (14ull << 20));  // 2 MB bf16

  dim3 b256(256);

  // 1. h = img_feat @ W_img^T + b_img   (M=4096,N=256,K=2048) split-K x4
  gemm_img_splitk<<<dim3(64, 4, 4), b256, 0, stream>>>(img, W_img, imgpart);
  gemm_img_reduce<<<1024, b256, 0, stream>>>(imgpart, b_img, h);
  // 2. qkv GEMM writes mha-ready buffers directly: Q|K -> qkb (bf16), V -> vtb (bf16 transposed)
  {
    GArgs ga;
    for (int i = 0; i < 8; i++)
      ga.t[i]  = { W_qkv + (size_t)i * 64 * 256, b_qkv + i * 64, (float*)qkb, i * 64, 512, 1 };
    for (int i = 8; i < 12; i++)
      ga.t[i]  = { W_qkv + (size_t)i * 64 * 256, b_qkv + i * 64, (float*)vtb, (i - 8) * 64, 4096, 2 };
    gemm_mfma<0><<<dim3(64, 12), b256, 0, stream>>>(h, ga, 256);
  }
  // 3. causal MHA v3 (64q blocks, LDS K/V, split-K x2) -> y
  mha_mfma3<<<512, b256, 0, stream>>>(qkb, vtb, Opart, mspart);
  mha_merge3<<<256, b256, 0, stream>>>(Opart, mspart, y);
  // 4. h_attn = sanitize(y @ W_o^T + b_o)
  {
    GArgs ga;
    for (int i = 0; i < 4; i++)
      ga.t[i] = { W_o + (size_t)i * 64 * 256, b_o + i * 64, hattn, i * 64, 256, 0 };
    gemm_mfma<1><<<dim3(64, 4), b256, 0, stream>>>(y, ga, 256);
  }
  // 5. CSR of video_adj_list grouped by dst
  zero_i32<<<16, b256, 0, stream>>>(cursor, NN);
  hist_dst<<<NE / 256, b256, 0, stream>>>(adj, cursor);
  scan4096<<<1, 1024, 0, stream>>>(cursor, indptr, cursor);
  scatter_edges<<<NE / 256, b256, 0, stream>>>(adj, cursor, esrc);

  // 6. conv path O: q/k/v/skip fused (N=1024,K=256), input h; k,v in bf16
  {
    const float* Wg[4] = { Wq_o, Wk_o, Wv_o, Ws_o };
    const float* bg[4] = { bq_o, bk_o, bv_o, bs_o };
    float*       og[4] = { qb, (float*)kb16, (float*)vb16, y };
    const int    bf[4] = { 0, 1, 1, 0 };
    GArgs ga;
    for (int i = 0; i < 16; i++) {
      int gdx = i >> 2, li = i & 3;
      ga.t[i] = { Wg[gdx] + (size_t)li * 64 * 256, bg[gdx] + li * 64, og[gdx], li * 64, 256, bf[gdx] };
    }
    gemm_mfma<0><<<dim3(64, 16), b256, 0, stream>>>(h, ga, 256);
  }
  conv_agg<<<NN, b256, 0, stream>>>(qb, kb16, vb16, indptr, esrc, y);
  colstats_partial<<<32, b256, 0, stream>>>(y, part);
  colstats_final<<<1, b256, 0, stream>>>(part, stats);
  norm_apply<<<256, b256, 0, stream>>>(y, stats, f, 0);

  // 7. conv path A: same, input hattn
  {
    const float* Wg[4] = { Wq_a, Wk_a, Wv_a, Ws_a };
    const float* bg[4] = { bq_a, bk_a, bv_a, bs_a };
    float*       og[4] = { qb, (float*)kb16, (float*)vb16, y };
    const int    bf[4] = { 0, 1, 1, 0 };
    GArgs ga;
    for (int i = 0; i < 16; i++) {
      int gdx = i >> 2, li = i & 3;
      ga.t[i] = { Wg[gdx] + (size_t)li * 64 * 256, bg[gdx] + li * 64, og[gdx], li * 64, 256, bf[gdx] };
    }
    gemm_mfma<0><<<dim3(64, 16), b256, 0, stream>>>(hattn, ga, 256);
  }
  conv_agg<<<NN, b256, 0, stream>>>(qb, kb16, vb16, indptr, esrc, y);
  colstats_partial<<<32, b256, 0, stream>>>(y, part);
  colstats_final<<<1, b256, 0, stream>>>(part, stats);
  norm_apply<<<256, b256, 0, stream>>>(y, stats, f, 256);

  // 8. f1 = lrelu(f @ W_c1^T + b_c1)   (N=128,K=512)
  {
    GArgs ga;
    for (int i = 0; i < 2; i++)
      ga.t[i] = { W_c1 + (size_t)i * 64 * 512, b_c1 + i * 64, f1, i * 64, 128, 0 };
    gemm_mfma<2><<<dim3(64, 2), b256, 0, stream>>>(f, ga, 512);
  }
  // 9. logits + softmax -> out (f32): [0:8192] logits, [8192:16384] probs
  final_softmax<<<NN / 4, b256, 0, stream>>>(f1, W_c2, b_c2, (float*)d_out);
}

// Round 14
// 273.469 us; speedup vs baseline: 1.7129x; 1.0296x over previous
//
#include <hip/hip_runtime.h>
#include <hip/hip_bf16.h>

typedef unsigned short u16;
typedef unsigned int   u32;
typedef __attribute__((ext_vector_type(8))) short short8;
typedef __attribute__((ext_vector_type(4))) float f32x4;

#define NN 4096        // nodes
#define NE 262144      // edges
#define EMB 256
#define NH 4
#define HD 64

__device__ __forceinline__ float4 load4f(const float* p) { return *reinterpret_cast<const float4*>(p); }
__device__ __forceinline__ float sanitize_f(float v) {
  v = (v != v) ? 0.f : v;                 // nan -> 0
  return fminf(fmaxf(v, -1000.f), 1000.f); // +-inf and clip -> +-1000
}
__device__ __forceinline__ u16 f2b_rne(float x) {          // f32 -> bf16 bits, round-nearest-even
  u32 b = __float_as_uint(x);
  b += 0x7fff + ((b >> 16) & 1);
  return (u16)(b >> 16);
}
__device__ __forceinline__ u32 pack2(float a, float b) {
  return (u32)f2b_rne(a) | ((u32)f2b_rne(b) << 16);
}
__device__ __forceinline__ float b2f(u16 u) { return __uint_as_float((u32)u << 16); }

// ================= generic MFMA GEMM: out = act(A[M,K] @ W^T + bias) =================
struct GTile {
  const float* W;     // 64 weight rows for this tile: [64][K]
  const float* bias;  // 64 entries
  float*       out;   // f32 / bf16 / bf16-transposed
  int          colOff;
  int          ldOut;
  int          obf16; // 0: f32 row-major; 1: bf16 row-major; 2: bf16 TRANSPOSED out[col*ldOut+row]
};
struct GArgs { GTile t[16]; };

// 256 threads = 4 waves; block tile 64x64; wave tile 32x32 (2x2 frags of 16x16x32).
template<int ACT>   // 0 none, 1 sanitize, 2 lrelu(0.2)
__global__ __launch_bounds__(256) void gemm_mfma(const float* __restrict__ A, const GArgs ga, int K) {
  __shared__ short As[64 * 40];
  __shared__ short Bs[64 * 40];
  const int t = threadIdx.x;
  const int bm = blockIdx.x * 64;
  const GTile tl = ga.t[blockIdx.y];
  const int w = t >> 6, l = t & 63, g = l >> 4, r16 = l & 15;
  const int wr = w >> 1, wc = w & 1;
  const int lrow = t >> 2, lseg = (t & 3) * 8;

  const float* Ap = A + (size_t)(bm + lrow) * K + lseg;
  const float* Wp = tl.W + (size_t)lrow * K + lseg;

  f32x4 acc[2][2] = {{{0.f,0.f,0.f,0.f},{0.f,0.f,0.f,0.f}},{{0.f,0.f,0.f,0.f},{0.f,0.f,0.f,0.f}}};
  for (int k0 = 0; k0 < K; k0 += 32) {
    float4 a0 = load4f(Ap + k0), a1 = load4f(Ap + k0 + 4);
    float4 b0 = load4f(Wp + k0), b1 = load4f(Wp + k0 + 4);
    __syncthreads();
    *(uint4*)&As[lrow * 40 + lseg] =
        make_uint4(pack2(a0.x,a0.y), pack2(a0.z,a0.w), pack2(a1.x,a1.y), pack2(a1.z,a1.w));
    *(uint4*)&Bs[lrow * 40 + lseg] =
        make_uint4(pack2(b0.x,b0.y), pack2(b0.z,b0.w), pack2(b1.x,b1.y), pack2(b1.z,b1.w));
    __syncthreads();
    short8 af0 = *(const short8*)&As[(wr*32 +      r16) * 40 + 8*g];
    short8 af1 = *(const short8*)&As[(wr*32 + 16 + r16) * 40 + 8*g];
    short8 bf0 = *(const short8*)&Bs[(wc*32 +      r16) * 40 + 8*g];
    short8 bf1 = *(const short8*)&Bs[(wc*32 + 16 + r16) * 40 + 8*g];
    acc[0][0] = __builtin_amdgcn_mfma_f32_16x16x32_bf16(af0, bf0, acc[0][0], 0, 0, 0);
    acc[0][1] = __builtin_amdgcn_mfma_f32_16x16x32_bf16(af0, bf1, acc[0][1], 0, 0, 0);
    acc[1][0] = __builtin_amdgcn_mfma_f32_16x16x32_bf16(af1, bf0, acc[1][0], 0, 0, 0);
    acc[1][1] = __builtin_amdgcn_mfma_f32_16x16x32_bf16(af1, bf1, acc[1][1], 0, 0, 0);
  }
  const float bj[2] = { tl.bias[wc*32 + r16], tl.bias[wc*32 + 16 + r16] };
#pragma unroll
  for (int i = 0; i < 2; i++) {
#pragma unroll
    for (int j = 0; j < 2; j++) {
      int col  = tl.colOff + wc*32 + 16*j + r16;
      int row0 = bm + wr*32 + 16*i + 4*g;
      if (tl.obf16 == 2) {           // transposed bf16: out[col*ldOut + row], 4 consecutive rows
        u16 pk[4];
#pragma unroll
        for (int r = 0; r < 4; r++) pk[r] = f2b_rne(acc[i][j][r] + bj[j]);
        *(uint2*)((u16*)tl.out + (size_t)col * tl.ldOut + row0) = *(uint2*)pk;
      } else {
#pragma unroll
        for (int r = 0; r < 4; r++) {
          float v = acc[i][j][r] + bj[j];
          if (ACT == 1) v = sanitize_f(v);
          if (ACT == 2) v = (v > 0.f) ? v : 0.2f * v;
          if (tl.obf16) ((u16*)tl.out)[(size_t)(row0 + r) * tl.ldOut + col] = f2b_rne(v);
          else          tl.out[(size_t)(row0 + r) * tl.ldOut + col] = v;
        }
      }
    }
  }
}

// ---------------- img GEMM split-K: K=2048 over 4 z-blocks of 512 ----------------
__global__ __launch_bounds__(256) void gemm_img_splitk(const float* __restrict__ A, const float* __restrict__ W,
                                                       float* __restrict__ part) {
  __shared__ short As[64 * 40];
  __shared__ short Bs[64 * 40];
  const int t = threadIdx.x;
  const int bm = blockIdx.x * 64, bn = blockIdx.y * 64, ks = blockIdx.z;
  const int w = t >> 6, l = t & 63, g = l >> 4, r16 = l & 15;
  const int wr = w >> 1, wc = w & 1;
  const int lrow = t >> 2, lseg = (t & 3) * 8;

  const float* Ap = A + (size_t)(bm + lrow) * 2048 + ks * 512 + lseg;
  const float* Wp = W + (size_t)(bn + lrow) * 2048 + ks * 512 + lseg;

  f32x4 acc[2][2] = {{{0.f,0.f,0.f,0.f},{0.f,0.f,0.f,0.f}},{{0.f,0.f,0.f,0.f},{0.f,0.f,0.f,0.f}}};
  for (int k0 = 0; k0 < 512; k0 += 32) {
    float4 a0 = load4f(Ap + k0), a1 = load4f(Ap + k0 + 4);
    float4 b0 = load4f(Wp + k0), b1 = load4f(Wp + k0 + 4);
    __syncthreads();
    *(uint4*)&As[lrow * 40 + lseg] =
        make_uint4(pack2(a0.x,a0.y), pack2(a0.z,a0.w), pack2(a1.x,a1.y), pack2(a1.z,a1.w));
    *(uint4*)&Bs[lrow * 40 + lseg] =
        make_uint4(pack2(b0.x,b0.y), pack2(b0.z,b0.w), pack2(b1.x,b1.y), pack2(b1.z,b1.w));
    __syncthreads();
    short8 af0 = *(const short8*)&As[(wr*32 +      r16) * 40 + 8*g];
    short8 af1 = *(const short8*)&As[(wr*32 + 16 + r16) * 40 + 8*g];
    short8 bf0 = *(const short8*)&Bs[(wc*32 +      r16) * 40 + 8*g];
    short8 bf1 = *(const short8*)&Bs[(wc*32 + 16 + r16) * 40 + 8*g];
    acc[0][0] = __builtin_amdgcn_mfma_f32_16x16x32_bf16(af0, bf0, acc[0][0], 0, 0, 0);
    acc[0][1] = __builtin_amdgcn_mfma_f32_16x16x32_bf16(af0, bf1, acc[0][1], 0, 0, 0);
    acc[1][0] = __builtin_amdgcn_mfma_f32_16x16x32_bf16(af1, bf0, acc[1][0], 0, 0, 0);
    acc[1][1] = __builtin_amdgcn_mfma_f32_16x16x32_bf16(af1, bf1, acc[1][1], 0, 0, 0);
  }
  float* op = part + (size_t)ks * (NN * 256);
#pragma unroll
  for (int i = 0; i < 2; i++) {
#pragma unroll
    for (int j = 0; j < 2; j++) {
      int col = bn + wc*32 + 16*j + r16;
#pragma unroll
      for (int r = 0; r < 4; r++) {
        int row = bm + wr*32 + 16*i + 4*g + r;
        op[(size_t)row * 256 + col] = acc[i][j][r];
      }
    }
  }
}
__global__ __launch_bounds__(256) void gemm_img_reduce(const float* __restrict__ part,
                                                       const float* __restrict__ bias,
                                                       float* __restrict__ h) {
  int idx = blockIdx.x * 256 + threadIdx.x;   // 262144 threads, 4 floats each
  int row = idx >> 6, c4 = (idx & 63) * 4;
  size_t o = (size_t)row * 256 + c4;
  float4 s = load4f(part + o);
  float4 p1 = load4f(part + 1048576 + o);
  float4 p2 = load4f(part + 2097152 + o);
  float4 p3 = load4f(part + 3145728 + o);
  float4 bb = load4f(bias + c4);
  s.x += p1.x + p2.x + p3.x + bb.x;
  s.y += p1.y + p2.y + p3.y + bb.y;
  s.z += p1.z + p2.z + p3.z + bb.z;
  s.w += p1.w + p2.w + p3.w + bb.w;
  *(float4*)&h[o] = s;
}

// ---------------- causal MHA v4: 64-q blocks, LDS-shared K/V, pipelined, split-K x4 ----------------
// grid 1024: ks = bid&3, h = (bid>>2)&3, T = 63-(bid>>4). Block handles k-tiles kt%4==ks.
#define KSTR 72   // LDS row stride in shorts
__global__ __launch_bounds__(256, 4) void mha_mfma3(const u16* __restrict__ qkb, const u16* __restrict__ vtb,
                                                    float* __restrict__ Opart, float* __restrict__ mspart) {
  __shared__ u16 Ks[64 * KSTR];
  __shared__ u16 Vs[64 * KSTR];
  const int bid = blockIdx.x;
  const int ks  = bid & 3;
  const int hh  = (bid >> 2) & 3;
  const int T   = 63 - (bid >> 4);
  const int q0  = T * 64;
  const int t   = threadIdx.x;
  const int w   = t >> 6, l = t & 63, g = l >> 4, r16 = l & 15;
  const int hofs = hh * 64;
  const int lrow = t >> 3, lc8 = (t & 7) * 8;   // staging: 32 rows x 64 cols per pass

  const u16* qrow = qkb + (size_t)(q0 + 16 * w + r16) * 512 + hofs;
  short8 Qf0 = *(const short8*)&qrow[8 * g];
  short8 Qf1 = *(const short8*)&qrow[32 + 8 * g];

  f32x4 O0 = {0.f,0.f,0.f,0.f}, O1 = O0, O2 = O0, O3 = O0;
  float m = -INFINITY, ssum = 0.f;

  uint4 rk0, rk1, rv0, rv1;
  if (ks <= T) {
    int k0 = ks * 64;
    rk0 = *(const uint4*)&qkb[(size_t)(k0 + lrow) * 512 + 256 + hofs + lc8];
    rk1 = *(const uint4*)&qkb[(size_t)(k0 + 32 + lrow) * 512 + 256 + hofs + lc8];
    rv0 = *(const uint4*)&vtb[(size_t)(hofs + lrow) * 4096 + k0 + lc8];
    rv1 = *(const uint4*)&vtb[(size_t)(hofs + 32 + lrow) * 4096 + k0 + lc8];
  }
  for (int kt = ks; kt <= T; kt += 4) {
    __syncthreads();
    *(uint4*)&Ks[lrow * KSTR + lc8]        = rk0;
    *(uint4*)&Ks[(32 + lrow) * KSTR + lc8] = rk1;
    *(uint4*)&Vs[lrow * KSTR + lc8]        = rv0;
    *(uint4*)&Vs[(32 + lrow) * KSTR + lc8] = rv1;
    __syncthreads();
    if (kt + 4 <= T) {
      int k2 = (kt + 4) * 64;
      rk0 = *(const uint4*)&qkb[(size_t)(k2 + lrow) * 512 + 256 + hofs + lc8];
      rk1 = *(const uint4*)&qkb[(size_t)(k2 + 32 + lrow) * 512 + 256 + hofs + lc8];
      rv0 = *(const uint4*)&vtb[(size_t)(hofs + lrow) * 4096 + k2 + lc8];
      rv1 = *(const uint4*)&vtb[(size_t)(hofs + 32 + lrow) * 4096 + k2 + lc8];
    }
    f32x4 S0 = {0.f,0.f,0.f,0.f}, S1 = S0, S2 = S0, S3 = S0;
    {
      short8 a0 = *(const short8*)&Ks[(r16)      * KSTR + 8*g];
      short8 a1 = *(const short8*)&Ks[(16 + r16) * KSTR + 8*g];
      short8 a2 = *(const short8*)&Ks[(32 + r16) * KSTR + 8*g];
      short8 a3 = *(const short8*)&Ks[(48 + r16) * KSTR + 8*g];
      S0 = __builtin_amdgcn_mfma_f32_16x16x32_bf16(a0, Qf0, S0, 0, 0, 0);
      S1 = __builtin_amdgcn_mfma_f32_16x16x32_bf16(a1, Qf0, S1, 0, 0, 0);
      S2 = __builtin_amdgcn_mfma_f32_16x16x32_bf16(a2, Qf0, S2, 0, 0, 0);
      S3 = __builtin_amdgcn_mfma_f32_16x16x32_bf16(a3, Qf0, S3, 0, 0, 0);
      short8 b0 = *(const short8*)&Ks[(r16)      * KSTR + 32 + 8*g];
      short8 b1 = *(const short8*)&Ks[(16 + r16) * KSTR + 32 + 8*g];
      short8 b2 = *(const short8*)&Ks[(32 + r16) * KSTR + 32 + 8*g];
      short8 b3 = *(const short8*)&Ks[(48 + r16) * KSTR + 32 + 8*g];
      S0 = __builtin_amdgcn_mfma_f32_16x16x32_bf16(b0, Qf1, S0, 0, 0, 0);
      S1 = __builtin_amdgcn_mfma_f32_16x16x32_bf16(b1, Qf1, S1, 0, 0, 0);
      S2 = __builtin_amdgcn_mfma_f32_16x16x32_bf16(b2, Qf1, S2, 0, 0, 0);
      S3 = __builtin_amdgcn_mfma_f32_16x16x32_bf16(b3, Qf1, S3, 0, 0, 0);
    }
    float sc[4][4];
#pragma unroll
    for (int r = 0; r < 4; r++) {
      sc[0][r] = S0[r] * 0.125f; sc[1][r] = S1[r] * 0.125f;
      sc[2][r] = S2[r] * 0.125f; sc[3][r] = S3[r] * 0.125f;
    }
    if (kt == T) {
#pragma unroll
      for (int mb = 0; mb < 4; mb++)
#pragma unroll
        for (int r = 0; r < 4; r++)
          if (16 * mb + 4 * g + r > 16 * w + r16) sc[mb][r] = -INFINITY;
    }
    float tm = sc[0][0];
#pragma unroll
    for (int mb = 0; mb < 4; mb++)
#pragma unroll
      for (int r = 0; r < 4; r++) tm = fmaxf(tm, sc[mb][r]);
    tm = fmaxf(tm, __shfl_xor(tm, 16));
    tm = fmaxf(tm, __shfl_xor(tm, 32));
    float mn = fmaxf(m, tm);
    float ef = __expf(m - mn);
    float pv[4][4];
    float ps = 0.f;
#pragma unroll
    for (int mb = 0; mb < 4; mb++)
#pragma unroll
      for (int r = 0; r < 4; r++) { pv[mb][r] = __expf(sc[mb][r] - mn); ps += pv[mb][r]; }
    ps += __shfl_xor(ps, 16);
    ps += __shfl_xor(ps, 32);
    ssum = ssum * ef + ps;
    m = mn;
#pragma unroll
    for (int r = 0; r < 4; r++) {
      float efr = __shfl(ef, 4 * g + r);
      O0[r] *= efr; O1[r] *= efr; O2[r] *= efr; O3[r] *= efr;
    }
    u32 pk[2][4];
#pragma unroll
    for (int c = 0; c < 2; c++)
#pragma unroll
      for (int rs = 0; rs < 4; rs++) pk[c][rs] = pack2(pv[2 * c][rs], pv[2 * c + 1][rs]);
    short8 ap[2];
#pragma unroll
    for (int c = 0; c < 2; c++) {
#pragma unroll
      for (int jb = 0; jb < 2; jb++) {
        int x = 2 * g + jb;
        int hi = x >> 2;
        int src = r16 + 16 * (x & 3);
#pragma unroll
        for (int rs = 0; rs < 4; rs++) {
          u32 v = __shfl(pk[c][rs], src);
          ap[c][jb * 4 + rs] = (short)(hi ? (v >> 16) : (v & 0xffff));
        }
      }
    }
    {
      short8 V00 = *(const short8*)&Vs[(r16)      * KSTR + 8*g];
      short8 V10 = *(const short8*)&Vs[(16 + r16) * KSTR + 8*g];
      short8 V20 = *(const short8*)&Vs[(32 + r16) * KSTR + 8*g];
      short8 V30 = *(const short8*)&Vs[(48 + r16) * KSTR + 8*g];
      O0 = __builtin_amdgcn_mfma_f32_16x16x32_bf16(ap[0], V00, O0, 0, 0, 0);
      O1 = __builtin_amdgcn_mfma_f32_16x16x32_bf16(ap[0], V10, O1, 0, 0, 0);
      O2 = __builtin_amdgcn_mfma_f32_16x16x32_bf16(ap[0], V20, O2, 0, 0, 0);
      O3 = __builtin_amdgcn_mfma_f32_16x16x32_bf16(ap[0], V30, O3, 0, 0, 0);
      short8 V01 = *(const short8*)&Vs[(r16)      * KSTR + 32 + 8*g];
      short8 V11 = *(const short8*)&Vs[(16 + r16) * KSTR + 32 + 8*g];
      short8 V21 = *(const short8*)&Vs[(32 + r16) * KSTR + 32 + 8*g];
      short8 V31 = *(const short8*)&Vs[(48 + r16) * KSTR + 32 + 8*g];
      O0 = __builtin_amdgcn_mfma_f32_16x16x32_bf16(ap[1], V01, O0, 0, 0, 0);
      O1 = __builtin_amdgcn_mfma_f32_16x16x32_bf16(ap[1], V11, O1, 0, 0, 0);
      O2 = __builtin_amdgcn_mfma_f32_16x16x32_bf16(ap[1], V21, O2, 0, 0, 0);
      O3 = __builtin_amdgcn_mfma_f32_16x16x32_bf16(ap[1], V31, O3, 0, 0, 0);
    }
  }

  size_t ob = (size_t)bid * 4096;
#pragma unroll
  for (int r = 0; r < 4; r++) {
    int q = 16 * w + 4 * g + r;
    Opart[ob + q * 64 + r16]      = O0[r];
    Opart[ob + q * 64 + 16 + r16] = O1[r];
    Opart[ob + q * 64 + 32 + r16] = O2[r];
    Opart[ob + q * 64 + 48 + r16] = O3[r];
  }
  if (l < 16) {
    mspart[bid * 128 + 16 * w + l]      = m;
    mspart[bid * 128 + 64 + 16 * w + l] = ssum;
  }
}

// merge 4 stripe-partials -> normalized output. grid 256: T = mb>>2, h = mb&3.
__global__ __launch_bounds__(256) void mha_merge3(const float* __restrict__ Opart, const float* __restrict__ mspart,
                                                  float* __restrict__ out) {
  int mb = blockIdx.x;
  int h = mb & 3, T = mb >> 2;
  int bid0 = ((63 - T) << 4) | (h << 2);
  int t = threadIdx.x;
  int q = t >> 2, dbase = (t & 3) * 16;
  float mm[4], ss[4];
#pragma unroll
  for (int i = 0; i < 4; i++) {
    mm[i] = mspart[(bid0 + i) * 128 + q];
    ss[i] = mspart[(bid0 + i) * 128 + 64 + q];
  }
  float M = fmaxf(fmaxf(mm[0], mm[1]), fmaxf(mm[2], mm[3]));   // mm[0] always finite
  float e[4];
  float S = 0.f;
#pragma unroll
  for (int i = 0; i < 4; i++) {
    e[i] = (mm[i] == -INFINITY) ? 0.f : __expf(mm[i] - M);
    S += e[i] * ss[i];
  }
  float inv = 1.f / S;
  float* Y = out + (size_t)(T * 64 + q) * EMB + h * 64 + dbase;
#pragma unroll
  for (int i = 0; i < 4; i++) {
    float4 a0 = load4f(Opart + (size_t)(bid0 + 0) * 4096 + q * 64 + dbase + 4 * i);
    float4 a1 = load4f(Opart + (size_t)(bid0 + 1) * 4096 + q * 64 + dbase + 4 * i);
    float4 a2 = load4f(Opart + (size_t)(bid0 + 2) * 4096 + q * 64 + dbase + 4 * i);
    float4 a3 = load4f(Opart + (size_t)(bid0 + 3) * 4096 + q * 64 + dbase + 4 * i);
    float4 r;
    r.x = (e[0]*a0.x + e[1]*a1.x + e[2]*a2.x + e[3]*a3.x) * inv;
    r.y = (e[0]*a0.y + e[1]*a1.y + e[2]*a2.y + e[3]*a3.y) * inv;
    r.z = (e[0]*a0.z + e[1]*a1.z + e[2]*a2.z + e[3]*a3.z) * inv;
    r.w = (e[0]*a0.w + e[1]*a1.w + e[2]*a2.w + e[3]*a3.w) * inv;
    *(float4*)(Y + 4 * i) = r;
  }
}

// ---------------- CSR build ----------------
__global__ void zero_i32(int* p, int n) {
  int i = blockIdx.x * 256 + threadIdx.x;
  if (i < n) p[i] = 0;
}
__global__ void hist_dst(const int* __restrict__ adj, int* __restrict__ cnt) {
  int e = blockIdx.x * 256 + threadIdx.x;
  if (e < NE) atomicAdd(&cnt[adj[NE + e]], 1);
}
__global__ __launch_bounds__(1024) void scan4096(const int* __restrict__ cnt, int* __restrict__ indptr,
                                                 int* __restrict__ cursor) {
  int t = threadIdx.x;
  int4 c = *reinterpret_cast<const int4*>(cnt + t * 4);
  int s0 = c.x, s1 = s0 + c.y, s2 = s1 + c.z, s3 = s2 + c.w;
  int lane = t & 63, w = t >> 6;
  int x = s3;
#pragma unroll
  for (int off = 1; off < 64; off <<= 1) {
    int y = __shfl_up(x, off);
    if (lane >= off) x += y;
  }
  __shared__ int wsum[16];
  if (lane == 63) wsum[w] = x;
  __syncthreads();
  if (t == 0) {
    int acc = 0;
    for (int i = 0; i < 16; i++) { int tv = wsum[i]; wsum[i] = acc; acc += tv; }
  }
  __syncthreads();
  int b = wsum[w] + x - s3;
  indptr[t*4+0] = b;      indptr[t*4+1] = b + s0;
  indptr[t*4+2] = b + s1; indptr[t*4+3] = b + s2;
  cursor[t*4+0] = b;      cursor[t*4+1] = b + s0;
  cursor[t*4+2] = b + s1; cursor[t*4+3] = b + s2;
  if (t == 1023) indptr[4096] = b + s3;
}
__global__ void scatter_edges(const int* __restrict__ adj, int* __restrict__ cursor, int* __restrict__ esrc) {
  int e = blockIdx.x * 256 + threadIdx.x;
  if (e < NE) {
    int dst = adj[NE + e];
    int pos = atomicAdd(&cursor[dst], 1);
    esrc[pos] = adj[e];
  }
}

// ---------------- TransformerConv aggregation: cooperative K-row gather + octet dot ----------------
__global__ __launch_bounds__(256, 4) void conv_agg(const float* __restrict__ qb, const u16* __restrict__ kb,
                                                   const u16* __restrict__ vb, const int* __restrict__ indptr,
                                                   const int* __restrict__ esrc, float* __restrict__ y) {
  __shared__ float q_s[EMB];
  __shared__ float sc_s[NH][64];
  __shared__ float p_s[NH][64];
  __shared__ int   s_s[64];
  int n = blockIdx.x;
  int tid = threadIdx.x;
  int h = tid >> 6, lane = tid & 63;
  int lr8 = lane >> 3;            // row within octet-group (0..7)
  int lseg = (lane & 7) * 8;      // dim octet base
  q_s[tid] = qb[(size_t)n * EMB + tid] * 0.125f;   // fold 1/sqrt(D) into q
  int start = indptr[n], end = indptr[n + 1];
  __syncthreads();
  const float* qh = &q_s[h * HD];
  float q8[8];
#pragma unroll
  for (int j = 0; j < 8; j++) q8[j] = qh[lseg + j];
  float m = -INFINITY, s = 0.f;
  float o0 = 0.f, o1 = 0.f, o2 = 0.f, o3 = 0.f;
  for (int p0 = start; p0 < end; p0 += 64) {
    int nk = end - p0; if (nk > 64) nk = 64;
    if (h == 0) s_s[lane] = (lane < nk) ? esrc[p0 + lane] : 0;
    __syncthreads();
#pragma unroll
    for (int pass = 0; pass < 8; pass++) {
      int row = pass * 8 + lr8;
      int src = s_s[row];
      short8 k8 = *(const short8*)&kb[(size_t)src * EMB + h * HD + lseg];
      float a0 = fmaf(b2f((u16)k8[0]), q8[0], 0.f);
      float a1 = fmaf(b2f((u16)k8[1]), q8[1], 0.f);
      a0 = fmaf(b2f((u16)k8[2]), q8[2], a0);
      a1 = fmaf(b2f((u16)k8[3]), q8[3], a1);
      a0 = fmaf(b2f((u16)k8[4]), q8[4], a0);
      a1 = fmaf(b2f((u16)k8[5]), q8[5], a1);
      a0 = fmaf(b2f((u16)k8[6]), q8[6], a0);
      a1 = fmaf(b2f((u16)k8[7]), q8[7], a1);
      float acc = a0 + a1;
      acc += __shfl_xor(acc, 1);
      acc += __shfl_xor(acc, 2);
      acc += __shfl_xor(acc, 4);
      if ((lane & 7) == 0) sc_s[h][row] = (row < nk) ? acc : -INFINITY;
    }
    float sc = sc_s[h][lane];
    float bm = sc;
#pragma unroll
    for (int off = 32; off; off >>= 1) bm = fmaxf(bm, __shfl_xor(bm, off));
    float mn = fmaxf(m, bm);
    float ef = __expf(m - mn);
    float p = __expf(sc - mn);
    float ps = p;
#pragma unroll
    for (int off = 32; off; off >>= 1) ps += __shfl_xor(ps, off);
    s = s * ef + ps;
    m = mn;
    o0 *= ef; o1 *= ef; o2 *= ef; o3 *= ef;
    p_s[h][lane] = p;
    const u16* vcol = vb + h * HD + lane;
    int nk4 = (nk + 3) & ~3;
    for (int jj = 0; jj < nk4; jj += 4) {
      float pa = p_s[h][jj],   pb = p_s[h][jj+1];
      float pc = p_s[h][jj+2], pd = p_s[h][jj+3];
      int sa = s_s[jj], sb = s_s[jj+1], scx = s_s[jj+2], sd = s_s[jj+3];
      o0 = fmaf(pa, b2f(vcol[(size_t)sa  * EMB]), o0);
      o1 = fmaf(pb, b2f(vcol[(size_t)sb  * EMB]), o1);
      o2 = fmaf(pc, b2f(vcol[(size_t)scx * EMB]), o2);
      o3 = fmaf(pd, b2f(vcol[(size_t)sd  * EMB]), o3);
    }
    __syncthreads();
  }
  float o = (o0 + o1) + (o2 + o3);
  float agg = o / (s + 1e-16f);
  y[(size_t)n * EMB + h * HD + lane] += agg;
}

// ---------------- instance norm + lrelu + sanitize ----------------
__global__ __launch_bounds__(256) void colstats_partial(const float* __restrict__ y, float* __restrict__ part) {
  int c = threadIdx.x;
  int r0 = blockIdx.x * 128;
  float s = 0.f, q = 0.f;
  for (int r = r0; r < r0 + 128; r++) {
    float v = y[(size_t)r * EMB + c];
    s += v; q = fmaf(v, v, q);
  }
  part[blockIdx.x * 512 + c] = s;
  part[blockIdx.x * 512 + 256 + c] = q;
}
__global__ __launch_bounds__(256) void colstats_final(const float* __restrict__ part, float* __restrict__ stats) {
  int c = threadIdx.x;
  float s = 0.f, q = 0.f;
  for (int b = 0; b < 32; b++) { s += part[b * 512 + c]; q += part[b * 512 + 256 + c]; }
  float mean = s * (1.f / 4096.f);
  float var  = q * (1.f / 4096.f) - mean * mean;
  stats[c] = mean;
  stats[256 + c] = rsqrtf(var + 1e-5f);
}
__global__ __launch_bounds__(256) void norm_apply(const float* __restrict__ y, const float* __restrict__ stats,
                                                  float* __restrict__ f, int colOff) {
  int c = threadIdx.x;
  float mean = stats[c], rstd = stats[256 + c];
  int r0 = blockIdx.x * 16;
  for (int r = r0; r < r0 + 16; r++) {
    float v = (y[(size_t)r * EMB + c] - mean) * rstd;
    v = (v > 0.f) ? v : 0.2f * v;
    v = sanitize_f(v);
    f[(size_t)r * 512 + colOff + c] = v;
  }
}

// ---------------- classifier tail ----------------
__global__ __launch_bounds__(256) void final_softmax(const float* __restrict__ f1, const float* __restrict__ W2,
                                                     const float* __restrict__ b2, float* __restrict__ out) {
  int w = threadIdx.x >> 6, lane = threadIdx.x & 63;
  int row = blockIdx.x * 4 + w;
  const float* fr = f1 + (size_t)row * 128;
  float x0 = fr[lane], x1 = fr[lane + 64];
  float p0 = x0 * W2[lane]       + x1 * W2[64 + lane];
  float p1 = x0 * W2[128 + lane] + x1 * W2[192 + lane];
#pragma unroll
  for (int off = 32; off; off >>= 1) { p0 += __shfl_xor(p0, off); p1 += __shfl_xor(p1, off); }
  if (lane == 0) {
    float l0 = p0 + b2[0], l1 = p1 + b2[1];
    float mx = fmaxf(l0, l1);
    float e0 = __expf(l0 - mx), e1 = __expf(l1 - mx);
    float inv = 1.f / (e0 + e1);
    out[(size_t)row * 2 + 0] = l0;
    out[(size_t)row * 2 + 1] = l1;
    out[8192 + (size_t)row * 2 + 0] = e0 * inv;
    out[8192 + (size_t)row * 2 + 1] = e1 * inv;
  }
}

extern "C" void kernel_launch(void* const* d_in, const int* in_sizes, int n_in,
                              void* d_out, int out_size, void* d_ws, size_t ws_size,
                              hipStream_t stream) {
  const float* img   = (const float*)d_in[2];
  const int*   adj   = (const int*)d_in[3];
  const float* W_img = (const float*)d_in[4];  const float* b_img = (const float*)d_in[5];
  const float* W_qkv = (const float*)d_in[6];  const float* b_qkv = (const float*)d_in[7];
  const float* W_o   = (const float*)d_in[8];  const float* b_o   = (const float*)d_in[9];
  const float* Wq_o  = (const float*)d_in[10]; const float* bq_o  = (const float*)d_in[11];
  const float* Wk_o  = (const float*)d_in[12]; const float* bk_o  = (const float*)d_in[13];
  const float* Wv_o  = (const float*)d_in[14]; const float* bv_o  = (const float*)d_in[15];
  const float* Ws_o  = (const float*)d_in[16]; const float* bs_o  = (const float*)d_in[17];
  const float* Wq_a  = (const float*)d_in[18]; const float* bq_a  = (const float*)d_in[19];
  const float* Wk_a  = (const float*)d_in[20]; const float* bk_a  = (const float*)d_in[21];
  const float* Wv_a  = (const float*)d_in[22]; const float* bv_a  = (const float*)d_in[23];
  const float* Ws_a  = (const float*)d_in[24]; const float* bs_a  = (const float*)d_in[25];
  const float* W_c1  = (const float*)d_in[26]; const float* b_c1  = (const float*)d_in[27];
  const float* W_c2  = (const float*)d_in[28]; const float* b_c2  = (const float*)d_in[29];

  char* ws = (char*)d_ws;
  float* h     = (float*)(ws + 0);                    // 4 MB
  float* hattn = (float*)(ws + (4ull << 20));         // 4 MB (aliased as qkb during mha)
  float* qkv   = (float*)(ws + (8ull << 20));         // 12 MB
  float* y     = (float*)(ws + (20ull << 20));        // 4 MB
  float* f     = (float*)(ws + (24ull << 20));        // 8 MB
  float* f1    = (float*)(ws + (32ull << 20));        // 2 MB (aliased as vtb during mha)
  int*   indptr= (int*)  (ws + (34ull << 20));
  int*   cursor= (int*)  (ws + (34ull << 20) + 20480);
  int*   esrc  = (int*)  (ws + (34ull << 20) + 40960);  // 1 MB
  float* part  = (float*)(ws + (34ull << 20) + 40960 + (1ull << 20));
  float* stats = (float*)(ws + (34ull << 20) + 40960 + (1ull << 20) + 65536);

  u16* qkb = (u16*)hattn;   // 4 MB, dead after mha (hattn written at step 4)
  u16* vtb = (u16*)f1;      // 2 MB, dead after mha (f1 written at step 8)

  float* imgpart = qkv;          // 16 MB contiguous (qkv+y), free during step 1
  float* Opart   = qkv;          // 16 MB (1024 blocks x 4096 floats) over qkv+y, free during mha
  float* mspart  = (float*)esrc; // 512 KB, free during mha (CSR built later)
  float* ymha    = f;            // 4 MB mha output in f region (free until norm_apply)

  float* qb   = qkv;                         // 4 MB f32 (step 6+)
  u16*   kb16 = (u16*)(ws + (12ull << 20));  // 2 MB bf16
  u16*   vb16 = (u16*)(ws + (14ull << 20));  // 2 MB bf16

  dim3 b256(256);

  // 1. h = img_feat @ W_img^T + b_img   (M=4096,N=256,K=2048) split-K x4
  gemm_img_splitk<<<dim3(64, 4, 4), b256, 0, stream>>>(img, W_img, imgpart);
  gemm_img_reduce<<<1024, b256, 0, stream>>>(imgpart, b_img, h);
  // 2. qkv GEMM writes mha-ready buffers directly: Q|K -> qkb (bf16), V -> vtb (bf16 transposed)
  {
    GArgs ga;
    for (int i = 0; i < 8; i++)
      ga.t[i]  = { W_qkv + (size_t)i * 64 * 256, b_qkv + i * 64, (float*)qkb, i * 64, 512, 1 };
    for (int i = 8; i < 12; i++)
      ga.t[i]  = { W_qkv + (size_t)i * 64 * 256, b_qkv + i * 64, (float*)vtb, (i - 8) * 64, 4096, 2 };
    gemm_mfma<0><<<dim3(64, 12), b256, 0, stream>>>(h, ga, 256);
  }
  // 3. causal MHA v4 (64q blocks, LDS K/V, split-K x4) -> ymha (f region)
  mha_mfma3<<<1024, b256, 0, stream>>>(qkb, vtb, Opart, mspart);
  mha_merge3<<<256, b256, 0, stream>>>(Opart, mspart, ymha);
  // 4. h_attn = sanitize(ymha @ W_o^T + b_o)
  {
    GArgs ga;
    for (int i = 0; i < 4; i++)
      ga.t[i] = { W_o + (size_t)i * 64 * 256, b_o + i * 64, hattn, i * 64, 256, 0 };
    gemm_mfma<1><<<dim3(64, 4), b256, 0, stream>>>(ymha, ga, 256);
  }
  // 5. CSR of video_adj_list grouped by dst
  zero_i32<<<16, b256, 0, stream>>>(cursor, NN);
  hist_dst<<<NE / 256, b256, 0, stream>>>(adj, cursor);
  scan4096<<<1, 1024, 0, stream>>>(cursor, indptr, cursor);
  scatter_edges<<<NE / 256, b256, 0, stream>>>(adj, cursor, esrc);

  // 6. conv path O: q/k/v/skip fused (N=1024,K=256), input h; k,v in bf16
  {
    const float* Wg[4] = { Wq_o, Wk_o, Wv_o, Ws_o };
    const float* bg[4] = { bq_o, bk_o, bv_o, bs_o };
    float*       og[4] = { qb, (float*)kb16, (float*)vb16, y };
    const int    bf[4] = { 0, 1, 1, 0 };
    GArgs ga;
    for (int i = 0; i < 16; i++) {
      int gdx = i >> 2, li = i & 3;
      ga.t[i] = { Wg[gdx] + (size_t)li * 64 * 256, bg[gdx] + li * 64, og[gdx], li * 64, 256, bf[gdx] };
    }
    gemm_mfma<0><<<dim3(64, 16), b256, 0, stream>>>(h, ga, 256);
  }
  conv_agg<<<NN, b256, 0, stream>>>(qb, kb16, vb16, indptr, esrc, y);
  colstats_partial<<<32, b256, 0, stream>>>(y, part);
  colstats_final<<<1, b256, 0, stream>>>(part, stats);
  norm_apply<<<256, b256, 0, stream>>>(y, stats, f, 0);

  // 7. conv path A: same, input hattn
  {
    const float* Wg[4] = { Wq_a, Wk_a, Wv_a, Ws_a };
    const float* bg[4] = { bq_a, bk_a, bv_a, bs_a };
    float*       og[4] = { qb, (float*)kb16, (float*)vb16, y };
    const int    bf[4] = { 0, 1, 1, 0 };
    GArgs ga;
    for (int i = 0; i < 16; i++) {
      int gdx = i >> 2, li = i & 3;
      ga.t[i] = { Wg[gdx] + (size_t)li * 64 * 256, bg[gdx] + li * 64, og[gdx], li * 64, 256, bf[gdx] };
    }
    gemm_mfma<0><<<dim3(64, 16), b256, 0, stream>>>(hattn, ga, 256);
  }
  conv_agg<<<NN, b256, 0, stream>>>(qb, kb16, vb16, indptr, esrc, y);
  colstats_partial<<<32, b256, 0, stream>>>(y, part);
  colstats_final<<<1, b256, 0, stream>>>(part, stats);
  norm_apply<<<256, b256, 0, stream>>>(y, stats, f, 256);

  // 8. f1 = lrelu(f @ W_c1^T + b_c1)   (N=128,K=512)
  {
    GArgs ga;
    for (int i = 0; i < 2; i++)
      ga.t[i] = { W_c1 + (size_t)i * 64 * 512, b_c1 + i * 64, f1, i * 64, 128, 0 };
    gemm_mfma<2><<<dim3(64, 2), b256, 0, stream>>>(f, ga, 512);
  }
  // 9. logits + softmax -> out (f32): [0:8192] logits, [8192:16384] probs
  final_softmax<<<NN / 4, b256, 0, stream>>>(f1, W_c2, b_c2, (float*)d_out);
}

// Round 15
// 250.814 us; speedup vs baseline: 1.8676x; 1.0903x over previous
//
#include <hip/hip_runtime.h>
#include <hip/hip_bf16.h>

typedef unsigned short u16;
typedef unsigned int   u32;
typedef __attribute__((ext_vector_type(8))) short short8;
typedef __attribute__((ext_vector_type(4))) float f32x4;

#define NN 4096        // nodes
#define NE 262144      // edges
#define EMB 256
#define NH 4
#define HD 64

__device__ __forceinline__ float4 load4f(const float* p) { return *reinterpret_cast<const float4*>(p); }
__device__ __forceinline__ float sanitize_f(float v) {
  v = (v != v) ? 0.f : v;                 // nan -> 0
  return fminf(fmaxf(v, -1000.f), 1000.f); // +-inf and clip -> +-1000
}
__device__ __forceinline__ u16 f2b_rne(float x) {          // f32 -> bf16 bits, round-nearest-even
  u32 b = __float_as_uint(x);
  b += 0x7fff + ((b >> 16) & 1);
  return (u16)(b >> 16);
}
__device__ __forceinline__ u32 pack2(float a, float b) {
  return (u32)f2b_rne(a) | ((u32)f2b_rne(b) << 16);
}
__device__ __forceinline__ float b2f(u16 u) { return __uint_as_float((u32)u << 16); }

// ================= generic MFMA GEMM: out = act(A[M,K] @ W^T + bias) =================
struct GTile {
  const float* A;     // input rows [M][K] (per-tile: lets one dispatch mix inputs)
  const float* W;     // 64 weight rows for this tile: [64][K]
  const float* bias;  // 64 entries
  float*       out;   // f32 / bf16 / bf16-transposed
  int          colOff;
  int          ldOut;
  int          obf16; // 0: f32 row-major; 1: bf16 row-major; 2: bf16 TRANSPOSED out[col*ldOut+row]
};
struct GArgs { GTile t[32]; };

// 256 threads = 4 waves; block tile 64x64; wave tile 32x32 (2x2 frags of 16x16x32).
template<int ACT>   // 0 none, 1 sanitize, 2 lrelu(0.2)
__global__ __launch_bounds__(256) void gemm_mfma(const GArgs ga, int K) {
  __shared__ short As[64 * 40];
  __shared__ short Bs[64 * 40];
  const int t = threadIdx.x;
  const int bm = blockIdx.x * 64;
  const GTile tl = ga.t[blockIdx.y];
  const int w = t >> 6, l = t & 63, g = l >> 4, r16 = l & 15;
  const int wr = w >> 1, wc = w & 1;
  const int lrow = t >> 2, lseg = (t & 3) * 8;

  const float* Ap = tl.A + (size_t)(bm + lrow) * K + lseg;
  const float* Wp = tl.W + (size_t)lrow * K + lseg;

  f32x4 acc[2][2] = {{{0.f,0.f,0.f,0.f},{0.f,0.f,0.f,0.f}},{{0.f,0.f,0.f,0.f},{0.f,0.f,0.f,0.f}}};
  for (int k0 = 0; k0 < K; k0 += 32) {
    float4 a0 = load4f(Ap + k0), a1 = load4f(Ap + k0 + 4);
    float4 b0 = load4f(Wp + k0), b1 = load4f(Wp + k0 + 4);
    __syncthreads();
    *(uint4*)&As[lrow * 40 + lseg] =
        make_uint4(pack2(a0.x,a0.y), pack2(a0.z,a0.w), pack2(a1.x,a1.y), pack2(a1.z,a1.w));
    *(uint4*)&Bs[lrow * 40 + lseg] =
        make_uint4(pack2(b0.x,b0.y), pack2(b0.z,b0.w), pack2(b1.x,b1.y), pack2(b1.z,b1.w));
    __syncthreads();
    short8 af0 = *(const short8*)&As[(wr*32 +      r16) * 40 + 8*g];
    short8 af1 = *(const short8*)&As[(wr*32 + 16 + r16) * 40 + 8*g];
    short8 bf0 = *(const short8*)&Bs[(wc*32 +      r16) * 40 + 8*g];
    short8 bf1 = *(const short8*)&Bs[(wc*32 + 16 + r16) * 40 + 8*g];
    acc[0][0] = __builtin_amdgcn_mfma_f32_16x16x32_bf16(af0, bf0, acc[0][0], 0, 0, 0);
    acc[0][1] = __builtin_amdgcn_mfma_f32_16x16x32_bf16(af0, bf1, acc[0][1], 0, 0, 0);
    acc[1][0] = __builtin_amdgcn_mfma_f32_16x16x32_bf16(af1, bf0, acc[1][0], 0, 0, 0);
    acc[1][1] = __builtin_amdgcn_mfma_f32_16x16x32_bf16(af1, bf1, acc[1][1], 0, 0, 0);
  }
  const float bj[2] = { tl.bias[wc*32 + r16], tl.bias[wc*32 + 16 + r16] };
#pragma unroll
  for (int i = 0; i < 2; i++) {
#pragma unroll
    for (int j = 0; j < 2; j++) {
      int col  = tl.colOff + wc*32 + 16*j + r16;
      int row0 = bm + wr*32 + 16*i + 4*g;
      if (tl.obf16 == 2) {           // transposed bf16: out[col*ldOut + row], 4 consecutive rows
        u16 pk[4];
#pragma unroll
        for (int r = 0; r < 4; r++) pk[r] = f2b_rne(acc[i][j][r] + bj[j]);
        *(uint2*)((u16*)tl.out + (size_t)col * tl.ldOut + row0) = *(uint2*)pk;
      } else {
#pragma unroll
        for (int r = 0; r < 4; r++) {
          float v = acc[i][j][r] + bj[j];
          if (ACT == 1) v = sanitize_f(v);
          if (ACT == 2) v = (v > 0.f) ? v : 0.2f * v;
          if (tl.obf16) ((u16*)tl.out)[(size_t)(row0 + r) * tl.ldOut + col] = f2b_rne(v);
          else          tl.out[(size_t)(row0 + r) * tl.ldOut + col] = v;
        }
      }
    }
  }
}

// ---------------- img GEMM split-K: K=2048 over 4 z-blocks of 512 ----------------
__global__ __launch_bounds__(256) void gemm_img_splitk(const float* __restrict__ A, const float* __restrict__ W,
                                                       float* __restrict__ part) {
  __shared__ short As[64 * 40];
  __shared__ short Bs[64 * 40];
  const int t = threadIdx.x;
  const int bm = blockIdx.x * 64, bn = blockIdx.y * 64, ks = blockIdx.z;
  const int w = t >> 6, l = t & 63, g = l >> 4, r16 = l & 15;
  const int wr = w >> 1, wc = w & 1;
  const int lrow = t >> 2, lseg = (t & 3) * 8;

  const float* Ap = A + (size_t)(bm + lrow) * 2048 + ks * 512 + lseg;
  const float* Wp = W + (size_t)(bn + lrow) * 2048 + ks * 512 + lseg;

  f32x4 acc[2][2] = {{{0.f,0.f,0.f,0.f},{0.f,0.f,0.f,0.f}},{{0.f,0.f,0.f,0.f},{0.f,0.f,0.f,0.f}}};
  for (int k0 = 0; k0 < 512; k0 += 32) {
    float4 a0 = load4f(Ap + k0), a1 = load4f(Ap + k0 + 4);
    float4 b0 = load4f(Wp + k0), b1 = load4f(Wp + k0 + 4);
    __syncthreads();
    *(uint4*)&As[lrow * 40 + lseg] =
        make_uint4(pack2(a0.x,a0.y), pack2(a0.z,a0.w), pack2(a1.x,a1.y), pack2(a1.z,a1.w));
    *(uint4*)&Bs[lrow * 40 + lseg] =
        make_uint4(pack2(b0.x,b0.y), pack2(b0.z,b0.w), pack2(b1.x,b1.y), pack2(b1.z,b1.w));
    __syncthreads();
    short8 af0 = *(const short8*)&As[(wr*32 +      r16) * 40 + 8*g];
    short8 af1 = *(const short8*)&As[(wr*32 + 16 + r16) * 40 + 8*g];
    short8 bf0 = *(const short8*)&Bs[(wc*32 +      r16) * 40 + 8*g];
    short8 bf1 = *(const short8*)&Bs[(wc*32 + 16 + r16) * 40 + 8*g];
    acc[0][0] = __builtin_amdgcn_mfma_f32_16x16x32_bf16(af0, bf0, acc[0][0], 0, 0, 0);
    acc[0][1] = __builtin_amdgcn_mfma_f32_16x16x32_bf16(af0, bf1, acc[0][1], 0, 0, 0);
    acc[1][0] = __builtin_amdgcn_mfma_f32_16x16x32_bf16(af1, bf0, acc[1][0], 0, 0, 0);
    acc[1][1] = __builtin_amdgcn_mfma_f32_16x16x32_bf16(af1, bf1, acc[1][1], 0, 0, 0);
  }
  float* op = part + (size_t)ks * (NN * 256);
#pragma unroll
  for (int i = 0; i < 2; i++) {
#pragma unroll
    for (int j = 0; j < 2; j++) {
      int col = bn + wc*32 + 16*j + r16;
#pragma unroll
      for (int r = 0; r < 4; r++) {
        int row = bm + wr*32 + 16*i + 4*g + r;
        op[(size_t)row * 256 + col] = acc[i][j][r];
      }
    }
  }
}
__global__ __launch_bounds__(256) void gemm_img_reduce(const float* __restrict__ part,
                                                       const float* __restrict__ bias,
                                                       float* __restrict__ h) {
  int idx = blockIdx.x * 256 + threadIdx.x;
  int row = idx >> 6, c4 = (idx & 63) * 4;
  size_t o = (size_t)row * 256 + c4;
  float4 s = load4f(part + o);
  float4 p1 = load4f(part + 1048576 + o);
  float4 p2 = load4f(part + 2097152 + o);
  float4 p3 = load4f(part + 3145728 + o);
  float4 bb = load4f(bias + c4);
  s.x += p1.x + p2.x + p3.x + bb.x;
  s.y += p1.y + p2.y + p3.y + bb.y;
  s.z += p1.z + p2.z + p3.z + bb.z;
  s.w += p1.w + p2.w + p3.w + bb.w;
  *(float4*)&h[o] = s;
}

// ---------------- causal MHA v4: 64-q blocks, LDS-shared K/V, pipelined, split-K x4 ----------------
#define KSTR 72
__global__ __launch_bounds__(256, 4) void mha_mfma3(const u16* __restrict__ qkb, const u16* __restrict__ vtb,
                                                    float* __restrict__ Opart, float* __restrict__ mspart) {
  __shared__ u16 Ks[64 * KSTR];
  __shared__ u16 Vs[64 * KSTR];
  const int bid = blockIdx.x;
  const int ks  = bid & 3;
  const int hh  = (bid >> 2) & 3;
  const int T   = 63 - (bid >> 4);
  const int q0  = T * 64;
  const int t   = threadIdx.x;
  const int w   = t >> 6, l = t & 63, g = l >> 4, r16 = l & 15;
  const int hofs = hh * 64;
  const int lrow = t >> 3, lc8 = (t & 7) * 8;

  const u16* qrow = qkb + (size_t)(q0 + 16 * w + r16) * 512 + hofs;
  short8 Qf0 = *(const short8*)&qrow[8 * g];
  short8 Qf1 = *(const short8*)&qrow[32 + 8 * g];

  f32x4 O0 = {0.f,0.f,0.f,0.f}, O1 = O0, O2 = O0, O3 = O0;
  float m = -INFINITY, ssum = 0.f;

  uint4 rk0, rk1, rv0, rv1;
  if (ks <= T) {
    int k0 = ks * 64;
    rk0 = *(const uint4*)&qkb[(size_t)(k0 + lrow) * 512 + 256 + hofs + lc8];
    rk1 = *(const uint4*)&qkb[(size_t)(k0 + 32 + lrow) * 512 + 256 + hofs + lc8];
    rv0 = *(const uint4*)&vtb[(size_t)(hofs + lrow) * 4096 + k0 + lc8];
    rv1 = *(const uint4*)&vtb[(size_t)(hofs + 32 + lrow) * 4096 + k0 + lc8];
  }
  for (int kt = ks; kt <= T; kt += 4) {
    __syncthreads();
    *(uint4*)&Ks[lrow * KSTR + lc8]        = rk0;
    *(uint4*)&Ks[(32 + lrow) * KSTR + lc8] = rk1;
    *(uint4*)&Vs[lrow * KSTR + lc8]        = rv0;
    *(uint4*)&Vs[(32 + lrow) * KSTR + lc8] = rv1;
    __syncthreads();
    if (kt + 4 <= T) {
      int k2 = (kt + 4) * 64;
      rk0 = *(const uint4*)&qkb[(size_t)(k2 + lrow) * 512 + 256 + hofs + lc8];
      rk1 = *(const uint4*)&qkb[(size_t)(k2 + 32 + lrow) * 512 + 256 + hofs + lc8];
      rv0 = *(const uint4*)&vtb[(size_t)(hofs + lrow) * 4096 + k2 + lc8];
      rv1 = *(const uint4*)&vtb[(size_t)(hofs + 32 + lrow) * 4096 + k2 + lc8];
    }
    f32x4 S0 = {0.f,0.f,0.f,0.f}, S1 = S0, S2 = S0, S3 = S0;
    {
      short8 a0 = *(const short8*)&Ks[(r16)      * KSTR + 8*g];
      short8 a1 = *(const short8*)&Ks[(16 + r16) * KSTR + 8*g];
      short8 a2 = *(const short8*)&Ks[(32 + r16) * KSTR + 8*g];
      short8 a3 = *(const short8*)&Ks[(48 + r16) * KSTR + 8*g];
      S0 = __builtin_amdgcn_mfma_f32_16x16x32_bf16(a0, Qf0, S0, 0, 0, 0);
      S1 = __builtin_amdgcn_mfma_f32_16x16x32_bf16(a1, Qf0, S1, 0, 0, 0);
      S2 = __builtin_amdgcn_mfma_f32_16x16x32_bf16(a2, Qf0, S2, 0, 0, 0);
      S3 = __builtin_amdgcn_mfma_f32_16x16x32_bf16(a3, Qf0, S3, 0, 0, 0);
      short8 b0 = *(const short8*)&Ks[(r16)      * KSTR + 32 + 8*g];
      short8 b1 = *(const short8*)&Ks[(16 + r16) * KSTR + 32 + 8*g];
      short8 b2 = *(const short8*)&Ks[(32 + r16) * KSTR + 32 + 8*g];
      short8 b3 = *(const short8*)&Ks[(48 + r16) * KSTR + 32 + 8*g];
      S0 = __builtin_amdgcn_mfma_f32_16x16x32_bf16(b0, Qf1, S0, 0, 0, 0);
      S1 = __builtin_amdgcn_mfma_f32_16x16x32_bf16(b1, Qf1, S1, 0, 0, 0);
      S2 = __builtin_amdgcn_mfma_f32_16x16x32_bf16(b2, Qf1, S2, 0, 0, 0);
      S3 = __builtin_amdgcn_mfma_f32_16x16x32_bf16(b3, Qf1, S3, 0, 0, 0);
    }
    float sc[4][4];
#pragma unroll
    for (int r = 0; r < 4; r++) {
      sc[0][r] = S0[r] * 0.125f; sc[1][r] = S1[r] * 0.125f;
      sc[2][r] = S2[r] * 0.125f; sc[3][r] = S3[r] * 0.125f;
    }
    if (kt == T) {
#pragma unroll
      for (int mb = 0; mb < 4; mb++)
#pragma unroll
        for (int r = 0; r < 4; r++)
          if (16 * mb + 4 * g + r > 16 * w + r16) sc[mb][r] = -INFINITY;
    }
    float tm = sc[0][0];
#pragma unroll
    for (int mb = 0; mb < 4; mb++)
#pragma unroll
      for (int r = 0; r < 4; r++) tm = fmaxf(tm, sc[mb][r]);
    tm = fmaxf(tm, __shfl_xor(tm, 16));
    tm = fmaxf(tm, __shfl_xor(tm, 32));
    float mn = fmaxf(m, tm);
    float ef = __expf(m - mn);
    float pv[4][4];
    float ps = 0.f;
#pragma unroll
    for (int mb = 0; mb < 4; mb++)
#pragma unroll
      for (int r = 0; r < 4; r++) { pv[mb][r] = __expf(sc[mb][r] - mn); ps += pv[mb][r]; }
    ps += __shfl_xor(ps, 16);
    ps += __shfl_xor(ps, 32);
    ssum = ssum * ef + ps;
    m = mn;
#pragma unroll
    for (int r = 0; r < 4; r++) {
      float efr = __shfl(ef, 4 * g + r);
      O0[r] *= efr; O1[r] *= efr; O2[r] *= efr; O3[r] *= efr;
    }
    u32 pk[2][4];
#pragma unroll
    for (int c = 0; c < 2; c++)
#pragma unroll
      for (int rs = 0; rs < 4; rs++) pk[c][rs] = pack2(pv[2 * c][rs], pv[2 * c + 1][rs]);
    short8 ap[2];
#pragma unroll
    for (int c = 0; c < 2; c++) {
#pragma unroll
      for (int jb = 0; jb < 2; jb++) {
        int x = 2 * g + jb;
        int hi = x >> 2;
        int src = r16 + 16 * (x & 3);
#pragma unroll
        for (int rs = 0; rs < 4; rs++) {
          u32 v = __shfl(pk[c][rs], src);
          ap[c][jb * 4 + rs] = (short)(hi ? (v >> 16) : (v & 0xffff));
        }
      }
    }
    {
      short8 V00 = *(const short8*)&Vs[(r16)      * KSTR + 8*g];
      short8 V10 = *(const short8*)&Vs[(16 + r16) * KSTR + 8*g];
      short8 V20 = *(const short8*)&Vs[(32 + r16) * KSTR + 8*g];
      short8 V30 = *(const short8*)&Vs[(48 + r16) * KSTR + 8*g];
      O0 = __builtin_amdgcn_mfma_f32_16x16x32_bf16(ap[0], V00, O0, 0, 0, 0);
      O1 = __builtin_amdgcn_mfma_f32_16x16x32_bf16(ap[0], V10, O1, 0, 0, 0);
      O2 = __builtin_amdgcn_mfma_f32_16x16x32_bf16(ap[0], V20, O2, 0, 0, 0);
      O3 = __builtin_amdgcn_mfma_f32_16x16x32_bf16(ap[0], V30, O3, 0, 0, 0);
      short8 V01 = *(const short8*)&Vs[(r16)      * KSTR + 32 + 8*g];
      short8 V11 = *(const short8*)&Vs[(16 + r16) * KSTR + 32 + 8*g];
      short8 V21 = *(const short8*)&Vs[(32 + r16) * KSTR + 32 + 8*g];
      short8 V31 = *(const short8*)&Vs[(48 + r16) * KSTR + 32 + 8*g];
      O0 = __builtin_amdgcn_mfma_f32_16x16x32_bf16(ap[1], V01, O0, 0, 0, 0);
      O1 = __builtin_amdgcn_mfma_f32_16x16x32_bf16(ap[1], V11, O1, 0, 0, 0);
      O2 = __builtin_amdgcn_mfma_f32_16x16x32_bf16(ap[1], V21, O2, 0, 0, 0);
      O3 = __builtin_amdgcn_mfma_f32_16x16x32_bf16(ap[1], V31, O3, 0, 0, 0);
    }
  }

  size_t ob = (size_t)bid * 4096;
#pragma unroll
  for (int r = 0; r < 4; r++) {
    int q = 16 * w + 4 * g + r;
    Opart[ob + q * 64 + r16]      = O0[r];
    Opart[ob + q * 64 + 16 + r16] = O1[r];
    Opart[ob + q * 64 + 32 + r16] = O2[r];
    Opart[ob + q * 64 + 48 + r16] = O3[r];
  }
  if (l < 16) {
    mspart[bid * 128 + 16 * w + l]      = m;
    mspart[bid * 128 + 64 + 16 * w + l] = ssum;
  }
}

// merge 4 stripe-partials -> normalized output. grid 256: T = mb>>2, h = mb&3.
__global__ __launch_bounds__(256) void mha_merge3(const float* __restrict__ Opart, const float* __restrict__ mspart,
                                                  float* __restrict__ out) {
  int mb = blockIdx.x;
  int h = mb & 3, T = mb >> 2;
  int bid0 = ((63 - T) << 4) | (h << 2);
  int t = threadIdx.x;
  int q = t >> 2, dbase = (t & 3) * 16;
  float mm[4], ss[4];
#pragma unroll
  for (int i = 0; i < 4; i++) {
    mm[i] = mspart[(bid0 + i) * 128 + q];
    ss[i] = mspart[(bid0 + i) * 128 + 64 + q];
  }
  float M = fmaxf(fmaxf(mm[0], mm[1]), fmaxf(mm[2], mm[3]));
  float e[4];
  float S = 0.f;
#pragma unroll
  for (int i = 0; i < 4; i++) {
    e[i] = (mm[i] == -INFINITY) ? 0.f : __expf(mm[i] - M);
    S += e[i] * ss[i];
  }
  float inv = 1.f / S;
  float* Y = out + (size_t)(T * 64 + q) * EMB + h * 64 + dbase;
#pragma unroll
  for (int i = 0; i < 4; i++) {
    float4 a0 = load4f(Opart + (size_t)(bid0 + 0) * 4096 + q * 64 + dbase + 4 * i);
    float4 a1 = load4f(Opart + (size_t)(bid0 + 1) * 4096 + q * 64 + dbase + 4 * i);
    float4 a2 = load4f(Opart + (size_t)(bid0 + 2) * 4096 + q * 64 + dbase + 4 * i);
    float4 a3 = load4f(Opart + (size_t)(bid0 + 3) * 4096 + q * 64 + dbase + 4 * i);
    float4 r;
    r.x = (e[0]*a0.x + e[1]*a1.x + e[2]*a2.x + e[3]*a3.x) * inv;
    r.y = (e[0]*a0.y + e[1]*a1.y + e[2]*a2.y + e[3]*a3.y) * inv;
    r.z = (e[0]*a0.z + e[1]*a1.z + e[2]*a2.z + e[3]*a3.z) * inv;
    r.w = (e[0]*a0.w + e[1]*a1.w + e[2]*a2.w + e[3]*a3.w) * inv;
    *(float4*)(Y + 4 * i) = r;
  }
}

// ---------------- CSR build ----------------
__global__ void zero_i32(int* p, int n) {
  int i = blockIdx.x * 256 + threadIdx.x;
  if (i < n) p[i] = 0;
}
__global__ void hist_dst(const int* __restrict__ adj, int* __restrict__ cnt) {
  int e = blockIdx.x * 256 + threadIdx.x;
  if (e < NE) atomicAdd(&cnt[adj[NE + e]], 1);
}
__global__ __launch_bounds__(1024) void scan4096(const int* __restrict__ cnt, int* __restrict__ indptr,
                                                 int* __restrict__ cursor) {
  int t = threadIdx.x;
  int4 c = *reinterpret_cast<const int4*>(cnt + t * 4);
  int s0 = c.x, s1 = s0 + c.y, s2 = s1 + c.z, s3 = s2 + c.w;
  int lane = t & 63, w = t >> 6;
  int x = s3;
#pragma unroll
  for (int off = 1; off < 64; off <<= 1) {
    int y = __shfl_up(x, off);
    if (lane >= off) x += y;
  }
  __shared__ int wsum[16];
  if (lane == 63) wsum[w] = x;
  __syncthreads();
  if (t == 0) {
    int acc = 0;
    for (int i = 0; i < 16; i++) { int tv = wsum[i]; wsum[i] = acc; acc += tv; }
  }
  __syncthreads();
  int b = wsum[w] + x - s3;
  indptr[t*4+0] = b;      indptr[t*4+1] = b + s0;
  indptr[t*4+2] = b + s1; indptr[t*4+3] = b + s2;
  cursor[t*4+0] = b;      cursor[t*4+1] = b + s0;
  cursor[t*4+2] = b + s1; cursor[t*4+3] = b + s2;
  if (t == 1023) indptr[4096] = b + s3;
}
__global__ void scatter_edges(const int* __restrict__ adj, int* __restrict__ cursor, int* __restrict__ esrc) {
  int e = blockIdx.x * 256 + threadIdx.x;
  if (e < NE) {
    int dst = adj[NE + e];
    int pos = atomicAdd(&cursor[dst], 1);
    esrc[pos] = adj[e];
  }
}

// ---------------- TransformerConv aggregation (both paths fused): coop K gather, f32 V ----------------
// grid 8192: path = bid>>12, n = bid&4095.
__global__ __launch_bounds__(256, 4) void conv_agg2(const float* __restrict__ qbO, const float* __restrict__ qbA,
                                                    const u16* __restrict__ kbO, const u16* __restrict__ kbA,
                                                    const float* __restrict__ vbO, const float* __restrict__ vbA,
                                                    const int* __restrict__ indptr, const int* __restrict__ esrc,
                                                    float* __restrict__ yO, float* __restrict__ yA) {
  __shared__ float q_s[EMB];
  __shared__ float sc_s[NH][64];
  __shared__ float p_s[NH][64];
  __shared__ int   s_s[64];
  int bid = blockIdx.x;
  int path = bid >> 12;
  int n = bid & 4095;
  const float* qb = path ? qbA : qbO;
  const u16*   kb = path ? kbA : kbO;
  const float* vb = path ? vbA : vbO;
  float*       y  = path ? yA  : yO;
  int tid = threadIdx.x;
  int h = tid >> 6, lane = tid & 63;
  int lr8 = lane >> 3;
  int lseg = (lane & 7) * 8;
  q_s[tid] = qb[(size_t)n * EMB + tid] * 0.125f;
  int start = indptr[n], end = indptr[n + 1];
  __syncthreads();
  const float* qh = &q_s[h * HD];
  float q8[8];
#pragma unroll
  for (int j = 0; j < 8; j++) q8[j] = qh[lseg + j];
  float m = -INFINITY, s = 0.f;
  float o0 = 0.f, o1 = 0.f, o2 = 0.f, o3 = 0.f;
  for (int p0 = start; p0 < end; p0 += 64) {
    int nk = end - p0; if (nk > 64) nk = 64;
    if (h == 0) s_s[lane] = (lane < nk) ? esrc[p0 + lane] : 0;
    __syncthreads();
#pragma unroll
    for (int pass = 0; pass < 8; pass++) {
      int row = pass * 8 + lr8;
      int src = s_s[row];
      short8 k8 = *(const short8*)&kb[(size_t)src * EMB + h * HD + lseg];
      float a0 = fmaf(b2f((u16)k8[0]), q8[0], 0.f);
      float a1 = fmaf(b2f((u16)k8[1]), q8[1], 0.f);
      a0 = fmaf(b2f((u16)k8[2]), q8[2], a0);
      a1 = fmaf(b2f((u16)k8[3]), q8[3], a1);
      a0 = fmaf(b2f((u16)k8[4]), q8[4], a0);
      a1 = fmaf(b2f((u16)k8[5]), q8[5], a1);
      a0 = fmaf(b2f((u16)k8[6]), q8[6], a0);
      a1 = fmaf(b2f((u16)k8[7]), q8[7], a1);
      float acc = a0 + a1;
      acc += __shfl_xor(acc, 1);
      acc += __shfl_xor(acc, 2);
      acc += __shfl_xor(acc, 4);
      if ((lane & 7) == 0) sc_s[h][row] = (row < nk) ? acc : -INFINITY;
    }
    float sc = sc_s[h][lane];
    float bm = sc;
#pragma unroll
    for (int off = 32; off; off >>= 1) bm = fmaxf(bm, __shfl_xor(bm, off));
    float mn = fmaxf(m, bm);
    float ef = __expf(m - mn);
    float p = __expf(sc - mn);
    float ps = p;
#pragma unroll
    for (int off = 32; off; off >>= 1) ps += __shfl_xor(ps, off);
    s = s * ef + ps;
    m = mn;
    o0 *= ef; o1 *= ef; o2 *= ef; o3 *= ef;
    p_s[h][lane] = p;
    const float* vcol = vb + h * HD + lane;
    int nk4 = (nk + 3) & ~3;
    for (int jj = 0; jj < nk4; jj += 4) {
      float pa = p_s[h][jj],   pb = p_s[h][jj+1];
      float pc = p_s[h][jj+2], pd = p_s[h][jj+3];
      int sa = s_s[jj], sb = s_s[jj+1], scx = s_s[jj+2], sd = s_s[jj+3];
      o0 = fmaf(pa, vcol[(size_t)sa  * EMB], o0);
      o1 = fmaf(pb, vcol[(size_t)sb  * EMB], o1);
      o2 = fmaf(pc, vcol[(size_t)scx * EMB], o2);
      o3 = fmaf(pd, vcol[(size_t)sd  * EMB], o3);
    }
    __syncthreads();
  }
  float o = (o0 + o1) + (o2 + o3);
  float agg = o / (s + 1e-16f);
  y[(size_t)n * EMB + h * HD + lane] += agg;
}

// ---------------- instance norm (both paths): partial stats, then fused final+apply ----------------
__global__ __launch_bounds__(256) void colstats_partial2(const float* __restrict__ yO, const float* __restrict__ yA,
                                                         float* __restrict__ part) {
  int bid = blockIdx.x;              // 64: path = bid>>5, pb = bid&31
  int path = bid >> 5, pb = bid & 31;
  const float* y = path ? yA : yO;
  int c = threadIdx.x;
  int r0 = pb * 128;
  float s = 0.f, q = 0.f;
  for (int r = r0; r < r0 + 128; r++) {
    float v = y[(size_t)r * EMB + c];
    s += v; q = fmaf(v, v, q);
  }
  part[(size_t)path * 16384 + pb * 512 + c] = s;
  part[(size_t)path * 16384 + pb * 512 + 256 + c] = q;
}
__global__ __launch_bounds__(256) void norm_apply2(const float* __restrict__ yO, const float* __restrict__ yA,
                                                   const float* __restrict__ part, float* __restrict__ f) {
  int bid = blockIdx.x;              // 512: path = bid>>8, rb = bid&255
  int path = bid >> 8, rb = bid & 255;
  const float* y = path ? yA : yO;
  const float* pp = part + (size_t)path * 16384;
  int c = threadIdx.x;
  float s = 0.f, q = 0.f;
  for (int b = 0; b < 32; b++) { s += pp[b * 512 + c]; q += pp[b * 512 + 256 + c]; }
  float mean = s * (1.f / 4096.f);
  float var  = q * (1.f / 4096.f) - mean * mean;
  float rstd = rsqrtf(var + 1e-5f);
  int r0 = rb * 16;
  int colOff = path * 256;
  for (int r = r0; r < r0 + 16; r++) {
    float v = (y[(size_t)r * EMB + c] - mean) * rstd;
    v = (v > 0.f) ? v : 0.2f * v;
    v = sanitize_f(v);
    f[(size_t)r * 512 + colOff + c] = v;
  }
}

// ---------------- classifier tail ----------------
__global__ __launch_bounds__(256) void final_softmax(const float* __restrict__ f1, const float* __restrict__ W2,
                                                     const float* __restrict__ b2, float* __restrict__ out) {
  int w = threadIdx.x >> 6, lane = threadIdx.x & 63;
  int row = blockIdx.x * 4 + w;
  const float* fr = f1 + (size_t)row * 128;
  float x0 = fr[lane], x1 = fr[lane + 64];
  float p0 = x0 * W2[lane]       + x1 * W2[64 + lane];
  float p1 = x0 * W2[128 + lane] + x1 * W2[192 + lane];
#pragma unroll
  for (int off = 32; off; off >>= 1) { p0 += __shfl_xor(p0, off); p1 += __shfl_xor(p1, off); }
  if (lane == 0) {
    float l0 = p0 + b2[0], l1 = p1 + b2[1];
    float mx = fmaxf(l0, l1);
    float e0 = __expf(l0 - mx), e1 = __expf(l1 - mx);
    float inv = 1.f / (e0 + e1);
    out[(size_t)row * 2 + 0] = l0;
    out[(size_t)row * 2 + 1] = l1;
    out[8192 + (size_t)row * 2 + 0] = e0 * inv;
    out[8192 + (size_t)row * 2 + 1] = e1 * inv;
  }
}

extern "C" void kernel_launch(void* const* d_in, const int* in_sizes, int n_in,
                              void* d_out, int out_size, void* d_ws, size_t ws_size,
                              hipStream_t stream) {
  const float* img   = (const float*)d_in[2];
  const int*   adj   = (const int*)d_in[3];
  const float* W_img = (const float*)d_in[4];  const float* b_img = (const float*)d_in[5];
  const float* W_qkv = (const float*)d_in[6];  const float* b_qkv = (const float*)d_in[7];
  const float* W_o   = (const float*)d_in[8];  const float* b_o   = (const float*)d_in[9];
  const float* Wq_o  = (const float*)d_in[10]; const float* bq_o  = (const float*)d_in[11];
  const float* Wk_o  = (const float*)d_in[12]; const float* bk_o  = (const float*)d_in[13];
  const float* Wv_o  = (const float*)d_in[14]; const float* bv_o  = (const float*)d_in[15];
  const float* Ws_o  = (const float*)d_in[16]; const float* bs_o  = (const float*)d_in[17];
  const float* Wq_a  = (const float*)d_in[18]; const float* bq_a  = (const float*)d_in[19];
  const float* Wk_a  = (const float*)d_in[20]; const float* bk_a  = (const float*)d_in[21];
  const float* Wv_a  = (const float*)d_in[22]; const float* bv_a  = (const float*)d_in[23];
  const float* Ws_a  = (const float*)d_in[24]; const float* bs_a  = (const float*)d_in[25];
  const float* W_c1  = (const float*)d_in[26]; const float* b_c1  = (const float*)d_in[27];
  const float* W_c2  = (const float*)d_in[28]; const float* b_c2  = (const float*)d_in[29];

  char* ws = (char*)d_ws;
  float* h     = (float*)(ws + 0);                    // 4 MB
  float* hattn = (float*)(ws + (4ull  << 20));        // 4 MB (qkb aliases during mha)
  float* qbO   = (float*)(ws + (8ull  << 20));        // 4 MB
  u16*   kbO   = (u16*)  (ws + (12ull << 20));        // 2 MB
  float* vbO   = (float*)(ws + (14ull << 20));        // 4 MB
  float* qbA   = (float*)(ws + (18ull << 20));        // 4 MB
  u16*   kbA   = (u16*)  (ws + (22ull << 20));        // 2 MB
  float* vbA   = (float*)(ws + (24ull << 20));        // 4 MB
  float* yO    = (float*)(ws + (28ull << 20));        // 4 MB (ymha aliases)
  float* yA    = (float*)(ws + (32ull << 20));        // 4 MB
  float* f     = (float*)(ws + (36ull << 20));        // 8 MB
  float* f1    = (float*)(ws + (44ull << 20));        // 2 MB (vtb aliases)
  int*   indptr= (int*)  (ws + (46ull << 20));
  int*   cursor= (int*)  (ws + (46ull << 20) + 20480);
  int*   esrc  = (int*)  (ws + (46ull << 20) + 40960);  // 1 MB (mspart aliases)
  float* part  = (float*)(ws + (46ull << 20) + 40960 + (1ull << 20)); // 128 KB

  u16*   qkb     = (u16*)hattn;      // 4 MB, dead until step 4
  u16*   vtb     = (u16*)f1;         // 2 MB, dead until step 8
  float* imgpart = qbO;              // 16 MB (ws+8..24M), free during step 1
  float* Opart   = qbO;              // 16 MB (ws+8..24M), free during mha
  float* mspart  = (float*)esrc;     // 512 KB, free during mha
  float* ymha    = yO;               // 4 MB, free until conv GEMM writes skip

  dim3 b256(256);

  // 1. h = img_feat @ W_img^T + b_img   (split-K x4)
  gemm_img_splitk<<<dim3(64, 4, 4), b256, 0, stream>>>(img, W_img, imgpart);
  gemm_img_reduce<<<1024, b256, 0, stream>>>(imgpart, b_img, h);
  // 2. qkv GEMM -> qkb (Q|K bf16), vtb (V^T bf16)
  {
    GArgs ga;
    for (int i = 0; i < 8; i++)
      ga.t[i]  = { h, W_qkv + (size_t)i * 64 * 256, b_qkv + i * 64, (float*)qkb, i * 64, 512, 1 };
    for (int i = 8; i < 12; i++)
      ga.t[i]  = { h, W_qkv + (size_t)i * 64 * 256, b_qkv + i * 64, (float*)vtb, (i - 8) * 64, 4096, 2 };
    gemm_mfma<0><<<dim3(64, 12), b256, 0, stream>>>(ga, 256);
  }
  // 3. causal MHA (split-K x4) -> ymha
  mha_mfma3<<<1024, b256, 0, stream>>>(qkb, vtb, Opart, mspart);
  mha_merge3<<<256, b256, 0, stream>>>(Opart, mspart, ymha);
  // 4. h_attn = sanitize(ymha @ W_o^T + b_o)
  {
    GArgs ga;
    for (int i = 0; i < 4; i++)
      ga.t[i] = { ymha, W_o + (size_t)i * 64 * 256, b_o + i * 64, hattn, i * 64, 256, 0 };
    gemm_mfma<1><<<dim3(64, 4), b256, 0, stream>>>(ga, 256);
  }
  // 5. CSR of video_adj_list grouped by dst
  zero_i32<<<16, b256, 0, stream>>>(cursor, NN);
  hist_dst<<<NE / 256, b256, 0, stream>>>(adj, cursor);
  scan4096<<<1, 1024, 0, stream>>>(cursor, indptr, cursor);
  scatter_edges<<<NE / 256, b256, 0, stream>>>(adj, cursor, esrc);

  // 6. both conv paths' q/k/v/skip in ONE dispatch (32 tiles)
  {
    const float* Wg[8] = { Wq_o, Wk_o, Wv_o, Ws_o, Wq_a, Wk_a, Wv_a, Ws_a };
    const float* bg[8] = { bq_o, bk_o, bv_o, bs_o, bq_a, bk_a, bv_a, bs_a };
    float*       og[8] = { qbO, (float*)kbO, vbO, yO, qbA, (float*)kbA, vbA, yA };
    const float* Ag[8] = { h, h, h, h, hattn, hattn, hattn, hattn };
    const int    bf[8] = { 0, 1, 0, 0, 0, 1, 0, 0 };
    GArgs ga;
    for (int i = 0; i < 32; i++) {
      int gdx = i >> 2, li = i & 3;
      ga.t[i] = { Ag[gdx], Wg[gdx] + (size_t)li * 64 * 256, bg[gdx] + li * 64, og[gdx], li * 64, 256, bf[gdx] };
    }
    gemm_mfma<0><<<dim3(64, 32), b256, 0, stream>>>(ga, 256);
  }
  // 7. both conv aggregations in ONE dispatch
  conv_agg2<<<8192, b256, 0, stream>>>(qbO, qbA, kbO, kbA, vbO, vbA, indptr, esrc, yO, yA);
  // 8. instance norm both paths
  colstats_partial2<<<64, b256, 0, stream>>>(yO, yA, part);
  norm_apply2<<<512, b256, 0, stream>>>(yO, yA, part, f);
  // 9. f1 = lrelu(f @ W_c1^T + b_c1)
  {
    GArgs ga;
    for (int i = 0; i < 2; i++)
      ga.t[i] = { f, W_c1 + (size_t)i * 64 * 512, b_c1 + i * 64, f1, i * 64, 128, 0 };
    gemm_mfma<2><<<dim3(64, 2), b256, 0, stream>>>(ga, 512);
  }
  // 10. logits + softmax -> out
  final_softmax<<<NN / 4, b256, 0, stream>>>(f1, W_c2, b_c2, (float*)d_out);
}

// Round 16
// 244.567 us; speedup vs baseline: 1.9153x; 1.0255x over previous
//
#include <hip/hip_runtime.h>
#include <hip/hip_bf16.h>

typedef unsigned short u16;
typedef unsigned int   u32;
typedef __attribute__((ext_vector_type(8))) short short8;
typedef __attribute__((ext_vector_type(4))) float f32x4;
typedef _Float16 half2v __attribute__((ext_vector_type(2)));

#define NN 4096        // nodes
#define NE 262144      // edges
#define EMB 256
#define NH 4
#define HD 64

__device__ __forceinline__ float4 load4f(const float* p) { return *reinterpret_cast<const float4*>(p); }
__device__ __forceinline__ float sanitize_f(float v) {
  v = (v != v) ? 0.f : v;                 // nan -> 0
  return fminf(fmaxf(v, -1000.f), 1000.f); // +-inf and clip -> +-1000
}
__device__ __forceinline__ u16 f2b_rne(float x) {          // f32 -> bf16 bits, round-nearest-even
  u32 b = __float_as_uint(x);
  b += 0x7fff + ((b >> 16) & 1);
  return (u16)(b >> 16);
}
__device__ __forceinline__ u32 pack2(float a, float b) {
  return (u32)f2b_rne(a) | ((u32)f2b_rne(b) << 16);
}
__device__ __forceinline__ float b2f(u16 u) { return __uint_as_float((u32)u << 16); }
__device__ __forceinline__ u16 f2h(float x) {              // f32 -> f16 bits (rte)
  _Float16 h = (_Float16)x;
  return *reinterpret_cast<u16*>(&h);
}

// ================= generic MFMA GEMM: out = act(A[M,K] @ W^T + bias) =================
struct GTile {
  const float* A;     // input rows [M][K]
  const float* W;     // 64 weight rows for this tile: [64][K]
  const float* bias;  // 64 entries
  float*       out;
  int          colOff;
  int          ldOut;
  int          obf16; // 0 f32 | 1 bf16 | 2 bf16-TRANSPOSED out[col*ld+row] | 3 f16
};
struct GArgs { GTile t[32]; };

template<int ACT>   // 0 none, 1 sanitize, 2 lrelu(0.2)
__global__ __launch_bounds__(256) void gemm_mfma(const GArgs ga, int K) {
  __shared__ short As[64 * 40];
  __shared__ short Bs[64 * 40];
  const int t = threadIdx.x;
  const int bm = blockIdx.x * 64;
  const GTile tl = ga.t[blockIdx.y];
  const int w = t >> 6, l = t & 63, g = l >> 4, r16 = l & 15;
  const int wr = w >> 1, wc = w & 1;
  const int lrow = t >> 2, lseg = (t & 3) * 8;

  const float* Ap = tl.A + (size_t)(bm + lrow) * K + lseg;
  const float* Wp = tl.W + (size_t)lrow * K + lseg;

  f32x4 acc[2][2] = {{{0.f,0.f,0.f,0.f},{0.f,0.f,0.f,0.f}},{{0.f,0.f,0.f,0.f},{0.f,0.f,0.f,0.f}}};
  for (int k0 = 0; k0 < K; k0 += 32) {
    float4 a0 = load4f(Ap + k0), a1 = load4f(Ap + k0 + 4);
    float4 b0 = load4f(Wp + k0), b1 = load4f(Wp + k0 + 4);
    __syncthreads();
    *(uint4*)&As[lrow * 40 + lseg] =
        make_uint4(pack2(a0.x,a0.y), pack2(a0.z,a0.w), pack2(a1.x,a1.y), pack2(a1.z,a1.w));
    *(uint4*)&Bs[lrow * 40 + lseg] =
        make_uint4(pack2(b0.x,b0.y), pack2(b0.z,b0.w), pack2(b1.x,b1.y), pack2(b1.z,b1.w));
    __syncthreads();
    short8 af0 = *(const short8*)&As[(wr*32 +      r16) * 40 + 8*g];
    short8 af1 = *(const short8*)&As[(wr*32 + 16 + r16) * 40 + 8*g];
    short8 bf0 = *(const short8*)&Bs[(wc*32 +      r16) * 40 + 8*g];
    short8 bf1 = *(const short8*)&Bs[(wc*32 + 16 + r16) * 40 + 8*g];
    acc[0][0] = __builtin_amdgcn_mfma_f32_16x16x32_bf16(af0, bf0, acc[0][0], 0, 0, 0);
    acc[0][1] = __builtin_amdgcn_mfma_f32_16x16x32_bf16(af0, bf1, acc[0][1], 0, 0, 0);
    acc[1][0] = __builtin_amdgcn_mfma_f32_16x16x32_bf16(af1, bf0, acc[1][0], 0, 0, 0);
    acc[1][1] = __builtin_amdgcn_mfma_f32_16x16x32_bf16(af1, bf1, acc[1][1], 0, 0, 0);
  }
  const float bj[2] = { tl.bias[wc*32 + r16], tl.bias[wc*32 + 16 + r16] };
#pragma unroll
  for (int i = 0; i < 2; i++) {
#pragma unroll
    for (int j = 0; j < 2; j++) {
      int col  = tl.colOff + wc*32 + 16*j + r16;
      int row0 = bm + wr*32 + 16*i + 4*g;
      if (tl.obf16 == 2) {
        u16 pk[4];
#pragma unroll
        for (int r = 0; r < 4; r++) pk[r] = f2b_rne(acc[i][j][r] + bj[j]);
        *(uint2*)((u16*)tl.out + (size_t)col * tl.ldOut + row0) = *(uint2*)pk;
      } else {
#pragma unroll
        for (int r = 0; r < 4; r++) {
          float v = acc[i][j][r] + bj[j];
          if (ACT == 1) v = sanitize_f(v);
          if (ACT == 2) v = (v > 0.f) ? v : 0.2f * v;
          if (tl.obf16 == 1)      ((u16*)tl.out)[(size_t)(row0 + r) * tl.ldOut + col] = f2b_rne(v);
          else if (tl.obf16 == 3) ((u16*)tl.out)[(size_t)(row0 + r) * tl.ldOut + col] = f2h(v);
          else                    tl.out[(size_t)(row0 + r) * tl.ldOut + col] = v;
        }
      }
    }
  }
}

// ---------------- img GEMM split-K: K=2048 over 4 z-blocks of 512 ----------------
__global__ __launch_bounds__(256) void gemm_img_splitk(const float* __restrict__ A, const float* __restrict__ W,
                                                       float* __restrict__ part) {
  __shared__ short As[64 * 40];
  __shared__ short Bs[64 * 40];
  const int t = threadIdx.x;
  const int bm = blockIdx.x * 64, bn = blockIdx.y * 64, ks = blockIdx.z;
  const int w = t >> 6, l = t & 63, g = l >> 4, r16 = l & 15;
  const int wr = w >> 1, wc = w & 1;
  const int lrow = t >> 2, lseg = (t & 3) * 8;

  const float* Ap = A + (size_t)(bm + lrow) * 2048 + ks * 512 + lseg;
  const float* Wp = W + (size_t)(bn + lrow) * 2048 + ks * 512 + lseg;

  f32x4 acc[2][2] = {{{0.f,0.f,0.f,0.f},{0.f,0.f,0.f,0.f}},{{0.f,0.f,0.f,0.f},{0.f,0.f,0.f,0.f}}};
  for (int k0 = 0; k0 < 512; k0 += 32) {
    float4 a0 = load4f(Ap + k0), a1 = load4f(Ap + k0 + 4);
    float4 b0 = load4f(Wp + k0), b1 = load4f(Wp + k0 + 4);
    __syncthreads();
    *(uint4*)&As[lrow * 40 + lseg] =
        make_uint4(pack2(a0.x,a0.y), pack2(a0.z,a0.w), pack2(a1.x,a1.y), pack2(a1.z,a1.w));
    *(uint4*)&Bs[lrow * 40 + lseg] =
        make_uint4(pack2(b0.x,b0.y), pack2(b0.z,b0.w), pack2(b1.x,b1.y), pack2(b1.z,b1.w));
    __syncthreads();
    short8 af0 = *(const short8*)&As[(wr*32 +      r16) * 40 + 8*g];
    short8 af1 = *(const short8*)&As[(wr*32 + 16 + r16) * 40 + 8*g];
    short8 bf0 = *(const short8*)&Bs[(wc*32 +      r16) * 40 + 8*g];
    short8 bf1 = *(const short8*)&Bs[(wc*32 + 16 + r16) * 40 + 8*g];
    acc[0][0] = __builtin_amdgcn_mfma_f32_16x16x32_bf16(af0, bf0, acc[0][0], 0, 0, 0);
    acc[0][1] = __builtin_amdgcn_mfma_f32_16x16x32_bf16(af0, bf1, acc[0][1], 0, 0, 0);
    acc[1][0] = __builtin_amdgcn_mfma_f32_16x16x32_bf16(af1, bf0, acc[1][0], 0, 0, 0);
    acc[1][1] = __builtin_amdgcn_mfma_f32_16x16x32_bf16(af1, bf1, acc[1][1], 0, 0, 0);
  }
  float* op = part + (size_t)ks * (NN * 256);
#pragma unroll
  for (int i = 0; i < 2; i++) {
#pragma unroll
    for (int j = 0; j < 2; j++) {
      int col = bn + wc*32 + 16*j + r16;
#pragma unroll
      for (int r = 0; r < 4; r++) {
        int row = bm + wr*32 + 16*i + 4*g + r;
        op[(size_t)row * 256 + col] = acc[i][j][r];
      }
    }
  }
}
__global__ __launch_bounds__(256) void gemm_img_reduce(const float* __restrict__ part,
                                                       const float* __restrict__ bias,
                                                       float* __restrict__ h) {
  int idx = blockIdx.x * 256 + threadIdx.x;
  int row = idx >> 6, c4 = (idx & 63) * 4;
  size_t o = (size_t)row * 256 + c4;
  float4 s = load4f(part + o);
  float4 p1 = load4f(part + 1048576 + o);
  float4 p2 = load4f(part + 2097152 + o);
  float4 p3 = load4f(part + 3145728 + o);
  float4 bb = load4f(bias + c4);
  s.x += p1.x + p2.x + p3.x + bb.x;
  s.y += p1.y + p2.y + p3.y + bb.y;
  s.z += p1.z + p2.z + p3.z + bb.z;
  s.w += p1.w + p2.w + p3.w + bb.w;
  *(float4*)&h[o] = s;
}

// ---------------- causal MHA v4: 64-q blocks, LDS-shared K/V, pipelined, split-K x4 ----------------
#define KSTR 72
__global__ __launch_bounds__(256, 4) void mha_mfma3(const u16* __restrict__ qkb, const u16* __restrict__ vtb,
                                                    float* __restrict__ Opart, float* __restrict__ mspart) {
  __shared__ u16 Ks[64 * KSTR];
  __shared__ u16 Vs[64 * KSTR];
  const int bid = blockIdx.x;
  const int ks  = bid & 3;
  const int hh  = (bid >> 2) & 3;
  const int T   = 63 - (bid >> 4);
  const int q0  = T * 64;
  const int t   = threadIdx.x;
  const int w   = t >> 6, l = t & 63, g = l >> 4, r16 = l & 15;
  const int hofs = hh * 64;
  const int lrow = t >> 3, lc8 = (t & 7) * 8;

  const u16* qrow = qkb + (size_t)(q0 + 16 * w + r16) * 512 + hofs;
  short8 Qf0 = *(const short8*)&qrow[8 * g];
  short8 Qf1 = *(const short8*)&qrow[32 + 8 * g];

  f32x4 O0 = {0.f,0.f,0.f,0.f}, O1 = O0, O2 = O0, O3 = O0;
  float m = -INFINITY, ssum = 0.f;

  uint4 rk0, rk1, rv0, rv1;
  if (ks <= T) {
    int k0 = ks * 64;
    rk0 = *(const uint4*)&qkb[(size_t)(k0 + lrow) * 512 + 256 + hofs + lc8];
    rk1 = *(const uint4*)&qkb[(size_t)(k0 + 32 + lrow) * 512 + 256 + hofs + lc8];
    rv0 = *(const uint4*)&vtb[(size_t)(hofs + lrow) * 4096 + k0 + lc8];
    rv1 = *(const uint4*)&vtb[(size_t)(hofs + 32 + lrow) * 4096 + k0 + lc8];
  }
  for (int kt = ks; kt <= T; kt += 4) {
    __syncthreads();
    *(uint4*)&Ks[lrow * KSTR + lc8]        = rk0;
    *(uint4*)&Ks[(32 + lrow) * KSTR + lc8] = rk1;
    *(uint4*)&Vs[lrow * KSTR + lc8]        = rv0;
    *(uint4*)&Vs[(32 + lrow) * KSTR + lc8] = rv1;
    __syncthreads();
    if (kt + 4 <= T) {
      int k2 = (kt + 4) * 64;
      rk0 = *(const uint4*)&qkb[(size_t)(k2 + lrow) * 512 + 256 + hofs + lc8];
      rk1 = *(const uint4*)&qkb[(size_t)(k2 + 32 + lrow) * 512 + 256 + hofs + lc8];
      rv0 = *(const uint4*)&vtb[(size_t)(hofs + lrow) * 4096 + k2 + lc8];
      rv1 = *(const uint4*)&vtb[(size_t)(hofs + 32 + lrow) * 4096 + k2 + lc8];
    }
    f32x4 S0 = {0.f,0.f,0.f,0.f}, S1 = S0, S2 = S0, S3 = S0;
    {
      short8 a0 = *(const short8*)&Ks[(r16)      * KSTR + 8*g];
      short8 a1 = *(const short8*)&Ks[(16 + r16) * KSTR + 8*g];
      short8 a2 = *(const short8*)&Ks[(32 + r16) * KSTR + 8*g];
      short8 a3 = *(const short8*)&Ks[(48 + r16) * KSTR + 8*g];
      S0 = __builtin_amdgcn_mfma_f32_16x16x32_bf16(a0, Qf0, S0, 0, 0, 0);
      S1 = __builtin_amdgcn_mfma_f32_16x16x32_bf16(a1, Qf0, S1, 0, 0, 0);
      S2 = __builtin_amdgcn_mfma_f32_16x16x32_bf16(a2, Qf0, S2, 0, 0, 0);
      S3 = __builtin_amdgcn_mfma_f32_16x16x32_bf16(a3, Qf0, S3, 0, 0, 0);
      short8 b0 = *(const short8*)&Ks[(r16)      * KSTR + 32 + 8*g];
      short8 b1 = *(const short8*)&Ks[(16 + r16) * KSTR + 32 + 8*g];
      short8 b2 = *(const short8*)&Ks[(32 + r16) * KSTR + 32 + 8*g];
      short8 b3 = *(const short8*)&Ks[(48 + r16) * KSTR + 32 + 8*g];
      S0 = __builtin_amdgcn_mfma_f32_16x16x32_bf16(b0, Qf1, S0, 0, 0, 0);
      S1 = __builtin_amdgcn_mfma_f32_16x16x32_bf16(b1, Qf1, S1, 0, 0, 0);
      S2 = __builtin_amdgcn_mfma_f32_16x16x32_bf16(b2, Qf1, S2, 0, 0, 0);
      S3 = __builtin_amdgcn_mfma_f32_16x16x32_bf16(b3, Qf1, S3, 0, 0, 0);
    }
    float sc[4][4];
#pragma unroll
    for (int r = 0; r < 4; r++) {
      sc[0][r] = S0[r] * 0.125f; sc[1][r] = S1[r] * 0.125f;
      sc[2][r] = S2[r] * 0.125f; sc[3][r] = S3[r] * 0.125f;
    }
    if (kt == T) {
#pragma unroll
      for (int mb = 0; mb < 4; mb++)
#pragma unroll
        for (int r = 0; r < 4; r++)
          if (16 * mb + 4 * g + r > 16 * w + r16) sc[mb][r] = -INFINITY;
    }
    float tm = sc[0][0];
#pragma unroll
    for (int mb = 0; mb < 4; mb++)
#pragma unroll
      for (int r = 0; r < 4; r++) tm = fmaxf(tm, sc[mb][r]);
    tm = fmaxf(tm, __shfl_xor(tm, 16));
    tm = fmaxf(tm, __shfl_xor(tm, 32));
    float mn = fmaxf(m, tm);
    float ef = __expf(m - mn);
    float pv[4][4];
    float ps = 0.f;
#pragma unroll
    for (int mb = 0; mb < 4; mb++)
#pragma unroll
      for (int r = 0; r < 4; r++) { pv[mb][r] = __expf(sc[mb][r] - mn); ps += pv[mb][r]; }
    ps += __shfl_xor(ps, 16);
    ps += __shfl_xor(ps, 32);
    ssum = ssum * ef + ps;
    m = mn;
#pragma unroll
    for (int r = 0; r < 4; r++) {
      float efr = __shfl(ef, 4 * g + r);
      O0[r] *= efr; O1[r] *= efr; O2[r] *= efr; O3[r] *= efr;
    }
    u32 pk[2][4];
#pragma unroll
    for (int c = 0; c < 2; c++)
#pragma unroll
      for (int rs = 0; rs < 4; rs++) pk[c][rs] = pack2(pv[2 * c][rs], pv[2 * c + 1][rs]);
    short8 ap[2];
#pragma unroll
    for (int c = 0; c < 2; c++) {
#pragma unroll
      for (int jb = 0; jb < 2; jb++) {
        int x = 2 * g + jb;
        int hi = x >> 2;
        int src = r16 + 16 * (x & 3);
#pragma unroll
        for (int rs = 0; rs < 4; rs++) {
          u32 v = __shfl(pk[c][rs], src);
          ap[c][jb * 4 + rs] = (short)(hi ? (v >> 16) : (v & 0xffff));
        }
      }
    }
    {
      short8 V00 = *(const short8*)&Vs[(r16)      * KSTR + 8*g];
      short8 V10 = *(const short8*)&Vs[(16 + r16) * KSTR + 8*g];
      short8 V20 = *(const short8*)&Vs[(32 + r16) * KSTR + 8*g];
      short8 V30 = *(const short8*)&Vs[(48 + r16) * KSTR + 8*g];
      O0 = __builtin_amdgcn_mfma_f32_16x16x32_bf16(ap[0], V00, O0, 0, 0, 0);
      O1 = __builtin_amdgcn_mfma_f32_16x16x32_bf16(ap[0], V10, O1, 0, 0, 0);
      O2 = __builtin_amdgcn_mfma_f32_16x16x32_bf16(ap[0], V20, O2, 0, 0, 0);
      O3 = __builtin_amdgcn_mfma_f32_16x16x32_bf16(ap[0], V30, O3, 0, 0, 0);
      short8 V01 = *(const short8*)&Vs[(r16)      * KSTR + 32 + 8*g];
      short8 V11 = *(const short8*)&Vs[(16 + r16) * KSTR + 32 + 8*g];
      short8 V21 = *(const short8*)&Vs[(32 + r16) * KSTR + 32 + 8*g];
      short8 V31 = *(const short8*)&Vs[(48 + r16) * KSTR + 32 + 8*g];
      O0 = __builtin_amdgcn_mfma_f32_16x16x32_bf16(ap[1], V01, O0, 0, 0, 0);
      O1 = __builtin_amdgcn_mfma_f32_16x16x32_bf16(ap[1], V11, O1, 0, 0, 0);
      O2 = __builtin_amdgcn_mfma_f32_16x16x32_bf16(ap[1], V21, O2, 0, 0, 0);
      O3 = __builtin_amdgcn_mfma_f32_16x16x32_bf16(ap[1], V31, O3, 0, 0, 0);
    }
  }

  size_t ob = (size_t)bid * 4096;
#pragma unroll
  for (int r = 0; r < 4; r++) {
    int q = 16 * w + 4 * g + r;
    Opart[ob + q * 64 + r16]      = O0[r];
    Opart[ob + q * 64 + 16 + r16] = O1[r];
    Opart[ob + q * 64 + 32 + r16] = O2[r];
    Opart[ob + q * 64 + 48 + r16] = O3[r];
  }
  if (l < 16) {
    mspart[bid * 128 + 16 * w + l]      = m;
    mspart[bid * 128 + 64 + 16 * w + l] = ssum;
  }
}

// merge 4 stripe-partials -> normalized output. grid 256: T = mb>>2, h = mb&3.
__global__ __launch_bounds__(256) void mha_merge3(const float* __restrict__ Opart, const float* __restrict__ mspart,
                                                  float* __restrict__ out) {
  int mb = blockIdx.x;
  int h = mb & 3, T = mb >> 2;
  int bid0 = ((63 - T) << 4) | (h << 2);
  int t = threadIdx.x;
  int q = t >> 2, dbase = (t & 3) * 16;
  float mm[4], ss[4];
#pragma unroll
  for (int i = 0; i < 4; i++) {
    mm[i] = mspart[(bid0 + i) * 128 + q];
    ss[i] = mspart[(bid0 + i) * 128 + 64 + q];
  }
  float M = fmaxf(fmaxf(mm[0], mm[1]), fmaxf(mm[2], mm[3]));
  float e[4];
  float S = 0.f;
#pragma unroll
  for (int i = 0; i < 4; i++) {
    e[i] = (mm[i] == -INFINITY) ? 0.f : __expf(mm[i] - M);
    S += e[i] * ss[i];
  }
  float inv = 1.f / S;
  float* Y = out + (size_t)(T * 64 + q) * EMB + h * 64 + dbase;
#pragma unroll
  for (int i = 0; i < 4; i++) {
    float4 a0 = load4f(Opart + (size_t)(bid0 + 0) * 4096 + q * 64 + dbase + 4 * i);
    float4 a1 = load4f(Opart + (size_t)(bid0 + 1) * 4096 + q * 64 + dbase + 4 * i);
    float4 a2 = load4f(Opart + (size_t)(bid0 + 2) * 4096 + q * 64 + dbase + 4 * i);
    float4 a3 = load4f(Opart + (size_t)(bid0 + 3) * 4096 + q * 64 + dbase + 4 * i);
    float4 r;
    r.x = (e[0]*a0.x + e[1]*a1.x + e[2]*a2.x + e[3]*a3.x) * inv;
    r.y = (e[0]*a0.y + e[1]*a1.y + e[2]*a2.y + e[3]*a3.y) * inv;
    r.z = (e[0]*a0.z + e[1]*a1.z + e[2]*a2.z + e[3]*a3.z) * inv;
    r.w = (e[0]*a0.w + e[1]*a1.w + e[2]*a2.w + e[3]*a3.w) * inv;
    *(float4*)(Y + 4 * i) = r;
  }
}

// ---------------- CSR build ----------------
__global__ void zero_i32(int* p, int n) {
  int i = blockIdx.x * 256 + threadIdx.x;
  if (i < n) p[i] = 0;
}
__global__ void hist_dst(const int* __restrict__ adj, int* __restrict__ cnt) {
  int e = blockIdx.x * 256 + threadIdx.x;
  if (e < NE) atomicAdd(&cnt[adj[NE + e]], 1);
}
__global__ __launch_bounds__(1024) void scan4096(const int* __restrict__ cnt, int* __restrict__ indptr,
                                                 int* __restrict__ cursor) {
  int t = threadIdx.x;
  int4 c = *reinterpret_cast<const int4*>(cnt + t * 4);
  int s0 = c.x, s1 = s0 + c.y, s2 = s1 + c.z, s3 = s2 + c.w;
  int lane = t & 63, w = t >> 6;
  int x = s3;
#pragma unroll
  for (int off = 1; off < 64; off <<= 1) {
    int y = __shfl_up(x, off);
    if (lane >= off) x += y;
  }
  __shared__ int wsum[16];
  if (lane == 63) wsum[w] = x;
  __syncthreads();
  if (t == 0) {
    int acc = 0;
    for (int i = 0; i < 16; i++) { int tv = wsum[i]; wsum[i] = acc; acc += tv; }
  }
  __syncthreads();
  int b = wsum[w] + x - s3;
  indptr[t*4+0] = b;      indptr[t*4+1] = b + s0;
  indptr[t*4+2] = b + s1; indptr[t*4+3] = b + s2;
  cursor[t*4+0] = b;      cursor[t*4+1] = b + s0;
  cursor[t*4+2] = b + s1; cursor[t*4+3] = b + s2;
  if (t == 1023) indptr[4096] = b + s3;
}
__global__ void scatter_edges(const int* __restrict__ adj, int* __restrict__ cursor, int* __restrict__ esrc) {
  int e = blockIdx.x * 256 + threadIdx.x;
  if (e < NE) {
    int dst = adj[NE + e];
    int pos = atomicAdd(&cursor[dst], 1);
    esrc[pos] = adj[e];
  }
}

// ---------------- TransformerConv aggregation (both paths): coop f16-K gather (fdot2), bf16 V ----------------
// grid 8192: path = bid>>12, n = bid&4095.
__global__ __launch_bounds__(256, 4) void conv_agg2(const float* __restrict__ qbO, const float* __restrict__ qbA,
                                                    const u16* __restrict__ kbO, const u16* __restrict__ kbA,
                                                    const u16* __restrict__ vbO, const u16* __restrict__ vbA,
                                                    const int* __restrict__ indptr, const int* __restrict__ esrc,
                                                    float* __restrict__ yO, float* __restrict__ yA) {
  __shared__ float q_s[EMB];
  __shared__ float sc_s[NH][64];
  __shared__ float p_s[NH][64];
  __shared__ int   s_s[64];
  int bid = blockIdx.x;
  int path = bid >> 12;
  int n = bid & 4095;
  const float* qb = path ? qbA : qbO;
  const u16*   kb = path ? kbA : kbO;
  const u16*   vb = path ? vbA : vbO;
  float*       y  = path ? yA  : yO;
  int tid = threadIdx.x;
  int h = tid >> 6, lane = tid & 63;
  int lr8 = lane >> 3;
  int lseg = (lane & 7) * 8;
  q_s[tid] = qb[(size_t)n * EMB + tid] * 0.125f;   // fold 1/sqrt(D)
  int start = indptr[n], end = indptr[n + 1];
  __syncthreads();
  const float* qh = &q_s[h * HD];
  half2v qp[4];
#pragma unroll
  for (int j = 0; j < 4; j++) {
    qp[j][0] = (_Float16)qh[lseg + 2*j];
    qp[j][1] = (_Float16)qh[lseg + 2*j + 1];
  }
  float m = -INFINITY, s = 0.f;
  float o0 = 0.f, o1 = 0.f, o2 = 0.f, o3 = 0.f;
  for (int p0 = start; p0 < end; p0 += 64) {
    int nk = end - p0; if (nk > 64) nk = 64;
    if (h == 0) s_s[lane] = (lane < nk) ? esrc[p0 + lane] : 0;
    __syncthreads();
#pragma unroll
    for (int pass = 0; pass < 8; pass++) {
      int row = pass * 8 + lr8;
      int src = s_s[row];
      uint4 k4 = *(const uint4*)&kb[(size_t)src * EMB + h * HD + lseg];
      float acc = __builtin_amdgcn_fdot2(*(half2v*)&k4.x, qp[0],
                  __builtin_amdgcn_fdot2(*(half2v*)&k4.y, qp[1],
                  __builtin_amdgcn_fdot2(*(half2v*)&k4.z, qp[2],
                  __builtin_amdgcn_fdot2(*(half2v*)&k4.w, qp[3], 0.f, false), false), false), false);
      acc += __shfl_xor(acc, 1);
      acc += __shfl_xor(acc, 2);
      acc += __shfl_xor(acc, 4);
      if ((lane & 7) == 0) sc_s[h][row] = (row < nk) ? acc : -INFINITY;
    }
    float sc = sc_s[h][lane];
    float bm = sc;
#pragma unroll
    for (int off = 32; off; off >>= 1) bm = fmaxf(bm, __shfl_xor(bm, off));
    float mn = fmaxf(m, bm);
    float ef = __expf(m - mn);
    float p = __expf(sc - mn);
    float ps = p;
#pragma unroll
    for (int off = 32; off; off >>= 1) ps += __shfl_xor(ps, off);
    s = s * ef + ps;
    m = mn;
    o0 *= ef; o1 *= ef; o2 *= ef; o3 *= ef;
    p_s[h][lane] = p;
    const u16* vcol = vb + h * HD + lane;
    int nk4 = (nk + 3) & ~3;
    for (int jj = 0; jj < nk4; jj += 4) {
      float pa = p_s[h][jj],   pb = p_s[h][jj+1];
      float pc = p_s[h][jj+2], pd = p_s[h][jj+3];
      int sa = s_s[jj], sb = s_s[jj+1], scx = s_s[jj+2], sd = s_s[jj+3];
      o0 = fmaf(pa, b2f(vcol[(size_t)sa  * EMB]), o0);
      o1 = fmaf(pb, b2f(vcol[(size_t)sb  * EMB]), o1);
      o2 = fmaf(pc, b2f(vcol[(size_t)scx * EMB]), o2);
      o3 = fmaf(pd, b2f(vcol[(size_t)sd  * EMB]), o3);
    }
    __syncthreads();
  }
  float o = (o0 + o1) + (o2 + o3);
  float agg = o / (s + 1e-16f);
  y[(size_t)n * EMB + h * HD + lane] += agg;
}

// ---------------- instance norm (both paths) ----------------
__global__ __launch_bounds__(256) void colstats_partial2(const float* __restrict__ yO, const float* __restrict__ yA,
                                                         float* __restrict__ part) {
  int bid = blockIdx.x;              // 64: path = bid>>5, pb = bid&31
  int path = bid >> 5, pb = bid & 31;
  const float* y = path ? yA : yO;
  int c = threadIdx.x;
  int r0 = pb * 128;
  float s = 0.f, q = 0.f;
  for (int r = r0; r < r0 + 128; r++) {
    float v = y[(size_t)r * EMB + c];
    s += v; q = fmaf(v, v, q);
  }
  part[(size_t)path * 16384 + pb * 512 + c] = s;
  part[(size_t)path * 16384 + pb * 512 + 256 + c] = q;
}
__global__ __launch_bounds__(256) void norm_apply2(const float* __restrict__ yO, const float* __restrict__ yA,
                                                   const float* __restrict__ part, float* __restrict__ f) {
  int bid = blockIdx.x;              // 512: path = bid>>8, rb = bid&255
  int path = bid >> 8, rb = bid & 255;
  const float* y = path ? yA : yO;
  const float* pp = part + (size_t)path * 16384;
  int c = threadIdx.x;
  float s = 0.f, q = 0.f;
  for (int b = 0; b < 32; b++) { s += pp[b * 512 + c]; q += pp[b * 512 + 256 + c]; }
  float mean = s * (1.f / 4096.f);
  float var  = q * (1.f / 4096.f) - mean * mean;
  float rstd = rsqrtf(var + 1e-5f);
  int r0 = rb * 16;
  int colOff = path * 256;
  for (int r = r0; r < r0 + 16; r++) {
    float v = (y[(size_t)r * EMB + c] - mean) * rstd;
    v = (v > 0.f) ? v : 0.2f * v;
    v = sanitize_f(v);
    f[(size_t)r * 512 + colOff + c] = v;
  }
}

// ---------------- classifier tail ----------------
__global__ __launch_bounds__(256) void final_softmax(const float* __restrict__ f1, const float* __restrict__ W2,
                                                     const float* __restrict__ b2, float* __restrict__ out) {
  int w = threadIdx.x >> 6, lane = threadIdx.x & 63;
  int row = blockIdx.x * 4 + w;
  const float* fr = f1 + (size_t)row * 128;
  float x0 = fr[lane], x1 = fr[lane + 64];
  float p0 = x0 * W2[lane]       + x1 * W2[64 + lane];
  float p1 = x0 * W2[128 + lane] + x1 * W2[192 + lane];
#pragma unroll
  for (int off = 32; off; off >>= 1) { p0 += __shfl_xor(p0, off); p1 += __shfl_xor(p1, off); }
  if (lane == 0) {
    float l0 = p0 + b2[0], l1 = p1 + b2[1];
    float mx = fmaxf(l0, l1);
    float e0 = __expf(l0 - mx), e1 = __expf(l1 - mx);
    float inv = 1.f / (e0 + e1);
    out[(size_t)row * 2 + 0] = l0;
    out[(size_t)row * 2 + 1] = l1;
    out[8192 + (size_t)row * 2 + 0] = e0 * inv;
    out[8192 + (size_t)row * 2 + 1] = e1 * inv;
  }
}

extern "C" void kernel_launch(void* const* d_in, const int* in_sizes, int n_in,
                              void* d_out, int out_size, void* d_ws, size_t ws_size,
                              hipStream_t stream) {
  const float* img   = (const float*)d_in[2];
  const int*   adj   = (const int*)d_in[3];
  const float* W_img = (const float*)d_in[4];  const float* b_img = (const float*)d_in[5];
  const float* W_qkv = (const float*)d_in[6];  const float* b_qkv = (const float*)d_in[7];
  const float* W_o   = (const float*)d_in[8];  const float* b_o   = (const float*)d_in[9];
  const float* Wq_o  = (const float*)d_in[10]; const float* bq_o  = (const float*)d_in[11];
  const float* Wk_o  = (const float*)d_in[12]; const float* bk_o  = (const float*)d_in[13];
  const float* Wv_o  = (const float*)d_in[14]; const float* bv_o  = (const float*)d_in[15];
  const float* Ws_o  = (const float*)d_in[16]; const float* bs_o  = (const float*)d_in[17];
  const float* Wq_a  = (const float*)d_in[18]; const float* bq_a  = (const float*)d_in[19];
  const float* Wk_a  = (const float*)d_in[20]; const float* bk_a  = (const float*)d_in[21];
  const float* Wv_a  = (const float*)d_in[22]; const float* bv_a  = (const float*)d_in[23];
  const float* Ws_a  = (const float*)d_in[24]; const float* bs_a  = (const float*)d_in[25];
  const float* W_c1  = (const float*)d_in[26]; const float* b_c1  = (const float*)d_in[27];
  const float* W_c2  = (const float*)d_in[28]; const float* b_c2  = (const float*)d_in[29];

  char* ws = (char*)d_ws;
  float* h     = (float*)(ws + 0);                    // 4 MB
  float* hattn = (float*)(ws + (4ull  << 20));        // 4 MB (qkb aliases during mha)
  float* qbO   = (float*)(ws + (8ull  << 20));        // 4 MB
  u16*   kbO   = (u16*)  (ws + (12ull << 20));        // 2 MB (f16)
  u16*   vbO   = (u16*)  (ws + (14ull << 20));        // 2 MB (bf16)
  float* qbA   = (float*)(ws + (16ull << 20));        // 4 MB
  u16*   kbA   = (u16*)  (ws + (20ull << 20));        // 2 MB (f16)
  u16*   vbA   = (u16*)  (ws + (22ull << 20));        // 2 MB (bf16)
  float* yO    = (float*)(ws + (24ull << 20));        // 4 MB (ymha aliases)
  float* yA    = (float*)(ws + (28ull << 20));        // 4 MB
  float* f     = (float*)(ws + (32ull << 20));        // 8 MB
  float* f1    = (float*)(ws + (40ull << 20));        // 2 MB (vtb aliases)
  int*   indptr= (int*)  (ws + (42ull << 20));
  int*   cursor= (int*)  (ws + (42ull << 20) + 20480);
  int*   esrc  = (int*)  (ws + (42ull << 20) + 40960);  // 1 MB (mspart aliases)
  float* part  = (float*)(ws + (42ull << 20) + 40960 + (1ull << 20)); // 128 KB

  u16*   qkb     = (u16*)hattn;      // 4 MB, dead until step 4
  u16*   vtb     = (u16*)f1;         // 2 MB, dead until step 8
  float* imgpart = qbO;              // 16 MB (ws+8..24M), free during step 1
  float* Opart   = qbO;              // 16 MB (ws+8..24M), free during mha
  float* mspart  = (float*)esrc;     // 512 KB, free during mha
  float* ymha    = yO;               // 4 MB, free until conv GEMM writes skip

  dim3 b256(256);

  // 1. h = img_feat @ W_img^T + b_img   (split-K x4)
  gemm_img_splitk<<<dim3(64, 4, 4), b256, 0, stream>>>(img, W_img, imgpart);
  gemm_img_reduce<<<1024, b256, 0, stream>>>(imgpart, b_img, h);
  // 2. qkv GEMM -> qkb (Q|K bf16), vtb (V^T bf16)
  {
    GArgs ga;
    for (int i = 0; i < 8; i++)
      ga.t[i]  = { h, W_qkv + (size_t)i * 64 * 256, b_qkv + i * 64, (float*)qkb, i * 64, 512, 1 };
    for (int i = 8; i < 12; i++)
      ga.t[i]  = { h, W_qkv + (size_t)i * 64 * 256, b_qkv + i * 64, (float*)vtb, (i - 8) * 64, 4096, 2 };
    gemm_mfma<0><<<dim3(64, 12), b256, 0, stream>>>(ga, 256);
  }
  // 3. causal MHA (split-K x4) -> ymha
  mha_mfma3<<<1024, b256, 0, stream>>>(qkb, vtb, Opart, mspart);
  mha_merge3<<<256, b256, 0, stream>>>(Opart, mspart, ymha);
  // 4. h_attn = sanitize(ymha @ W_o^T + b_o)
  {
    GArgs ga;
    for (int i = 0; i < 4; i++)
      ga.t[i] = { ymha, W_o + (size_t)i * 64 * 256, b_o + i * 64, hattn, i * 64, 256, 0 };
    gemm_mfma<1><<<dim3(64, 4), b256, 0, stream>>>(ga, 256);
  }
  // 5. CSR of video_adj_list grouped by dst
  zero_i32<<<16, b256, 0, stream>>>(cursor, NN);
  hist_dst<<<NE / 256, b256, 0, stream>>>(adj, cursor);
  scan4096<<<1, 1024, 0, stream>>>(cursor, indptr, cursor);
  scatter_edges<<<NE / 256, b256, 0, stream>>>(adj, cursor, esrc);

  // 6. both conv paths' q/k/v/skip in ONE dispatch (32 tiles); K in f16, V in bf16
  {
    const float* Wg[8] = { Wq_o, Wk_o, Wv_o, Ws_o, Wq_a, Wk_a, Wv_a, Ws_a };
    const float* bg[8] = { bq_o, bk_o, bv_o, bs_o, bq_a, bk_a, bv_a, bs_a };
    float*       og[8] = { qbO, (float*)kbO, (float*)vbO, yO, qbA, (float*)kbA, (float*)vbA, yA };
    const float* Ag[8] = { h, h, h, h, hattn, hattn, hattn, hattn };
    const int    bf[8] = { 0, 3, 1, 0, 0, 3, 1, 0 };
    GArgs ga;
    for (int i = 0; i < 32; i++) {
      int gdx = i >> 2, li = i & 3;
      ga.t[i] = { Ag[gdx], Wg[gdx] + (size_t)li * 64 * 256, bg[gdx] + li * 64, og[gdx], li * 64, 256, bf[gdx] };
    }
    gemm_mfma<0><<<dim3(64, 32), b256, 0, stream>>>(ga, 256);
  }
  // 7. both conv aggregations in ONE dispatch
  conv_agg2<<<8192, b256, 0, stream>>>(qbO, qbA, kbO, kbA, vbO, vbA, indptr, esrc, yO, yA);
  // 8. instance norm both paths
  colstats_partial2<<<64, b256, 0, stream>>>(yO, yA, part);
  norm_apply2<<<512, b256, 0, stream>>>(yO, yA, part, f);
  // 9. f1 = lrelu(f @ W_c1^T + b_c1)
  {
    GArgs ga;
    for (int i = 0; i < 2; i++)
      ga.t[i] = { f, W_c1 + (size_t)i * 64 * 512, b_c1 + i * 64, f1, i * 64, 128, 0 };
    gemm_mfma<2><<<dim3(64, 2), b256, 0, stream>>>(ga, 512);
  }
  // 10. logits + softmax -> out
  final_softmax<<<NN / 4, b256, 0, stream>>>(f1, W_c2, b_c2, (float*)d_out);
}

// Round 17
// 244.098 us; speedup vs baseline: 1.9190x; 1.0019x over previous
//
#include <hip/hip_runtime.h>
#include <hip/hip_bf16.h>

typedef unsigned short u16;
typedef unsigned int   u32;
typedef __attribute__((ext_vector_type(8))) short short8;
typedef __attribute__((ext_vector_type(4))) float f32x4;
typedef _Float16 half2v __attribute__((ext_vector_type(2)));

#define NN 4096        // nodes
#define NE 262144      // edges
#define EMB 256
#define NH 4
#define HD 64

__device__ __forceinline__ float4 load4f(const float* p) { return *reinterpret_cast<const float4*>(p); }
__device__ __forceinline__ float sanitize_f(float v) {
  v = (v != v) ? 0.f : v;                 // nan -> 0
  return fminf(fmaxf(v, -1000.f), 1000.f); // +-inf and clip -> +-1000
}
__device__ __forceinline__ u16 f2b_rne(float x) {          // f32 -> bf16 bits, round-nearest-even
  u32 b = __float_as_uint(x);
  b += 0x7fff + ((b >> 16) & 1);
  return (u16)(b >> 16);
}
__device__ __forceinline__ u32 pack2(float a, float b) {
  return (u32)f2b_rne(a) | ((u32)f2b_rne(b) << 16);
}
__device__ __forceinline__ float b2f(u16 u) { return __uint_as_float((u32)u << 16); }
__device__ __forceinline__ u16 f2h(float x) {              // f32 -> f16 bits (rte)
  _Float16 h = (_Float16)x;
  return *reinterpret_cast<u16*>(&h);
}

// ================= generic MFMA GEMM: out = act(A[M,K] @ W^T + bias) =================
struct GTile {
  const float* A;     // input rows [M][K]
  const float* W;     // 64 weight rows for this tile: [64][K]
  const float* bias;  // 64 entries
  float*       out;
  int          colOff;
  int          ldOut;
  int          obf16; // 0 f32 | 1 bf16 | 2 bf16-TRANSPOSED out[col*ld+row] | 3 f16
};
struct GArgs { GTile t[32]; };

template<int ACT>   // 0 none, 1 sanitize, 2 lrelu(0.2)
__global__ __launch_bounds__(256) void gemm_mfma(const GArgs ga, int K) {
  __shared__ short As[64 * 40];
  __shared__ short Bs[64 * 40];
  const int t = threadIdx.x;
  const int bm = blockIdx.x * 64;
  const GTile tl = ga.t[blockIdx.y];
  const int w = t >> 6, l = t & 63, g = l >> 4, r16 = l & 15;
  const int wr = w >> 1, wc = w & 1;
  const int lrow = t >> 2, lseg = (t & 3) * 8;

  const float* Ap = tl.A + (size_t)(bm + lrow) * K + lseg;
  const float* Wp = tl.W + (size_t)lrow * K + lseg;

  f32x4 acc[2][2] = {{{0.f,0.f,0.f,0.f},{0.f,0.f,0.f,0.f}},{{0.f,0.f,0.f,0.f},{0.f,0.f,0.f,0.f}}};
  for (int k0 = 0; k0 < K; k0 += 32) {
    float4 a0 = load4f(Ap + k0), a1 = load4f(Ap + k0 + 4);
    float4 b0 = load4f(Wp + k0), b1 = load4f(Wp + k0 + 4);
    __syncthreads();
    *(uint4*)&As[lrow * 40 + lseg] =
        make_uint4(pack2(a0.x,a0.y), pack2(a0.z,a0.w), pack2(a1.x,a1.y), pack2(a1.z,a1.w));
    *(uint4*)&Bs[lrow * 40 + lseg] =
        make_uint4(pack2(b0.x,b0.y), pack2(b0.z,b0.w), pack2(b1.x,b1.y), pack2(b1.z,b1.w));
    __syncthreads();
    short8 af0 = *(const short8*)&As[(wr*32 +      r16) * 40 + 8*g];
    short8 af1 = *(const short8*)&As[(wr*32 + 16 + r16) * 40 + 8*g];
    short8 bf0 = *(const short8*)&Bs[(wc*32 +      r16) * 40 + 8*g];
    short8 bf1 = *(const short8*)&Bs[(wc*32 + 16 + r16) * 40 + 8*g];
    acc[0][0] = __builtin_amdgcn_mfma_f32_16x16x32_bf16(af0, bf0, acc[0][0], 0, 0, 0);
    acc[0][1] = __builtin_amdgcn_mfma_f32_16x16x32_bf16(af0, bf1, acc[0][1], 0, 0, 0);
    acc[1][0] = __builtin_amdgcn_mfma_f32_16x16x32_bf16(af1, bf0, acc[1][0], 0, 0, 0);
    acc[1][1] = __builtin_amdgcn_mfma_f32_16x16x32_bf16(af1, bf1, acc[1][1], 0, 0, 0);
  }
  const float bj[2] = { tl.bias[wc*32 + r16], tl.bias[wc*32 + 16 + r16] };
#pragma unroll
  for (int i = 0; i < 2; i++) {
#pragma unroll
    for (int j = 0; j < 2; j++) {
      int col  = tl.colOff + wc*32 + 16*j + r16;
      int row0 = bm + wr*32 + 16*i + 4*g;
      if (tl.obf16 == 2) {
        u16 pk[4];
#pragma unroll
        for (int r = 0; r < 4; r++) pk[r] = f2b_rne(acc[i][j][r] + bj[j]);
        *(uint2*)((u16*)tl.out + (size_t)col * tl.ldOut + row0) = *(uint2*)pk;
      } else {
#pragma unroll
        for (int r = 0; r < 4; r++) {
          float v = acc[i][j][r] + bj[j];
          if (ACT == 1) v = sanitize_f(v);
          if (ACT == 2) v = (v > 0.f) ? v : 0.2f * v;
          if (tl.obf16 == 1)      ((u16*)tl.out)[(size_t)(row0 + r) * tl.ldOut + col] = f2b_rne(v);
          else if (tl.obf16 == 3) ((u16*)tl.out)[(size_t)(row0 + r) * tl.ldOut + col] = f2h(v);
          else                    tl.out[(size_t)(row0 + r) * tl.ldOut + col] = v;
        }
      }
    }
  }
}

// ---------------- img GEMM split-K: K=2048 over 4 z-blocks of 512 ----------------
__global__ __launch_bounds__(256) void gemm_img_splitk(const float* __restrict__ A, const float* __restrict__ W,
                                                       float* __restrict__ part) {
  __shared__ short As[64 * 40];
  __shared__ short Bs[64 * 40];
  const int t = threadIdx.x;
  const int bm = blockIdx.x * 64, bn = blockIdx.y * 64, ks = blockIdx.z;
  const int w = t >> 6, l = t & 63, g = l >> 4, r16 = l & 15;
  const int wr = w >> 1, wc = w & 1;
  const int lrow = t >> 2, lseg = (t & 3) * 8;

  const float* Ap = A + (size_t)(bm + lrow) * 2048 + ks * 512 + lseg;
  const float* Wp = W + (size_t)(bn + lrow) * 2048 + ks * 512 + lseg;

  f32x4 acc[2][2] = {{{0.f,0.f,0.f,0.f},{0.f,0.f,0.f,0.f}},{{0.f,0.f,0.f,0.f},{0.f,0.f,0.f,0.f}}};
  for (int k0 = 0; k0 < 512; k0 += 32) {
    float4 a0 = load4f(Ap + k0), a1 = load4f(Ap + k0 + 4);
    float4 b0 = load4f(Wp + k0), b1 = load4f(Wp + k0 + 4);
    __syncthreads();
    *(uint4*)&As[lrow * 40 + lseg] =
        make_uint4(pack2(a0.x,a0.y), pack2(a0.z,a0.w), pack2(a1.x,a1.y), pack2(a1.z,a1.w));
    *(uint4*)&Bs[lrow * 40 + lseg] =
        make_uint4(pack2(b0.x,b0.y), pack2(b0.z,b0.w), pack2(b1.x,b1.y), pack2(b1.z,b1.w));
    __syncthreads();
    short8 af0 = *(const short8*)&As[(wr*32 +      r16) * 40 + 8*g];
    short8 af1 = *(const short8*)&As[(wr*32 + 16 + r16) * 40 + 8*g];
    short8 bf0 = *(const short8*)&Bs[(wc*32 +      r16) * 40 + 8*g];
    short8 bf1 = *(const short8*)&Bs[(wc*32 + 16 + r16) * 40 + 8*g];
    acc[0][0] = __builtin_amdgcn_mfma_f32_16x16x32_bf16(af0, bf0, acc[0][0], 0, 0, 0);
    acc[0][1] = __builtin_amdgcn_mfma_f32_16x16x32_bf16(af0, bf1, acc[0][1], 0, 0, 0);
    acc[1][0] = __builtin_amdgcn_mfma_f32_16x16x32_bf16(af1, bf0, acc[1][0], 0, 0, 0);
    acc[1][1] = __builtin_amdgcn_mfma_f32_16x16x32_bf16(af1, bf1, acc[1][1], 0, 0, 0);
  }
  float* op = part + (size_t)ks * (NN * 256);
#pragma unroll
  for (int i = 0; i < 2; i++) {
#pragma unroll
    for (int j = 0; j < 2; j++) {
      int col = bn + wc*32 + 16*j + r16;
#pragma unroll
      for (int r = 0; r < 4; r++) {
        int row = bm + wr*32 + 16*i + 4*g + r;
        op[(size_t)row * 256 + col] = acc[i][j][r];
      }
    }
  }
}
__global__ __launch_bounds__(256) void gemm_img_reduce(const float* __restrict__ part,
                                                       const float* __restrict__ bias,
                                                       float* __restrict__ h) {
  int idx = blockIdx.x * 256 + threadIdx.x;
  int row = idx >> 6, c4 = (idx & 63) * 4;
  size_t o = (size_t)row * 256 + c4;
  float4 s = load4f(part + o);
  float4 p1 = load4f(part + 1048576 + o);
  float4 p2 = load4f(part + 2097152 + o);
  float4 p3 = load4f(part + 3145728 + o);
  float4 bb = load4f(bias + c4);
  s.x += p1.x + p2.x + p3.x + bb.x;
  s.y += p1.y + p2.y + p3.y + bb.y;
  s.z += p1.z + p2.z + p3.z + bb.z;
  s.w += p1.w + p2.w + p3.w + bb.w;
  *(float4*)&h[o] = s;
}

// ---------------- causal MHA v4: 64-q blocks, LDS-shared K/V, pipelined, split-K x4 ----------------
#define KSTR 72
__global__ __launch_bounds__(256, 4) void mha_mfma3(const u16* __restrict__ qkb, const u16* __restrict__ vtb,
                                                    float* __restrict__ Opart, float* __restrict__ mspart) {
  __shared__ u16 Ks[64 * KSTR];
  __shared__ u16 Vs[64 * KSTR];
  const int bid = blockIdx.x;
  const int ks  = bid & 3;
  const int hh  = (bid >> 2) & 3;
  const int T   = 63 - (bid >> 4);
  const int q0  = T * 64;
  const int t   = threadIdx.x;
  const int w   = t >> 6, l = t & 63, g = l >> 4, r16 = l & 15;
  const int hofs = hh * 64;
  const int lrow = t >> 3, lc8 = (t & 7) * 8;

  const u16* qrow = qkb + (size_t)(q0 + 16 * w + r16) * 512 + hofs;
  short8 Qf0 = *(const short8*)&qrow[8 * g];
  short8 Qf1 = *(const short8*)&qrow[32 + 8 * g];

  f32x4 O0 = {0.f,0.f,0.f,0.f}, O1 = O0, O2 = O0, O3 = O0;
  float m = -INFINITY, ssum = 0.f;

  uint4 rk0, rk1, rv0, rv1;
  if (ks <= T) {
    int k0 = ks * 64;
    rk0 = *(const uint4*)&qkb[(size_t)(k0 + lrow) * 512 + 256 + hofs + lc8];
    rk1 = *(const uint4*)&qkb[(size_t)(k0 + 32 + lrow) * 512 + 256 + hofs + lc8];
    rv0 = *(const uint4*)&vtb[(size_t)(hofs + lrow) * 4096 + k0 + lc8];
    rv1 = *(const uint4*)&vtb[(size_t)(hofs + 32 + lrow) * 4096 + k0 + lc8];
  }
  for (int kt = ks; kt <= T; kt += 4) {
    __syncthreads();
    *(uint4*)&Ks[lrow * KSTR + lc8]        = rk0;
    *(uint4*)&Ks[(32 + lrow) * KSTR + lc8] = rk1;
    *(uint4*)&Vs[lrow * KSTR + lc8]        = rv0;
    *(uint4*)&Vs[(32 + lrow) * KSTR + lc8] = rv1;
    __syncthreads();
    if (kt + 4 <= T) {
      int k2 = (kt + 4) * 64;
      rk0 = *(const uint4*)&qkb[(size_t)(k2 + lrow) * 512 + 256 + hofs + lc8];
      rk1 = *(const uint4*)&qkb[(size_t)(k2 + 32 + lrow) * 512 + 256 + hofs + lc8];
      rv0 = *(const uint4*)&vtb[(size_t)(hofs + lrow) * 4096 + k2 + lc8];
      rv1 = *(const uint4*)&vtb[(size_t)(hofs + 32 + lrow) * 4096 + k2 + lc8];
    }
    f32x4 S0 = {0.f,0.f,0.f,0.f}, S1 = S0, S2 = S0, S3 = S0;
    {
      short8 a0 = *(const short8*)&Ks[(r16)      * KSTR + 8*g];
      short8 a1 = *(const short8*)&Ks[(16 + r16) * KSTR + 8*g];
      short8 a2 = *(const short8*)&Ks[(32 + r16) * KSTR + 8*g];
      short8 a3 = *(const short8*)&Ks[(48 + r16) * KSTR + 8*g];
      S0 = __builtin_amdgcn_mfma_f32_16x16x32_bf16(a0, Qf0, S0, 0, 0, 0);
      S1 = __builtin_amdgcn_mfma_f32_16x16x32_bf16(a1, Qf0, S1, 0, 0, 0);
      S2 = __builtin_amdgcn_mfma_f32_16x16x32_bf16(a2, Qf0, S2, 0, 0, 0);
      S3 = __builtin_amdgcn_mfma_f32_16x16x32_bf16(a3, Qf0, S3, 0, 0, 0);
      short8 b0 = *(const short8*)&Ks[(r16)      * KSTR + 32 + 8*g];
      short8 b1 = *(const short8*)&Ks[(16 + r16) * KSTR + 32 + 8*g];
      short8 b2 = *(const short8*)&Ks[(32 + r16) * KSTR + 32 + 8*g];
      short8 b3 = *(const short8*)&Ks[(48 + r16) * KSTR + 32 + 8*g];
      S0 = __builtin_amdgcn_mfma_f32_16x16x32_bf16(b0, Qf1, S0, 0, 0, 0);
      S1 = __builtin_amdgcn_mfma_f32_16x16x32_bf16(b1, Qf1, S1, 0, 0, 0);
      S2 = __builtin_amdgcn_mfma_f32_16x16x32_bf16(b2, Qf1, S2, 0, 0, 0);
      S3 = __builtin_amdgcn_mfma_f32_16x16x32_bf16(b3, Qf1, S3, 0, 0, 0);
    }
    float sc[4][4];
#pragma unroll
    for (int r = 0; r < 4; r++) {
      sc[0][r] = S0[r] * 0.125f; sc[1][r] = S1[r] * 0.125f;
      sc[2][r] = S2[r] * 0.125f; sc[3][r] = S3[r] * 0.125f;
    }
    if (kt == T) {
#pragma unroll
      for (int mb = 0; mb < 4; mb++)
#pragma unroll
        for (int r = 0; r < 4; r++)
          if (16 * mb + 4 * g + r > 16 * w + r16) sc[mb][r] = -INFINITY;
    }
    float tm = sc[0][0];
#pragma unroll
    for (int mb = 0; mb < 4; mb++)
#pragma unroll
      for (int r = 0; r < 4; r++) tm = fmaxf(tm, sc[mb][r]);
    tm = fmaxf(tm, __shfl_xor(tm, 16));
    tm = fmaxf(tm, __shfl_xor(tm, 32));
    float mn = fmaxf(m, tm);
    float ef = __expf(m - mn);
    float pv[4][4];
    float ps = 0.f;
#pragma unroll
    for (int mb = 0; mb < 4; mb++)
#pragma unroll
      for (int r = 0; r < 4; r++) { pv[mb][r] = __expf(sc[mb][r] - mn); ps += pv[mb][r]; }
    ps += __shfl_xor(ps, 16);
    ps += __shfl_xor(ps, 32);
    ssum = ssum * ef + ps;
    m = mn;
#pragma unroll
    for (int r = 0; r < 4; r++) {
      float efr = __shfl(ef, 4 * g + r);
      O0[r] *= efr; O1[r] *= efr; O2[r] *= efr; O3[r] *= efr;
    }
    u32 pk[2][4];
#pragma unroll
    for (int c = 0; c < 2; c++)
#pragma unroll
      for (int rs = 0; rs < 4; rs++) pk[c][rs] = pack2(pv[2 * c][rs], pv[2 * c + 1][rs]);
    short8 ap[2];
#pragma unroll
    for (int c = 0; c < 2; c++) {
#pragma unroll
      for (int jb = 0; jb < 2; jb++) {
        int x = 2 * g + jb;
        int hi = x >> 2;
        int src = r16 + 16 * (x & 3);
#pragma unroll
        for (int rs = 0; rs < 4; rs++) {
          u32 v = __shfl(pk[c][rs], src);
          ap[c][jb * 4 + rs] = (short)(hi ? (v >> 16) : (v & 0xffff));
        }
      }
    }
    {
      short8 V00 = *(const short8*)&Vs[(r16)      * KSTR + 8*g];
      short8 V10 = *(const short8*)&Vs[(16 + r16) * KSTR + 8*g];
      short8 V20 = *(const short8*)&Vs[(32 + r16) * KSTR + 8*g];
      short8 V30 = *(const short8*)&Vs[(48 + r16) * KSTR + 8*g];
      O0 = __builtin_amdgcn_mfma_f32_16x16x32_bf16(ap[0], V00, O0, 0, 0, 0);
      O1 = __builtin_amdgcn_mfma_f32_16x16x32_bf16(ap[0], V10, O1, 0, 0, 0);
      O2 = __builtin_amdgcn_mfma_f32_16x16x32_bf16(ap[0], V20, O2, 0, 0, 0);
      O3 = __builtin_amdgcn_mfma_f32_16x16x32_bf16(ap[0], V30, O3, 0, 0, 0);
      short8 V01 = *(const short8*)&Vs[(r16)      * KSTR + 32 + 8*g];
      short8 V11 = *(const short8*)&Vs[(16 + r16) * KSTR + 32 + 8*g];
      short8 V21 = *(const short8*)&Vs[(32 + r16) * KSTR + 32 + 8*g];
      short8 V31 = *(const short8*)&Vs[(48 + r16) * KSTR + 32 + 8*g];
      O0 = __builtin_amdgcn_mfma_f32_16x16x32_bf16(ap[1], V01, O0, 0, 0, 0);
      O1 = __builtin_amdgcn_mfma_f32_16x16x32_bf16(ap[1], V11, O1, 0, 0, 0);
      O2 = __builtin_amdgcn_mfma_f32_16x16x32_bf16(ap[1], V21, O2, 0, 0, 0);
      O3 = __builtin_amdgcn_mfma_f32_16x16x32_bf16(ap[1], V31, O3, 0, 0, 0);
    }
  }

  size_t ob = (size_t)bid * 4096;
#pragma unroll
  for (int r = 0; r < 4; r++) {
    int q = 16 * w + 4 * g + r;
    Opart[ob + q * 64 + r16]      = O0[r];
    Opart[ob + q * 64 + 16 + r16] = O1[r];
    Opart[ob + q * 64 + 32 + r16] = O2[r];
    Opart[ob + q * 64 + 48 + r16] = O3[r];
  }
  if (l < 16) {
    mspart[bid * 128 + 16 * w + l]      = m;
    mspart[bid * 128 + 64 + 16 * w + l] = ssum;
  }
}

// merge 4 stripe-partials -> normalized output. grid 256: T = mb>>2, h = mb&3.
__global__ __launch_bounds__(256) void mha_merge3(const float* __restrict__ Opart, const float* __restrict__ mspart,
                                                  float* __restrict__ out) {
  int mb = blockIdx.x;
  int h = mb & 3, T = mb >> 2;
  int bid0 = ((63 - T) << 4) | (h << 2);
  int t = threadIdx.x;
  int q = t >> 2, dbase = (t & 3) * 16;
  float mm[4], ss[4];
#pragma unroll
  for (int i = 0; i < 4; i++) {
    mm[i] = mspart[(bid0 + i) * 128 + q];
    ss[i] = mspart[(bid0 + i) * 128 + 64 + q];
  }
  float M = fmaxf(fmaxf(mm[0], mm[1]), fmaxf(mm[2], mm[3]));
  float e[4];
  float S = 0.f;
#pragma unroll
  for (int i = 0; i < 4; i++) {
    e[i] = (mm[i] == -INFINITY) ? 0.f : __expf(mm[i] - M);
    S += e[i] * ss[i];
  }
  float inv = 1.f / S;
  float* Y = out + (size_t)(T * 64 + q) * EMB + h * 64 + dbase;
#pragma unroll
  for (int i = 0; i < 4; i++) {
    float4 a0 = load4f(Opart + (size_t)(bid0 + 0) * 4096 + q * 64 + dbase + 4 * i);
    float4 a1 = load4f(Opart + (size_t)(bid0 + 1) * 4096 + q * 64 + dbase + 4 * i);
    float4 a2 = load4f(Opart + (size_t)(bid0 + 2) * 4096 + q * 64 + dbase + 4 * i);
    float4 a3 = load4f(Opart + (size_t)(bid0 + 3) * 4096 + q * 64 + dbase + 4 * i);
    float4 r;
    r.x = (e[0]*a0.x + e[1]*a1.x + e[2]*a2.x + e[3]*a3.x) * inv;
    r.y = (e[0]*a0.y + e[1]*a1.y + e[2]*a2.y + e[3]*a3.y) * inv;
    r.z = (e[0]*a0.z + e[1]*a1.z + e[2]*a2.z + e[3]*a3.z) * inv;
    r.w = (e[0]*a0.w + e[1]*a1.w + e[2]*a2.w + e[3]*a3.w) * inv;
    *(float4*)(Y + 4 * i) = r;
  }
}

// ---------------- CSR build ----------------
__global__ void zero_i32(int* p, int n) {
  int i = blockIdx.x * 256 + threadIdx.x;
  if (i < n) p[i] = 0;
}
__global__ void hist_dst(const int* __restrict__ adj, int* __restrict__ cnt) {
  int e = blockIdx.x * 256 + threadIdx.x;
  if (e < NE) atomicAdd(&cnt[adj[NE + e]], 1);
}
__global__ __launch_bounds__(1024) void scan4096(const int* __restrict__ cnt, int* __restrict__ indptr,
                                                 int* __restrict__ cursor) {
  int t = threadIdx.x;
  int4 c = *reinterpret_cast<const int4*>(cnt + t * 4);
  int s0 = c.x, s1 = s0 + c.y, s2 = s1 + c.z, s3 = s2 + c.w;
  int lane = t & 63, w = t >> 6;
  int x = s3;
#pragma unroll
  for (int off = 1; off < 64; off <<= 1) {
    int y = __shfl_up(x, off);
    if (lane >= off) x += y;
  }
  __shared__ int wsum[16];
  if (lane == 63) wsum[w] = x;
  __syncthreads();
  if (t == 0) {
    int acc = 0;
    for (int i = 0; i < 16; i++) { int tv = wsum[i]; wsum[i] = acc; acc += tv; }
  }
  __syncthreads();
  int b = wsum[w] + x - s3;
  indptr[t*4+0] = b;      indptr[t*4+1] = b + s0;
  indptr[t*4+2] = b + s1; indptr[t*4+3] = b + s2;
  cursor[t*4+0] = b;      cursor[t*4+1] = b + s0;
  cursor[t*4+2] = b + s1; cursor[t*4+3] = b + s2;
  if (t == 1023) indptr[4096] = b + s3;
}
__global__ void scatter_edges(const int* __restrict__ adj, int* __restrict__ cursor, int* __restrict__ esrc) {
  int e = blockIdx.x * 256 + threadIdx.x;
  if (e < NE) {
    int dst = adj[NE + e];
    int pos = atomicAdd(&cursor[dst], 1);
    esrc[pos] = adj[e];
  }
}

// ---------------- TransformerConv aggregation (both paths): f16-K fdot2, scalar-addressed PV ----------------
// grid 8192: path = bid>>12, n = bid&4095.
__global__ __launch_bounds__(256, 4) void conv_agg2(const float* __restrict__ qbO, const float* __restrict__ qbA,
                                                    const u16* __restrict__ kbO, const u16* __restrict__ kbA,
                                                    const u16* __restrict__ vbO, const u16* __restrict__ vbA,
                                                    const int* __restrict__ indptr, const int* __restrict__ esrc,
                                                    float* __restrict__ yO, float* __restrict__ yA) {
  __shared__ float q_s[EMB];
  __shared__ float sc_s[NH][64];
  __shared__ float p_s[NH][64];
  __shared__ int   s_s[64];
  int bid = blockIdx.x;
  int path = bid >> 12;
  int n = bid & 4095;
  const float* qb = path ? qbA : qbO;
  const u16*   kb = path ? kbA : kbO;
  const u16*   vb = path ? vbA : vbO;
  float*       y  = path ? yA  : yO;
  int tid = threadIdx.x;
  int h = tid >> 6, lane = tid & 63;
  int lr8 = lane >> 3;
  int lseg = (lane & 7) * 8;
  q_s[tid] = qb[(size_t)n * EMB + tid] * 0.125f;   // fold 1/sqrt(D)
  int start = indptr[n], end = indptr[n + 1];
  __syncthreads();
  const float* qh = &q_s[h * HD];
  half2v qp[4];
#pragma unroll
  for (int j = 0; j < 4; j++) {
    qp[j][0] = (_Float16)qh[lseg + 2*j];
    qp[j][1] = (_Float16)qh[lseg + 2*j + 1];
  }
  float m = -INFINITY, s = 0.f;
  float o0 = 0.f, o1 = 0.f, o2 = 0.f, o3 = 0.f;
  for (int p0 = start; p0 < end; p0 += 64) {
    int nk = end - p0; if (nk > 64) nk = 64;
    if (h == 0) s_s[lane] = (lane < nk) ? esrc[p0 + lane] : 0;
    __syncthreads();
#pragma unroll
    for (int pass = 0; pass < 8; pass++) {
      int row = pass * 8 + lr8;
      int src = s_s[row];
      uint4 k4 = *(const uint4*)&kb[(size_t)src * EMB + h * HD + lseg];
      float acc = __builtin_amdgcn_fdot2(*(half2v*)&k4.x, qp[0],
                  __builtin_amdgcn_fdot2(*(half2v*)&k4.y, qp[1],
                  __builtin_amdgcn_fdot2(*(half2v*)&k4.z, qp[2],
                  __builtin_amdgcn_fdot2(*(half2v*)&k4.w, qp[3], 0.f, false), false), false), false);
      acc += __shfl_xor(acc, 1);
      acc += __shfl_xor(acc, 2);
      acc += __shfl_xor(acc, 4);
      if ((lane & 7) == 0) sc_s[h][row] = (row < nk) ? acc : -INFINITY;
    }
    float sc = sc_s[h][lane];
    float bm = sc;
#pragma unroll
    for (int off = 32; off; off >>= 1) bm = fmaxf(bm, __shfl_xor(bm, off));
    float mn = fmaxf(m, bm);
    float ef = __expf(m - mn);
    float p = __expf(sc - mn);
    float ps = p;
#pragma unroll
    for (int off = 32; off; off >>= 1) ps += __shfl_xor(ps, off);
    s = s * ef + ps;
    m = mn;
    o0 *= ef; o1 *= ef; o2 *= ef; o3 *= ef;
    p_s[h][lane] = p;
    const u16* vcol = vb + h * HD + lane;
    int nk4 = (nk + 3) & ~3;
    // PV: src index is wave-uniform -> force scalar addressing via readfirstlane.
    for (int jj = 0; jj < nk4; jj += 4) {
      int sa  = __builtin_amdgcn_readfirstlane(s_s[jj]);
      int sb  = __builtin_amdgcn_readfirstlane(s_s[jj+1]);
      int scx = __builtin_amdgcn_readfirstlane(s_s[jj+2]);
      int sd  = __builtin_amdgcn_readfirstlane(s_s[jj+3]);
      float pa = p_s[h][jj],   pb = p_s[h][jj+1];
      float pc = p_s[h][jj+2], pd = p_s[h][jj+3];
      o0 = fmaf(pa, b2f(vcol[(size_t)sa  * EMB]), o0);
      o1 = fmaf(pb, b2f(vcol[(size_t)sb  * EMB]), o1);
      o2 = fmaf(pc, b2f(vcol[(size_t)scx * EMB]), o2);
      o3 = fmaf(pd, b2f(vcol[(size_t)sd  * EMB]), o3);
    }
    __syncthreads();
  }
  float o = (o0 + o1) + (o2 + o3);
  float agg = o / (s + 1e-16f);
  y[(size_t)n * EMB + h * HD + lane] += agg;
}

// ---------------- instance norm (both paths) ----------------
__global__ __launch_bounds__(256) void colstats_partial2(const float* __restrict__ yO, const float* __restrict__ yA,
                                                         float* __restrict__ part) {
  int bid = blockIdx.x;              // 64: path = bid>>5, pb = bid&31
  int path = bid >> 5, pb = bid & 31;
  const float* y = path ? yA : yO;
  int c = threadIdx.x;
  int r0 = pb * 128;
  float s = 0.f, q = 0.f;
  for (int r = r0; r < r0 + 128; r++) {
    float v = y[(size_t)r * EMB + c];
    s += v; q = fmaf(v, v, q);
  }
  part[(size_t)path * 16384 + pb * 512 + c] = s;
  part[(size_t)path * 16384 + pb * 512 + 256 + c] = q;
}
__global__ __launch_bounds__(256) void norm_apply2(const float* __restrict__ yO, const float* __restrict__ yA,
                                                   const float* __restrict__ part, float* __restrict__ f) {
  int bid = blockIdx.x;              // 512: path = bid>>8, rb = bid&255
  int path = bid >> 8, rb = bid & 255;
  const float* y = path ? yA : yO;
  const float* pp = part + (size_t)path * 16384;
  int c = threadIdx.x;
  float s = 0.f, q = 0.f;
  for (int b = 0; b < 32; b++) { s += pp[b * 512 + c]; q += pp[b * 512 + 256 + c]; }
  float mean = s * (1.f / 4096.f);
  float var  = q * (1.f / 4096.f) - mean * mean;
  float rstd = rsqrtf(var + 1e-5f);
  int r0 = rb * 16;
  int colOff = path * 256;
  for (int r = r0; r < r0 + 16; r++) {
    float v = (y[(size_t)r * EMB + c] - mean) * rstd;
    v = (v > 0.f) ? v : 0.2f * v;
    v = sanitize_f(v);
    f[(size_t)r * 512 + colOff + c] = v;
  }
}

// ---------------- classifier tail ----------------
__global__ __launch_bounds__(256) void final_softmax(const float* __restrict__ f1, const float* __restrict__ W2,
                                                     const float* __restrict__ b2, float* __restrict__ out) {
  int w = threadIdx.x >> 6, lane = threadIdx.x & 63;
  int row = blockIdx.x * 4 + w;
  const float* fr = f1 + (size_t)row * 128;
  float x0 = fr[lane], x1 = fr[lane + 64];
  float p0 = x0 * W2[lane]       + x1 * W2[64 + lane];
  float p1 = x0 * W2[128 + lane] + x1 * W2[192 + lane];
#pragma unroll
  for (int off = 32; off; off >>= 1) { p0 += __shfl_xor(p0, off); p1 += __shfl_xor(p1, off); }
  if (lane == 0) {
    float l0 = p0 + b2[0], l1 = p1 + b2[1];
    float mx = fmaxf(l0, l1);
    float e0 = __expf(l0 - mx), e1 = __expf(l1 - mx);
    float inv = 1.f / (e0 + e1);
    out[(size_t)row * 2 + 0] = l0;
    out[(size_t)row * 2 + 1] = l1;
    out[8192 + (size_t)row * 2 + 0] = e0 * inv;
    out[8192 + (size_t)row * 2 + 1] = e1 * inv;
  }
}

extern "C" void kernel_launch(void* const* d_in, const int* in_sizes, int n_in,
                              void* d_out, int out_size, void* d_ws, size_t ws_size,
                              hipStream_t stream) {
  const float* img   = (const float*)d_in[2];
  const int*   adj   = (const int*)d_in[3];
  const float* W_img = (const float*)d_in[4];  const float* b_img = (const float*)d_in[5];
  const float* W_qkv = (const float*)d_in[6];  const float* b_qkv = (const float*)d_in[7];
  const float* W_o   = (const float*)d_in[8];  const float* b_o   = (const float*)d_in[9];
  const float* Wq_o  = (const float*)d_in[10]; const float* bq_o  = (const float*)d_in[11];
  const float* Wk_o  = (const float*)d_in[12]; const float* bk_o  = (const float*)d_in[13];
  const float* Wv_o  = (const float*)d_in[14]; const float* bv_o  = (const float*)d_in[15];
  const float* Ws_o  = (const float*)d_in[16]; const float* bs_o  = (const float*)d_in[17];
  const float* Wq_a  = (const float*)d_in[18]; const float* bq_a  = (const float*)d_in[19];
  const float* Wk_a  = (const float*)d_in[20]; const float* bk_a  = (const float*)d_in[21];
  const float* Wv_a  = (const float*)d_in[22]; const float* bv_a  = (const float*)d_in[23];
  const float* Ws_a  = (const float*)d_in[24]; const float* bs_a  = (const float*)d_in[25];
  const float* W_c1  = (const float*)d_in[26]; const float* b_c1  = (const float*)d_in[27];
  const float* W_c2  = (const float*)d_in[28]; const float* b_c2  = (const float*)d_in[29];

  char* ws = (char*)d_ws;
  float* h     = (float*)(ws + 0);                    // 4 MB
  float* hattn = (float*)(ws + (4ull  << 20));        // 4 MB (qkb aliases during mha)
  float* qbO   = (float*)(ws + (8ull  << 20));        // 4 MB
  u16*   kbO   = (u16*)  (ws + (12ull << 20));        // 2 MB (f16)
  u16*   vbO   = (u16*)  (ws + (14ull << 20));        // 2 MB (bf16)
  float* qbA   = (float*)(ws + (16ull << 20));        // 4 MB
  u16*   kbA   = (u16*)  (ws + (20ull << 20));        // 2 MB (f16)
  u16*   vbA   = (u16*)  (ws + (22ull << 20));        // 2 MB (bf16)
  float* yO    = (float*)(ws + (24ull << 20));        // 4 MB (ymha aliases)
  float* yA    = (float*)(ws + (28ull << 20));        // 4 MB
  float* f     = (float*)(ws + (32ull << 20));        // 8 MB
  float* f1    = (float*)(ws + (40ull << 20));        // 2 MB (vtb aliases)
  int*   indptr= (int*)  (ws + (42ull << 20));
  int*   cursor= (int*)  (ws + (42ull << 20) + 20480);
  int*   esrc  = (int*)  (ws + (42ull << 20) + 40960);  // 1 MB (mspart aliases)
  float* part  = (float*)(ws + (42ull << 20) + 40960 + (1ull << 20)); // 128 KB

  u16*   qkb     = (u16*)hattn;      // 4 MB, dead until step 4
  u16*   vtb     = (u16*)f1;         // 2 MB, dead until step 8
  float* imgpart = qbO;              // 16 MB (ws+8..24M), free during step 1
  float* Opart   = qbO;              // 16 MB (ws+8..24M), free during mha
  float* mspart  = (float*)esrc;     // 512 KB, free during mha
  float* ymha    = yO;               // 4 MB, free until conv GEMM writes skip

  dim3 b256(256);

  // 1. h = img_feat @ W_img^T + b_img   (split-K x4)
  gemm_img_splitk<<<dim3(64, 4, 4), b256, 0, stream>>>(img, W_img, imgpart);
  gemm_img_reduce<<<1024, b256, 0, stream>>>(imgpart, b_img, h);
  // 2. qkv GEMM -> qkb (Q|K bf16), vtb (V^T bf16)
  {
    GArgs ga;
    for (int i = 0; i < 8; i++)
      ga.t[i]  = { h, W_qkv + (size_t)i * 64 * 256, b_qkv + i * 64, (float*)qkb, i * 64, 512, 1 };
    for (int i = 8; i < 12; i++)
      ga.t[i]  = { h, W_qkv + (size_t)i * 64 * 256, b_qkv + i * 64, (float*)vtb, (i - 8) * 64, 4096, 2 };
    gemm_mfma<0><<<dim3(64, 12), b256, 0, stream>>>(ga, 256);
  }
  // 3. causal MHA (split-K x4) -> ymha
  mha_mfma3<<<1024, b256, 0, stream>>>(qkb, vtb, Opart, mspart);
  mha_merge3<<<256, b256, 0, stream>>>(Opart, mspart, ymha);
  // 4. h_attn = sanitize(ymha @ W_o^T + b_o)
  {
    GArgs ga;
    for (int i = 0; i < 4; i++)
      ga.t[i] = { ymha, W_o + (size_t)i * 64 * 256, b_o + i * 64, hattn, i * 64, 256, 0 };
    gemm_mfma<1><<<dim3(64, 4), b256, 0, stream>>>(ga, 256);
  }
  // 5. CSR of video_adj_list grouped by dst
  zero_i32<<<16, b256, 0, stream>>>(cursor, NN);
  hist_dst<<<NE / 256, b256, 0, stream>>>(adj, cursor);
  scan4096<<<1, 1024, 0, stream>>>(cursor, indptr, cursor);
  scatter_edges<<<NE / 256, b256, 0, stream>>>(adj, cursor, esrc);

  // 6. both conv paths' q/k/v/skip in ONE dispatch (32 tiles); K in f16, V in bf16
  {
    const float* Wg[8] = { Wq_o, Wk_o, Wv_o, Ws_o, Wq_a, Wk_a, Wv_a, Ws_a };
    const float* bg[8] = { bq_o, bk_o, bv_o, bs_o, bq_a, bk_a, bv_a, bs_a };
    float*       og[8] = { qbO, (float*)kbO, (float*)vbO, yO, qbA, (float*)kbA, (float*)vbA, yA };
    const float* Ag[8] = { h, h, h, h, hattn, hattn, hattn, hattn };
    const int    bf[8] = { 0, 3, 1, 0, 0, 3, 1, 0 };
    GArgs ga;
    for (int i = 0; i < 32; i++) {
      int gdx = i >> 2, li = i & 3;
      ga.t[i] = { Ag[gdx], Wg[gdx] + (size_t)li * 64 * 256, bg[gdx] + li * 64, og[gdx], li * 64, 256, bf[gdx] };
    }
    gemm_mfma<0><<<dim3(64, 32), b256, 0, stream>>>(ga, 256);
  }
  // 7. both conv aggregations in ONE dispatch
  conv_agg2<<<8192, b256, 0, stream>>>(qbO, qbA, kbO, kbA, vbO, vbA, indptr, esrc, yO, yA);
  // 8. instance norm both paths
  colstats_partial2<<<64, b256, 0, stream>>>(yO, yA, part);
  norm_apply2<<<512, b256, 0, stream>>>(yO, yA, part, f);
  // 9. f1 = lrelu(f @ W_c1^T + b_c1)
  {
    GArgs ga;
    for (int i = 0; i < 2; i++)
      ga.t[i] = { f, W_c1 + (size_t)i * 64 * 512, b_c1 + i * 64, f1, i * 64, 128, 0 };
    gemm_mfma<2><<<dim3(64, 2), b256, 0, stream>>>(ga, 512);
  }
  // 10. logits + softmax -> out
  final_softmax<<<NN / 4, b256, 0, stream>>>(f1, W_c2, b_c2, (float*)d_out);
}